// Round 9
// baseline (3002.174 us; speedup 1.0000x reference)
//
#include <hip/hip_runtime.h>
#include <cstddef>
#include <cstdint>

// ---------------------------------------------------------------------------
// Hyperbolic (Poincare-ball) entity-typing forward pass, MI355X / gfx950.
// Round 9: GRU v8 — counted-vmcnt software pipeline (T3/T4): 12x32KB chunks
// per step in 4 LDS buffers, depth-3 prefetch, raw s_barrier (no vmcnt(0)
// drain). Chain math identical to round 8. Non-GRU path unchanged.
// ---------------------------------------------------------------------------

#define EPS_  1e-15f
#define PMAX_ 0.99999f    // 1 - 1e-5

typedef __attribute__((ext_vector_type(8))) short bf16x8;
typedef __attribute__((ext_vector_type(4))) float f32x4;
typedef __attribute__((ext_vector_type(8))) unsigned short us8;

#define WAITC8 asm volatile("s_waitcnt vmcnt(8)" ::: "memory")
#define WAITC4 asm volatile("s_waitcnt vmcnt(4)" ::: "memory")
#define WAITC0 asm volatile("s_waitcnt vmcnt(0)" ::: "memory")
#define LGKM0  asm volatile("s_waitcnt lgkmcnt(0)" ::: "memory")
#define BARR   do{ __builtin_amdgcn_s_barrier(); __builtin_amdgcn_sched_barrier(0); }while(0)

__device__ __forceinline__ float wred(float v){
#pragma unroll
  for (int o = 32; o; o >>= 1) v += __shfl_xor(v, o, 64);
  return v;
}
__device__ __forceinline__ void wred2(float& a, float& b){
#pragma unroll
  for (int o = 32; o; o >>= 1){ a += __shfl_xor(a, o, 64); b += __shfl_xor(b, o, 64); }
}
__device__ __forceinline__ void wred3(float& a, float& b, float& c){
#pragma unroll
  for (int o = 32; o; o >>= 1){
    a += __shfl_xor(a, o, 64); b += __shfl_xor(b, o, 64); c += __shfl_xor(c, o, 64);
  }
}
__device__ __forceinline__ void wred4(float& a, float& b, float& c, float& d){
#pragma unroll
  for (int o = 32; o; o >>= 1){
    a += __shfl_xor(a, o, 64); b += __shfl_xor(b, o, 64);
    c += __shfl_xor(c, o, 64); d += __shfl_xor(d, o, 64);
  }
}
__device__ __forceinline__ float wredmax(float v){
#pragma unroll
  for (int o = 32; o; o >>= 1) v = fmaxf(v, __shfl_xor(v, o, 64));
  return v;
}
__device__ __forceinline__ float snorm(float s){ return sqrtf(fmaxf(s, EPS_)); }
__device__ __forceinline__ float clamp11(float x){
  return fminf(fmaxf(x, -1.f + 1e-7f), 1.f - 1e-7f);
}
__device__ __forceinline__ float bf2f(unsigned short u){
  union { unsigned int i; float f; } v; v.i = ((unsigned int)u) << 16; return v.f;
}
__device__ __forceinline__ unsigned short f2bf(float f){
  union { float f; unsigned int i; } v; v.f = f;
  unsigned int x = v.i;
  x += 0x7fffu + ((x >> 16) & 1u);   // RNE
  return (unsigned short)(x >> 16);
}
__device__ __forceinline__ float bflo(unsigned u){
  union { unsigned i; float f; } v; v.i = u << 16; return v.f;
}
__device__ __forceinline__ float bfhi(unsigned u){
  union { unsigned i; float f; } v; v.i = u & 0xffff0000u; return v.f;
}

template<int N>
__device__ __forceinline__ float sq_part(const float* a){
  float s = 0.f;
#pragma unroll
  for (int i = 0; i < N; i++) s += a[i]*a[i];
  return s;
}
template<int N>
__device__ __forceinline__ float dot_part(const float* a, const float* b){
  float s = 0.f;
#pragma unroll
  for (int i = 0; i < N; i++) s += a[i]*b[i];
  return s;
}
template<int N>
__device__ __forceinline__ void madd_vec(const float* x, float x2, const float* y,
                                         float y2, float xy, float* o){
  const float c1 = 1.f + 2.f*xy + y2;
  const float c2 = 1.f - x2;
  const float inv = 1.f / fmaxf(1.f + 2.f*xy + x2*y2, EPS_);
#pragma unroll
  for (int i = 0; i < N; i++) o[i] = (c1*x[i] + c2*y[i]) * inv;
}
template<int N>
__device__ __forceinline__ void mt_project(float* v, float mxn2, float xn2, float* n2out){
  const float xn  = snorm(xn2);
  const float mxn = snorm(mxn2);
  const float t   = tanhf(mxn/xn * atanhf(clamp11(xn)));
  float sc = t/mxn;
  float n2 = sc*sc*mxn2;
  const float n = snorm(n2);
  if (n > PMAX_){ const float s = PMAX_/n; sc *= s; n2 *= s*s; }
#pragma unroll
  for (int i = 0; i < N; i++) v[i] *= sc;
  *n2out = n2;
}
__device__ __forceinline__ void mt_scale(float mxn2, float xn, float art,
                                         float* sc, float* n2){
  const float mxn = snorm(mxn2);
  const float t   = tanhf(mxn/xn * art);
  float s  = t/mxn;
  float nn = t*t;
  const float n = snorm(nn);
  if (n > PMAX_){ const float f = PMAX_/n; s *= f; nn *= f*f; }
  *sc = s; *n2 = nn;
}
template<int N>
__device__ __forceinline__ void project_vec(float* v, float* n2io){
  float n2 = *n2io;
  const float n = snorm(n2);
  if (n > PMAX_){
    const float s = PMAX_/n;
#pragma unroll
    for (int i = 0; i < N; i++) v[i] *= s;
    n2 *= s*s;
  }
  *n2io = n2;
}

// async 16B global->LDS: linear wave-uniform-base + lane*16
__device__ __forceinline__ void gll16(const void* g, void* l){
  __builtin_amdgcn_global_load_lds(
      (const __attribute__((address_space(1))) void*)g,
      (__attribute__((address_space(3))) void*)l, 16, 0, 0);
}
// stage 32KB with 512 threads (8 waves x 4 x 16B/lane), linear layout
__device__ __forceinline__ void stage32k8(const void* gsrc, float* lbase, int w, int lane){
#pragma unroll
  for (int i = 0; i < 4; i++){
    const char* g = (const char*)gsrc + (size_t)((i*8 + w)*64 + lane)*16;
    char* l = (char*)lbase + (size_t)((i*8 + w)*64)*16;
    gll16(g, l);
  }
}

// ---------------------------------------------------------------------------
// MFMA bf16 GEMM (unchanged)
// ---------------------------------------------------------------------------
template<int AMODE>
__global__ __launch_bounds__(256) void mfma_mm(const void* __restrict__ Aptr,
    const int* __restrict__ idx, const unsigned short* __restrict__ Bt,
    float* __restrict__ Cm, int M, int N, int K, int Kp)
{
  __shared__ __align__(16) unsigned short As[128][40];
  __shared__ __align__(16) unsigned short Bs[128][40];
  const int tid = threadIdx.x;
  const int n0 = blockIdx.x * 128;
  const int m0 = blockIdx.y * 128;
  const int srow = tid >> 1, shalf = tid & 1;
  const int wv = tid >> 6, lane = tid & 63;
  const int wm = wv >> 1, wn = wv & 1;
  const int lr = lane & 15, lk = lane >> 4;

  long arow;
  if constexpr (AMODE == 1) arow = (long)idx[m0 + srow] * K;
  else                      arow = (long)(m0 + srow) * K;

  f32x4 acc[4][4];
#pragma unroll
  for (int mf = 0; mf < 4; mf++)
#pragma unroll
    for (int nf = 0; nf < 4; nf++) acc[mf][nf] = (f32x4){0.f,0.f,0.f,0.f};

  for (int k0 = 0; k0 < Kp; k0 += 32){
    const int kb = k0 + shalf*16;
    unsigned short av[16];
    if constexpr (AMODE == 1){
      const float* ar = (const float*)Aptr + arow;
      if (kb + 16 <= K){
#pragma unroll
        for (int v = 0; v < 4; v++){
          const float4 f = *(const float4*)(ar + kb + v*4);
          av[v*4+0]=f2bf(f.x); av[v*4+1]=f2bf(f.y);
          av[v*4+2]=f2bf(f.z); av[v*4+3]=f2bf(f.w);
        }
      } else {
#pragma unroll
        for (int v = 0; v < 16; v++){
          const int col = kb + v;
          av[v] = (col < K) ? f2bf(ar[col]) : (unsigned short)0;
        }
      }
    } else {
      const unsigned short* ar = (const unsigned short*)Aptr + arow + kb;
      const us8 u0 = *(const us8*)ar;
      const us8 u1 = *(const us8*)(ar + 8);
#pragma unroll
      for (int v = 0; v < 8; v++){ av[v] = u0[v]; av[8+v] = u1[v]; }
    }
    unsigned short bvv[16];
    {
      const unsigned short* br = Bt + (long)(n0 + srow)*Kp + kb;
      const us8 u0 = *(const us8*)br;
      const us8 u1 = *(const us8*)(br + 8);
#pragma unroll
      for (int v = 0; v < 8; v++){ bvv[v] = u0[v]; bvv[8+v] = u1[v]; }
    }
    __syncthreads();
    *(us8*)&As[srow][shalf*16]   = *(const us8*)&av[0];
    *(us8*)&As[srow][shalf*16+8] = *(const us8*)&av[8];
    *(us8*)&Bs[srow][shalf*16]   = *(const us8*)&bvv[0];
    *(us8*)&Bs[srow][shalf*16+8] = *(const us8*)&bvv[8];
    __syncthreads();
    bf16x8 af[4], bfr[4];
#pragma unroll
    for (int mf = 0; mf < 4; mf++)
      af[mf] = *(const bf16x8*)&As[wm*64 + mf*16 + lr][lk*8];
#pragma unroll
    for (int nf = 0; nf < 4; nf++)
      bfr[nf] = *(const bf16x8*)&Bs[wn*64 + nf*16 + lr][lk*8];
#pragma unroll
    for (int mf = 0; mf < 4; mf++)
#pragma unroll
      for (int nf = 0; nf < 4; nf++)
        acc[mf][nf] = __builtin_amdgcn_mfma_f32_16x16x32_bf16(af[mf], bfr[nf],
                                                              acc[mf][nf], 0, 0, 0);
  }
#pragma unroll
  for (int mf = 0; mf < 4; mf++){
#pragma unroll
    for (int nf = 0; nf < 4; nf++){
#pragma unroll
      for (int r = 0; r < 4; r++){
        const long grow = m0 + wm*64 + mf*16 + lk*4 + r;
        Cm[grow*N + n0 + wn*64 + nf*16 + lr] = acc[mf][nf][r];
      }
    }
  }
}

// ---------------------------------------------------------------------------
// Generic tiled f32 GEMM (small fc GEMMs only)
// ---------------------------------------------------------------------------
template<int AMODE>
__global__ __launch_bounds__(256) void mm_kernel(const void* __restrict__ Aptr,
    const int* __restrict__ idx, const float* __restrict__ Bm,
    float* __restrict__ Cm, int M, int N, int K)
{
  __shared__ __align__(16) float As[8][128];
  __shared__ __align__(16) float Bs[8][132];
  const int tid = threadIdx.x;
  const int n0 = blockIdx.x * 128;
  const int m0 = blockIdx.y * 128;
  const int tr = tid >> 4, tc = tid & 15;
  const int sm = tid & 127, sk = (tid >> 7) * 4;
  const int bk = tid >> 5,  bn = (tid & 31) * 4;
  long arow;
  if constexpr (AMODE == 1) arow = (long)idx[m0 + sm] * K;
  else                      arow = (long)(m0 + sm) * K;
  float acc[8][8];
#pragma unroll
  for (int i = 0; i < 8; i++)
#pragma unroll
    for (int j = 0; j < 8; j++) acc[i][j] = 0.f;

  for (int k0 = 0; k0 < K; k0 += 8){
    float av[4], bv[4];
    {
      const float* A = (const float*)Aptr;
      if (k0 + sk + 3 < K){
        const float4 f = *reinterpret_cast<const float4*>(A + arow + k0 + sk);
        av[0]=f.x; av[1]=f.y; av[2]=f.z; av[3]=f.w;
      } else {
#pragma unroll
        for (int i = 0; i < 4; i++){
          const int kk = k0 + sk + i;
          av[i] = (kk < K) ? A[arow + kk] : 0.f;
        }
      }
    }
    {
      const int kb = k0 + bk;
      if (kb < K){
        const float4 f = *reinterpret_cast<const float4*>(Bm + (long)kb*N + n0 + bn);
        bv[0]=f.x; bv[1]=f.y; bv[2]=f.z; bv[3]=f.w;
      } else { bv[0]=bv[1]=bv[2]=bv[3]=0.f; }
    }
    __syncthreads();
    As[sk+0][sm]=av[0]; As[sk+1][sm]=av[1]; As[sk+2][sm]=av[2]; As[sk+3][sm]=av[3];
    *reinterpret_cast<float4*>(&Bs[bk][bn]) = make_float4(bv[0],bv[1],bv[2],bv[3]);
    __syncthreads();
#pragma unroll
    for (int k = 0; k < 8; k++){
      float a[8], bb[8];
      *(float4*)&a[0]  = *(const float4*)&As[k][tr*8];
      *(float4*)&a[4]  = *(const float4*)&As[k][tr*8+4];
      *(float4*)&bb[0] = *(const float4*)&Bs[k][tc*8];
      *(float4*)&bb[4] = *(const float4*)&Bs[k][tc*8+4];
#pragma unroll
      for (int i = 0; i < 8; i++)
#pragma unroll
        for (int j = 0; j < 8; j++) acc[i][j] += a[i]*bb[j];
    }
  }
#pragma unroll
  for (int i = 0; i < 8; i++){
    const long row = m0 + tr*8 + i;
    *(float4*)(Cm + row*N + n0 + tc*8)     = make_float4(acc[i][0],acc[i][1],acc[i][2],acc[i][3]);
    *(float4*)(Cm + row*N + n0 + tc*8 + 4) = make_float4(acc[i][4],acc[i][5],acc[i][6],acc[i][7]);
  }
}

// ---------------------------------------------------------------------------
// 32x32 LDS-tiled transpose: dst[k*R + j] = src[j*Kc + k]   (f32 -> f32)
// ---------------------------------------------------------------------------
__global__ __launch_bounds__(256) void transpose_k(const float* __restrict__ src,
    float* __restrict__ dst, int R, int Kc)
{
  __shared__ float t[32][33];
  const int bx = blockIdx.x * 32;
  const int by = blockIdx.y * 32;
  const int tx = threadIdx.x & 31, ty = threadIdx.x >> 5;
#pragma unroll
  for (int i = 0; i < 32; i += 8){
    const int j = by + ty + i, k = bx + tx;
    t[ty+i][tx] = (j < R && k < Kc) ? src[(long)j*Kc + k] : 0.f;
  }
  __syncthreads();
#pragma unroll
  for (int i = 0; i < 32; i += 8){
    const int k = bx + ty + i, j = by + tx;
    if (k < Kc && j < R) dst[(long)k*R + j] = t[tx][ty+i];
  }
}

// transpose + bf16 pack: src [K][N] f32 -> dst [N][Kp] bf16 (zero-pad K..Kp)
__global__ __launch_bounds__(256) void packT16(const float* __restrict__ src,
    unsigned short* __restrict__ dst, int K, int N, int Kp)
{
  __shared__ float t[32][33];
  const int bx = blockIdx.x*32;
  const int by = blockIdx.y*32;
  const int tx = threadIdx.x & 31, ty = threadIdx.x >> 5;
#pragma unroll
  for (int i = 0; i < 32; i += 8){
    const int k = bx + ty + i, n = by + tx;
    t[ty+i][tx] = (k < K && n < N) ? src[(long)k*N + n] : 0.f;
  }
  __syncthreads();
#pragma unroll
  for (int i = 0; i < 32; i += 8){
    const int k = bx + tx, n = by + ty + i;
    if (k < Kp && n < N) dst[(long)n*Kp + k] = f2bf(t[tx][ty+i]);
  }
}

// pack Wih (already [768][300] = B^T layout) -> [2][768][320] bf16 zero-padded
__global__ void pack_wih(const float* __restrict__ w0, const float* __restrict__ w1,
                         unsigned short* __restrict__ dst)
{
  const int tid = blockIdx.x*256 + threadIdx.x;
  if (tid < 2*768*320){
    const int d = tid / (768*320);
    const int rem = tid - d*768*320;
    const int n = rem / 320, k = rem - n*320;
    const float* src = d ? w1 : w0;
    dst[tid] = (k < 300) ? f2bf(src[n*300 + k]) : (unsigned short)0;
  }
}

// split+pack WtHH [2][256][768] (r|h|z) f32 -> Wrz16 (r|z) bf16, Wh16 bf16
__global__ void pack_whh16(const float* __restrict__ WtHH,
                           unsigned short* __restrict__ Wrz16,
                           unsigned short* __restrict__ Wh16)
{
  const int tid = blockIdx.x*256 + threadIdx.x;
  if (tid < 2*256*768){
    const int col = tid % 768, rk = tid / 768;
    const unsigned short v = f2bf(WtHH[tid]);
    if (col < 256)       Wrz16[(long)rk*512 + col] = v;
    else if (col < 512)  Wh16 [(long)rk*256 + (col - 256)] = v;
    else                 Wrz16[(long)rk*512 + 256 + (col - 512)] = v;
  }
}

// build gather-index arrays
__global__ void build_idx(const int* __restrict__ context, const int* __restrict__ mchars,
                          int* __restrict__ ctxidx, int* __restrict__ chidx)
{
  const int tid = blockIdx.x*256 + threadIdx.x;
  if (tid < 32768){
    const int t = tid >> 8, b = tid & 255;
    ctxidx[tid] = context[b*128 + t];
  } else if (tid < 32768 + 4096){
    const int o = tid - 32768;
    const int t = o >> 8, b = o & 255;
    chidx[o] = mchars[b*16 + t];
  }
}

// out[r] = sum_k lut[idx[r]][k]^2   (one wave per row)
__global__ __launch_bounds__(256) void sqn_gather(const float* __restrict__ lut,
    const int* __restrict__ idx, int K, float* __restrict__ outp)
{
  const int wv = threadIdx.x >> 6, lane = threadIdx.x & 63;
  const int r = blockIdx.x*4 + wv;
  const float* row = lut + (long)idx[r]*K;
  float s = 0.f;
  for (int k = lane; k < K; k += 64) s += row[k]*row[k];
  s = wred(s);
  if (lane == 0) outp[r] = s;
}

// mobius_matvec tail transform per (row, gate); out bf16 + |out_bf16|^2
__global__ __launch_bounds__(256) void xg_transform(const float* __restrict__ mx,
    const float* __restrict__ xsqn, unsigned short* __restrict__ outp,
    float* __restrict__ n2o, int G)
{
  const int wv = threadIdx.x >> 6, lane = threadIdx.x & 63;
  const int wg = blockIdx.x*4 + wv;
  const int row = wg / G, g = wg - row*G;
  const long base = (long)row*(G*256) + g*256;
  float M[4];
#pragma unroll
  for (int i = 0; i < 4; i++) M[i] = mx[base + i*64 + lane];
  const float mxn2 = wred(sq_part<4>(M));
  float pn2; mt_project<4>(M, mxn2, xsqn[row], &pn2);
  float s = 0.f;
#pragma unroll
  for (int i = 0; i < 4; i++){
    const unsigned short u = f2bf(M[i]);
    outp[base + i*64 + lane] = u;
    const float rv = bf2f(u);
    s += rv*rv;
  }
  s = wred(s);
  if (lane == 0) n2o[wg] = s;
}

// ---------------------------------------------------------------------------
// Mobius GRU v8: 256 blocks x 512 thr; 2 batch rows/block.
// 12 x 32KB bf16 weight chunks/step (Wrz 8 + Wh 4), 4 LDS buffers, depth-3
// counted-vmcnt pipeline (loads in flight across raw s_barrier).
// Phase1 roles (fg=w&1 gate, kq4=w>>1: 8k per 32k chunk);
// phase2 roles (qk8=w: 8k per 64k chunk). Chains identical to round 8.
// LDS: wbuf 4x32KB | hs 2K | part 16K | rhb 2K | zb 2K | scal.
// ---------------------------------------------------------------------------
#define GRU_LDS_BYTES 153664

__global__ __launch_bounds__(512,1) void gru_kernel(
    const unsigned short* __restrict__ xg,
    const float* __restrict__ xgn2,
    const unsigned short* __restrict__ Wrz16,
    const unsigned short* __restrict__ Wh16,
    const float* __restrict__ bias_f, const float* __restrict__ bias_b,
    unsigned short* __restrict__ states_f, unsigned short* __restrict__ states_b)
{
  extern __shared__ __align__(16) char smem[];
  float* wbuf = (float*)smem;                    // 4 x 8192 f32 slots (32KB each)
  float* hs   = (float*)(smem + 131072);         // [2][256]
  float* part = (float*)(smem + 133120);         // 4096 floats (16KB)
  float* rhb  = (float*)(smem + 149504);         // [2][256]
  float* zb   = (float*)(smem + 151552);         // [2][256]
  float* scal = (float*)(smem + 153600);         // [2][2]

  const int bid = blockIdx.x;                    // 0..255
  const int dir = bid >> 7;
  const int brow0 = (bid & 127) * 2;
  const int tid = threadIdx.x;
  const int w = tid >> 6, lane = tid & 63;       // w in 0..7
  const int j0 = lane << 2;

  const unsigned short* xgd = xg + (long)dir*32768*768;
  const float* xnd = xgn2 + (long)dir*32768*3;
  const unsigned short* wrz_d = Wrz16 + (long)dir*256*512;
  const unsigned short* wh_d  = Wh16  + (long)dir*256*256;
  const float* bias = dir ? bias_b : bias_f;
  unsigned short* states = dir ? states_b : states_f;

  // FMA roles
  const int fg  = w & 1;             // phase1 gate (0=r cols 0..255, 1=z)
  const int kq4 = w >> 1;            // phase1 k-quarter (8 k) within 32-k chunk
  const int qk8 = w;                 // phase2 k-eighth (8 k) within 64-k chunk
  // chain roles
  const int crow  = (w >> 1) & 1;
  const int cgate = w & 1;

  float bg[4], bh4[4] = {0,0,0,0};
  float bg2, bh2 = 0.f;
#pragma unroll
  for (int i = 0; i < 4; i++) bg[i] = bias[(cgate ? 512 : 0) + j0 + i];
  bg2 = wred(sq_part<4>(bg));
  if (w < 2){
#pragma unroll
    for (int i = 0; i < 4; i++) bh4[i] = bias[256 + j0 + i];
    bh2 = wred(sq_part<4>(bh4));
  }

  float h[4] = {0.f,0.f,0.f,0.f};
  float hn2 = 0.f;
  if (w < 2){
#pragma unroll
    for (int i = 0; i < 4; i++) hs[w*256 + j0 + i] = 0.f;
    if (lane == 0){ scal[w*2 + 0] = 0.f; scal[w*2 + 1] = 0.f; }
  }
  __syncthreads();   // initial hs/scal visible (full drain OK here, nothing in flight)

  // chunk content: slot c (0..11): c<8 -> Wrz + c*16384 elems; else Wh + (c-8)*16384
  // prologue: stage slots 0,1,2 into bufs 0,1,2
  stage32k8(wrz_d,           wbuf + 0*8192, w, lane);
  stage32k8(wrz_d + 16384,   wbuf + 1*8192, w, lane);
  stage32k8(wrz_d + 2*16384, wbuf + 2*8192, w, lane);

#pragma unroll 1
  for (int t = 0; t < 128; t++){
    const int tt = dir ? (127 - t) : t;
    // ---- role input loads (guarded: only chain waves) ----
    float xgv[4] = {0,0,0,0}, y2g = 0.f, xgh4[4] = {0,0,0,0}, y2h = 0.f;
    if (w < 4){
      const long rxg = (long)tt*256 + brow0 + crow;
      const ushort4 u = *(const ushort4*)(xgd + rxg*768 + (cgate ? 512 : 0) + j0);
      xgv[0]=bf2f(u.x); xgv[1]=bf2f(u.y); xgv[2]=bf2f(u.z); xgv[3]=bf2f(u.w);
      y2g = xnd[rxg*3 + (cgate ? 2 : 0)];
      if (w < 2){
        const long rxh = (long)tt*256 + brow0 + w;
        const ushort4 uh = *(const ushort4*)(xgd + rxh*768 + 256 + j0);
        xgh4[0]=bf2f(uh.x); xgh4[1]=bf2f(uh.y); xgh4[2]=bf2f(uh.z); xgh4[3]=bf2f(uh.w);
        y2h = xnd[rxh*3 + 1];
      }
    }

    // ===== phase 1: slots 0..7 (Wrz chunks, 32 k x 512 cols each) =====
    float s00=0.f,s01=0.f,s02=0.f,s03=0.f, s10=0.f,s11=0.f,s12=0.f,s13=0.f;
#pragma unroll 1
    for (int c = 0; c < 8; c++){
      WAITC8;                                   // own stage of chunk c landed
      BARR;                                     // all waves' stages landed
      {                                         // issue stage for slot c+3
        const int is = c + 3;                   // 3..10, always within step
        const unsigned short* src = (is < 8) ? (wrz_d + is*16384)
                                             : (wh_d + (is - 8)*16384);
        stage32k8(src, wbuf + (is & 3)*8192, w, lane);
      }
      const uint2* wb2 = (const uint2*)(wbuf + (c & 3)*8192);  // [32][128] uint2
      const int kb = c*32 + kq4*8;
#pragma unroll
      for (int kk = 0; kk < 2; kk++){
        const float4 hb0 = *(const float4*)&hs[0*256 + kb + kk*4];
        const float4 hb1 = *(const float4*)&hs[1*256 + kb + kk*4];
#pragma unroll
        for (int q = 0; q < 4; q++){
          const uint2 wvv = wb2[(kq4*8 + kk*4 + q)*128 + fg*64 + lane];
          const float w0 = bflo(wvv.x), w1 = bfhi(wvv.x);
          const float w2 = bflo(wvv.y), w3 = bfhi(wvv.y);
          const float h0 = (&hb0.x)[q], h1 = (&hb1.x)[q];
          s00 += h0*w0; s01 += h0*w1; s02 += h0*w2; s03 += h0*w3;
          s10 += h1*w0; s11 += h1*w1; s12 += h1*w2; s13 += h1*w3;
        }
      }
    }
    {
      // part1 layout: [kq4][row][512]; col = fg*256 + j0
      float* p1 = part + kq4*1024 + fg*256 + j0;
      *(float4*)p1         = make_float4(s00,s01,s02,s03);
      *(float4*)(p1 + 512) = make_float4(s10,s11,s12,s13);
    }
    LGKM0;
    BARR;                                       // B_a: partials visible

    // ===== gate chain: waves 0..3, role (crow, cgate) =====
    if (w < 4){
      const float* pa = part + crow*512 + cgate*256 + j0;
      const float4 a0 = *(const float4*)pa;
      const float4 a1 = *(const float4*)(pa + 1024);
      const float4 a2 = *(const float4*)(pa + 2048);
      const float4 a3 = *(const float4*)(pa + 3072);
      float a[4] = { (a0.x+a1.x)+(a2.x+a3.x), (a0.y+a1.y)+(a2.y+a3.y),
                     (a0.z+a1.z)+(a2.z+a3.z), (a0.w+a1.w)+(a2.w+a3.w) };
      const float hn2v = scal[crow*2 + 0];
      const float xn_h = snorm(hn2v), art_h = atanhf(clamp11(xn_h));
      const float p2 = wred(sq_part<4>(a));
      float sc, n2; mt_scale(p2, xn_h, art_h, &sc, &n2);
#pragma unroll
      for (int i = 0; i < 4; i++) a[i] *= sc;
      const float xy = wred(dot_part<4>(a, xgv));
      float m1[4]; madd_vec<4>(a, n2, xgv, y2g, xy, m1);
      float m1n2 = sq_part<4>(m1), xyb = dot_part<4>(m1, bg);
      wred2(m1n2, xyb);
      float m2[4]; madd_vec<4>(m1, m1n2, bg, bg2, xyb, m2);
      const float m2n2 = wred(sq_part<4>(m2));
      const float nn = snorm(m2n2), fgc = atanhf(clamp11(nn))/nn;
      float g4[4];
#pragma unroll
      for (int i = 0; i < 4; i++) g4[i] = 1.f/(1.f + expf(-fgc*m2[i]));
      if (cgate == 0){
        float h4[4];
        *(float4*)h4 = *(const float4*)&hs[crow*256 + j0];
        float rh[4]; float wx2 = 0.f;
#pragma unroll
        for (int i = 0; i < 4; i++){ rh[i] = g4[i]*h4[i]; wx2 += rh[i]*rh[i]; }
        wx2 = wred(wx2);
        float rhn2, scrh;
        {
          const float wxn = snorm(wx2);
          const float trh = tanhf(wxn/xn_h * art_h);
          scrh = trh/wxn; rhn2 = trh*trh;
          const float n = snorm(rhn2);
          if (n > PMAX_){ const float f = PMAX_/n; scrh *= f; rhn2 *= f*f; }
        }
#pragma unroll
        for (int i = 0; i < 4; i++) rh[i] *= scrh;
        *(float4*)&rhb[crow*256 + j0] = make_float4(rh[0],rh[1],rh[2],rh[3]);
        if (lane == 0) scal[crow*2 + 1] = rhn2;
      } else {
        *(float4*)&zb[crow*256 + j0] = make_float4(g4[0],g4[1],g4[2],g4[3]);
      }
    }

    // ===== phase 2: slots 8..11 (Wh chunks, 64 k x 256 cols each) =====
    float r00=0.f,r01=0.f,r02=0.f,r03=0.f, r10=0.f,r11=0.f,r12=0.f,r13=0.f;
#pragma unroll 1
    for (int c = 0; c < 4; c++){
      const int s = 8 + c;
      if (t < 127){ WAITC8; }
      else {
        if      (c <  2){ WAITC8; }
        else if (c == 2){ WAITC4; }
        else            { WAITC0; }
      }
      if (c == 0){ LGKM0; }                     // rhb/zb ds_writes visible
      BARR;
      {
        const int is = s + 3;                   // 11..14
        if (is < 12){
          stage32k8(wh_d + (is - 8)*16384, wbuf + (is & 3)*8192, w, lane);
        } else if (t < 127){
          const int nis = is - 12;              // next step slots 0..2 (Wrz)
          stage32k8(wrz_d + nis*16384, wbuf + (nis & 3)*8192, w, lane);
        }
      }
      const uint2* wb2 = (const uint2*)(wbuf + (s & 3)*8192);  // [64][64] uint2
      const int kb = c*64 + qk8*8;
#pragma unroll
      for (int kk = 0; kk < 2; kk++){
        const float4 hb0 = *(const float4*)&rhb[0*256 + kb + kk*4];
        const float4 hb1 = *(const float4*)&rhb[1*256 + kb + kk*4];
#pragma unroll
        for (int q = 0; q < 4; q++){
          const uint2 wvv = wb2[(qk8*8 + kk*4 + q)*64 + lane];
          const float w0 = bflo(wvv.x), w1 = bfhi(wvv.x);
          const float w2 = bflo(wvv.y), w3 = bfhi(wvv.y);
          const float h0 = (&hb0.x)[q], h1 = (&hb1.x)[q];
          r00 += h0*w0; r01 += h0*w1; r02 += h0*w2; r03 += h0*w3;
          r10 += h1*w0; r11 += h1*w1; r12 += h1*w2; r13 += h1*w3;
        }
      }
    }
    {
      // part2 layout: [qk8][row][256]
      float* p2 = part + qk8*512 + j0;
      *(float4*)p2         = make_float4(r00,r01,r02,r03);
      *(float4*)(p2 + 256) = make_float4(r10,r11,r12,r13);
    }
    LGKM0;
    BARR;                                       // B_c: part2 visible

    // ===== h-update chain: waves 0..1, row = w =====
    if (w < 2){
      float ah[4];
      {
        float4 p[8];
#pragma unroll
        for (int q = 0; q < 8; q++)
          p[q] = *(const float4*)(part + q*512 + w*256 + j0);
        ah[0] = ((p[0].x+p[1].x)+(p[2].x+p[3].x)) + ((p[4].x+p[5].x)+(p[6].x+p[7].x));
        ah[1] = ((p[0].y+p[1].y)+(p[2].y+p[3].y)) + ((p[4].y+p[5].y)+(p[6].y+p[7].y));
        ah[2] = ((p[0].z+p[1].z)+(p[2].z+p[3].z)) + ((p[4].z+p[5].z)+(p[6].z+p[7].z));
        ah[3] = ((p[0].w+p[1].w)+(p[2].w+p[3].w)) + ((p[4].w+p[5].w)+(p[6].w+p[7].w));
      }
      const float rhn2v = scal[w*2 + 1];
      const float rxn = snorm(rhn2v), artr = atanhf(clamp11(rxn));
      float mx2 = sq_part<4>(ah), xyraw = dot_part<4>(ah, xgh4);
      wred2(mx2, xyraw);
      float sch, pn2; mt_scale(mx2, rxn, artr, &sch, &pn2);
#pragma unroll
      for (int i = 0; i < 4; i++) ah[i] *= sch;
      const float xy = xyraw * sch;
      float m1[4]; madd_vec<4>(ah, pn2, xgh4, y2h, xy, m1);
      float m1n2 = sq_part<4>(m1), xyb = dot_part<4>(m1, bh4);
      wred2(m1n2, xyb);
      float ht[4]; madd_vec<4>(m1, m1n2, bh4, bh2, xyb, ht);
      float htn2 = sq_part<4>(ht);
      float nh[4];
#pragma unroll
      for (int i = 0; i < 4; i++) nh[i] = -h[i];
      float xyd = dot_part<4>(nh, ht);
      wred2(htn2, xyd);
      float dl[4]; madd_vec<4>(nh, hn2, ht, htn2, xyd, dl);
      float z4[4];
      *(float4*)z4 = *(const float4*)&zb[w*256 + j0];
      float pw[4]; float dln2 = 0.f, wz2 = 0.f, xyhr = 0.f;
#pragma unroll
      for (int i = 0; i < 4; i++){
        dln2 += dl[i]*dl[i];
        pw[i] = z4[i]*dl[i];
        wz2  += pw[i]*pw[i];
        xyhr += h[i]*pw[i];
      }
      wred3(dln2, wz2, xyhr);
      float pwn2, scpw;
      {
        const float dn   = snorm(dln2);
        const float artd = atanhf(clamp11(dn));
        const float wzn  = snorm(wz2);
        const float tpw  = tanhf(wzn/dn * artd);
        scpw = tpw/wzn; pwn2 = tpw*tpw;
        const float n = snorm(pwn2);
        if (n > PMAX_){ const float f = PMAX_/n; scpw *= f; pwn2 *= f*f; }
      }
#pragma unroll
      for (int i = 0; i < 4; i++) pw[i] *= scpw;
      const float xyh = xyhr * scpw;
      float hnew[4]; madd_vec<4>(h, hn2, pw, pwn2, xyh, hnew);
#pragma unroll
      for (int i = 0; i < 4; i++) h[i] = hnew[i];
      hn2 = wred(sq_part<4>(h));
      *(float4*)&hs[w*256 + j0] = make_float4(h[0],h[1],h[2],h[3]);
      if (lane == 0) scal[w*2 + 0] = hn2;
      unsigned short* srow = states + ((long)(brow0 + w)*128 + tt)*256 + j0;
      ushort4 su; su.x=f2bf(h[0]); su.y=f2bf(h[1]); su.z=f2bf(h[2]); su.w=f2bf(h[3]);
      *(ushort4*)srow = su;
    }
    LGKM0;
    BARR;                                       // B_d: hs/scal ready for next step
  }
}

// ---------------------------------------------------------------------------
// Char Mobius-RNN (unchanged)
// ---------------------------------------------------------------------------
__global__ __launch_bounds__(256) void char_rnn(
    const unsigned short* __restrict__ xgc,
    const float* __restrict__ Wc,
    const float* __restrict__ cb,
    float* __restrict__ cstates)
{
  const int wv = threadIdx.x >> 6, lane = threadIdx.x & 63;
  const int b = blockIdx.x*4 + wv;
  const int j0 = lane << 2;
  __shared__ __align__(16) float hs[4][256];
  float h[4] = {0.f,0.f,0.f,0.f};
  float hn2 = 0.f;
#pragma unroll
  for (int i = 0; i < 4; i++) hs[wv][j0+i] = 0.f;
  float cbv[4];
#pragma unroll
  for (int i = 0; i < 4; i++) cbv[i] = cb[j0+i];
  const float cb2 = wred(sq_part<4>(cbv));
  for (int t = 0; t < 16; t++){
    __syncthreads();
    const unsigned short* xr = xgc + ((long)t*256 + b)*256;
    float xgv[4];
    { const ushort4 u = *(const ushort4*)(xr + j0); xgv[0]=bf2f(u.x); xgv[1]=bf2f(u.y); xgv[2]=bf2f(u.z); xgv[3]=bf2f(u.w); }
    float a[4]={0.f,0.f,0.f,0.f};
#pragma unroll 2
    for (int k0 = 0; k0 < 256; k0 += 4){
      const float4 hk = *(const float4*)&hs[wv][k0];
#pragma unroll
      for (int kk = 0; kk < 4; kk++){
        const float hv = (&hk.x)[kk];
        const float4 w4 = *(const float4*)(Wc + (long)(k0+kk)*256 + j0);
        a[0] += hv*w4.x; a[1] += hv*w4.y; a[2] += hv*w4.z; a[3] += hv*w4.w;
      }
    }
    const float mxn2 = wred(sq_part<4>(a));
    float pn2; mt_project<4>(a, mxn2, hn2, &pn2);
    const float y2 = wred(sq_part<4>(xgv));
    const float xy = wred(dot_part<4>(a, xgv));
    float m1[4]; madd_vec<4>(a, pn2, xgv, y2, xy, m1);
    const float m1n2 = wred(sq_part<4>(m1));
    const float xyb  = wred(dot_part<4>(m1, cbv));
    float m2[4]; madd_vec<4>(m1, m1n2, cbv, cb2, xyb, m2);
    float m2n2 = wred(sq_part<4>(m2));
    project_vec<4>(m2, &m2n2);
#pragma unroll
    for (int i = 0; i < 4; i++) h[i] = m2[i];
    hn2 = m2n2;
    *(float4*)&hs[wv][j0] = make_float4(h[0],h[1],h[2],h[3]);
    *(float4*)(cstates + ((long)b*16 + t)*256 + j0) = make_float4(h[0],h[1],h[2],h[3]);
  }
}

// ---------------------------------------------------------------------------
// cc concat (unchanged)
// ---------------------------------------------------------------------------
__global__ __launch_bounds__(256) void cc_rowwise(const unsigned short* __restrict__ sf,
    const unsigned short* __restrict__ sb, const float* __restrict__ mxa,
    const float* __restrict__ mxb, const float* __restrict__ ccb,
    unsigned short* __restrict__ ctxo, int rowoff)
{
  const int wv = threadIdx.x >> 6, lane = threadIdx.x & 63;
  const int rloc = blockIdx.x*4 + wv;
  const long r = rowoff + rloc;
  float s = 0.f;
#pragma unroll
  for (int i = 0; i < 4; i++){ const float v = bf2f(sf[r*256 + i*64+lane]); s += v*v; }
  const float sfn2 = wred(s);
  s = 0.f;
#pragma unroll
  for (int i = 0; i < 4; i++){ const float v = bf2f(sb[r*256 + i*64+lane]); s += v*v; }
  const float sbn2 = wred(s);
  float A[8], Bv[8];
#pragma unroll
  for (int i = 0; i < 8; i++){ A[i]  = mxa[(long)rloc*512 + i*64+lane];
                               Bv[i] = mxb[(long)rloc*512 + i*64+lane]; }
  float pan2, pbn2;
  { const float n2 = wred(sq_part<8>(A));  mt_project<8>(A,  n2, sfn2, &pan2); }
  { const float n2 = wred(sq_part<8>(Bv)); mt_project<8>(Bv, n2, sbn2, &pbn2); }
  const float xy = wred(dot_part<8>(A, Bv));
  float M1[8]; madd_vec<8>(A, pan2, Bv, pbn2, xy, M1);
  const float m1n2 = wred(sq_part<8>(M1));
  float Cb[8];
#pragma unroll
  for (int i = 0; i < 8; i++) Cb[i] = ccb[i*64+lane];
  const float cb2 = wred(sq_part<8>(Cb));
  const float xyb = wred(dot_part<8>(M1, Cb));
  float M2[8]; madd_vec<8>(M1, m1n2, Cb, cb2, xyb, M2);
  float m2n2 = wred(sq_part<8>(M2));
  project_vec<8>(M2, &m2n2);
#pragma unroll
  for (int i = 0; i < 8; i++) ctxo[r*512 + i*64+lane] = f2bf(M2[i]);
}

// attn_emb = madd(ctx(bf16), pe) -> BF16 out + sqn of rounded
__global__ __launch_bounds__(256) void attn_add(const unsigned short* __restrict__ ctxv,
    const int* __restrict__ pos, const float* __restrict__ pet,
    unsigned short* __restrict__ oemb, float* __restrict__ osqn)
{
  const int wv = threadIdx.x >> 6, lane = threadIdx.x & 63;
  const long r = blockIdx.x*4 + wv;
  float X[8];
#pragma unroll
  for (int i = 0; i < 8; i++) X[i] = bf2f(ctxv[r*512 + i*64+lane]);
  const float x2 = wred(sq_part<8>(X));
  const int p = pos[r];
  float Y[8];
#pragma unroll
  for (int i = 0; i < 8; i++) Y[i] = pet[(long)p*512 + i*64+lane];
  const float y2 = wred(sq_part<8>(Y));
  const float xy = wred(dot_part<8>(X, Y));
  float O[8]; madd_vec<8>(X, x2, Y, y2, xy, O);
  float s = 0.f;
#pragma unroll
  for (int i = 0; i < 8; i++){
    const unsigned short u = f2bf(O[i]);
    oemb[r*512 + i*64+lane] = u;
    const float rv = bf2f(u);
    s += rv*rv;
  }
  s = wred(s);
  if (lane == 0) osqn[r] = s;
}

// mention variant (bf16 out)
__global__ __launch_bounds__(256) void attn_add_m(const float* __restrict__ mvv,
    const int* __restrict__ mentions, const float* __restrict__ pet,
    unsigned short* __restrict__ oemb, float* __restrict__ osqn)
{
  const int wv = threadIdx.x >> 6, lane = threadIdx.x & 63;
  const long r = blockIdx.x*4 + wv;
  float X[8];
#pragma unroll
  for (int i = 0; i < 8; i++) X[i] = mvv[r*512 + i*64+lane];
  const float x2 = wred(sq_part<8>(X));
  const int men = mentions[r];
  const int p = (men > 0) ? (int)(r & 7) + 1 : 0;
  float Y[8];
#pragma unroll
  for (int i = 0; i < 8; i++) Y[i] = pet[(long)p*512 + i*64+lane];
  const float y2 = wred(sq_part<8>(Y));
  const float xy = wred(dot_part<8>(X, Y));
  float O[8]; madd_vec<8>(X, x2, Y, y2, xy, O);
  float s = 0.f;
#pragma unroll
  for (int i = 0; i < 8; i++){
    const unsigned short u = f2bf(O[i]);
    oemb[r*512 + i*64+lane] = u;
    const float rv = bf2f(u);
    s += rv*rv;
  }
  s = wred(s);
  if (lane == 0) osqn[r] = s;
}

// q/k projection + pdist (unchanged)
__global__ __launch_bounds__(256) void qk_pdist(const float* __restrict__ mxq,
    const float* __restrict__ mxk, const float* __restrict__ sqn,
    const float* __restrict__ bq, const float* __restrict__ bk,
    float* __restrict__ dout)
{
  const int wv = threadIdx.x >> 6, lane = threadIdx.x & 63;
  const int r = blockIdx.x*4 + wv;
  const float xn2 = sqn[r];
  float Q[8];
#pragma unroll
  for (int i = 0; i < 8; i++) Q[i] = mxq[(long)r*512 + i*64+lane];
  { const float n2 = wred(sq_part<8>(Q)); float pn2; mt_project<8>(Q, n2, xn2, &pn2);
    float Bq[8];
#pragma unroll
    for (int i = 0; i < 8; i++) Bq[i] = bq[i*64+lane];
    const float b2 = wred(sq_part<8>(Bq));
    const float xy = wred(dot_part<8>(Q, Bq));
    float O[8]; madd_vec<8>(Q, pn2, Bq, b2, xy, O);
#pragma unroll
    for (int i = 0; i < 8; i++) Q[i] = O[i];
  }
  float qn2 = wred(sq_part<8>(Q));
  project_vec<8>(Q, &qn2);
  float Kv[8];
#pragma unroll
  for (int i = 0; i < 8; i++) Kv[i] = mxk[(long)r*512 + i*64+lane];
  { const float n2 = wred(sq_part<8>(Kv)); float pn2; mt_project<8>(Kv, n2, xn2, &pn2);
    float Bk[8];
#pragma unroll
    for (int i = 0; i < 8; i++) Bk[i] = bk[i*64+lane];
    const float b2 = wred(sq_part<8>(Bk));
    const float xy = wred(dot_part<8>(Kv, Bk));
    float O[8]; madd_vec<8>(Kv, pn2, Bk, b2, xy, O);
#pragma unroll
    for (int i = 0; i < 8; i++) Kv[i] = O[i];
  }
  float kn2 = wred(sq_part<8>(Kv));
  project_vec<8>(Kv, &kn2);
  float NQ[8];
#pragma unroll
  for (int i = 0; i < 8; i++) NQ[i] = -Q[i];
  const float xy = wred(dot_part<8>(NQ, Kv));
  float Z[8]; madd_vec<8>(NQ, qn2, Kv, kn2, xy, Z);
  const float zn2 = wred(sq_part<8>(Z));
  const float d = 2.f * atanhf(clamp11(snorm(zn2)));
  if (lane == 0) dout[r] = d;
}

__global__ __launch_bounds__(256) void softmax128(const float* __restrict__ d,
    const float* __restrict__ beta, float* __restrict__ w)
{
  const int wv = threadIdx.x >> 6, lane = threadIdx.x & 63;
  const int b = blockIdx.x*4 + wv;
  const float bt = beta[0];
  const float x0 = -bt * d[b*128 + lane];
  const float x1 = -bt * d[b*128 + 64 + lane];
  const float m = wredmax(fmaxf(x0, x1));
  const float e0 = expf(x0 - m), e1 = expf(x1 - m);
  const float s = wred(e0 + e1);
  w[b*128 + lane]      = e0 / s;
  w[b*128 + 64 + lane] = e1 / s;
}

__global__ void softmax8(const float* __restrict__ d, const float* __restrict__ beta,
                         float* __restrict__ w)
{
  const int b = threadIdx.x;   // 256
  const float bt = beta[0];
  float x[8]; float m = -1e30f;
#pragma unroll
  for (int i = 0; i < 8; i++){ x[i] = -bt * d[b*8+i]; m = fmaxf(m, x[i]); }
  float s = 0.f;
#pragma unroll
  for (int i = 0; i < 8; i++){ x[i] = expf(x[i]-m); s += x[i]; }
#pragma unroll
  for (int i = 0; i < 8; i++) w[b*8+i] = x[i] / s;
}

// weighted gyromidpoint via Klein model; one wave per batch row (small Lseq)
template<int NPL, bool BF16V, bool HASW>
__global__ __launch_bounds__(256) void midpoint_kernel(const void* __restrict__ vals,
    const float* __restrict__ wts, float* __restrict__ outp, int Lseq)
{
  const int wv = threadIdx.x >> 6, lane = threadIdx.x & 63;
  const int b = blockIdx.x*4 + wv;
  const int D = NPL*64;
  float num[NPL];
#pragma unroll
  for (int i = 0; i < NPL; i++) num[i] = 0.f;
  float den = 0.f;
  for (int l = 0; l < Lseq; l++){
    const long base = ((long)b*Lseq + l)*D;
    float v[NPL]; float s = 0.f;
#pragma unroll
    for (int i = 0; i < NPL; i++){
      v[i] = BF16V ? bf2f(((const unsigned short*)vals)[base + i*64+lane])
                   : ((const float*)vals)[base + i*64+lane];
      s += v[i]*v[i];
    }
    const float v2 = wred(s);
    const float f = 2.f/(1.f + v2);
    const float kl2 = v2*f*f;
    const float gamma = 1.f/sqrtf(fmaxf(1.f - kl2, EPS_));
    const float wgt = HASW ? wts[b*Lseq + l] : 1.f;
    const float wg = wgt*gamma;
#pragma unroll
    for (int i = 0; i < NPL; i++) num[i] += wg*(f*v[i]);
    den += wg;
  }
  den = fmaxf(den, EPS_);
  float x[NPL]; float s = 0.f;
#pragma unroll
  for (int i = 0; i < NPL; i++){ x[i] = num[i]/den; s += x[i]*x[i]; }
  const float k2 = wred(s);
  const float inv = 1.f/(1.f + sqrtf(fmaxf(1.f - k2, EPS_)));
#pragma unroll
  for (int i = 0; i < NPL; i++) outp[(long)b*D + i*64+lane] = x[i]*inv;
}

// wide gyromidpoint for ctx (unchanged)
__global__ __launch_bounds__(512) void midpoint_wide(
    const unsigned short* __restrict__ vals,
    const float* __restrict__ wts,
    float* __restrict__ outp)
{
  __shared__ float pnum[8][512];
  __shared__ float pden[8];
  __shared__ float red[512];
  __shared__ float kk2[1];
  const int b = blockIdx.x;
  const int tid = threadIdx.x;
  const int w = tid >> 6, lane = tid & 63;
  float num[8] = {0.f,0.f,0.f,0.f,0.f,0.f,0.f,0.f};
  float den = 0.f;
  for (int l = w; l < 128; l += 8){
    const long base = ((long)b*128 + l)*512;
    float v[8]; float s = 0.f;
#pragma unroll
    for (int i = 0; i < 8; i++){
      v[i] = bf2f(vals[base + i*64 + lane]);
      s += v[i]*v[i];
    }
    const float v2 = wred(s);
    const float f = 2.f/(1.f + v2);
    const float kl2 = v2*f*f;
    const float gamma = 1.f/sqrtf(fmaxf(1.f - kl2, EPS_));
    const float wg = wts[b*128 + l]*gamma;
#pragma unroll
    for (int i = 0; i < 8; i++) num[i] += wg*(f*v[i]);
    den += wg;
  }
#pragma unroll
  for (int i = 0; i < 8; i++) pnum[w][i*64 + lane] = num[i];
  if (lane == 0) pden[w] = den;
  __syncthreads();
  float nsum = 0.f, dsum = 0.f;
#pragma unroll
  for (int p = 0; p < 8; p++){ nsum += pnum[p][tid]; dsum += pden[p]; }
  dsum = fmaxf(dsum, EPS_);
  const float x = nsum/dsum;
  red[tid] = x*x;
  __syncthreads();
  if (tid < 64){
    float s2 = 0.f;
#pragma unroll
    for (int i = 0; i < 8; i++) s2 += red[tid + i*64];
    s2 = wred(s2);
    if (tid == 0) kk2[0] = s2;
  }
  __syncthreads();
  const float k2 = kk2[0];
  const float inv = 1.f/(1.f + sqrtf(fmaxf(1.f - k2, EPS_)));
  outp[(long)b*512 + tid] = x*inv;
}

// mention w2s mobius_linear with tanh nonlinearity (unchanged)
__global__ __launch_bounds__(256) void mv_rowwise(const float* __restrict__ mx,
    const float* __restrict__ xsqn, const float* __restrict__ bb, float* __restrict__ outp)
{
  const int wv = threadIdx.x >> 6, lane = threadIdx.x & 63;
  const long r = blockIdx.x*4 + wv;
  float M[8];
#pragma unroll
  for (int i = 0; i < 8; i++) M[i] = mx[r*512 + i*64+lane];
  { const float n2 = wred(sq_part<8>(M)); float pn2; mt_project<8>(M, n2, xsqn[r], &pn2);
    float Bv[8];
#pragma unroll
    for (int i = 0; i < 8; i++) Bv[i] = bb[i*64+lane];
    const float b2 = wred(sq_part<8>(Bv));
    const float xy = wred(dot_part<8>(M, Bv));
    float O[8]; madd_vec<8>(M, pn2, Bv, b2, xy, O);
#pragma unroll
    for (int i = 0; i < 8; i++) M[i] = O[i];
  }
  float on2 = wred(sq_part<8>(M));
  project_vec<8>(M, &on2);
  { const float n = snorm(on2);
    const float fac = atanhf(clamp11(n))/n;
#pragma unroll
    for (int i = 0; i < 8; i++) M[i] = tanhf(fac*M[i]); }
  const float un2 = wred(sq_part<8>(M));
  { const float n = snorm(un2);
    const float fac = tanhf(n)/n;
    float en2 = fac*fac*un2;
#pragma unroll
    for (int i = 0; i < 8; i++) M[i] *= fac;
    project_vec<8>(M, &en2); }
#pragma unroll
  for (int i = 0; i < 8; i++) outp[r*512 + i*64+lane] = M[i];
}

// joint concat (unchanged)
__global__ __launch_bounds__(256) void final_rowwise(const float* __restrict__ jm,
    const float* __restrict__ jc, const float* __restrict__ jch,
    const float* __restrict__ mvec, const float* __restrict__ cvec,
    const float* __restrict__ chvec, const float* __restrict__ fcb,
    float* __restrict__ joint)
{
  const int wv = threadIdx.x >> 6, lane = threadIdx.x & 63;
  const long b = blockIdx.x*4 + wv;
  float s;
  s = 0.f; for (int i = 0; i < 8; i++){ const float v = mvec[b*512 + i*64+lane]; s += v*v; }
  const float mn2 = wred(s);
  s = 0.f; for (int i = 0; i < 8; i++){ const float v = cvec[b*512 + i*64+lane]; s += v*v; }
  const float cn2 = wred(s);
  s = 0.f; for (int i = 0; i < 4; i++){ const float v = chvec[b*256 + i*64+lane]; s += v*v; }
  const float chn2 = wred(s);
  float A[20];
#pragma unroll
  for (int i = 0; i < 20; i++) A[i] = jm[b*1280 + i*64+lane];
  float an2;
  { const float n2 = wred(sq_part<20>(A)); mt_project<20>(A, n2, mn2, &an2); }
  float T[20];
#pragma unroll
  for (int i = 0; i < 20; i++) T[i] = jc[b*1280 + i*64+lane];
  float tn2;
  { const float n2 = wred(sq_part<20>(T)); mt_project<20>(T, n2, cn2, &tn2); }
  { const float xy = wred(dot_part<20>(A, T));
    float O[20]; madd_vec<20>(A, an2, T, tn2, xy, O);
#pragma unroll
    for (int i = 0; i < 20; i++) A[i] = O[i];
    an2 = wred(sq_part<20>(A)); }
#pragma unroll
  for (int i = 0; i < 20; i++) T[i] = jch[b*1280 + i*64+lane];
  { const float n2 = wred(sq_part<20>(T)); mt_project<20>(T, n2, chn2, &tn2); }
  { const float xy = wred(dot_part<20>(A, T));
    float O[20]; madd_vec<20>(A, an2, T, tn2, xy, O);
#pragma unroll
    for (int i = 0; i < 20; i++) A[i] = O[i];
    an2 = wred(sq_part<20>(A)); }
#pragma unroll
  for (int i = 0; i < 20; i++) T[i] = fcb[i*64+lane];
  tn2 = wred(sq_part<20>(T));
  { const float xy = wred(dot_part<20>(A, T));
    float O[20]; madd_vec<20>(A, an2, T, tn2, xy, O);
#pragma unroll
    for (int i = 0; i < 20; i++) A[i] = O[i];
    an2 = wred(sq_part<20>(A)); }
  project_vec<20>(A, &an2);
#pragma unroll
  for (int i = 0; i < 20; i++) joint[b*1280 + i*64+lane] = A[i];
}

// hyperbolic MLR head (unchanged)
__global__ __launch_bounds__(256) void mlr_kernel(const float* __restrict__ joint,
    const float* __restrict__ P, const float* __restrict__ A, float* __restrict__ outp)
{
  const int wv = threadIdx.x >> 6, lane = threadIdx.x & 63;
  const int pair = blockIdx.x*4 + wv;
  const long b = pair >> 7, c = pair & 127;
  float Pv[20], J[20];
#pragma unroll
  for (int i = 0; i < 20; i++){
    Pv[i] = -P[c*1280 + i*64+lane];
    J[i]  = joint[b*1280 + i*64+lane];
  }
  const float p2 = wred(sq_part<20>(Pv));
  const float j2 = wred(sq_part<20>(J));
  const float xy = wred(dot_part<20>(Pv, J));
  float Z[20]; madd_vec<20>(Pv, p2, J, j2, xy, Z);
  float sza = 0.f, sz2 = 0.f, sa2 = 0.f;
#pragma unroll
  for (int i = 0; i < 20; i++){
    const float a = A[c*1280 + i*64+lane];
    sza += Z[i]*a; sz2 += Z[i]*Z[i]; sa2 += a*a;
  }
  float za = sza, z2 = sz2, a2 = sa2;
  wred3(za, z2, a2);
  const float an = sqrtf(fmaxf(a2, EPS_));
  const float v = 2.f*za / (fmaxf(1.f - z2, EPS_)*an);
  if (lane == 0) outp[pair] = 2.f*an*asinhf(v);
}

// ---------------------------------------------------------------------------
extern "C" void kernel_launch(void* const* d_in, const int* in_sizes, int n_in,
                              void* d_out, int out_size, void* d_ws, size_t ws_size,
                              hipStream_t stream)
{
  (void)in_sizes; (void)n_in; (void)out_size;
  const int*   context   = (const int*)  d_in[0];
  const int*   ctx_position=(const int*) d_in[1];
  const int*   mentions  = (const int*)  d_in[2];
  const int*   mchars    = (const int*)  d_in[3];
  const float* word_lut  = (const float*)d_in[4];
  const float* char_lut  = (const float*)d_in[5];
  const float* gf_Wih    = (const float*)d_in[6];
  const float* gf_Whh    = (const float*)d_in[7];
  const float* gf_b      = (const float*)d_in[8];
  const float* gb_Wih    = (const float*)d_in[9];
  const float* gb_Whh    = (const float*)d_in[10];
  const float* gb_b      = (const float*)d_in[11];
  const float* w2s_W     = (const float*)d_in[12];
  const float* w2s_b     = (const float*)d_in[13];
  const float* men_pos   = (const float*)d_in[14];
  const float* men_Wq    = (const float*)d_in[15];
  const float* men_bq    = (const float*)d_in[16];
  const float* men_Wk    = (const float*)d_in[17];
  const float* men_bk    = (const float*)d_in[18];
  const float* men_beta  = (const float*)d_in[19];
  const float* char_W    = (const float*)d_in[20];
  const float* char_U    = (const float*)d_in[21];
  const float* char_b    = (const float*)d_in[22];
  const float* cc_Wa     = (const float*)d_in[23];
  const float* cc_Wb     = (const float*)d_in[24];
  const float* cc_bias   = (const float*)d_in[25];
  const float* ctx_pos_t = (const float*)d_in[26];
  const float* ctx_Wq    = (const float*)d_in[27];
  const float* ctx_bq    = (const float*)d_in[28];
  const float* ctx_Wk    = (const float*)d_in[29];
  const float* ctx_bk    = (const float*)d_in[30];
  const float* ctx_beta  = (const float*)d_in[31];
  const float* fc_Wm     = (const float*)d_in[32];
  const float* fc_Wc     = (const float*)d_in[33];
  const float* fc_Wch    = (const float*)d_in[34];
  const float* fc_bias   = (const float*)d_in[35];
  const float* mlr_p     = (const float*)d_in[36];
  const float* mlr_a     = (const float*)d_in[37];
  float* out = (float*)d_out;

  // ---- workspace bump allocator ----
  char* wsb = (char*)d_ws;
  size_t off = 0;
  auto alloc = [&](size_t bytes) -> void* {
    void* p = wsb + off;
    off += (bytes + 255) & ~(size_t)255;
    return p;
  };
  float* WtHH = (float*)alloc(2UL*256*768*4);
  unsigned short* Wrz16 = (unsigned short*)alloc(2UL*256*512*2);
  unsigned short* Wh16  = (unsigned short*)alloc(2UL*256*256*2);
  unsigned short* WihP  = (unsigned short*)alloc(2UL*768*320*2);
  unsigned short* ctxWqP= (unsigned short*)alloc(512UL*512*2);
  unsigned short* ctxWkP= (unsigned short*)alloc(512UL*512*2);
  unsigned short* ccWaP = (unsigned short*)alloc(512UL*256*2);
  unsigned short* ccWbP = (unsigned short*)alloc(512UL*256*2);
  unsigned short* menWqP= (unsigned short*)alloc(512UL*512*2);
  unsigned short* menWkP= (unsigned short*)alloc(512UL*512*2);
  unsigned short* w2sP  = (unsigned short*)alloc(512UL*320*2);
  unsigned short* charUP= (unsigned short*)alloc(256UL*256*2);
  int*   ctxidx = (int*)alloc(32768UL*4);
  int*   chidx  = (int*)alloc(4096UL*4);
  float* xsqn   = (float*)alloc(32768UL*4);
  float* msqn   = (float*)alloc(2048UL*4);
  float* chsqn  = (float*)alloc(4096UL*4);
  unsigned short* xg = (unsigned short*)alloc(2UL*32768*768*2);
  float* xgn2 = (float*)alloc(2UL*32768*3*4);
  float* chn2d = (float*)alloc(4096UL*4);
  unsigned short* states_f = (unsigned short*)alloc(32768UL*256*2);
  unsigned short* states_b = (unsigned short*)alloc(32768UL*256*2);
  unsigned short* ctxv = (unsigned short*)alloc(32768UL*512*2);
  float* attn_sqn = (float*)alloc(32768UL*4);
  float* dctx = (float*)alloc(32768UL*4);
  float* wctx = (float*)alloc(32768UL*4);
  float* ctx_vec = (float*)alloc(256UL*512*4);
  float* mxbuf = (float*)alloc(2UL*8192*512*4);
  float* mv = (float*)alloc(2048UL*512*4);
  unsigned short* attn_embm = (unsigned short*)alloc(2048UL*512*2);
  float* amsqn = (float*)alloc(2048UL*4);
  float* dm = (float*)alloc(2048UL*4);
  float* wm = (float*)alloc(2048UL*4);
  float* mention_vec = (float*)alloc(256UL*512*4);
  unsigned short* xgc = (unsigned short*)alloc(4096UL*256*2);
  float* char_states = (float*)alloc(4096UL*256*4);
  float* char_vec = (float*)alloc(256UL*256*4);
  float* joint = (float*)alloc(256UL*1280*4);
  if (off > ws_size) return;
  unsigned short* attn_embc = xg;                  // overlay: xg dead after GRU
  float* mxh0 = mxbuf;
  float* mxh1 = mxbuf + 8192UL*512;

  // ---- weight transposes + bf16 packs ----
  transpose_k<<<dim3(8,24), 256,0,stream>>>(gf_Whh, WtHH,            768, 256);
  transpose_k<<<dim3(8,24), 256,0,stream>>>(gb_Whh, WtHH + 256*768,  768, 256);
  pack_whh16<<<1536,256,0,stream>>>(WtHH, Wrz16, Wh16);
  pack_wih<<<1920,256,0,stream>>>(gf_Wih, gb_Wih, WihP);
  packT16<<<dim3(16,16),256,0,stream>>>(ctx_Wq, ctxWqP, 512, 512, 512);
  packT16<<<dim3(16,16),256,0,stream>>>(ctx_Wk, ctxWkP, 512, 512, 512);
  packT16<<<dim3(8,16), 256,0,stream>>>(cc_Wa,  ccWaP,  256, 512, 256);
  packT16<<<dim3(8,16), 256,0,stream>>>(cc_Wb,  ccWbP,  256, 512, 256);
  packT16<<<dim3(16,16),256,0,stream>>>(men_Wq, menWqP, 512, 512, 512);
  packT16<<<dim3(16,16),256,0,stream>>>(men_Wk, menWkP, 512, 512, 512);
  packT16<<<dim3(10,16),256,0,stream>>>(w2s_W,  w2sP,   300, 512, 320);
  packT16<<<dim3(8,8),  256,0,stream>>>(char_U, charUP, 256, 256, 256);

  // ---- gather indices + input sqn ----
  build_idx<<<144,256,0,stream>>>(context, mchars, ctxidx, chidx);
  sqn_gather<<<8192,256,0,stream>>>(word_lut, ctxidx, 300, xsqn);
  sqn_gather<<<512, 256,0,stream>>>(word_lut, mentions, 300, msqn);
  sqn_gather<<<1024,256,0,stream>>>(char_lut, chidx, 256, chsqn);

  // ---- GRU input precompute: xg[dir] = mobius_matvec(emb, Wih^T), bf16 ----
  for (int d2 = 0; d2 < 2; d2++){
    const unsigned short* wihp = WihP + (size_t)d2*768*320;
    for (int c = 0; c < 4; c++){
      mfma_mm<1><<<dim3(6,64),256,0,stream>>>(word_lut, ctxidx + c*8192, wihp,
                                              mxbuf, 8192, 768, 300, 320);
      xg_transform<<<6144,256,0,stream>>>(mxbuf, xsqn + c*8192,
          xg + ((size_t)d2*32768 + (size_t)c*8192)*768,
          xgn2 + ((size_t)d2*32768 + (size_t)c*8192)*3, 3);
    }
  }

  // ---- bidirectional Mobius GRU (pipelined v8) ----
  (void)hipFuncSetAttribute((const void*)gru_kernel,
      hipFuncAttributeMaxDynamicSharedMemorySize, GRU_LDS_BYTES);
  gru_kernel<<<256,512,GRU_LDS_BYTES,stream>>>(xg, xgn2, Wrz16, Wh16,
                                               gf_b, gb_b, states_f, states_b);

  // ---- mobius concat of directions -> ctx (bf16) ----
  for (int c = 0; c < 4; c++){
    mfma_mm<2><<<dim3(4,64),256,0,stream>>>(states_f + (size_t)c*8192*256, nullptr,
                                            ccWaP, mxh0, 8192, 512, 256, 256);
    mfma_mm<2><<<dim3(4,64),256,0,stream>>>(states_b + (size_t)c*8192*256, nullptr,
                                            ccWbP, mxh1, 8192, 512, 256, 256);
    cc_rowwise<<<2048,256,0,stream>>>(states_f, states_b, mxh0, mxh1, cc_bias,
                                      ctxv, c*8192);
  }

  // ---- context distance attention ----
  attn_add<<<8192,256,0,stream>>>(ctxv, ctx_position, ctx_pos_t, attn_embc, attn_sqn);
  for (int c = 0; c < 4; c++){
    mfma_mm<2><<<dim3(4,64),256,0,stream>>>(attn_embc + (size_t)c*8192*512, nullptr,
                                            ctxWqP, mxh0, 8192, 512, 512, 512);
    mfma_mm<2><<<dim3(4,64),256,0,stream>>>(attn_embc + (size_t)c*8192*512, nullptr,
                                            ctxWkP, mxh1, 8192, 512, 512, 512);
    qk_pdist<<<2048,256,0,stream>>>(mxh0, mxh1, attn_sqn + c*8192, ctx_bq, ctx_bk,
                                    dctx + c*8192);
  }
  softmax128<<<64,256,0,stream>>>(dctx, ctx_beta, wctx);
  midpoint_wide<<<256,512,0,stream>>>(ctxv, wctx, ctx_vec);

  // ---- mention encoder ----
  mfma_mm<1><<<dim3(4,16),256,0,stream>>>(word_lut, mentions, w2sP, mxh0,
                                          2048, 512, 300, 320);
  mv_rowwise<<<512,256,0,stream>>>(mxh0, msqn, w2s_b, mv);
  attn_add_m<<<512,256,0,stream>>>(mv, mentions, men_pos, attn_embm, amsqn);
  mfma_mm<2><<<dim3(4,16),256,0,stream>>>(attn_embm, nullptr, menWqP, mxh0,
                                          2048, 512, 512, 512);
  mfma_mm<2><<<dim3(4,16),256,0,stream>>>(attn_embm, nullptr, menWkP, mxh1,
                                          2048, 512, 512, 512);
  qk_pdist<<<512,256,0,stream>>>(mxh0, mxh1, amsqn, men_bq, men_bk, dm);
  softmax8<<<1,256,0,stream>>>(dm, men_beta, wm);
  midpoint_kernel<8,false,true><<<64,256,0,stream>>>(mv, wm, mention_vec, 8);

  // ---- char encoder ----
  mfma_mm<1><<<dim3(2,32),256,0,stream>>>(char_lut, chidx, charUP, mxh0,
                                          4096, 256, 256, 256);
  xg_transform<<<1024,256,0,stream>>>(mxh0, chsqn, xgc, chn2d, 1);
  char_rnn<<<64,256,0,stream>>>(xgc, char_W, char_b, char_states);
  midpoint_kernel<4,false,false><<<64,256,0,stream>>>(char_states, nullptr, char_vec, 16);

  // ---- full mobius concat + MLR (small, f32 path) ----
  float* jm = mxh0;
  float* jc = mxh0 + 256UL*1280;
  float* jch = mxh0 + 2UL*256*1280;
  mm_kernel<0><<<dim3(10,2),256,0,stream>>>(mention_vec, nullptr, fc_Wm, jm, 256, 1280, 512);
  mm_kernel<0><<<dim3(10,2),256,0,stream>>>(ctx_vec,     nullptr, fc_Wc, jc, 256, 1280, 512);
  mm_kernel<0><<<dim3(10,2),256,0,stream>>>(char_vec,    nullptr, fc_Wch, jch, 256, 1280, 256);
  final_rowwise<<<64,256,0,stream>>>(jm, jc, jch, mention_vec, ctx_vec, char_vec,
                                     fc_bias, joint);
  mlr_kernel<<<8192,256,0,stream>>>(joint, mlr_p, mlr_a, out);
}

// Round 10
// 2736.919 us; speedup vs baseline: 1.0969x; 1.0969x over previous
//
#include <hip/hip_runtime.h>
#include <cstddef>
#include <cstdint>

// ---------------------------------------------------------------------------
// Hyperbolic (Poincare-ball) entity-typing forward pass, MI355X / gfx950.
// Round 10: GRU reverted to round-8 v7 (measured 1700us). mfma_mm re-tiled
// to 64x128 (2+ blocks/CU so barrier stalls overlap across blocks).
// ---------------------------------------------------------------------------

#define EPS_  1e-15f
#define PMAX_ 0.99999f    // 1 - 1e-5

typedef __attribute__((ext_vector_type(8))) short bf16x8;
typedef __attribute__((ext_vector_type(4))) float f32x4;
typedef __attribute__((ext_vector_type(8))) unsigned short us8;

__device__ __forceinline__ float wred(float v){
#pragma unroll
  for (int o = 32; o; o >>= 1) v += __shfl_xor(v, o, 64);
  return v;
}
__device__ __forceinline__ void wred2(float& a, float& b){
#pragma unroll
  for (int o = 32; o; o >>= 1){ a += __shfl_xor(a, o, 64); b += __shfl_xor(b, o, 64); }
}
__device__ __forceinline__ void wred3(float& a, float& b, float& c){
#pragma unroll
  for (int o = 32; o; o >>= 1){
    a += __shfl_xor(a, o, 64); b += __shfl_xor(b, o, 64); c += __shfl_xor(c, o, 64);
  }
}
__device__ __forceinline__ void wred4(float& a, float& b, float& c, float& d){
#pragma unroll
  for (int o = 32; o; o >>= 1){
    a += __shfl_xor(a, o, 64); b += __shfl_xor(b, o, 64);
    c += __shfl_xor(c, o, 64); d += __shfl_xor(d, o, 64);
  }
}
__device__ __forceinline__ float wredmax(float v){
#pragma unroll
  for (int o = 32; o; o >>= 1) v = fmaxf(v, __shfl_xor(v, o, 64));
  return v;
}
__device__ __forceinline__ float snorm(float s){ return sqrtf(fmaxf(s, EPS_)); }
__device__ __forceinline__ float clamp11(float x){
  return fminf(fmaxf(x, -1.f + 1e-7f), 1.f - 1e-7f);
}
__device__ __forceinline__ float bf2f(unsigned short u){
  union { unsigned int i; float f; } v; v.i = ((unsigned int)u) << 16; return v.f;
}
__device__ __forceinline__ unsigned short f2bf(float f){
  union { float f; unsigned int i; } v; v.f = f;
  unsigned int x = v.i;
  x += 0x7fffu + ((x >> 16) & 1u);   // RNE
  return (unsigned short)(x >> 16);
}
__device__ __forceinline__ float bflo(unsigned u){
  union { unsigned i; float f; } v; v.i = u << 16; return v.f;
}
__device__ __forceinline__ float bfhi(unsigned u){
  union { unsigned i; float f; } v; v.i = u & 0xffff0000u; return v.f;
}

template<int N>
__device__ __forceinline__ float sq_part(const float* a){
  float s = 0.f;
#pragma unroll
  for (int i = 0; i < N; i++) s += a[i]*a[i];
  return s;
}
template<int N>
__device__ __forceinline__ float dot_part(const float* a, const float* b){
  float s = 0.f;
#pragma unroll
  for (int i = 0; i < N; i++) s += a[i]*b[i];
  return s;
}
template<int N>
__device__ __forceinline__ void madd_vec(const float* x, float x2, const float* y,
                                         float y2, float xy, float* o){
  const float c1 = 1.f + 2.f*xy + y2;
  const float c2 = 1.f - x2;
  const float inv = 1.f / fmaxf(1.f + 2.f*xy + x2*y2, EPS_);
#pragma unroll
  for (int i = 0; i < N; i++) o[i] = (c1*x[i] + c2*y[i]) * inv;
}
template<int N>
__device__ __forceinline__ void mt_project(float* v, float mxn2, float xn2, float* n2out){
  const float xn  = snorm(xn2);
  const float mxn = snorm(mxn2);
  const float t   = tanhf(mxn/xn * atanhf(clamp11(xn)));
  float sc = t/mxn;
  float n2 = sc*sc*mxn2;
  const float n = snorm(n2);
  if (n > PMAX_){ const float s = PMAX_/n; sc *= s; n2 *= s*s; }
#pragma unroll
  for (int i = 0; i < N; i++) v[i] *= sc;
  *n2out = n2;
}
__device__ __forceinline__ void mt_scale(float mxn2, float xn, float art,
                                         float* sc, float* n2){
  const float mxn = snorm(mxn2);
  const float t   = tanhf(mxn/xn * art);
  float s  = t/mxn;
  float nn = t*t;
  const float n = snorm(nn);
  if (n > PMAX_){ const float f = PMAX_/n; s *= f; nn *= f*f; }
  *sc = s; *n2 = nn;
}
template<int N>
__device__ __forceinline__ void project_vec(float* v, float* n2io){
  float n2 = *n2io;
  const float n = snorm(n2);
  if (n > PMAX_){
    const float s = PMAX_/n;
#pragma unroll
    for (int i = 0; i < N; i++) v[i] *= s;
    n2 *= s*s;
  }
  *n2io = n2;
}

// async 16B global->LDS: linear wave-uniform-base + lane*16
__device__ __forceinline__ void gll16(const void* g, void* l){
  __builtin_amdgcn_global_load_lds(
      (const __attribute__((address_space(1))) void*)g,
      (__attribute__((address_space(3))) void*)l, 16, 0, 0);
}
// stage 64KB with 512 threads (8 waves x 8 x 16B/lane), linear layout
__device__ __forceinline__ void stage64k8(const void* gsrc, float* lbase, int w, int lane){
#pragma unroll
  for (int i = 0; i < 8; i++){
    const char* g = (const char*)gsrc + (size_t)((i*8 + w)*64 + lane)*16;
    char* l = (char*)lbase + (size_t)((i*8 + w)*64)*16;
    gll16(g, l);
  }
}

// ---------------------------------------------------------------------------
// MFMA bf16 GEMM: C[M,N] = A[M,K] @ B[K,N], B pre-packed as B^T bf16 [N][Kp].
// Tile 64x128, BK=32; 4 waves each own a 32x64 quadrant (2x4 fragments).
// M mult of 64, N mult of 128. Grid (N/128, M/64) -> 2+ blocks/CU.
// ---------------------------------------------------------------------------
template<int AMODE>
__global__ __launch_bounds__(256) void mfma_mm(const void* __restrict__ Aptr,
    const int* __restrict__ idx, const unsigned short* __restrict__ Bt,
    float* __restrict__ Cm, int M, int N, int K, int Kp)
{
  __shared__ __align__(16) unsigned short As[64][40];
  __shared__ __align__(16) unsigned short Bs[128][40];
  const int tid = threadIdx.x;
  const int n0 = blockIdx.x * 128;
  const int m0 = blockIdx.y * 64;
  const int arow_s = tid >> 2, aq = tid & 3;    // A: 64 rows x 4 quarters (8 k each)
  const int brow_s = tid >> 1, bhf = tid & 1;   // B: 128 rows x 2 halves (16 k each)
  const int wv = tid >> 6, lane = tid & 63;
  const int wm = wv >> 1, wn = wv & 1;
  const int lr = lane & 15, lk = lane >> 4;

  long arow;
  if constexpr (AMODE == 1) arow = (long)idx[m0 + arow_s] * K;
  else                      arow = (long)(m0 + arow_s) * K;

  f32x4 acc[2][4];
#pragma unroll
  for (int mf = 0; mf < 2; mf++)
#pragma unroll
    for (int nf = 0; nf < 4; nf++) acc[mf][nf] = (f32x4){0.f,0.f,0.f,0.f};

  for (int k0 = 0; k0 < Kp; k0 += 32){
    // ---- A: 8 bf16 per thread ----
    const int kbA = k0 + aq*8;
    unsigned short av[8];
    if constexpr (AMODE == 1){
      const float* ar = (const float*)Aptr + arow;
      if (kbA + 8 <= K){
        const float4 f0 = *(const float4*)(ar + kbA);
        const float4 f1 = *(const float4*)(ar + kbA + 4);
        av[0]=f2bf(f0.x); av[1]=f2bf(f0.y); av[2]=f2bf(f0.z); av[3]=f2bf(f0.w);
        av[4]=f2bf(f1.x); av[5]=f2bf(f1.y); av[6]=f2bf(f1.z); av[7]=f2bf(f1.w);
      } else {
#pragma unroll
        for (int v = 0; v < 8; v++){
          const int col = kbA + v;
          av[v] = (col < K) ? f2bf(ar[col]) : (unsigned short)0;
        }
      }
    } else {
      const us8 u0 = *(const us8*)((const unsigned short*)Aptr + arow + kbA);
#pragma unroll
      for (int v = 0; v < 8; v++) av[v] = u0[v];
    }
    // ---- B: 16 bf16 per thread ----
    unsigned short bvv[16];
    {
      const unsigned short* br = Bt + (long)(n0 + brow_s)*Kp + k0 + bhf*16;
      const us8 u0 = *(const us8*)br;
      const us8 u1 = *(const us8*)(br + 8);
#pragma unroll
      for (int v = 0; v < 8; v++){ bvv[v] = u0[v]; bvv[8+v] = u1[v]; }
    }
    __syncthreads();                    // previous compute done, LDS free
    *(us8*)&As[arow_s][aq*8] = *(const us8*)&av[0];
    *(us8*)&Bs[brow_s][bhf*16]   = *(const us8*)&bvv[0];
    *(us8*)&Bs[brow_s][bhf*16+8] = *(const us8*)&bvv[8];
    __syncthreads();
    bf16x8 af[2], bfr[4];
#pragma unroll
    for (int mf = 0; mf < 2; mf++)
      af[mf] = *(const bf16x8*)&As[wm*32 + mf*16 + lr][lk*8];
#pragma unroll
    for (int nf = 0; nf < 4; nf++)
      bfr[nf] = *(const bf16x8*)&Bs[wn*64 + nf*16 + lr][lk*8];
#pragma unroll
    for (int mf = 0; mf < 2; mf++)
#pragma unroll
      for (int nf = 0; nf < 4; nf++)
        acc[mf][nf] = __builtin_amdgcn_mfma_f32_16x16x32_bf16(af[mf], bfr[nf],
                                                              acc[mf][nf], 0, 0, 0);
  }
  // epilogue: D row=(lane>>4)*4+reg, col=lane&15 per fragment
#pragma unroll
  for (int mf = 0; mf < 2; mf++){
#pragma unroll
    for (int nf = 0; nf < 4; nf++){
#pragma unroll
      for (int r = 0; r < 4; r++){
        const long grow = m0 + wm*32 + mf*16 + lk*4 + r;
        Cm[grow*N + n0 + wn*64 + nf*16 + lr] = acc[mf][nf][r];
      }
    }
  }
}

// ---------------------------------------------------------------------------
// Generic tiled f32 GEMM (small fc GEMMs only)
// ---------------------------------------------------------------------------
template<int AMODE>
__global__ __launch_bounds__(256) void mm_kernel(const void* __restrict__ Aptr,
    const int* __restrict__ idx, const float* __restrict__ Bm,
    float* __restrict__ Cm, int M, int N, int K)
{
  __shared__ __align__(16) float As[8][128];
  __shared__ __align__(16) float Bs[8][132];
  const int tid = threadIdx.x;
  const int n0 = blockIdx.x * 128;
  const int m0 = blockIdx.y * 128;
  const int tr = tid >> 4, tc = tid & 15;
  const int sm = tid & 127, sk = (tid >> 7) * 4;
  const int bk = tid >> 5,  bn = (tid & 31) * 4;
  long arow;
  if constexpr (AMODE == 1) arow = (long)idx[m0 + sm] * K;
  else                      arow = (long)(m0 + sm) * K;
  float acc[8][8];
#pragma unroll
  for (int i = 0; i < 8; i++)
#pragma unroll
    for (int j = 0; j < 8; j++) acc[i][j] = 0.f;

  for (int k0 = 0; k0 < K; k0 += 8){
    float av[4], bv[4];
    {
      const float* A = (const float*)Aptr;
      if (k0 + sk + 3 < K){
        const float4 f = *reinterpret_cast<const float4*>(A + arow + k0 + sk);
        av[0]=f.x; av[1]=f.y; av[2]=f.z; av[3]=f.w;
      } else {
#pragma unroll
        for (int i = 0; i < 4; i++){
          const int kk = k0 + sk + i;
          av[i] = (kk < K) ? A[arow + kk] : 0.f;
        }
      }
    }
    {
      const int kb = k0 + bk;
      if (kb < K){
        const float4 f = *reinterpret_cast<const float4*>(Bm + (long)kb*N + n0 + bn);
        bv[0]=f.x; bv[1]=f.y; bv[2]=f.z; bv[3]=f.w;
      } else { bv[0]=bv[1]=bv[2]=bv[3]=0.f; }
    }
    __syncthreads();
    As[sk+0][sm]=av[0]; As[sk+1][sm]=av[1]; As[sk+2][sm]=av[2]; As[sk+3][sm]=av[3];
    *reinterpret_cast<float4*>(&Bs[bk][bn]) = make_float4(bv[0],bv[1],bv[2],bv[3]);
    __syncthreads();
#pragma unroll
    for (int k = 0; k < 8; k++){
      float a[8], bb[8];
      *(float4*)&a[0]  = *(const float4*)&As[k][tr*8];
      *(float4*)&a[4]  = *(const float4*)&As[k][tr*8+4];
      *(float4*)&bb[0] = *(const float4*)&Bs[k][tc*8];
      *(float4*)&bb[4] = *(const float4*)&Bs[k][tc*8+4];
#pragma unroll
      for (int i = 0; i < 8; i++)
#pragma unroll
        for (int j = 0; j < 8; j++) acc[i][j] += a[i]*bb[j];
    }
  }
#pragma unroll
  for (int i = 0; i < 8; i++){
    const long row = m0 + tr*8 + i;
    *(float4*)(Cm + row*N + n0 + tc*8)     = make_float4(acc[i][0],acc[i][1],acc[i][2],acc[i][3]);
    *(float4*)(Cm + row*N + n0 + tc*8 + 4) = make_float4(acc[i][4],acc[i][5],acc[i][6],acc[i][7]);
  }
}

// ---------------------------------------------------------------------------
// 32x32 LDS-tiled transpose: dst[k*R + j] = src[j*Kc + k]   (f32 -> f32)
// ---------------------------------------------------------------------------
__global__ __launch_bounds__(256) void transpose_k(const float* __restrict__ src,
    float* __restrict__ dst, int R, int Kc)
{
  __shared__ float t[32][33];
  const int bx = blockIdx.x * 32;
  const int by = blockIdx.y * 32;
  const int tx = threadIdx.x & 31, ty = threadIdx.x >> 5;
#pragma unroll
  for (int i = 0; i < 32; i += 8){
    const int j = by + ty + i, k = bx + tx;
    t[ty+i][tx] = (j < R && k < Kc) ? src[(long)j*Kc + k] : 0.f;
  }
  __syncthreads();
#pragma unroll
  for (int i = 0; i < 32; i += 8){
    const int k = bx + ty + i, j = by + tx;
    if (k < Kc && j < R) dst[(long)k*R + j] = t[tx][ty+i];
  }
}

// transpose + bf16 pack: src [K][N] f32 -> dst [N][Kp] bf16 (zero-pad K..Kp)
__global__ __launch_bounds__(256) void packT16(const float* __restrict__ src,
    unsigned short* __restrict__ dst, int K, int N, int Kp)
{
  __shared__ float t[32][33];
  const int bx = blockIdx.x*32;
  const int by = blockIdx.y*32;
  const int tx = threadIdx.x & 31, ty = threadIdx.x >> 5;
#pragma unroll
  for (int i = 0; i < 32; i += 8){
    const int k = bx + ty + i, n = by + tx;
    t[ty+i][tx] = (k < K && n < N) ? src[(long)k*N + n] : 0.f;
  }
  __syncthreads();
#pragma unroll
  for (int i = 0; i < 32; i += 8){
    const int k = bx + tx, n = by + ty + i;
    if (k < Kp && n < N) dst[(long)n*Kp + k] = f2bf(t[tx][ty+i]);
  }
}

// pack Wih (already [768][300] = B^T layout) -> [2][768][320] bf16 zero-padded
__global__ void pack_wih(const float* __restrict__ w0, const float* __restrict__ w1,
                         unsigned short* __restrict__ dst)
{
  const int tid = blockIdx.x*256 + threadIdx.x;
  if (tid < 2*768*320){
    const int d = tid / (768*320);
    const int rem = tid - d*768*320;
    const int n = rem / 320, k = rem - n*320;
    const float* src = d ? w1 : w0;
    dst[tid] = (k < 300) ? f2bf(src[n*300 + k]) : (unsigned short)0;
  }
}

// split+pack WtHH [2][256][768] (r|h|z) f32 -> Wrz16 (r|z) bf16, Wh16 bf16
__global__ void pack_whh16(const float* __restrict__ WtHH,
                           unsigned short* __restrict__ Wrz16,
                           unsigned short* __restrict__ Wh16)
{
  const int tid = blockIdx.x*256 + threadIdx.x;
  if (tid < 2*256*768){
    const int col = tid % 768, rk = tid / 768;
    const unsigned short v = f2bf(WtHH[tid]);
    if (col < 256)       Wrz16[(long)rk*512 + col] = v;
    else if (col < 512)  Wh16 [(long)rk*256 + (col - 256)] = v;
    else                 Wrz16[(long)rk*512 + 256 + (col - 512)] = v;
  }
}

// build gather-index arrays
__global__ void build_idx(const int* __restrict__ context, const int* __restrict__ mchars,
                          int* __restrict__ ctxidx, int* __restrict__ chidx)
{
  const int tid = blockIdx.x*256 + threadIdx.x;
  if (tid < 32768){
    const int t = tid >> 8, b = tid & 255;
    ctxidx[tid] = context[b*128 + t];
  } else if (tid < 32768 + 4096){
    const int o = tid - 32768;
    const int t = o >> 8, b = o & 255;
    chidx[o] = mchars[b*16 + t];
  }
}

// out[r] = sum_k lut[idx[r]][k]^2   (one wave per row)
__global__ __launch_bounds__(256) void sqn_gather(const float* __restrict__ lut,
    const int* __restrict__ idx, int K, float* __restrict__ outp)
{
  const int wv = threadIdx.x >> 6, lane = threadIdx.x & 63;
  const int r = blockIdx.x*4 + wv;
  const float* row = lut + (long)idx[r]*K;
  float s = 0.f;
  for (int k = lane; k < K; k += 64) s += row[k]*row[k];
  s = wred(s);
  if (lane == 0) outp[r] = s;
}

// mobius_matvec tail transform per (row, gate); out bf16 + |out_bf16|^2
__global__ __launch_bounds__(256) void xg_transform(const float* __restrict__ mx,
    const float* __restrict__ xsqn, unsigned short* __restrict__ outp,
    float* __restrict__ n2o, int G)
{
  const int wv = threadIdx.x >> 6, lane = threadIdx.x & 63;
  const int wg = blockIdx.x*4 + wv;
  const int row = wg / G, g = wg - row*G;
  const long base = (long)row*(G*256) + g*256;
  float M[4];
#pragma unroll
  for (int i = 0; i < 4; i++) M[i] = mx[base + i*64 + lane];
  const float mxn2 = wred(sq_part<4>(M));
  float pn2; mt_project<4>(M, mxn2, xsqn[row], &pn2);
  float s = 0.f;
#pragma unroll
  for (int i = 0; i < 4; i++){
    const unsigned short u = f2bf(M[i]);
    outp[base + i*64 + lane] = u;
    const float rv = bf2f(u);
    s += rv*rv;
  }
  s = wred(s);
  if (lane == 0) n2o[wg] = s;
}

// ---------------------------------------------------------------------------
// Mobius GRU v7 (round-8 version, measured 1700us): 256 blocks x 512 thr;
// 2 batch rows/block. Staging over 8 waves; phase1 roles (gate, k-quarter);
// phase2 roles (k-eighth). Chains on waves 0-3 / 0-1.
// LDS: wbuf 2x64KB | hs 2K | part 16K | rhb 2K | zb 2K | scal = ~150KB.
// ---------------------------------------------------------------------------
#define GRU_LDS_BYTES 153664

__global__ __launch_bounds__(512,1) void gru_kernel(
    const unsigned short* __restrict__ xg,
    const float* __restrict__ xgn2,
    const unsigned short* __restrict__ Wrz16,
    const unsigned short* __restrict__ Wh16,
    const float* __restrict__ bias_f, const float* __restrict__ bias_b,
    unsigned short* __restrict__ states_f, unsigned short* __restrict__ states_b)
{
  extern __shared__ __align__(16) char smem[];
  float* wbuf = (float*)smem;                    // 2 x 16384 f32 slots (64KB each)
  float* hs   = (float*)(smem + 131072);         // [2][256]
  float* part = (float*)(smem + 133120);         // 4096 floats (16KB)
  float* rhb  = (float*)(smem + 149504);         // [2][256]
  float* zb   = (float*)(smem + 151552);         // [2][256]
  float* scal = (float*)(smem + 153600);         // [2][2]

  const int bid = blockIdx.x;                    // 0..255
  const int dir = bid >> 7;
  const int brow0 = (bid & 127) * 2;
  const int tid = threadIdx.x;
  const int w = tid >> 6, lane = tid & 63;       // w in 0..7
  const int j0 = lane << 2;

  const unsigned short* xgd = xg + (long)dir*32768*768;
  const float* xnd = xgn2 + (long)dir*32768*3;
  const unsigned short* wrz_d = Wrz16 + (long)dir*256*512;
  const unsigned short* wh_d  = Wh16  + (long)dir*256*256;
  const float* bias = dir ? bias_b : bias_f;
  unsigned short* states = dir ? states_b : states_f;

  // FMA roles
  const int fg  = w & 1;             // phase1 gate (0=r cols 0..255, 1=z)
  const int kq4 = w >> 1;            // phase1 k-quarter (16 k) within 64-k chunk
  const int qk8 = w;                 // phase2 k-eighth (16 k) within 128-k chunk
  // chain roles
  const int crow  = (w >> 1) & 1;    // gate-chain row (w<4)
  const int cgate = w & 1;           // gate-chain gate (0=r, 1=z)

  float bg[4], bh4[4] = {0,0,0,0};
  float bg2, bh2 = 0.f;
#pragma unroll
  for (int i = 0; i < 4; i++) bg[i] = bias[(cgate ? 512 : 0) + j0 + i];
  bg2 = wred(sq_part<4>(bg));
  if (w < 2){
#pragma unroll
    for (int i = 0; i < 4; i++) bh4[i] = bias[256 + j0 + i];
    bh2 = wred(sq_part<4>(bh4));
  }

  float h[4] = {0.f,0.f,0.f,0.f};    // update-wave register state (w<2)
  float hn2 = 0.f;
  if (w < 2){
#pragma unroll
    for (int i = 0; i < 4; i++) hs[w*256 + j0 + i] = 0.f;
    if (lane == 0){ scal[w*2 + 0] = 0.f; scal[w*2 + 1] = 0.f; }
  }

  int cb = 0;
  stage64k8(wrz_d, wbuf, w, lane);   // Wrz chunk 0 -> buf 0

  for (int t = 0; t < 128; t++){
    const int tt = dir ? (127 - t) : t;
    // ---- role input loads (guarded: only chain waves) ----
    float xgv[4] = {0,0,0,0}, y2g = 0.f, xgh4[4] = {0,0,0,0}, y2h = 0.f;
    if (w < 4){
      const long rxg = (long)tt*256 + brow0 + crow;
      const ushort4 u = *(const ushort4*)(xgd + rxg*768 + (cgate ? 512 : 0) + j0);
      xgv[0]=bf2f(u.x); xgv[1]=bf2f(u.y); xgv[2]=bf2f(u.z); xgv[3]=bf2f(u.w);
      y2g = xnd[rxg*3 + (cgate ? 2 : 0)];
      if (w < 2){
        const long rxh = (long)tt*256 + brow0 + w;
        const ushort4 uh = *(const ushort4*)(xgd + rxh*768 + 256 + j0);
        xgh4[0]=bf2f(uh.x); xgh4[1]=bf2f(uh.y); xgh4[2]=bf2f(uh.z); xgh4[3]=bf2f(uh.w);
        y2h = xnd[rxh*3 + 1];
      }
    }

    // ===== phase 1: r/z matvec, 4 chunks of [64 k][512 cols] bf16 =====
    float s00=0.f,s01=0.f,s02=0.f,s03=0.f, s10=0.f,s11=0.f,s12=0.f,s13=0.f;
#pragma unroll 1
    for (int c = 0; c < 4; c++){
      __syncthreads();                          // chunk c landed, other buf free
      if (c < 3) stage64k8((const char*)wrz_d + (size_t)(c+1)*65536,
                           wbuf + (cb^1)*16384, w, lane);
      const uint2* wb2 = (const uint2*)(wbuf + cb*16384);  // [64][128] uint2
      const int kb = c*64 + kq4*16;
#pragma unroll
      for (int kk = 0; kk < 4; kk++){
        const float4 hb0 = *(const float4*)&hs[0*256 + kb + kk*4];
        const float4 hb1 = *(const float4*)&hs[1*256 + kb + kk*4];
#pragma unroll
        for (int q = 0; q < 4; q++){
          const uint2 wvv = wb2[(kq4*16 + kk*4 + q)*128 + fg*64 + lane];
          const float w0 = bflo(wvv.x), w1 = bfhi(wvv.x);
          const float w2 = bflo(wvv.y), w3 = bfhi(wvv.y);
          const float h0 = (&hb0.x)[q], h1 = (&hb1.x)[q];
          s00 += h0*w0; s01 += h0*w1; s02 += h0*w2; s03 += h0*w3;
          s10 += h1*w0; s11 += h1*w1; s12 += h1*w2; s13 += h1*w3;
        }
      }
      cb ^= 1;
    }
    {
      // part1 layout: [kq4][row][512]; col = fg*256 + j0
      float* p1 = part + kq4*1024 + fg*256 + j0;
      *(float4*)p1         = make_float4(s00,s01,s02,s03);
      *(float4*)(p1 + 512) = make_float4(s10,s11,s12,s13);
    }
    __syncthreads();                            // B_a: partials visible
    stage64k8(wh_d, wbuf + (cb^1)*16384, w, lane);   // prefetch Wh chunk0
    cb ^= 1;

    // ===== gate chain: waves 0..3, role (crow, cgate) =====
    if (w < 4){
      const float* pa = part + crow*512 + cgate*256 + j0;
      const float4 a0 = *(const float4*)pa;
      const float4 a1 = *(const float4*)(pa + 1024);
      const float4 a2 = *(const float4*)(pa + 2048);
      const float4 a3 = *(const float4*)(pa + 3072);
      float a[4] = { (a0.x+a1.x)+(a2.x+a3.x), (a0.y+a1.y)+(a2.y+a3.y),
                     (a0.z+a1.z)+(a2.z+a3.z), (a0.w+a1.w)+(a2.w+a3.w) };
      const float hn2v = scal[crow*2 + 0];
      const float xn_h = snorm(hn2v), art_h = atanhf(clamp11(xn_h));
      const float p2 = wred(sq_part<4>(a));
      float sc, n2; mt_scale(p2, xn_h, art_h, &sc, &n2);
#pragma unroll
      for (int i = 0; i < 4; i++) a[i] *= sc;
      const float xy = wred(dot_part<4>(a, xgv));
      float m1[4]; madd_vec<4>(a, n2, xgv, y2g, xy, m1);
      float m1n2 = sq_part<4>(m1), xyb = dot_part<4>(m1, bg);
      wred2(m1n2, xyb);
      float m2[4]; madd_vec<4>(m1, m1n2, bg, bg2, xyb, m2);
      const float m2n2 = wred(sq_part<4>(m2));
      const float nn = snorm(m2n2), fgc = atanhf(clamp11(nn))/nn;
      float g4[4];
#pragma unroll
      for (int i = 0; i < 4; i++) g4[i] = 1.f/(1.f + expf(-fgc*m2[i]));
      if (cgate == 0){                          // r-gate: compute rh = pwmul(r,h)
        float h4[4];
        *(float4*)h4 = *(const float4*)&hs[crow*256 + j0];
        float rh[4]; float wx2 = 0.f;
#pragma unroll
        for (int i = 0; i < 4; i++){ rh[i] = g4[i]*h4[i]; wx2 += rh[i]*rh[i]; }
        wx2 = wred(wx2);
        float rhn2, scrh;
        {
          const float wxn = snorm(wx2);
          const float trh = tanhf(wxn/xn_h * art_h);
          scrh = trh/wxn; rhn2 = trh*trh;
          const float n = snorm(rhn2);
          if (n > PMAX_){ const float f = PMAX_/n; scrh *= f; rhn2 *= f*f; }
        }
#pragma unroll
        for (int i = 0; i < 4; i++) rh[i] *= scrh;
        *(float4*)&rhb[crow*256 + j0] = make_float4(rh[0],rh[1],rh[2],rh[3]);
        if (lane == 0) scal[crow*2 + 1] = rhn2;
      } else {
        *(float4*)&zb[crow*256 + j0] = make_float4(g4[0],g4[1],g4[2],g4[3]);
      }
    }

    // ===== phase 2: h-gate matvec, 2 chunks of [128 k][256 cols] bf16 =====
    float r00=0.f,r01=0.f,r02=0.f,r03=0.f, r10=0.f,r11=0.f,r12=0.f,r13=0.f;
#pragma unroll 1
    for (int c = 0; c < 2; c++){
      __syncthreads();                          // c==0: rhb/zb ready + chunk landed
      if (c < 1) stage64k8((const char*)wh_d + 65536, wbuf + (cb^1)*16384, w, lane);
      const uint2* wb2 = (const uint2*)(wbuf + cb*16384);  // [128][64] uint2
      const int kb = c*128 + qk8*16;
#pragma unroll
      for (int kk = 0; kk < 4; kk++){
        const float4 hb0 = *(const float4*)&rhb[0*256 + kb + kk*4];
        const float4 hb1 = *(const float4*)&rhb[1*256 + kb + kk*4];
#pragma unroll
        for (int q = 0; q < 4; q++){
          const uint2 wvv = wb2[(qk8*16 + kk*4 + q)*64 + lane];
          const float w0 = bflo(wvv.x), w1 = bfhi(wvv.x);
          const float w2 = bflo(wvv.y), w3 = bfhi(wvv.y);
          const float h0 = (&hb0.x)[q], h1 = (&hb1.x)[q];
          r00 += h0*w0; r01 += h0*w1; r02 += h0*w2; r03 += h0*w3;
          r10 += h1*w0; r11 += h1*w1; r12 += h1*w2; r13 += h1*w3;
        }
      }
      cb ^= 1;
    }
    {
      // part2 layout: [qk8][row][256]
      float* p2 = part + qk8*512 + j0;
      *(float4*)p2         = make_float4(r00,r01,r02,r03);
      *(float4*)(p2 + 256) = make_float4(r10,r11,r12,r13);
    }
    __syncthreads();                            // B_c
    if (t < 127){
      stage64k8(wrz_d, wbuf + (cb^1)*16384, w, lane);
      cb ^= 1;
    }

    // ===== h-update chain: waves 0..1, row = w =====
    if (w < 2){
      float ah[4];
      {
        float4 p[8];
#pragma unroll
        for (int q = 0; q < 8; q++)
          p[q] = *(const float4*)(part + q*512 + w*256 + j0);
        ah[0] = ((p[0].x+p[1].x)+(p[2].x+p[3].x)) + ((p[4].x+p[5].x)+(p[6].x+p[7].x));
        ah[1] = ((p[0].y+p[1].y)+(p[2].y+p[3].y)) + ((p[4].y+p[5].y)+(p[6].y+p[7].y));
        ah[2] = ((p[0].z+p[1].z)+(p[2].z+p[3].z)) + ((p[4].z+p[5].z)+(p[6].z+p[7].z));
        ah[3] = ((p[0].w+p[1].w)+(p[2].w+p[3].w)) + ((p[4].w+p[5].w)+(p[6].w+p[7].w));
      }
      const float rhn2v = scal[w*2 + 1];
      const float rxn = snorm(rhn2v), artr = atanhf(clamp11(rxn));
      float mx2 = sq_part<4>(ah), xyraw = dot_part<4>(ah, xgh4);
      wred2(mx2, xyraw);
      float sch, pn2; mt_scale(mx2, rxn, artr, &sch, &pn2);
#pragma unroll
      for (int i = 0; i < 4; i++) ah[i] *= sch;
      const float xy = xyraw * sch;
      float m1[4]; madd_vec<4>(ah, pn2, xgh4, y2h, xy, m1);
      float m1n2 = sq_part<4>(m1), xyb = dot_part<4>(m1, bh4);
      wred2(m1n2, xyb);
      float ht[4]; madd_vec<4>(m1, m1n2, bh4, bh2, xyb, ht);
      float htn2 = sq_part<4>(ht);
      float nh[4];
#pragma unroll
      for (int i = 0; i < 4; i++) nh[i] = -h[i];
      float xyd = dot_part<4>(nh, ht);
      wred2(htn2, xyd);
      float dl[4]; madd_vec<4>(nh, hn2, ht, htn2, xyd, dl);
      float z4[4];
      *(float4*)z4 = *(const float4*)&zb[w*256 + j0];
      float pw[4]; float dln2 = 0.f, wz2 = 0.f, xyhr = 0.f;
#pragma unroll
      for (int i = 0; i < 4; i++){
        dln2 += dl[i]*dl[i];
        pw[i] = z4[i]*dl[i];
        wz2  += pw[i]*pw[i];
        xyhr += h[i]*pw[i];
      }
      wred3(dln2, wz2, xyhr);
      float pwn2, scpw;
      {
        const float dn   = snorm(dln2);
        const float artd = atanhf(clamp11(dn));
        const float wzn  = snorm(wz2);
        const float tpw  = tanhf(wzn/dn * artd);
        scpw = tpw/wzn; pwn2 = tpw*tpw;
        const float n = snorm(pwn2);
        if (n > PMAX_){ const float f = PMAX_/n; scpw *= f; pwn2 *= f*f; }
      }
#pragma unroll
      for (int i = 0; i < 4; i++) pw[i] *= scpw;
      const float xyh = xyhr * scpw;
      float hnew[4]; madd_vec<4>(h, hn2, pw, pwn2, xyh, hnew);
#pragma unroll
      for (int i = 0; i < 4; i++) h[i] = hnew[i];
      hn2 = wred(sq_part<4>(h));
      *(float4*)&hs[w*256 + j0] = make_float4(h[0],h[1],h[2],h[3]);
      if (lane == 0) scal[w*2 + 0] = hn2;
      unsigned short* srow = states + ((long)(brow0 + w)*128 + tt)*256 + j0;
      ushort4 su; su.x=f2bf(h[0]); su.y=f2bf(h[1]); su.z=f2bf(h[2]); su.w=f2bf(h[3]);
      *(ushort4*)srow = su;
    }
    // next iteration's first __syncthreads orders hs/scal writes vs reads
  }
}

// ---------------------------------------------------------------------------
// Char Mobius-RNN (unchanged)
// ---------------------------------------------------------------------------
__global__ __launch_bounds__(256) void char_rnn(
    const unsigned short* __restrict__ xgc,
    const float* __restrict__ Wc,
    const float* __restrict__ cb,
    float* __restrict__ cstates)
{
  const int wv = threadIdx.x >> 6, lane = threadIdx.x & 63;
  const int b = blockIdx.x*4 + wv;
  const int j0 = lane << 2;
  __shared__ __align__(16) float hs[4][256];
  float h[4] = {0.f,0.f,0.f,0.f};
  float hn2 = 0.f;
#pragma unroll
  for (int i = 0; i < 4; i++) hs[wv][j0+i] = 0.f;
  float cbv[4];
#pragma unroll
  for (int i = 0; i < 4; i++) cbv[i] = cb[j0+i];
  const float cb2 = wred(sq_part<4>(cbv));
  for (int t = 0; t < 16; t++){
    __syncthreads();
    const unsigned short* xr = xgc + ((long)t*256 + b)*256;
    float xgv[4];
    { const ushort4 u = *(const ushort4*)(xr + j0); xgv[0]=bf2f(u.x); xgv[1]=bf2f(u.y); xgv[2]=bf2f(u.z); xgv[3]=bf2f(u.w); }
    float a[4]={0.f,0.f,0.f,0.f};
#pragma unroll 2
    for (int k0 = 0; k0 < 256; k0 += 4){
      const float4 hk = *(const float4*)&hs[wv][k0];
#pragma unroll
      for (int kk = 0; kk < 4; kk++){
        const float hv = (&hk.x)[kk];
        const float4 w4 = *(const float4*)(Wc + (long)(k0+kk)*256 + j0);
        a[0] += hv*w4.x; a[1] += hv*w4.y; a[2] += hv*w4.z; a[3] += hv*w4.w;
      }
    }
    const float mxn2 = wred(sq_part<4>(a));
    float pn2; mt_project<4>(a, mxn2, hn2, &pn2);
    const float y2 = wred(sq_part<4>(xgv));
    const float xy = wred(dot_part<4>(a, xgv));
    float m1[4]; madd_vec<4>(a, pn2, xgv, y2, xy, m1);
    const float m1n2 = wred(sq_part<4>(m1));
    const float xyb  = wred(dot_part<4>(m1, cbv));
    float m2[4]; madd_vec<4>(m1, m1n2, cbv, cb2, xyb, m2);
    float m2n2 = wred(sq_part<4>(m2));
    project_vec<4>(m2, &m2n2);
#pragma unroll
    for (int i = 0; i < 4; i++) h[i] = m2[i];
    hn2 = m2n2;
    *(float4*)&hs[wv][j0] = make_float4(h[0],h[1],h[2],h[3]);
    *(float4*)(cstates + ((long)b*16 + t)*256 + j0) = make_float4(h[0],h[1],h[2],h[3]);
  }
}

// ---------------------------------------------------------------------------
// cc concat (unchanged)
// ---------------------------------------------------------------------------
__global__ __launch_bounds__(256) void cc_rowwise(const unsigned short* __restrict__ sf,
    const unsigned short* __restrict__ sb, const float* __restrict__ mxa,
    const float* __restrict__ mxb, const float* __restrict__ ccb,
    unsigned short* __restrict__ ctxo, int rowoff)
{
  const int wv = threadIdx.x >> 6, lane = threadIdx.x & 63;
  const int rloc = blockIdx.x*4 + wv;
  const long r = rowoff + rloc;
  float s = 0.f;
#pragma unroll
  for (int i = 0; i < 4; i++){ const float v = bf2f(sf[r*256 + i*64+lane]); s += v*v; }
  const float sfn2 = wred(s);
  s = 0.f;
#pragma unroll
  for (int i = 0; i < 4; i++){ const float v = bf2f(sb[r*256 + i*64+lane]); s += v*v; }
  const float sbn2 = wred(s);
  float A[8], Bv[8];
#pragma unroll
  for (int i = 0; i < 8; i++){ A[i]  = mxa[(long)rloc*512 + i*64+lane];
                               Bv[i] = mxb[(long)rloc*512 + i*64+lane]; }
  float pan2, pbn2;
  { const float n2 = wred(sq_part<8>(A));  mt_project<8>(A,  n2, sfn2, &pan2); }
  { const float n2 = wred(sq_part<8>(Bv)); mt_project<8>(Bv, n2, sbn2, &pbn2); }
  const float xy = wred(dot_part<8>(A, Bv));
  float M1[8]; madd_vec<8>(A, pan2, Bv, pbn2, xy, M1);
  const float m1n2 = wred(sq_part<8>(M1));
  float Cb[8];
#pragma unroll
  for (int i = 0; i < 8; i++) Cb[i] = ccb[i*64+lane];
  const float cb2 = wred(sq_part<8>(Cb));
  const float xyb = wred(dot_part<8>(M1, Cb));
  float M2[8]; madd_vec<8>(M1, m1n2, Cb, cb2, xyb, M2);
  float m2n2 = wred(sq_part<8>(M2));
  project_vec<8>(M2, &m2n2);
#pragma unroll
  for (int i = 0; i < 8; i++) ctxo[r*512 + i*64+lane] = f2bf(M2[i]);
}

// attn_emb = madd(ctx(bf16), pe) -> BF16 out + sqn of rounded
__global__ __launch_bounds__(256) void attn_add(const unsigned short* __restrict__ ctxv,
    const int* __restrict__ pos, const float* __restrict__ pet,
    unsigned short* __restrict__ oemb, float* __restrict__ osqn)
{
  const int wv = threadIdx.x >> 6, lane = threadIdx.x & 63;
  const long r = blockIdx.x*4 + wv;
  float X[8];
#pragma unroll
  for (int i = 0; i < 8; i++) X[i] = bf2f(ctxv[r*512 + i*64+lane]);
  const float x2 = wred(sq_part<8>(X));
  const int p = pos[r];
  float Y[8];
#pragma unroll
  for (int i = 0; i < 8; i++) Y[i] = pet[(long)p*512 + i*64+lane];
  const float y2 = wred(sq_part<8>(Y));
  const float xy = wred(dot_part<8>(X, Y));
  float O[8]; madd_vec<8>(X, x2, Y, y2, xy, O);
  float s = 0.f;
#pragma unroll
  for (int i = 0; i < 8; i++){
    const unsigned short u = f2bf(O[i]);
    oemb[r*512 + i*64+lane] = u;
    const float rv = bf2f(u);
    s += rv*rv;
  }
  s = wred(s);
  if (lane == 0) osqn[r] = s;
}

// mention variant (bf16 out)
__global__ __launch_bounds__(256) void attn_add_m(const float* __restrict__ mvv,
    const int* __restrict__ mentions, const float* __restrict__ pet,
    unsigned short* __restrict__ oemb, float* __restrict__ osqn)
{
  const int wv = threadIdx.x >> 6, lane = threadIdx.x & 63;
  const long r = blockIdx.x*4 + wv;
  float X[8];
#pragma unroll
  for (int i = 0; i < 8; i++) X[i] = mvv[r*512 + i*64+lane];
  const float x2 = wred(sq_part<8>(X));
  const int men = mentions[r];
  const int p = (men > 0) ? (int)(r & 7) + 1 : 0;
  float Y[8];
#pragma unroll
  for (int i = 0; i < 8; i++) Y[i] = pet[(long)p*512 + i*64+lane];
  const float y2 = wred(sq_part<8>(Y));
  const float xy = wred(dot_part<8>(X, Y));
  float O[8]; madd_vec<8>(X, x2, Y, y2, xy, O);
  float s = 0.f;
#pragma unroll
  for (int i = 0; i < 8; i++){
    const unsigned short u = f2bf(O[i]);
    oemb[r*512 + i*64+lane] = u;
    const float rv = bf2f(u);
    s += rv*rv;
  }
  s = wred(s);
  if (lane == 0) osqn[r] = s;
}

// q/k projection + pdist (unchanged)
__global__ __launch_bounds__(256) void qk_pdist(const float* __restrict__ mxq,
    const float* __restrict__ mxk, const float* __restrict__ sqn,
    const float* __restrict__ bq, const float* __restrict__ bk,
    float* __restrict__ dout)
{
  const int wv = threadIdx.x >> 6, lane = threadIdx.x & 63;
  const int r = blockIdx.x*4 + wv;
  const float xn2 = sqn[r];
  float Q[8];
#pragma unroll
  for (int i = 0; i < 8; i++) Q[i] = mxq[(long)r*512 + i*64+lane];
  { const float n2 = wred(sq_part<8>(Q)); float pn2; mt_project<8>(Q, n2, xn2, &pn2);
    float Bq[8];
#pragma unroll
    for (int i = 0; i < 8; i++) Bq[i] = bq[i*64+lane];
    const float b2 = wred(sq_part<8>(Bq));
    const float xy = wred(dot_part<8>(Q, Bq));
    float O[8]; madd_vec<8>(Q, pn2, Bq, b2, xy, O);
#pragma unroll
    for (int i = 0; i < 8; i++) Q[i] = O[i];
  }
  float qn2 = wred(sq_part<8>(Q));
  project_vec<8>(Q, &qn2);
  float Kv[8];
#pragma unroll
  for (int i = 0; i < 8; i++) Kv[i] = mxk[(long)r*512 + i*64+lane];
  { const float n2 = wred(sq_part<8>(Kv)); float pn2; mt_project<8>(Kv, n2, xn2, &pn2);
    float Bk[8];
#pragma unroll
    for (int i = 0; i < 8; i++) Bk[i] = bk[i*64+lane];
    const float b2 = wred(sq_part<8>(Bk));
    const float xy = wred(dot_part<8>(Kv, Bk));
    float O[8]; madd_vec<8>(Kv, pn2, Bk, b2, xy, O);
#pragma unroll
    for (int i = 0; i < 8; i++) Kv[i] = O[i];
  }
  float kn2 = wred(sq_part<8>(Kv));
  project_vec<8>(Kv, &kn2);
  float NQ[8];
#pragma unroll
  for (int i = 0; i < 8; i++) NQ[i] = -Q[i];
  const float xy = wred(dot_part<8>(NQ, Kv));
  float Z[8]; madd_vec<8>(NQ, qn2, Kv, kn2, xy, Z);
  const float zn2 = wred(sq_part<8>(Z));
  const float d = 2.f * atanhf(clamp11(snorm(zn2)));
  if (lane == 0) dout[r] = d;
}

__global__ __launch_bounds__(256) void softmax128(const float* __restrict__ d,
    const float* __restrict__ beta, float* __restrict__ w)
{
  const int wv = threadIdx.x >> 6, lane = threadIdx.x & 63;
  const int b = blockIdx.x*4 + wv;
  const float bt = beta[0];
  const float x0 = -bt * d[b*128 + lane];
  const float x1 = -bt * d[b*128 + 64 + lane];
  const float m = wredmax(fmaxf(x0, x1));
  const float e0 = expf(x0 - m), e1 = expf(x1 - m);
  const float s = wred(e0 + e1);
  w[b*128 + lane]      = e0 / s;
  w[b*128 + 64 + lane] = e1 / s;
}

__global__ void softmax8(const float* __restrict__ d, const float* __restrict__ beta,
                         float* __restrict__ w)
{
  const int b = threadIdx.x;   // 256
  const float bt = beta[0];
  float x[8]; float m = -1e30f;
#pragma unroll
  for (int i = 0; i < 8; i++){ x[i] = -bt * d[b*8+i]; m = fmaxf(m, x[i]); }
  float s = 0.f;
#pragma unroll
  for (int i = 0; i < 8; i++){ x[i] = expf(x[i]-m); s += x[i]; }
#pragma unroll
  for (int i = 0; i < 8; i++) w[b*8+i] = x[i] / s;
}

// weighted gyromidpoint via Klein model; one wave per batch row (small Lseq)
template<int NPL, bool BF16V, bool HASW>
__global__ __launch_bounds__(256) void midpoint_kernel(const void* __restrict__ vals,
    const float* __restrict__ wts, float* __restrict__ outp, int Lseq)
{
  const int wv = threadIdx.x >> 6, lane = threadIdx.x & 63;
  const int b = blockIdx.x*4 + wv;
  const int D = NPL*64;
  float num[NPL];
#pragma unroll
  for (int i = 0; i < NPL; i++) num[i] = 0.f;
  float den = 0.f;
  for (int l = 0; l < Lseq; l++){
    const long base = ((long)b*Lseq + l)*D;
    float v[NPL]; float s = 0.f;
#pragma unroll
    for (int i = 0; i < NPL; i++){
      v[i] = BF16V ? bf2f(((const unsigned short*)vals)[base + i*64+lane])
                   : ((const float*)vals)[base + i*64+lane];
      s += v[i]*v[i];
    }
    const float v2 = wred(s);
    const float f = 2.f/(1.f + v2);
    const float kl2 = v2*f*f;
    const float gamma = 1.f/sqrtf(fmaxf(1.f - kl2, EPS_));
    const float wgt = HASW ? wts[b*Lseq + l] : 1.f;
    const float wg = wgt*gamma;
#pragma unroll
    for (int i = 0; i < NPL; i++) num[i] += wg*(f*v[i]);
    den += wg;
  }
  den = fmaxf(den, EPS_);
  float x[NPL]; float s = 0.f;
#pragma unroll
  for (int i = 0; i < NPL; i++){ x[i] = num[i]/den; s += x[i]*x[i]; }
  const float k2 = wred(s);
  const float inv = 1.f/(1.f + sqrtf(fmaxf(1.f - k2, EPS_)));
#pragma unroll
  for (int i = 0; i < NPL; i++) outp[(long)b*D + i*64+lane] = x[i]*inv;
}

// wide gyromidpoint for ctx (unchanged)
__global__ __launch_bounds__(512) void midpoint_wide(
    const unsigned short* __restrict__ vals,
    const float* __restrict__ wts,
    float* __restrict__ outp)
{
  __shared__ float pnum[8][512];
  __shared__ float pden[8];
  __shared__ float red[512];
  __shared__ float kk2[1];
  const int b = blockIdx.x;
  const int tid = threadIdx.x;
  const int w = tid >> 6, lane = tid & 63;
  float num[8] = {0.f,0.f,0.f,0.f,0.f,0.f,0.f,0.f};
  float den = 0.f;
  for (int l = w; l < 128; l += 8){
    const long base = ((long)b*128 + l)*512;
    float v[8]; float s = 0.f;
#pragma unroll
    for (int i = 0; i < 8; i++){
      v[i] = bf2f(vals[base + i*64 + lane]);
      s += v[i]*v[i];
    }
    const float v2 = wred(s);
    const float f = 2.f/(1.f + v2);
    const float kl2 = v2*f*f;
    const float gamma = 1.f/sqrtf(fmaxf(1.f - kl2, EPS_));
    const float wg = wts[b*128 + l]*gamma;
#pragma unroll
    for (int i = 0; i < 8; i++) num[i] += wg*(f*v[i]);
    den += wg;
  }
#pragma unroll
  for (int i = 0; i < 8; i++) pnum[w][i*64 + lane] = num[i];
  if (lane == 0) pden[w] = den;
  __syncthreads();
  float nsum = 0.f, dsum = 0.f;
#pragma unroll
  for (int p = 0; p < 8; p++){ nsum += pnum[p][tid]; dsum += pden[p]; }
  dsum = fmaxf(dsum, EPS_);
  const float x = nsum/dsum;
  red[tid] = x*x;
  __syncthreads();
  if (tid < 64){
    float s2 = 0.f;
#pragma unroll
    for (int i = 0; i < 8; i++) s2 += red[tid + i*64];
    s2 = wred(s2);
    if (tid == 0) kk2[0] = s2;
  }
  __syncthreads();
  const float k2 = kk2[0];
  const float inv = 1.f/(1.f + sqrtf(fmaxf(1.f - k2, EPS_)));
  outp[(long)b*512 + tid] = x*inv;
}

// mention w2s mobius_linear with tanh nonlinearity (unchanged)
__global__ __launch_bounds__(256) void mv_rowwise(const float* __restrict__ mx,
    const float* __restrict__ xsqn, const float* __restrict__ bb, float* __restrict__ outp)
{
  const int wv = threadIdx.x >> 6, lane = threadIdx.x & 63;
  const long r = blockIdx.x*4 + wv;
  float M[8];
#pragma unroll
  for (int i = 0; i < 8; i++) M[i] = mx[r*512 + i*64+lane];
  { const float n2 = wred(sq_part<8>(M)); float pn2; mt_project<8>(M, n2, xsqn[r], &pn2);
    float Bv[8];
#pragma unroll
    for (int i = 0; i < 8; i++) Bv[i] = bb[i*64+lane];
    const float b2 = wred(sq_part<8>(Bv));
    const float xy = wred(dot_part<8>(M, Bv));
    float O[8]; madd_vec<8>(M, pn2, Bv, b2, xy, O);
#pragma unroll
    for (int i = 0; i < 8; i++) M[i] = O[i];
  }
  float on2 = wred(sq_part<8>(M));
  project_vec<8>(M, &on2);
  { const float n = snorm(on2);
    const float fac = atanhf(clamp11(n))/n;
#pragma unroll
    for (int i = 0; i < 8; i++) M[i] = tanhf(fac*M[i]); }
  const float un2 = wred(sq_part<8>(M));
  { const float n = snorm(un2);
    const float fac = tanhf(n)/n;
    float en2 = fac*fac*un2;
#pragma unroll
    for (int i = 0; i < 8; i++) M[i] *= fac;
    project_vec<8>(M, &en2); }
#pragma unroll
  for (int i = 0; i < 8; i++) outp[r*512 + i*64+lane] = M[i];
}

// joint concat (unchanged)
__global__ __launch_bounds__(256) void final_rowwise(const float* __restrict__ jm,
    const float* __restrict__ jc, const float* __restrict__ jch,
    const float* __restrict__ mvec, const float* __restrict__ cvec,
    const float* __restrict__ chvec, const float* __restrict__ fcb,
    float* __restrict__ joint)
{
  const int wv = threadIdx.x >> 6, lane = threadIdx.x & 63;
  const long b = blockIdx.x*4 + wv;
  float s;
  s = 0.f; for (int i = 0; i < 8; i++){ const float v = mvec[b*512 + i*64+lane]; s += v*v; }
  const float mn2 = wred(s);
  s = 0.f; for (int i = 0; i < 8; i++){ const float v = cvec[b*512 + i*64+lane]; s += v*v; }
  const float cn2 = wred(s);
  s = 0.f; for (int i = 0; i < 4; i++){ const float v = chvec[b*256 + i*64+lane]; s += v*v; }
  const float chn2 = wred(s);
  float A[20];
#pragma unroll
  for (int i = 0; i < 20; i++) A[i] = jm[b*1280 + i*64+lane];
  float an2;
  { const float n2 = wred(sq_part<20>(A)); mt_project<20>(A, n2, mn2, &an2); }
  float T[20];
#pragma unroll
  for (int i = 0; i < 20; i++) T[i] = jc[b*1280 + i*64+lane];
  float tn2;
  { const float n2 = wred(sq_part<20>(T)); mt_project<20>(T, n2, cn2, &tn2); }
  { const float xy = wred(dot_part<20>(A, T));
    float O[20]; madd_vec<20>(A, an2, T, tn2, xy, O);
#pragma unroll
    for (int i = 0; i < 20; i++) A[i] = O[i];
    an2 = wred(sq_part<20>(A)); }
#pragma unroll
  for (int i = 0; i < 20; i++) T[i] = jch[b*1280 + i*64+lane];
  { const float n2 = wred(sq_part<20>(T)); mt_project<20>(T, n2, chn2, &tn2); }
  { const float xy = wred(dot_part<20>(A, T));
    float O[20]; madd_vec<20>(A, an2, T, tn2, xy, O);
#pragma unroll
    for (int i = 0; i < 20; i++) A[i] = O[i];
    an2 = wred(sq_part<20>(A)); }
#pragma unroll
  for (int i = 0; i < 20; i++) T[i] = fcb[i*64+lane];
  tn2 = wred(sq_part<20>(T));
  { const float xy = wred(dot_part<20>(A, T));
    float O[20]; madd_vec<20>(A, an2, T, tn2, xy, O);
#pragma unroll
    for (int i = 0; i < 20; i++) A[i] = O[i];
    an2 = wred(sq_part<20>(A)); }
  project_vec<20>(A, &an2);
#pragma unroll
  for (int i = 0; i < 20; i++) joint[b*1280 + i*64+lane] = A[i];
}

// hyperbolic MLR head (unchanged)
__global__ __launch_bounds__(256) void mlr_kernel(const float* __restrict__ joint,
    const float* __restrict__ P, const float* __restrict__ A, float* __restrict__ outp)
{
  const int wv = threadIdx.x >> 6, lane = threadIdx.x & 63;
  const int pair = blockIdx.x*4 + wv;
  const long b = pair >> 7, c = pair & 127;
  float Pv[20], J[20];
#pragma unroll
  for (int i = 0; i < 20; i++){
    Pv[i] = -P[c*1280 + i*64+lane];
    J[i]  = joint[b*1280 + i*64+lane];
  }
  const float p2 = wred(sq_part<20>(Pv));
  const float j2 = wred(sq_part<20>(J));
  const float xy = wred(dot_part<20>(Pv, J));
  float Z[20]; madd_vec<20>(Pv, p2, J, j2, xy, Z);
  float sza = 0.f, sz2 = 0.f, sa2 = 0.f;
#pragma unroll
  for (int i = 0; i < 20; i++){
    const float a = A[c*1280 + i*64+lane];
    sza += Z[i]*a; sz2 += Z[i]*Z[i]; sa2 += a*a;
  }
  float za = sza, z2 = sz2, a2 = sa2;
  wred3(za, z2, a2);
  const float an = sqrtf(fmaxf(a2, EPS_));
  const float v = 2.f*za / (fmaxf(1.f - z2, EPS_)*an);
  if (lane == 0) outp[pair] = 2.f*an*asinhf(v);
}

// ---------------------------------------------------------------------------
extern "C" void kernel_launch(void* const* d_in, const int* in_sizes, int n_in,
                              void* d_out, int out_size, void* d_ws, size_t ws_size,
                              hipStream_t stream)
{
  (void)in_sizes; (void)n_in; (void)out_size;
  const int*   context   = (const int*)  d_in[0];
  const int*   ctx_position=(const int*) d_in[1];
  const int*   mentions  = (const int*)  d_in[2];
  const int*   mchars    = (const int*)  d_in[3];
  const float* word_lut  = (const float*)d_in[4];
  const float* char_lut  = (const float*)d_in[5];
  const float* gf_Wih    = (const float*)d_in[6];
  const float* gf_Whh    = (const float*)d_in[7];
  const float* gf_b      = (const float*)d_in[8];
  const float* gb_Wih    = (const float*)d_in[9];
  const float* gb_Whh    = (const float*)d_in[10];
  const float* gb_b      = (const float*)d_in[11];
  const float* w2s_W     = (const float*)d_in[12];
  const float* w2s_b     = (const float*)d_in[13];
  const float* men_pos   = (const float*)d_in[14];
  const float* men_Wq    = (const float*)d_in[15];
  const float* men_bq    = (const float*)d_in[16];
  const float* men_Wk    = (const float*)d_in[17];
  const float* men_bk    = (const float*)d_in[18];
  const float* men_beta  = (const float*)d_in[19];
  const float* char_W    = (const float*)d_in[20];
  const float* char_U    = (const float*)d_in[21];
  const float* char_b    = (const float*)d_in[22];
  const float* cc_Wa     = (const float*)d_in[23];
  const float* cc_Wb     = (const float*)d_in[24];
  const float* cc_bias   = (const float*)d_in[25];
  const float* ctx_pos_t = (const float*)d_in[26];
  const float* ctx_Wq    = (const float*)d_in[27];
  const float* ctx_bq    = (const float*)d_in[28];
  const float* ctx_Wk    = (const float*)d_in[29];
  const float* ctx_bk    = (const float*)d_in[30];
  const float* ctx_beta  = (const float*)d_in[31];
  const float* fc_Wm     = (const float*)d_in[32];
  const float* fc_Wc     = (const float*)d_in[33];
  const float* fc_Wch    = (const float*)d_in[34];
  const float* fc_bias   = (const float*)d_in[35];
  const float* mlr_p     = (const float*)d_in[36];
  const float* mlr_a     = (const float*)d_in[37];
  float* out = (float*)d_out;

  // ---- workspace bump allocator ----
  char* wsb = (char*)d_ws;
  size_t off = 0;
  auto alloc = [&](size_t bytes) -> void* {
    void* p = wsb + off;
    off += (bytes + 255) & ~(size_t)255;
    return p;
  };
  float* WtHH = (float*)alloc(2UL*256*768*4);
  unsigned short* Wrz16 = (unsigned short*)alloc(2UL*256*512*2);
  unsigned short* Wh16  = (unsigned short*)alloc(2UL*256*256*2);
  unsigned short* WihP  = (unsigned short*)alloc(2UL*768*320*2);
  unsigned short* ctxWqP= (unsigned short*)alloc(512UL*512*2);
  unsigned short* ctxWkP= (unsigned short*)alloc(512UL*512*2);
  unsigned short* ccWaP = (unsigned short*)alloc(512UL*256*2);
  unsigned short* ccWbP = (unsigned short*)alloc(512UL*256*2);
  unsigned short* menWqP= (unsigned short*)alloc(512UL*512*2);
  unsigned short* menWkP= (unsigned short*)alloc(512UL*512*2);
  unsigned short* w2sP  = (unsigned short*)alloc(512UL*320*2);
  unsigned short* charUP= (unsigned short*)alloc(256UL*256*2);
  int*   ctxidx = (int*)alloc(32768UL*4);
  int*   chidx  = (int*)alloc(4096UL*4);
  float* xsqn   = (float*)alloc(32768UL*4);
  float* msqn   = (float*)alloc(2048UL*4);
  float* chsqn  = (float*)alloc(4096UL*4);
  unsigned short* xg = (unsigned short*)alloc(2UL*32768*768*2);
  float* xgn2 = (float*)alloc(2UL*32768*3*4);
  float* chn2d = (float*)alloc(4096UL*4);
  unsigned short* states_f = (unsigned short*)alloc(32768UL*256*2);
  unsigned short* states_b = (unsigned short*)alloc(32768UL*256*2);
  unsigned short* ctxv = (unsigned short*)alloc(32768UL*512*2);
  float* attn_sqn = (float*)alloc(32768UL*4);
  float* dctx = (float*)alloc(32768UL*4);
  float* wctx = (float*)alloc(32768UL*4);
  float* ctx_vec = (float*)alloc(256UL*512*4);
  float* mxbuf = (float*)alloc(2UL*8192*512*4);
  float* mv = (float*)alloc(2048UL*512*4);
  unsigned short* attn_embm = (unsigned short*)alloc(2048UL*512*2);
  float* amsqn = (float*)alloc(2048UL*4);
  float* dm = (float*)alloc(2048UL*4);
  float* wm = (float*)alloc(2048UL*4);
  float* mention_vec = (float*)alloc(256UL*512*4);
  unsigned short* xgc = (unsigned short*)alloc(4096UL*256*2);
  float* char_states = (float*)alloc(4096UL*256*4);
  float* char_vec = (float*)alloc(256UL*256*4);
  float* joint = (float*)alloc(256UL*1280*4);
  if (off > ws_size) return;
  unsigned short* attn_embc = xg;                  // overlay: xg dead after GRU
  float* mxh0 = mxbuf;
  float* mxh1 = mxbuf + 8192UL*512;

  // ---- weight transposes + bf16 packs ----
  transpose_k<<<dim3(8,24), 256,0,stream>>>(gf_Whh, WtHH,            768, 256);
  transpose_k<<<dim3(8,24), 256,0,stream>>>(gb_Whh, WtHH + 256*768,  768, 256);
  pack_whh16<<<1536,256,0,stream>>>(WtHH, Wrz16, Wh16);
  pack_wih<<<1920,256,0,stream>>>(gf_Wih, gb_Wih, WihP);
  packT16<<<dim3(16,16),256,0,stream>>>(ctx_Wq, ctxWqP, 512, 512, 512);
  packT16<<<dim3(16,16),256,0,stream>>>(ctx_Wk, ctxWkP, 512, 512, 512);
  packT16<<<dim3(8,16), 256,0,stream>>>(cc_Wa,  ccWaP,  256, 512, 256);
  packT16<<<dim3(8,16), 256,0,stream>>>(cc_Wb,  ccWbP,  256, 512, 256);
  packT16<<<dim3(16,16),256,0,stream>>>(men_Wq, menWqP, 512, 512, 512);
  packT16<<<dim3(16,16),256,0,stream>>>(men_Wk, menWkP, 512, 512, 512);
  packT16<<<dim3(10,16),256,0,stream>>>(w2s_W,  w2sP,   300, 512, 320);
  packT16<<<dim3(8,8),  256,0,stream>>>(char_U, charUP, 256, 256, 256);

  // ---- gather indices + input sqn ----
  build_idx<<<144,256,0,stream>>>(context, mchars, ctxidx, chidx);
  sqn_gather<<<8192,256,0,stream>>>(word_lut, ctxidx, 300, xsqn);
  sqn_gather<<<512, 256,0,stream>>>(word_lut, mentions, 300, msqn);
  sqn_gather<<<1024,256,0,stream>>>(char_lut, chidx, 256, chsqn);

  // ---- GRU input precompute: xg[dir] = mobius_matvec(emb, Wih^T), bf16 ----
  for (int d2 = 0; d2 < 2; d2++){
    const unsigned short* wihp = WihP + (size_t)d2*768*320;
    for (int c = 0; c < 4; c++){
      mfma_mm<1><<<dim3(6,128),256,0,stream>>>(word_lut, ctxidx + c*8192, wihp,
                                               mxbuf, 8192, 768, 300, 320);
      xg_transform<<<6144,256,0,stream>>>(mxbuf, xsqn + c*8192,
          xg + ((size_t)d2*32768 + (size_t)c*8192)*768,
          xgn2 + ((size_t)d2*32768 + (size_t)c*8192)*3, 3);
    }
  }

  // ---- bidirectional Mobius GRU (8-wave v7, round-8 proven) ----
  (void)hipFuncSetAttribute((const void*)gru_kernel,
      hipFuncAttributeMaxDynamicSharedMemorySize, GRU_LDS_BYTES);
  gru_kernel<<<256,512,GRU_LDS_BYTES,stream>>>(xg, xgn2, Wrz16, Wh16,
                                               gf_b, gb_b, states_f, states_b);

  // ---- mobius concat of directions -> ctx (bf16) ----
  for (int c = 0; c < 4; c++){
    mfma_mm<2><<<dim3(4,128),256,0,stream>>>(states_f + (size_t)c*8192*256, nullptr,
                                             ccWaP, mxh0, 8192, 512, 256, 256);
    mfma_mm<2><<<dim3(4,128),256,0,stream>>>(states_b + (size_t)c*8192*256, nullptr,
                                             ccWbP, mxh1, 8192, 512, 256, 256);
    cc_rowwise<<<2048,256,0,stream>>>(states_f, states_b, mxh0, mxh1, cc_bias,
                                      ctxv, c*8192);
  }

  // ---- context distance attention ----
  attn_add<<<8192,256,0,stream>>>(ctxv, ctx_position, ctx_pos_t, attn_embc, attn_sqn);
  for (int c = 0; c < 4; c++){
    mfma_mm<2><<<dim3(4,128),256,0,stream>>>(attn_embc + (size_t)c*8192*512, nullptr,
                                             ctxWqP, mxh0, 8192, 512, 512, 512);
    mfma_mm<2><<<dim3(4,128),256,0,stream>>>(attn_embc + (size_t)c*8192*512, nullptr,
                                             ctxWkP, mxh1, 8192, 512, 512, 512);
    qk_pdist<<<2048,256,0,stream>>>(mxh0, mxh1, attn_sqn + c*8192, ctx_bq, ctx_bk,
                                    dctx + c*8192);
  }
  softmax128<<<64,256,0,stream>>>(dctx, ctx_beta, wctx);
  midpoint_wide<<<256,512,0,stream>>>(ctxv, wctx, ctx_vec);

  // ---- mention encoder ----
  mfma_mm<1><<<dim3(4,32),256,0,stream>>>(word_lut, mentions, w2sP, mxh0,
                                          2048, 512, 300, 320);
  mv_rowwise<<<512,256,0,stream>>>(mxh0, msqn, w2s_b, mv);
  attn_add_m<<<512,256,0,stream>>>(mv, mentions, men_pos, attn_embm, amsqn);
  mfma_mm<2><<<dim3(4,32),256,0,stream>>>(attn_embm, nullptr, menWqP, mxh0,
                                          2048, 512, 512, 512);
  mfma_mm<2><<<dim3(4,32),256,0,stream>>>(attn_embm, nullptr, menWkP, mxh1,
                                          2048, 512, 512, 512);
  qk_pdist<<<512,256,0,stream>>>(mxh0, mxh1, amsqn, men_bq, men_bk, dm);
  softmax8<<<1,256,0,stream>>>(dm, men_beta, wm);
  midpoint_kernel<8,false,true><<<64,256,0,stream>>>(mv, wm, mention_vec, 8);

  // ---- char encoder ----
  mfma_mm<1><<<dim3(2,64),256,0,stream>>>(char_lut, chidx, charUP, mxh0,
                                          4096, 256, 256, 256);
  xg_transform<<<1024,256,0,stream>>>(mxh0, chsqn, xgc, chn2d, 1);
  char_rnn<<<64,256,0,stream>>>(xgc, char_W, char_b, char_states);
  midpoint_kernel<4,false,false><<<64,256,0,stream>>>(char_states, nullptr, char_vec, 16);

  // ---- full mobius concat + MLR (small, f32 path) ----
  float* jm = mxh0;
  float* jc = mxh0 + 256UL*1280;
  float* jch = mxh0 + 2UL*256*1280;
  mm_kernel<0><<<dim3(10,2),256,0,stream>>>(mention_vec, nullptr, fc_Wm, jm, 256, 1280, 512);
  mm_kernel<0><<<dim3(10,2),256,0,stream>>>(ctx_vec,     nullptr, fc_Wc, jc, 256, 1280, 512);
  mm_kernel<0><<<dim3(10,2),256,0,stream>>>(char_vec,    nullptr, fc_Wch, jch, 256, 1280, 256);
  final_rowwise<<<64,256,0,stream>>>(jm, jc, jch, mention_vec, ctx_vec, char_vec,
                                     fc_bias, joint);
  mlr_kernel<<<8192,256,0,stream>>>(joint, mlr_p, mlr_a, out);
}

// Round 11
// 2524.067 us; speedup vs baseline: 1.1894x; 1.0843x over previous
//
#include <hip/hip_runtime.h>
#include <cstddef>
#include <cstdint>

// ---------------------------------------------------------------------------
// Hyperbolic (Poincare-ball) entity-typing forward pass, MI355X / gfx950.
// Round 11: GRU v9 — f16 k-pair packed weights + v_dot2_f32_f16
// (__builtin_amdgcn_fdot2) for the matvec FMA walls (~2.3x fewer VALU ops).
// Structure/barriers identical to round-10 v7 (1700us). h/rh stored as f16
// pairs in LDS (finer rounding than the proven-invisible bf16 weights).
// Non-GRU path unchanged from round 10 (2737us, passing).
// ---------------------------------------------------------------------------

#define EPS_  1e-15f
#define PMAX_ 0.99999f    // 1 - 1e-5

typedef __attribute__((ext_vector_type(8))) short bf16x8;
typedef __attribute__((ext_vector_type(4))) float f32x4;
typedef __attribute__((ext_vector_type(8))) unsigned short us8;
typedef _Float16 half2_t __attribute__((ext_vector_type(2)));

__device__ __forceinline__ half2_t as_h2(unsigned u){
  union { unsigned u; half2_t h; } v; v.u = u; return v.h;
}
__device__ __forceinline__ unsigned packh2(float a, float b){
  union { half2_t h; unsigned u; } v;
  v.h[0] = (_Float16)a; v.h[1] = (_Float16)b; return v.u;
}
#if __has_builtin(__builtin_amdgcn_fdot2)
#define FDOT2(a,b,c) __builtin_amdgcn_fdot2((a),(b),(c),false)
#else
#define FDOT2(a,b,c) ((c) + (float)(a)[0]*(float)(b)[0] + (float)(a)[1]*(float)(b)[1])
#endif

__device__ __forceinline__ float wred(float v){
#pragma unroll
  for (int o = 32; o; o >>= 1) v += __shfl_xor(v, o, 64);
  return v;
}
__device__ __forceinline__ void wred2(float& a, float& b){
#pragma unroll
  for (int o = 32; o; o >>= 1){ a += __shfl_xor(a, o, 64); b += __shfl_xor(b, o, 64); }
}
__device__ __forceinline__ void wred3(float& a, float& b, float& c){
#pragma unroll
  for (int o = 32; o; o >>= 1){
    a += __shfl_xor(a, o, 64); b += __shfl_xor(b, o, 64); c += __shfl_xor(c, o, 64);
  }
}
__device__ __forceinline__ void wred4(float& a, float& b, float& c, float& d){
#pragma unroll
  for (int o = 32; o; o >>= 1){
    a += __shfl_xor(a, o, 64); b += __shfl_xor(b, o, 64);
    c += __shfl_xor(c, o, 64); d += __shfl_xor(d, o, 64);
  }
}
__device__ __forceinline__ float wredmax(float v){
#pragma unroll
  for (int o = 32; o; o >>= 1) v = fmaxf(v, __shfl_xor(v, o, 64));
  return v;
}
__device__ __forceinline__ float snorm(float s){ return sqrtf(fmaxf(s, EPS_)); }
__device__ __forceinline__ float clamp11(float x){
  return fminf(fmaxf(x, -1.f + 1e-7f), 1.f - 1e-7f);
}
__device__ __forceinline__ float bf2f(unsigned short u){
  union { unsigned int i; float f; } v; v.i = ((unsigned int)u) << 16; return v.f;
}
__device__ __forceinline__ unsigned short f2bf(float f){
  union { float f; unsigned int i; } v; v.f = f;
  unsigned int x = v.i;
  x += 0x7fffu + ((x >> 16) & 1u);   // RNE
  return (unsigned short)(x >> 16);
}
__device__ __forceinline__ float bflo(unsigned u){
  union { unsigned i; float f; } v; v.i = u << 16; return v.f;
}
__device__ __forceinline__ float bfhi(unsigned u){
  union { unsigned i; float f; } v; v.i = u & 0xffff0000u; return v.f;
}

template<int N>
__device__ __forceinline__ float sq_part(const float* a){
  float s = 0.f;
#pragma unroll
  for (int i = 0; i < N; i++) s += a[i]*a[i];
  return s;
}
template<int N>
__device__ __forceinline__ float dot_part(const float* a, const float* b){
  float s = 0.f;
#pragma unroll
  for (int i = 0; i < N; i++) s += a[i]*b[i];
  return s;
}
template<int N>
__device__ __forceinline__ void madd_vec(const float* x, float x2, const float* y,
                                         float y2, float xy, float* o){
  const float c1 = 1.f + 2.f*xy + y2;
  const float c2 = 1.f - x2;
  const float inv = 1.f / fmaxf(1.f + 2.f*xy + x2*y2, EPS_);
#pragma unroll
  for (int i = 0; i < N; i++) o[i] = (c1*x[i] + c2*y[i]) * inv;
}
template<int N>
__device__ __forceinline__ void mt_project(float* v, float mxn2, float xn2, float* n2out){
  const float xn  = snorm(xn2);
  const float mxn = snorm(mxn2);
  const float t   = tanhf(mxn/xn * atanhf(clamp11(xn)));
  float sc = t/mxn;
  float n2 = sc*sc*mxn2;
  const float n = snorm(n2);
  if (n > PMAX_){ const float s = PMAX_/n; sc *= s; n2 *= s*s; }
#pragma unroll
  for (int i = 0; i < N; i++) v[i] *= sc;
  *n2out = n2;
}
__device__ __forceinline__ void mt_scale(float mxn2, float xn, float art,
                                         float* sc, float* n2){
  const float mxn = snorm(mxn2);
  const float t   = tanhf(mxn/xn * art);
  float s  = t/mxn;
  float nn = t*t;
  const float n = snorm(nn);
  if (n > PMAX_){ const float f = PMAX_/n; s *= f; nn *= f*f; }
  *sc = s; *n2 = nn;
}
template<int N>
__device__ __forceinline__ void project_vec(float* v, float* n2io){
  float n2 = *n2io;
  const float n = snorm(n2);
  if (n > PMAX_){
    const float s = PMAX_/n;
#pragma unroll
    for (int i = 0; i < N; i++) v[i] *= s;
    n2 *= s*s;
  }
  *n2io = n2;
}

// async 16B global->LDS: linear wave-uniform-base + lane*16
__device__ __forceinline__ void gll16(const void* g, void* l){
  __builtin_amdgcn_global_load_lds(
      (const __attribute__((address_space(1))) void*)g,
      (__attribute__((address_space(3))) void*)l, 16, 0, 0);
}
// stage 64KB with 512 threads (8 waves x 8 x 16B/lane), linear layout
__device__ __forceinline__ void stage64k8(const void* gsrc, float* lbase, int w, int lane){
#pragma unroll
  for (int i = 0; i < 8; i++){
    const char* g = (const char*)gsrc + (size_t)((i*8 + w)*64 + lane)*16;
    char* l = (char*)lbase + (size_t)((i*8 + w)*64)*16;
    gll16(g, l);
  }
}

// ---------------------------------------------------------------------------
// MFMA bf16 GEMM (64x128 tile, round-10 version, unchanged)
// ---------------------------------------------------------------------------
template<int AMODE>
__global__ __launch_bounds__(256) void mfma_mm(const void* __restrict__ Aptr,
    const int* __restrict__ idx, const unsigned short* __restrict__ Bt,
    float* __restrict__ Cm, int M, int N, int K, int Kp)
{
  __shared__ __align__(16) unsigned short As[64][40];
  __shared__ __align__(16) unsigned short Bs[128][40];
  const int tid = threadIdx.x;
  const int n0 = blockIdx.x * 128;
  const int m0 = blockIdx.y * 64;
  const int arow_s = tid >> 2, aq = tid & 3;
  const int brow_s = tid >> 1, bhf = tid & 1;
  const int wv = tid >> 6, lane = tid & 63;
  const int wm = wv >> 1, wn = wv & 1;
  const int lr = lane & 15, lk = lane >> 4;

  long arow;
  if constexpr (AMODE == 1) arow = (long)idx[m0 + arow_s] * K;
  else                      arow = (long)(m0 + arow_s) * K;

  f32x4 acc[2][4];
#pragma unroll
  for (int mf = 0; mf < 2; mf++)
#pragma unroll
    for (int nf = 0; nf < 4; nf++) acc[mf][nf] = (f32x4){0.f,0.f,0.f,0.f};

  for (int k0 = 0; k0 < Kp; k0 += 32){
    const int kbA = k0 + aq*8;
    unsigned short av[8];
    if constexpr (AMODE == 1){
      const float* ar = (const float*)Aptr + arow;
      if (kbA + 8 <= K){
        const float4 f0 = *(const float4*)(ar + kbA);
        const float4 f1 = *(const float4*)(ar + kbA + 4);
        av[0]=f2bf(f0.x); av[1]=f2bf(f0.y); av[2]=f2bf(f0.z); av[3]=f2bf(f0.w);
        av[4]=f2bf(f1.x); av[5]=f2bf(f1.y); av[6]=f2bf(f1.z); av[7]=f2bf(f1.w);
      } else {
#pragma unroll
        for (int v = 0; v < 8; v++){
          const int col = kbA + v;
          av[v] = (col < K) ? f2bf(ar[col]) : (unsigned short)0;
        }
      }
    } else {
      const us8 u0 = *(const us8*)((const unsigned short*)Aptr + arow + kbA);
#pragma unroll
      for (int v = 0; v < 8; v++) av[v] = u0[v];
    }
    unsigned short bvv[16];
    {
      const unsigned short* br = Bt + (long)(n0 + brow_s)*Kp + k0 + bhf*16;
      const us8 u0 = *(const us8*)br;
      const us8 u1 = *(const us8*)(br + 8);
#pragma unroll
      for (int v = 0; v < 8; v++){ bvv[v] = u0[v]; bvv[8+v] = u1[v]; }
    }
    __syncthreads();
    *(us8*)&As[arow_s][aq*8] = *(const us8*)&av[0];
    *(us8*)&Bs[brow_s][bhf*16]   = *(const us8*)&bvv[0];
    *(us8*)&Bs[brow_s][bhf*16+8] = *(const us8*)&bvv[8];
    __syncthreads();
    bf16x8 af[2], bfr[4];
#pragma unroll
    for (int mf = 0; mf < 2; mf++)
      af[mf] = *(const bf16x8*)&As[wm*32 + mf*16 + lr][lk*8];
#pragma unroll
    for (int nf = 0; nf < 4; nf++)
      bfr[nf] = *(const bf16x8*)&Bs[wn*64 + nf*16 + lr][lk*8];
#pragma unroll
    for (int mf = 0; mf < 2; mf++)
#pragma unroll
      for (int nf = 0; nf < 4; nf++)
        acc[mf][nf] = __builtin_amdgcn_mfma_f32_16x16x32_bf16(af[mf], bfr[nf],
                                                              acc[mf][nf], 0, 0, 0);
  }
#pragma unroll
  for (int mf = 0; mf < 2; mf++){
#pragma unroll
    for (int nf = 0; nf < 4; nf++){
#pragma unroll
      for (int r = 0; r < 4; r++){
        const long grow = m0 + wm*32 + mf*16 + lk*4 + r;
        Cm[grow*N + n0 + wn*64 + nf*16 + lr] = acc[mf][nf][r];
      }
    }
  }
}

// ---------------------------------------------------------------------------
// Generic tiled f32 GEMM (small fc GEMMs only)
// ---------------------------------------------------------------------------
template<int AMODE>
__global__ __launch_bounds__(256) void mm_kernel(const void* __restrict__ Aptr,
    const int* __restrict__ idx, const float* __restrict__ Bm,
    float* __restrict__ Cm, int M, int N, int K)
{
  __shared__ __align__(16) float As[8][128];
  __shared__ __align__(16) float Bs[8][132];
  const int tid = threadIdx.x;
  const int n0 = blockIdx.x * 128;
  const int m0 = blockIdx.y * 128;
  const int tr = tid >> 4, tc = tid & 15;
  const int sm = tid & 127, sk = (tid >> 7) * 4;
  const int bk = tid >> 5,  bn = (tid & 31) * 4;
  long arow;
  if constexpr (AMODE == 1) arow = (long)idx[m0 + sm] * K;
  else                      arow = (long)(m0 + sm) * K;
  float acc[8][8];
#pragma unroll
  for (int i = 0; i < 8; i++)
#pragma unroll
    for (int j = 0; j < 8; j++) acc[i][j] = 0.f;

  for (int k0 = 0; k0 < K; k0 += 8){
    float av[4], bv[4];
    {
      const float* A = (const float*)Aptr;
      if (k0 + sk + 3 < K){
        const float4 f = *reinterpret_cast<const float4*>(A + arow + k0 + sk);
        av[0]=f.x; av[1]=f.y; av[2]=f.z; av[3]=f.w;
      } else {
#pragma unroll
        for (int i = 0; i < 4; i++){
          const int kk = k0 + sk + i;
          av[i] = (kk < K) ? A[arow + kk] : 0.f;
        }
      }
    }
    {
      const int kb = k0 + bk;
      if (kb < K){
        const float4 f = *reinterpret_cast<const float4*>(Bm + (long)kb*N + n0 + bn);
        bv[0]=f.x; bv[1]=f.y; bv[2]=f.z; bv[3]=f.w;
      } else { bv[0]=bv[1]=bv[2]=bv[3]=0.f; }
    }
    __syncthreads();
    As[sk+0][sm]=av[0]; As[sk+1][sm]=av[1]; As[sk+2][sm]=av[2]; As[sk+3][sm]=av[3];
    *reinterpret_cast<float4*>(&Bs[bk][bn]) = make_float4(bv[0],bv[1],bv[2],bv[3]);
    __syncthreads();
#pragma unroll
    for (int k = 0; k < 8; k++){
      float a[8], bb[8];
      *(float4*)&a[0]  = *(const float4*)&As[k][tr*8];
      *(float4*)&a[4]  = *(const float4*)&As[k][tr*8+4];
      *(float4*)&bb[0] = *(const float4*)&Bs[k][tc*8];
      *(float4*)&bb[4] = *(const float4*)&Bs[k][tc*8+4];
#pragma unroll
      for (int i = 0; i < 8; i++)
#pragma unroll
        for (int j = 0; j < 8; j++) acc[i][j] += a[i]*bb[j];
    }
  }
#pragma unroll
  for (int i = 0; i < 8; i++){
    const long row = m0 + tr*8 + i;
    *(float4*)(Cm + row*N + n0 + tc*8)     = make_float4(acc[i][0],acc[i][1],acc[i][2],acc[i][3]);
    *(float4*)(Cm + row*N + n0 + tc*8 + 4) = make_float4(acc[i][4],acc[i][5],acc[i][6],acc[i][7]);
  }
}

// ---------------------------------------------------------------------------
// 32x32 LDS-tiled transpose: dst[k*R + j] = src[j*Kc + k]   (f32 -> f32)
// ---------------------------------------------------------------------------
__global__ __launch_bounds__(256) void transpose_k(const float* __restrict__ src,
    float* __restrict__ dst, int R, int Kc)
{
  __shared__ float t[32][33];
  const int bx = blockIdx.x * 32;
  const int by = blockIdx.y * 32;
  const int tx = threadIdx.x & 31, ty = threadIdx.x >> 5;
#pragma unroll
  for (int i = 0; i < 32; i += 8){
    const int j = by + ty + i, k = bx + tx;
    t[ty+i][tx] = (j < R && k < Kc) ? src[(long)j*Kc + k] : 0.f;
  }
  __syncthreads();
#pragma unroll
  for (int i = 0; i < 32; i += 8){
    const int k = bx + ty + i, j = by + tx;
    if (k < Kc && j < R) dst[(long)k*R + j] = t[tx][ty+i];
  }
}

// transpose + bf16 pack: src [K][N] f32 -> dst [N][Kp] bf16 (zero-pad K..Kp)
__global__ __launch_bounds__(256) void packT16(const float* __restrict__ src,
    unsigned short* __restrict__ dst, int K, int N, int Kp)
{
  __shared__ float t[32][33];
  const int bx = blockIdx.x*32;
  const int by = blockIdx.y*32;
  const int tx = threadIdx.x & 31, ty = threadIdx.x >> 5;
#pragma unroll
  for (int i = 0; i < 32; i += 8){
    const int k = bx + ty + i, n = by + tx;
    t[ty+i][tx] = (k < K && n < N) ? src[(long)k*N + n] : 0.f;
  }
  __syncthreads();
#pragma unroll
  for (int i = 0; i < 32; i += 8){
    const int k = bx + tx, n = by + ty + i;
    if (k < Kp && n < N) dst[(long)n*Kp + k] = f2bf(t[tx][ty+i]);
  }
}

// pack Wih (already [768][300] = B^T layout) -> [2][768][320] bf16 zero-padded
__global__ void pack_wih(const float* __restrict__ w0, const float* __restrict__ w1,
                         unsigned short* __restrict__ dst)
{
  const int tid = blockIdx.x*256 + threadIdx.x;
  if (tid < 2*768*320){
    const int d = tid / (768*320);
    const int rem = tid - d*768*320;
    const int n = rem / 320, k = rem - n*320;
    const float* src = d ? w1 : w0;
    dst[tid] = (k < 300) ? f2bf(src[n*300 + k]) : (unsigned short)0;
  }
}

// split+pack WtHH [2][256 k][768 (r|h|z)] f32 -> f16 k-pair layouts:
// Wrz2 [2][128 kp][512 cols r|z] u32 (lo=W[2kp], hi=W[2kp+1])
// Wh2  [2][128 kp][256 cols h]   u32
__global__ void pack_whh_f16(const float* __restrict__ WtHH,
                             unsigned* __restrict__ Wrz2,
                             unsigned* __restrict__ Wh2)
{
  const int tid = blockIdx.x*256 + threadIdx.x;   // 0 .. 196607
  if (tid < 2*128*768){
    const int col = tid % 768;
    const int rest = tid / 768;         // dir*128 + kp
    const int kp = rest & 127, dir = rest >> 7;
    const float* s0 = WtHH + ((long)(dir*256 + 2*kp))*768 + col;
    const unsigned u = packh2(s0[0], s0[768]);
    if (col < 256)       Wrz2[(long)(dir*128 + kp)*512 + col] = u;
    else if (col < 512)  Wh2 [(long)(dir*128 + kp)*256 + (col - 256)] = u;
    else                 Wrz2[(long)(dir*128 + kp)*512 + 256 + (col - 512)] = u;
  }
}

// build gather-index arrays
__global__ void build_idx(const int* __restrict__ context, const int* __restrict__ mchars,
                          int* __restrict__ ctxidx, int* __restrict__ chidx)
{
  const int tid = blockIdx.x*256 + threadIdx.x;
  if (tid < 32768){
    const int t = tid >> 8, b = tid & 255;
    ctxidx[tid] = context[b*128 + t];
  } else if (tid < 32768 + 4096){
    const int o = tid - 32768;
    const int t = o >> 8, b = o & 255;
    chidx[o] = mchars[b*16 + t];
  }
}

// out[r] = sum_k lut[idx[r]][k]^2   (one wave per row)
__global__ __launch_bounds__(256) void sqn_gather(const float* __restrict__ lut,
    const int* __restrict__ idx, int K, float* __restrict__ outp)
{
  const int wv = threadIdx.x >> 6, lane = threadIdx.x & 63;
  const int r = blockIdx.x*4 + wv;
  const float* row = lut + (long)idx[r]*K;
  float s = 0.f;
  for (int k = lane; k < K; k += 64) s += row[k]*row[k];
  s = wred(s);
  if (lane == 0) outp[r] = s;
}

// mobius_matvec tail transform per (row, gate); out bf16 + |out_bf16|^2
__global__ __launch_bounds__(256) void xg_transform(const float* __restrict__ mx,
    const float* __restrict__ xsqn, unsigned short* __restrict__ outp,
    float* __restrict__ n2o, int G)
{
  const int wv = threadIdx.x >> 6, lane = threadIdx.x & 63;
  const int wg = blockIdx.x*4 + wv;
  const int row = wg / G, g = wg - row*G;
  const long base = (long)row*(G*256) + g*256;
  float M[4];
#pragma unroll
  for (int i = 0; i < 4; i++) M[i] = mx[base + i*64 + lane];
  const float mxn2 = wred(sq_part<4>(M));
  float pn2; mt_project<4>(M, mxn2, xsqn[row], &pn2);
  float s = 0.f;
#pragma unroll
  for (int i = 0; i < 4; i++){
    const unsigned short u = f2bf(M[i]);
    outp[base + i*64 + lane] = u;
    const float rv = bf2f(u);
    s += rv*rv;
  }
  s = wred(s);
  if (lane == 0) n2o[wg] = s;
}

// ---------------------------------------------------------------------------
// Mobius GRU v9: 256 blocks x 512 thr; 2 batch rows/block (v7 structure).
// Weights f16 k-pair layout; matvec via FDOT2 (v_dot2_f32_f16).
// h / rh stored as packed f16 pairs in LDS; chains otherwise identical.
// LDS: wbuf 2x64KB | hsp 1K | rhp 1K | part 16K | zb 2K | scal.
// ---------------------------------------------------------------------------
#define GRU_LDS_BYTES 151808

__global__ __launch_bounds__(512,1) void gru_kernel(
    const unsigned short* __restrict__ xg,
    const float* __restrict__ xgn2,
    const unsigned* __restrict__ Wrz2,
    const unsigned* __restrict__ Wh2,
    const float* __restrict__ bias_f, const float* __restrict__ bias_b,
    unsigned short* __restrict__ states_f, unsigned short* __restrict__ states_b)
{
  extern __shared__ __align__(16) char smem[];
  float*    wbuf = (float*)smem;                 // 2 x 16384 f32 slots (64KB each)
  unsigned* hsp  = (unsigned*)(smem + 131072);   // [2][128] f16-pairs of h
  unsigned* rhp  = (unsigned*)(smem + 132096);   // [2][128] f16-pairs of rh
  float*    part = (float*)(smem + 133120);      // 4096 floats (16KB)
  float*    zb   = (float*)(smem + 149504);      // [2][256]
  float*    scal = (float*)(smem + 151552);      // [2][2]

  const int bid = blockIdx.x;                    // 0..255
  const int dir = bid >> 7;
  const int brow0 = (bid & 127) * 2;
  const int tid = threadIdx.x;
  const int w = tid >> 6, lane = tid & 63;       // w in 0..7
  const int j0 = lane << 2;

  const unsigned short* xgd = xg + (long)dir*32768*768;
  const float* xnd = xgn2 + (long)dir*32768*3;
  const unsigned* wrz_d = Wrz2 + (long)dir*128*512;
  const unsigned* wh_d  = Wh2  + (long)dir*128*256;
  const float* bias = dir ? bias_b : bias_f;
  unsigned short* states = dir ? states_b : states_f;

  // FMA roles
  const int fg  = w & 1;             // phase1 gate (0=r cols 0..255, 1=z)
  const int kq4 = w >> 1;            // phase1 kp-quarter (8 kp) within 32-kp chunk
  const int qk8 = w;                 // phase2 kp-eighth (8 kp) within 64-kp chunk
  // chain roles
  const int crow  = (w >> 1) & 1;
  const int cgate = w & 1;

  float bg[4], bh4[4] = {0,0,0,0};
  float bg2, bh2 = 0.f;
#pragma unroll
  for (int i = 0; i < 4; i++) bg[i] = bias[(cgate ? 512 : 0) + j0 + i];
  bg2 = wred(sq_part<4>(bg));
  if (w < 2){
#pragma unroll
    for (int i = 0; i < 4; i++) bh4[i] = bias[256 + j0 + i];
    bh2 = wred(sq_part<4>(bh4));
  }

  float h[4] = {0.f,0.f,0.f,0.f};    // update-wave register state (w<2), f32
  float hn2 = 0.f;
  if (w < 2){
    hsp[w*128 + lane*2]     = 0u;
    hsp[w*128 + lane*2 + 1] = 0u;
    if (lane == 0){ scal[w*2 + 0] = 0.f; scal[w*2 + 1] = 0.f; }
  }

  int cb = 0;
  stage64k8(wrz_d, wbuf, w, lane);   // Wrz chunk 0 (kp 0..31) -> buf 0

  for (int t = 0; t < 128; t++){
    const int tt = dir ? (127 - t) : t;
    // ---- role input loads (guarded: only chain waves) ----
    float xgv[4] = {0,0,0,0}, y2g = 0.f, xgh4[4] = {0,0,0,0}, y2h = 0.f;
    if (w < 4){
      const long rxg = (long)tt*256 + brow0 + crow;
      const ushort4 u = *(const ushort4*)(xgd + rxg*768 + (cgate ? 512 : 0) + j0);
      xgv[0]=bf2f(u.x); xgv[1]=bf2f(u.y); xgv[2]=bf2f(u.z); xgv[3]=bf2f(u.w);
      y2g = xnd[rxg*3 + (cgate ? 2 : 0)];
      if (w < 2){
        const long rxh = (long)tt*256 + brow0 + w;
        const ushort4 uh = *(const ushort4*)(xgd + rxh*768 + 256 + j0);
        xgh4[0]=bf2f(uh.x); xgh4[1]=bf2f(uh.y); xgh4[2]=bf2f(uh.z); xgh4[3]=bf2f(uh.w);
        y2h = xnd[rxh*3 + 1];
      }
    }

    // ===== phase 1: r/z matvec, 4 chunks of [32 kp][512 cols] f16-pairs =====
    float s00=0.f,s01=0.f,s02=0.f,s03=0.f, s10=0.f,s11=0.f,s12=0.f,s13=0.f;
#pragma unroll 1
    for (int c = 0; c < 4; c++){
      __syncthreads();                          // chunk c landed, other buf free
      if (c < 3) stage64k8((const char*)wrz_d + (size_t)(c+1)*65536,
                           wbuf + (cb^1)*16384, w, lane);
      const unsigned* wb = (const unsigned*)(wbuf + cb*16384);  // [32 kp][512] u32
      const int kpg = c*32;                     // global kp base of this chunk
#pragma unroll
      for (int kp8 = 0; kp8 < 8; kp8++){
        const int kpl = kq4*8 + kp8;            // local kp within chunk
        const half2_t h0 = as_h2(hsp[kpg + kpl]);
        const half2_t h1 = as_h2(hsp[128 + kpg + kpl]);
        const uint4 wq = *(const uint4*)&wb[kpl*512 + fg*256 + j0];
        s00 = FDOT2(as_h2(wq.x), h0, s00);
        s01 = FDOT2(as_h2(wq.y), h0, s01);
        s02 = FDOT2(as_h2(wq.z), h0, s02);
        s03 = FDOT2(as_h2(wq.w), h0, s03);
        s10 = FDOT2(as_h2(wq.x), h1, s10);
        s11 = FDOT2(as_h2(wq.y), h1, s11);
        s12 = FDOT2(as_h2(wq.z), h1, s12);
        s13 = FDOT2(as_h2(wq.w), h1, s13);
      }
      cb ^= 1;
    }
    {
      // part1 layout: [kq4][row][512]; col = fg*256 + j0
      float* p1 = part + kq4*1024 + fg*256 + j0;
      *(float4*)p1         = make_float4(s00,s01,s02,s03);
      *(float4*)(p1 + 512) = make_float4(s10,s11,s12,s13);
    }
    __syncthreads();                            // B_a: partials visible
    stage64k8(wh_d, wbuf + (cb^1)*16384, w, lane);   // prefetch Wh chunk0
    cb ^= 1;

    // ===== gate chain: waves 0..3, role (crow, cgate) =====
    if (w < 4){
      const float* pa = part + crow*512 + cgate*256 + j0;
      const float4 a0 = *(const float4*)pa;
      const float4 a1 = *(const float4*)(pa + 1024);
      const float4 a2 = *(const float4*)(pa + 2048);
      const float4 a3 = *(const float4*)(pa + 3072);
      float a[4] = { (a0.x+a1.x)+(a2.x+a3.x), (a0.y+a1.y)+(a2.y+a3.y),
                     (a0.z+a1.z)+(a2.z+a3.z), (a0.w+a1.w)+(a2.w+a3.w) };
      const float hn2v = scal[crow*2 + 0];
      const float xn_h = snorm(hn2v), art_h = atanhf(clamp11(xn_h));
      const float p2 = wred(sq_part<4>(a));
      float sc, n2; mt_scale(p2, xn_h, art_h, &sc, &n2);
#pragma unroll
      for (int i = 0; i < 4; i++) a[i] *= sc;
      const float xy = wred(dot_part<4>(a, xgv));
      float m1[4]; madd_vec<4>(a, n2, xgv, y2g, xy, m1);
      float m1n2 = sq_part<4>(m1), xyb = dot_part<4>(m1, bg);
      wred2(m1n2, xyb);
      float m2[4]; madd_vec<4>(m1, m1n2, bg, bg2, xyb, m2);
      const float m2n2 = wred(sq_part<4>(m2));
      const float nn = snorm(m2n2), fgc = atanhf(clamp11(nn))/nn;
      float g4[4];
#pragma unroll
      for (int i = 0; i < 4; i++) g4[i] = 1.f/(1.f + expf(-fgc*m2[i]));
      if (cgate == 0){                          // r-gate: rh = pwmul(r,h)
        float h4[4];
        {
          const half2_t pa0 = as_h2(hsp[crow*128 + lane*2]);
          const half2_t pa1 = as_h2(hsp[crow*128 + lane*2 + 1]);
          h4[0] = (float)pa0[0]; h4[1] = (float)pa0[1];
          h4[2] = (float)pa1[0]; h4[3] = (float)pa1[1];
        }
        float rh[4]; float wx2 = 0.f;
#pragma unroll
        for (int i = 0; i < 4; i++){ rh[i] = g4[i]*h4[i]; wx2 += rh[i]*rh[i]; }
        wx2 = wred(wx2);
        float rhn2, scrh;
        {
          const float wxn = snorm(wx2);
          const float trh = tanhf(wxn/xn_h * art_h);
          scrh = trh/wxn; rhn2 = trh*trh;
          const float n = snorm(rhn2);
          if (n > PMAX_){ const float f = PMAX_/n; scrh *= f; rhn2 *= f*f; }
        }
#pragma unroll
        for (int i = 0; i < 4; i++) rh[i] *= scrh;
        rhp[crow*128 + lane*2]     = packh2(rh[0], rh[1]);
        rhp[crow*128 + lane*2 + 1] = packh2(rh[2], rh[3]);
        if (lane == 0) scal[crow*2 + 1] = rhn2;
      } else {
        *(float4*)&zb[crow*256 + j0] = make_float4(g4[0],g4[1],g4[2],g4[3]);
      }
    }

    // ===== phase 2: h-gate matvec, 2 chunks of [64 kp][256 cols] f16-pairs =====
    float r00=0.f,r01=0.f,r02=0.f,r03=0.f, r10=0.f,r11=0.f,r12=0.f,r13=0.f;
#pragma unroll 1
    for (int c = 0; c < 2; c++){
      __syncthreads();                          // c==0: rhp/zb ready + chunk landed
      if (c < 1) stage64k8((const char*)wh_d + 65536, wbuf + (cb^1)*16384, w, lane);
      const unsigned* wb = (const unsigned*)(wbuf + cb*16384);  // [64 kp][256] u32
      const int kpg = c*64;
#pragma unroll
      for (int kp8 = 0; kp8 < 8; kp8++){
        const int kpl = qk8*8 + kp8;
        const half2_t h0 = as_h2(rhp[kpg + kpl]);
        const half2_t h1 = as_h2(rhp[128 + kpg + kpl]);
        const uint4 wq = *(const uint4*)&wb[kpl*256 + j0];
        r00 = FDOT2(as_h2(wq.x), h0, r00);
        r01 = FDOT2(as_h2(wq.y), h0, r01);
        r02 = FDOT2(as_h2(wq.z), h0, r02);
        r03 = FDOT2(as_h2(wq.w), h0, r03);
        r10 = FDOT2(as_h2(wq.x), h1, r10);
        r11 = FDOT2(as_h2(wq.y), h1, r11);
        r12 = FDOT2(as_h2(wq.z), h1, r12);
        r13 = FDOT2(as_h2(wq.w), h1, r13);
      }
      cb ^= 1;
    }
    {
      // part2 layout: [qk8][row][256]
      float* p2 = part + qk8*512 + j0;
      *(float4*)p2         = make_float4(r00,r01,r02,r03);
      *(float4*)(p2 + 256) = make_float4(r10,r11,r12,r13);
    }
    __syncthreads();                            // B_c
    if (t < 127){
      stage64k8(wrz_d, wbuf + (cb^1)*16384, w, lane);
      cb ^= 1;
    }

    // ===== h-update chain: waves 0..1, row = w =====
    if (w < 2){
      float ah[4];
      {
        float4 p[8];
#pragma unroll
        for (int q = 0; q < 8; q++)
          p[q] = *(const float4*)(part + q*512 + w*256 + j0);
        ah[0] = ((p[0].x+p[1].x)+(p[2].x+p[3].x)) + ((p[4].x+p[5].x)+(p[6].x+p[7].x));
        ah[1] = ((p[0].y+p[1].y)+(p[2].y+p[3].y)) + ((p[4].y+p[5].y)+(p[6].y+p[7].y));
        ah[2] = ((p[0].z+p[1].z)+(p[2].z+p[3].z)) + ((p[4].z+p[5].z)+(p[6].z+p[7].z));
        ah[3] = ((p[0].w+p[1].w)+(p[2].w+p[3].w)) + ((p[4].w+p[5].w)+(p[6].w+p[7].w));
      }
      const float rhn2v = scal[w*2 + 1];
      const float rxn = snorm(rhn2v), artr = atanhf(clamp11(rxn));
      float mx2 = sq_part<4>(ah), xyraw = dot_part<4>(ah, xgh4);
      wred2(mx2, xyraw);
      float sch, pn2; mt_scale(mx2, rxn, artr, &sch, &pn2);
#pragma unroll
      for (int i = 0; i < 4; i++) ah[i] *= sch;
      const float xy = xyraw * sch;
      float m1[4]; madd_vec<4>(ah, pn2, xgh4, y2h, xy, m1);
      float m1n2 = sq_part<4>(m1), xyb = dot_part<4>(m1, bh4);
      wred2(m1n2, xyb);
      float ht[4]; madd_vec<4>(m1, m1n2, bh4, bh2, xyb, ht);
      float htn2 = sq_part<4>(ht);
      float nh[4];
#pragma unroll
      for (int i = 0; i < 4; i++) nh[i] = -h[i];
      float xyd = dot_part<4>(nh, ht);
      wred2(htn2, xyd);
      float dl[4]; madd_vec<4>(nh, hn2, ht, htn2, xyd, dl);
      float z4[4];
      *(float4*)z4 = *(const float4*)&zb[w*256 + j0];
      float pw[4]; float dln2 = 0.f, wz2 = 0.f, xyhr = 0.f;
#pragma unroll
      for (int i = 0; i < 4; i++){
        dln2 += dl[i]*dl[i];
        pw[i] = z4[i]*dl[i];
        wz2  += pw[i]*pw[i];
        xyhr += h[i]*pw[i];
      }
      wred3(dln2, wz2, xyhr);
      float pwn2, scpw;
      {
        const float dn   = snorm(dln2);
        const float artd = atanhf(clamp11(dn));
        const float wzn  = snorm(wz2);
        const float tpw  = tanhf(wzn/dn * artd);
        scpw = tpw/wzn; pwn2 = tpw*tpw;
        const float n = snorm(pwn2);
        if (n > PMAX_){ const float f = PMAX_/n; scpw *= f; pwn2 *= f*f; }
      }
#pragma unroll
      for (int i = 0; i < 4; i++) pw[i] *= scpw;
      const float xyh = xyhr * scpw;
      float hnew[4]; madd_vec<4>(h, hn2, pw, pwn2, xyh, hnew);
#pragma unroll
      for (int i = 0; i < 4; i++) h[i] = hnew[i];
      hn2 = wred(sq_part<4>(h));
      hsp[w*128 + lane*2]     = packh2(h[0], h[1]);
      hsp[w*128 + lane*2 + 1] = packh2(h[2], h[3]);
      if (lane == 0) scal[w*2 + 0] = hn2;
      unsigned short* srow = states + ((long)(brow0 + w)*128 + tt)*256 + j0;
      ushort4 su; su.x=f2bf(h[0]); su.y=f2bf(h[1]); su.z=f2bf(h[2]); su.w=f2bf(h[3]);
      *(ushort4*)srow = su;
    }
    // next iteration's first __syncthreads orders hsp/scal writes vs reads
  }
}

// ---------------------------------------------------------------------------
// Char Mobius-RNN (unchanged)
// ---------------------------------------------------------------------------
__global__ __launch_bounds__(256) void char_rnn(
    const unsigned short* __restrict__ xgc,
    const float* __restrict__ Wc,
    const float* __restrict__ cb,
    float* __restrict__ cstates)
{
  const int wv = threadIdx.x >> 6, lane = threadIdx.x & 63;
  const int b = blockIdx.x*4 + wv;
  const int j0 = lane << 2;
  __shared__ __align__(16) float hs[4][256];
  float h[4] = {0.f,0.f,0.f,0.f};
  float hn2 = 0.f;
#pragma unroll
  for (int i = 0; i < 4; i++) hs[wv][j0+i] = 0.f;
  float cbv[4];
#pragma unroll
  for (int i = 0; i < 4; i++) cbv[i] = cb[j0+i];
  const float cb2 = wred(sq_part<4>(cbv));
  for (int t = 0; t < 16; t++){
    __syncthreads();
    const unsigned short* xr = xgc + ((long)t*256 + b)*256;
    float xgv[4];
    { const ushort4 u = *(const ushort4*)(xr + j0); xgv[0]=bf2f(u.x); xgv[1]=bf2f(u.y); xgv[2]=bf2f(u.z); xgv[3]=bf2f(u.w); }
    float a[4]={0.f,0.f,0.f,0.f};
#pragma unroll 2
    for (int k0 = 0; k0 < 256; k0 += 4){
      const float4 hk = *(const float4*)&hs[wv][k0];
#pragma unroll
      for (int kk = 0; kk < 4; kk++){
        const float hv = (&hk.x)[kk];
        const float4 w4 = *(const float4*)(Wc + (long)(k0+kk)*256 + j0);
        a[0] += hv*w4.x; a[1] += hv*w4.y; a[2] += hv*w4.z; a[3] += hv*w4.w;
      }
    }
    const float mxn2 = wred(sq_part<4>(a));
    float pn2; mt_project<4>(a, mxn2, hn2, &pn2);
    const float y2 = wred(sq_part<4>(xgv));
    const float xy = wred(dot_part<4>(a, xgv));
    float m1[4]; madd_vec<4>(a, pn2, xgv, y2, xy, m1);
    const float m1n2 = wred(sq_part<4>(m1));
    const float xyb  = wred(dot_part<4>(m1, cbv));
    float m2[4]; madd_vec<4>(m1, m1n2, cbv, cb2, xyb, m2);
    float m2n2 = wred(sq_part<4>(m2));
    project_vec<4>(m2, &m2n2);
#pragma unroll
    for (int i = 0; i < 4; i++) h[i] = m2[i];
    hn2 = m2n2;
    *(float4*)&hs[wv][j0] = make_float4(h[0],h[1],h[2],h[3]);
    *(float4*)(cstates + ((long)b*16 + t)*256 + j0) = make_float4(h[0],h[1],h[2],h[3]);
  }
}

// ---------------------------------------------------------------------------
// cc concat (unchanged)
// ---------------------------------------------------------------------------
__global__ __launch_bounds__(256) void cc_rowwise(const unsigned short* __restrict__ sf,
    const unsigned short* __restrict__ sb, const float* __restrict__ mxa,
    const float* __restrict__ mxb, const float* __restrict__ ccb,
    unsigned short* __restrict__ ctxo, int rowoff)
{
  const int wv = threadIdx.x >> 6, lane = threadIdx.x & 63;
  const int rloc = blockIdx.x*4 + wv;
  const long r = rowoff + rloc;
  float s = 0.f;
#pragma unroll
  for (int i = 0; i < 4; i++){ const float v = bf2f(sf[r*256 + i*64+lane]); s += v*v; }
  const float sfn2 = wred(s);
  s = 0.f;
#pragma unroll
  for (int i = 0; i < 4; i++){ const float v = bf2f(sb[r*256 + i*64+lane]); s += v*v; }
  const float sbn2 = wred(s);
  float A[8], Bv[8];
#pragma unroll
  for (int i = 0; i < 8; i++){ A[i]  = mxa[(long)rloc*512 + i*64+lane];
                               Bv[i] = mxb[(long)rloc*512 + i*64+lane]; }
  float pan2, pbn2;
  { const float n2 = wred(sq_part<8>(A));  mt_project<8>(A,  n2, sfn2, &pan2); }
  { const float n2 = wred(sq_part<8>(Bv)); mt_project<8>(Bv, n2, sbn2, &pbn2); }
  const float xy = wred(dot_part<8>(A, Bv));
  float M1[8]; madd_vec<8>(A, pan2, Bv, pbn2, xy, M1);
  const float m1n2 = wred(sq_part<8>(M1));
  float Cb[8];
#pragma unroll
  for (int i = 0; i < 8; i++) Cb[i] = ccb[i*64+lane];
  const float cb2 = wred(sq_part<8>(Cb));
  const float xyb = wred(dot_part<8>(M1, Cb));
  float M2[8]; madd_vec<8>(M1, m1n2, Cb, cb2, xyb, M2);
  float m2n2 = wred(sq_part<8>(M2));
  project_vec<8>(M2, &m2n2);
#pragma unroll
  for (int i = 0; i < 8; i++) ctxo[r*512 + i*64+lane] = f2bf(M2[i]);
}

// attn_emb = madd(ctx(bf16), pe) -> BF16 out + sqn of rounded
__global__ __launch_bounds__(256) void attn_add(const unsigned short* __restrict__ ctxv,
    const int* __restrict__ pos, const float* __restrict__ pet,
    unsigned short* __restrict__ oemb, float* __restrict__ osqn)
{
  const int wv = threadIdx.x >> 6, lane = threadIdx.x & 63;
  const long r = blockIdx.x*4 + wv;
  float X[8];
#pragma unroll
  for (int i = 0; i < 8; i++) X[i] = bf2f(ctxv[r*512 + i*64+lane]);
  const float x2 = wred(sq_part<8>(X));
  const int p = pos[r];
  float Y[8];
#pragma unroll
  for (int i = 0; i < 8; i++) Y[i] = pet[(long)p*512 + i*64+lane];
  const float y2 = wred(sq_part<8>(Y));
  const float xy = wred(dot_part<8>(X, Y));
  float O[8]; madd_vec<8>(X, x2, Y, y2, xy, O);
  float s = 0.f;
#pragma unroll
  for (int i = 0; i < 8; i++){
    const unsigned short u = f2bf(O[i]);
    oemb[r*512 + i*64+lane] = u;
    const float rv = bf2f(u);
    s += rv*rv;
  }
  s = wred(s);
  if (lane == 0) osqn[r] = s;
}

// mention variant (bf16 out)
__global__ __launch_bounds__(256) void attn_add_m(const float* __restrict__ mvv,
    const int* __restrict__ mentions, const float* __restrict__ pet,
    unsigned short* __restrict__ oemb, float* __restrict__ osqn)
{
  const int wv = threadIdx.x >> 6, lane = threadIdx.x & 63;
  const long r = blockIdx.x*4 + wv;
  float X[8];
#pragma unroll
  for (int i = 0; i < 8; i++) X[i] = mvv[r*512 + i*64+lane];
  const float x2 = wred(sq_part<8>(X));
  const int men = mentions[r];
  const int p = (men > 0) ? (int)(r & 7) + 1 : 0;
  float Y[8];
#pragma unroll
  for (int i = 0; i < 8; i++) Y[i] = pet[(long)p*512 + i*64+lane];
  const float y2 = wred(sq_part<8>(Y));
  const float xy = wred(dot_part<8>(X, Y));
  float O[8]; madd_vec<8>(X, x2, Y, y2, xy, O);
  float s = 0.f;
#pragma unroll
  for (int i = 0; i < 8; i++){
    const unsigned short u = f2bf(O[i]);
    oemb[r*512 + i*64+lane] = u;
    const float rv = bf2f(u);
    s += rv*rv;
  }
  s = wred(s);
  if (lane == 0) osqn[r] = s;
}

// q/k projection + pdist (unchanged)
__global__ __launch_bounds__(256) void qk_pdist(const float* __restrict__ mxq,
    const float* __restrict__ mxk, const float* __restrict__ sqn,
    const float* __restrict__ bq, const float* __restrict__ bk,
    float* __restrict__ dout)
{
  const int wv = threadIdx.x >> 6, lane = threadIdx.x & 63;
  const int r = blockIdx.x*4 + wv;
  const float xn2 = sqn[r];
  float Q[8];
#pragma unroll
  for (int i = 0; i < 8; i++) Q[i] = mxq[(long)r*512 + i*64+lane];
  { const float n2 = wred(sq_part<8>(Q)); float pn2; mt_project<8>(Q, n2, xn2, &pn2);
    float Bq[8];
#pragma unroll
    for (int i = 0; i < 8; i++) Bq[i] = bq[i*64+lane];
    const float b2 = wred(sq_part<8>(Bq));
    const float xy = wred(dot_part<8>(Q, Bq));
    float O[8]; madd_vec<8>(Q, pn2, Bq, b2, xy, O);
#pragma unroll
    for (int i = 0; i < 8; i++) Q[i] = O[i];
  }
  float qn2 = wred(sq_part<8>(Q));
  project_vec<8>(Q, &qn2);
  float Kv[8];
#pragma unroll
  for (int i = 0; i < 8; i++) Kv[i] = mxk[(long)r*512 + i*64+lane];
  { const float n2 = wred(sq_part<8>(Kv)); float pn2; mt_project<8>(Kv, n2, xn2, &pn2);
    float Bk[8];
#pragma unroll
    for (int i = 0; i < 8; i++) Bk[i] = bk[i*64+lane];
    const float b2 = wred(sq_part<8>(Bk));
    const float xy = wred(dot_part<8>(Kv, Bk));
    float O[8]; madd_vec<8>(Kv, pn2, Bk, b2, xy, O);
#pragma unroll
    for (int i = 0; i < 8; i++) Kv[i] = O[i];
  }
  float kn2 = wred(sq_part<8>(Kv));
  project_vec<8>(Kv, &kn2);
  float NQ[8];
#pragma unroll
  for (int i = 0; i < 8; i++) NQ[i] = -Q[i];
  const float xy = wred(dot_part<8>(NQ, Kv));
  float Z[8]; madd_vec<8>(NQ, qn2, Kv, kn2, xy, Z);
  const float zn2 = wred(sq_part<8>(Z));
  const float d = 2.f * atanhf(clamp11(snorm(zn2)));
  if (lane == 0) dout[r] = d;
}

__global__ __launch_bounds__(256) void softmax128(const float* __restrict__ d,
    const float* __restrict__ beta, float* __restrict__ w)
{
  const int wv = threadIdx.x >> 6, lane = threadIdx.x & 63;
  const int b = blockIdx.x*4 + wv;
  const float bt = beta[0];
  const float x0 = -bt * d[b*128 + lane];
  const float x1 = -bt * d[b*128 + 64 + lane];
  const float m = wredmax(fmaxf(x0, x1));
  const float e0 = expf(x0 - m), e1 = expf(x1 - m);
  const float s = wred(e0 + e1);
  w[b*128 + lane]      = e0 / s;
  w[b*128 + 64 + lane] = e1 / s;
}

__global__ void softmax8(const float* __restrict__ d, const float* __restrict__ beta,
                         float* __restrict__ w)
{
  const int b = threadIdx.x;   // 256
  const float bt = beta[0];
  float x[8]; float m = -1e30f;
#pragma unroll
  for (int i = 0; i < 8; i++){ x[i] = -bt * d[b*8+i]; m = fmaxf(m, x[i]); }
  float s = 0.f;
#pragma unroll
  for (int i = 0; i < 8; i++){ x[i] = expf(x[i]-m); s += x[i]; }
#pragma unroll
  for (int i = 0; i < 8; i++) w[b*8+i] = x[i] / s;
}

// weighted gyromidpoint via Klein model; one wave per batch row (small Lseq)
template<int NPL, bool BF16V, bool HASW>
__global__ __launch_bounds__(256) void midpoint_kernel(const void* __restrict__ vals,
    const float* __restrict__ wts, float* __restrict__ outp, int Lseq)
{
  const int wv = threadIdx.x >> 6, lane = threadIdx.x & 63;
  const int b = blockIdx.x*4 + wv;
  const int D = NPL*64;
  float num[NPL];
#pragma unroll
  for (int i = 0; i < NPL; i++) num[i] = 0.f;
  float den = 0.f;
  for (int l = 0; l < Lseq; l++){
    const long base = ((long)b*Lseq + l)*D;
    float v[NPL]; float s = 0.f;
#pragma unroll
    for (int i = 0; i < NPL; i++){
      v[i] = BF16V ? bf2f(((const unsigned short*)vals)[base + i*64+lane])
                   : ((const float*)vals)[base + i*64+lane];
      s += v[i]*v[i];
    }
    const float v2 = wred(s);
    const float f = 2.f/(1.f + v2);
    const float kl2 = v2*f*f;
    const float gamma = 1.f/sqrtf(fmaxf(1.f - kl2, EPS_));
    const float wgt = HASW ? wts[b*Lseq + l] : 1.f;
    const float wg = wgt*gamma;
#pragma unroll
    for (int i = 0; i < NPL; i++) num[i] += wg*(f*v[i]);
    den += wg;
  }
  den = fmaxf(den, EPS_);
  float x[NPL]; float s = 0.f;
#pragma unroll
  for (int i = 0; i < NPL; i++){ x[i] = num[i]/den; s += x[i]*x[i]; }
  const float k2 = wred(s);
  const float inv = 1.f/(1.f + sqrtf(fmaxf(1.f - k2, EPS_)));
#pragma unroll
  for (int i = 0; i < NPL; i++) outp[(long)b*D + i*64+lane] = x[i]*inv;
}

// wide gyromidpoint for ctx (unchanged)
__global__ __launch_bounds__(512) void midpoint_wide(
    const unsigned short* __restrict__ vals,
    const float* __restrict__ wts,
    float* __restrict__ outp)
{
  __shared__ float pnum[8][512];
  __shared__ float pden[8];
  __shared__ float red[512];
  __shared__ float kk2[1];
  const int b = blockIdx.x;
  const int tid = threadIdx.x;
  const int w = tid >> 6, lane = tid & 63;
  float num[8] = {0.f,0.f,0.f,0.f,0.f,0.f,0.f,0.f};
  float den = 0.f;
  for (int l = w; l < 128; l += 8){
    const long base = ((long)b*128 + l)*512;
    float v[8]; float s = 0.f;
#pragma unroll
    for (int i = 0; i < 8; i++){
      v[i] = bf2f(vals[base + i*64 + lane]);
      s += v[i]*v[i];
    }
    const float v2 = wred(s);
    const float f = 2.f/(1.f + v2);
    const float kl2 = v2*f*f;
    const float gamma = 1.f/sqrtf(fmaxf(1.f - kl2, EPS_));
    const float wg = wts[b*128 + l]*gamma;
#pragma unroll
    for (int i = 0; i < 8; i++) num[i] += wg*(f*v[i]);
    den += wg;
  }
#pragma unroll
  for (int i = 0; i < 8; i++) pnum[w][i*64 + lane] = num[i];
  if (lane == 0) pden[w] = den;
  __syncthreads();
  float nsum = 0.f, dsum = 0.f;
#pragma unroll
  for (int p = 0; p < 8; p++){ nsum += pnum[p][tid]; dsum += pden[p]; }
  dsum = fmaxf(dsum, EPS_);
  const float x = nsum/dsum;
  red[tid] = x*x;
  __syncthreads();
  if (tid < 64){
    float s2 = 0.f;
#pragma unroll
    for (int i = 0; i < 8; i++) s2 += red[tid + i*64];
    s2 = wred(s2);
    if (tid == 0) kk2[0] = s2;
  }
  __syncthreads();
  const float k2 = kk2[0];
  const float inv = 1.f/(1.f + sqrtf(fmaxf(1.f - k2, EPS_)));
  outp[(long)b*512 + tid] = x*inv;
}

// mention w2s mobius_linear with tanh nonlinearity (unchanged)
__global__ __launch_bounds__(256) void mv_rowwise(const float* __restrict__ mx,
    const float* __restrict__ xsqn, const float* __restrict__ bb, float* __restrict__ outp)
{
  const int wv = threadIdx.x >> 6, lane = threadIdx.x & 63;
  const long r = blockIdx.x*4 + wv;
  float M[8];
#pragma unroll
  for (int i = 0; i < 8; i++) M[i] = mx[r*512 + i*64+lane];
  { const float n2 = wred(sq_part<8>(M)); float pn2; mt_project<8>(M, n2, xsqn[r], &pn2);
    float Bv[8];
#pragma unroll
    for (int i = 0; i < 8; i++) Bv[i] = bb[i*64+lane];
    const float b2 = wred(sq_part<8>(Bv));
    const float xy = wred(dot_part<8>(M, Bv));
    float O[8]; madd_vec<8>(M, pn2, Bv, b2, xy, O);
#pragma unroll
    for (int i = 0; i < 8; i++) M[i] = O[i];
  }
  float on2 = wred(sq_part<8>(M));
  project_vec<8>(M, &on2);
  { const float n = snorm(on2);
    const float fac = atanhf(clamp11(n))/n;
#pragma unroll
    for (int i = 0; i < 8; i++) M[i] = tanhf(fac*M[i]); }
  const float un2 = wred(sq_part<8>(M));
  { const float n = snorm(un2);
    const float fac = tanhf(n)/n;
    float en2 = fac*fac*un2;
#pragma unroll
    for (int i = 0; i < 8; i++) M[i] *= fac;
    project_vec<8>(M, &en2); }
#pragma unroll
  for (int i = 0; i < 8; i++) outp[r*512 + i*64+lane] = M[i];
}

// joint concat (unchanged)
__global__ __launch_bounds__(256) void final_rowwise(const float* __restrict__ jm,
    const float* __restrict__ jc, const float* __restrict__ jch,
    const float* __restrict__ mvec, const float* __restrict__ cvec,
    const float* __restrict__ chvec, const float* __restrict__ fcb,
    float* __restrict__ joint)
{
  const int wv = threadIdx.x >> 6, lane = threadIdx.x & 63;
  const long b = blockIdx.x*4 + wv;
  float s;
  s = 0.f; for (int i = 0; i < 8; i++){ const float v = mvec[b*512 + i*64+lane]; s += v*v; }
  const float mn2 = wred(s);
  s = 0.f; for (int i = 0; i < 8; i++){ const float v = cvec[b*512 + i*64+lane]; s += v*v; }
  const float cn2 = wred(s);
  s = 0.f; for (int i = 0; i < 4; i++){ const float v = chvec[b*256 + i*64+lane]; s += v*v; }
  const float chn2 = wred(s);
  float A[20];
#pragma unroll
  for (int i = 0; i < 20; i++) A[i] = jm[b*1280 + i*64+lane];
  float an2;
  { const float n2 = wred(sq_part<20>(A)); mt_project<20>(A, n2, mn2, &an2); }
  float T[20];
#pragma unroll
  for (int i = 0; i < 20; i++) T[i] = jc[b*1280 + i*64+lane];
  float tn2;
  { const float n2 = wred(sq_part<20>(T)); mt_project<20>(T, n2, cn2, &tn2); }
  { const float xy = wred(dot_part<20>(A, T));
    float O[20]; madd_vec<20>(A, an2, T, tn2, xy, O);
#pragma unroll
    for (int i = 0; i < 20; i++) A[i] = O[i];
    an2 = wred(sq_part<20>(A)); }
#pragma unroll
  for (int i = 0; i < 20; i++) T[i] = jch[b*1280 + i*64+lane];
  { const float n2 = wred(sq_part<20>(T)); mt_project<20>(T, n2, chn2, &tn2); }
  { const float xy = wred(dot_part<20>(A, T));
    float O[20]; madd_vec<20>(A, an2, T, tn2, xy, O);
#pragma unroll
    for (int i = 0; i < 20; i++) A[i] = O[i];
    an2 = wred(sq_part<20>(A)); }
#pragma unroll
  for (int i = 0; i < 20; i++) T[i] = fcb[i*64+lane];
  tn2 = wred(sq_part<20>(T));
  { const float xy = wred(dot_part<20>(A, T));
    float O[20]; madd_vec<20>(A, an2, T, tn2, xy, O);
#pragma unroll
    for (int i = 0; i < 20; i++) A[i] = O[i];
    an2 = wred(sq_part<20>(A)); }
  project_vec<20>(A, &an2);
#pragma unroll
  for (int i = 0; i < 20; i++) joint[b*1280 + i*64+lane] = A[i];
}

// hyperbolic MLR head (unchanged)
__global__ __launch_bounds__(256) void mlr_kernel(const float* __restrict__ joint,
    const float* __restrict__ P, const float* __restrict__ A, float* __restrict__ outp)
{
  const int wv = threadIdx.x >> 6, lane = threadIdx.x & 63;
  const int pair = blockIdx.x*4 + wv;
  const long b = pair >> 7, c = pair & 127;
  float Pv[20], J[20];
#pragma unroll
  for (int i = 0; i < 20; i++){
    Pv[i] = -P[c*1280 + i*64+lane];
    J[i]  = joint[b*1280 + i*64+lane];
  }
  const float p2 = wred(sq_part<20>(Pv));
  const float j2 = wred(sq_part<20>(J));
  const float xy = wred(dot_part<20>(Pv, J));
  float Z[20]; madd_vec<20>(Pv, p2, J, j2, xy, Z);
  float sza = 0.f, sz2 = 0.f, sa2 = 0.f;
#pragma unroll
  for (int i = 0; i < 20; i++){
    const float a = A[c*1280 + i*64+lane];
    sza += Z[i]*a; sz2 += Z[i]*Z[i]; sa2 += a*a;
  }
  float za = sza, z2 = sz2, a2 = sa2;
  wred3(za, z2, a2);
  const float an = sqrtf(fmaxf(a2, EPS_));
  const float v = 2.f*za / (fmaxf(1.f - z2, EPS_)*an);
  if (lane == 0) outp[pair] = 2.f*an*asinhf(v);
}

// ---------------------------------------------------------------------------
extern "C" void kernel_launch(void* const* d_in, const int* in_sizes, int n_in,
                              void* d_out, int out_size, void* d_ws, size_t ws_size,
                              hipStream_t stream)
{
  (void)in_sizes; (void)n_in; (void)out_size;
  const int*   context   = (const int*)  d_in[0];
  const int*   ctx_position=(const int*) d_in[1];
  const int*   mentions  = (const int*)  d_in[2];
  const int*   mchars    = (const int*)  d_in[3];
  const float* word_lut  = (const float*)d_in[4];
  const float* char_lut  = (const float*)d_in[5];
  const float* gf_Wih    = (const float*)d_in[6];
  const float* gf_Whh    = (const float*)d_in[7];
  const float* gf_b      = (const float*)d_in[8];
  const float* gb_Wih    = (const float*)d_in[9];
  const float* gb_Whh    = (const float*)d_in[10];
  const float* gb_b      = (const float*)d_in[11];
  const float* w2s_W     = (const float*)d_in[12];
  const float* w2s_b     = (const float*)d_in[13];
  const float* men_pos   = (const float*)d_in[14];
  const float* men_Wq    = (const float*)d_in[15];
  const float* men_bq    = (const float*)d_in[16];
  const float* men_Wk    = (const float*)d_in[17];
  const float* men_bk    = (const float*)d_in[18];
  const float* men_beta  = (const float*)d_in[19];
  const float* char_W    = (const float*)d_in[20];
  const float* char_U    = (const float*)d_in[21];
  const float* char_b    = (const float*)d_in[22];
  const float* cc_Wa     = (const float*)d_in[23];
  const float* cc_Wb     = (const float*)d_in[24];
  const float* cc_bias   = (const float*)d_in[25];
  const float* ctx_pos_t = (const float*)d_in[26];
  const float* ctx_Wq    = (const float*)d_in[27];
  const float* ctx_bq    = (const float*)d_in[28];
  const float* ctx_Wk    = (const float*)d_in[29];
  const float* ctx_bk    = (const float*)d_in[30];
  const float* ctx_beta  = (const float*)d_in[31];
  const float* fc_Wm     = (const float*)d_in[32];
  const float* fc_Wc     = (const float*)d_in[33];
  const float* fc_Wch    = (const float*)d_in[34];
  const float* fc_bias   = (const float*)d_in[35];
  const float* mlr_p     = (const float*)d_in[36];
  const float* mlr_a     = (const float*)d_in[37];
  float* out = (float*)d_out;

  // ---- workspace bump allocator ----
  char* wsb = (char*)d_ws;
  size_t off = 0;
  auto alloc = [&](size_t bytes) -> void* {
    void* p = wsb + off;
    off += (bytes + 255) & ~(size_t)255;
    return p;
  };
  float* WtHH = (float*)alloc(2UL*256*768*4);
  unsigned* Wrz2 = (unsigned*)alloc(2UL*128*512*4);   // f16 k-pair (r|z)
  unsigned* Wh2  = (unsigned*)alloc(2UL*128*256*4);   // f16 k-pair (h)
  unsigned short* WihP  = (unsigned short*)alloc(2UL*768*320*2);
  unsigned short* ctxWqP= (unsigned short*)alloc(512UL*512*2);
  unsigned short* ctxWkP= (unsigned short*)alloc(512UL*512*2);
  unsigned short* ccWaP = (unsigned short*)alloc(512UL*256*2);
  unsigned short* ccWbP = (unsigned short*)alloc(512UL*256*2);
  unsigned short* menWqP= (unsigned short*)alloc(512UL*512*2);
  unsigned short* menWkP= (unsigned short*)alloc(512UL*512*2);
  unsigned short* w2sP  = (unsigned short*)alloc(512UL*320*2);
  unsigned short* charUP= (unsigned short*)alloc(256UL*256*2);
  int*   ctxidx = (int*)alloc(32768UL*4);
  int*   chidx  = (int*)alloc(4096UL*4);
  float* xsqn   = (float*)alloc(32768UL*4);
  float* msqn   = (float*)alloc(2048UL*4);
  float* chsqn  = (float*)alloc(4096UL*4);
  unsigned short* xg = (unsigned short*)alloc(2UL*32768*768*2);
  float* xgn2 = (float*)alloc(2UL*32768*3*4);
  float* chn2d = (float*)alloc(4096UL*4);
  unsigned short* states_f = (unsigned short*)alloc(32768UL*256*2);
  unsigned short* states_b = (unsigned short*)alloc(32768UL*256*2);
  unsigned short* ctxv = (unsigned short*)alloc(32768UL*512*2);
  float* attn_sqn = (float*)alloc(32768UL*4);
  float* dctx = (float*)alloc(32768UL*4);
  float* wctx = (float*)alloc(32768UL*4);
  float* ctx_vec = (float*)alloc(256UL*512*4);
  float* mxbuf = (float*)alloc(2UL*8192*512*4);
  float* mv = (float*)alloc(2048UL*512*4);
  unsigned short* attn_embm = (unsigned short*)alloc(2048UL*512*2);
  float* amsqn = (float*)alloc(2048UL*4);
  float* dm = (float*)alloc(2048UL*4);
  float* wm = (float*)alloc(2048UL*4);
  float* mention_vec = (float*)alloc(256UL*512*4);
  unsigned short* xgc = (unsigned short*)alloc(4096UL*256*2);
  float* char_states = (float*)alloc(4096UL*256*4);
  float* char_vec = (float*)alloc(256UL*256*4);
  float* joint = (float*)alloc(256UL*1280*4);
  if (off > ws_size) return;
  unsigned short* attn_embc = xg;                  // overlay: xg dead after GRU
  float* mxh0 = mxbuf;
  float* mxh1 = mxbuf + 8192UL*512;

  // ---- weight transposes + packs ----
  transpose_k<<<dim3(8,24), 256,0,stream>>>(gf_Whh, WtHH,            768, 256);
  transpose_k<<<dim3(8,24), 256,0,stream>>>(gb_Whh, WtHH + 256*768,  768, 256);
  pack_whh_f16<<<768,256,0,stream>>>(WtHH, Wrz2, Wh2);
  pack_wih<<<1920,256,0,stream>>>(gf_Wih, gb_Wih, WihP);
  packT16<<<dim3(16,16),256,0,stream>>>(ctx_Wq, ctxWqP, 512, 512, 512);
  packT16<<<dim3(16,16),256,0,stream>>>(ctx_Wk, ctxWkP, 512, 512, 512);
  packT16<<<dim3(8,16), 256,0,stream>>>(cc_Wa,  ccWaP,  256, 512, 256);
  packT16<<<dim3(8,16), 256,0,stream>>>(cc_Wb,  ccWbP,  256, 512, 256);
  packT16<<<dim3(16,16),256,0,stream>>>(men_Wq, menWqP, 512, 512, 512);
  packT16<<<dim3(16,16),256,0,stream>>>(men_Wk, menWkP, 512, 512, 512);
  packT16<<<dim3(10,16),256,0,stream>>>(w2s_W,  w2sP,   300, 512, 320);
  packT16<<<dim3(8,8),  256,0,stream>>>(char_U, charUP, 256, 256, 256);

  // ---- gather indices + input sqn ----
  build_idx<<<144,256,0,stream>>>(context, mchars, ctxidx, chidx);
  sqn_gather<<<8192,256,0,stream>>>(word_lut, ctxidx, 300, xsqn);
  sqn_gather<<<512, 256,0,stream>>>(word_lut, mentions, 300, msqn);
  sqn_gather<<<1024,256,0,stream>>>(char_lut, chidx, 256, chsqn);

  // ---- GRU input precompute: xg[dir] = mobius_matvec(emb, Wih^T), bf16 ----
  for (int d2 = 0; d2 < 2; d2++){
    const unsigned short* wihp = WihP + (size_t)d2*768*320;
    for (int c = 0; c < 4; c++){
      mfma_mm<1><<<dim3(6,128),256,0,stream>>>(word_lut, ctxidx + c*8192, wihp,
                                               mxbuf, 8192, 768, 300, 320);
      xg_transform<<<6144,256,0,stream>>>(mxbuf, xsqn + c*8192,
          xg + ((size_t)d2*32768 + (size_t)c*8192)*768,
          xgn2 + ((size_t)d2*32768 + (size_t)c*8192)*3, 3);
    }
  }

  // ---- bidirectional Mobius GRU (v9 f16-dot2) ----
  (void)hipFuncSetAttribute((const void*)gru_kernel,
      hipFuncAttributeMaxDynamicSharedMemorySize, GRU_LDS_BYTES);
  gru_kernel<<<256,512,GRU_LDS_BYTES,stream>>>(xg, xgn2, Wrz2, Wh2,
                                               gf_b, gb_b, states_f, states_b);

  // ---- mobius concat of directions -> ctx (bf16) ----
  for (int c = 0; c < 4; c++){
    mfma_mm<2><<<dim3(4,128),256,0,stream>>>(states_f + (size_t)c*8192*256, nullptr,
                                             ccWaP, mxh0, 8192, 512, 256, 256);
    mfma_mm<2><<<dim3(4,128),256,0,stream>>>(states_b + (size_t)c*8192*256, nullptr,
                                             ccWbP, mxh1, 8192, 512, 256, 256);
    cc_rowwise<<<2048,256,0,stream>>>(states_f, states_b, mxh0, mxh1, cc_bias,
                                      ctxv, c*8192);
  }

  // ---- context distance attention ----
  attn_add<<<8192,256,0,stream>>>(ctxv, ctx_position, ctx_pos_t, attn_embc, attn_sqn);
  for (int c = 0; c < 4; c++){
    mfma_mm<2><<<dim3(4,128),256,0,stream>>>(attn_embc + (size_t)c*8192*512, nullptr,
                                             ctxWqP, mxh0, 8192, 512, 512, 512);
    mfma_mm<2><<<dim3(4,128),256,0,stream>>>(attn_embc + (size_t)c*8192*512, nullptr,
                                             ctxWkP, mxh1, 8192, 512, 512, 512);
    qk_pdist<<<2048,256,0,stream>>>(mxh0, mxh1, attn_sqn + c*8192, ctx_bq, ctx_bk,
                                    dctx + c*8192);
  }
  softmax128<<<64,256,0,stream>>>(dctx, ctx_beta, wctx);
  midpoint_wide<<<256,512,0,stream>>>(ctxv, wctx, ctx_vec);

  // ---- mention encoder ----
  mfma_mm<1><<<dim3(4,32),256,0,stream>>>(word_lut, mentions, w2sP, mxh0,
                                          2048, 512, 300, 320);
  mv_rowwise<<<512,256,0,stream>>>(mxh0, msqn, w2s_b, mv);
  attn_add_m<<<512,256,0,stream>>>(mv, mentions, men_pos, attn_embm, amsqn);
  mfma_mm<2><<<dim3(4,32),256,0,stream>>>(attn_embm, nullptr, menWqP, mxh0,
                                          2048, 512, 512, 512);
  mfma_mm<2><<<dim3(4,32),256,0,stream>>>(attn_embm, nullptr, menWkP, mxh1,
                                          2048, 512, 512, 512);
  qk_pdist<<<512,256,0,stream>>>(mxh0, mxh1, amsqn, men_bq, men_bk, dm);
  softmax8<<<1,256,0,stream>>>(dm, men_beta, wm);
  midpoint_kernel<8,false,true><<<64,256,0,stream>>>(mv, wm, mention_vec, 8);

  // ---- char encoder ----
  mfma_mm<1><<<dim3(2,64),256,0,stream>>>(char_lut, chidx, charUP, mxh0,
                                          4096, 256, 256, 256);
  xg_transform<<<1024,256,0,stream>>>(mxh0, chsqn, xgc, chn2d, 1);
  char_rnn<<<64,256,0,stream>>>(xgc, char_W, char_b, char_states);
  midpoint_kernel<4,false,false><<<64,256,0,stream>>>(char_states, nullptr, char_vec, 16);

  // ---- full mobius concat + MLR (small, f32 path) ----
  float* jm = mxh0;
  float* jc = mxh0 + 256UL*1280;
  float* jch = mxh0 + 2UL*256*1280;
  mm_kernel<0><<<dim3(10,2),256,0,stream>>>(mention_vec, nullptr, fc_Wm, jm, 256, 1280, 512);
  mm_kernel<0><<<dim3(10,2),256,0,stream>>>(ctx_vec,     nullptr, fc_Wc, jc, 256, 1280, 512);
  mm_kernel<0><<<dim3(10,2),256,0,stream>>>(char_vec,    nullptr, fc_Wch, jch, 256, 1280, 256);
  final_rowwise<<<64,256,0,stream>>>(jm, jc, jch, mention_vec, ctx_vec, char_vec,
                                     fc_bias, joint);
  mlr_kernel<<<8192,256,0,stream>>>(joint, mlr_p, mlr_a, out);
}

// Round 12
// 2486.082 us; speedup vs baseline: 1.2076x; 1.0153x over previous
//
#include <hip/hip_runtime.h>
#include <cstddef>
#include <cstdint>

// ---------------------------------------------------------------------------
// Hyperbolic (Poincare-ball) entity-typing forward pass, MI355X / gfx950.
// Round 12: fused Q|K projection GEMMs (B^T packed [1024][512], one mfma_mm
// per chunk, A read once); qk_pdist takes a row-stride. GRU v9 (fdot2) and
// everything else unchanged from round 11 (2524us, passing).
// ---------------------------------------------------------------------------

#define EPS_  1e-15f
#define PMAX_ 0.99999f    // 1 - 1e-5

typedef __attribute__((ext_vector_type(8))) short bf16x8;
typedef __attribute__((ext_vector_type(4))) float f32x4;
typedef __attribute__((ext_vector_type(8))) unsigned short us8;
typedef _Float16 half2_t __attribute__((ext_vector_type(2)));

__device__ __forceinline__ half2_t as_h2(unsigned u){
  union { unsigned u; half2_t h; } v; v.u = u; return v.h;
}
__device__ __forceinline__ unsigned packh2(float a, float b){
  union { half2_t h; unsigned u; } v;
  v.h[0] = (_Float16)a; v.h[1] = (_Float16)b; return v.u;
}
#if __has_builtin(__builtin_amdgcn_fdot2)
#define FDOT2(a,b,c) __builtin_amdgcn_fdot2((a),(b),(c),false)
#else
#define FDOT2(a,b,c) ((c) + (float)(a)[0]*(float)(b)[0] + (float)(a)[1]*(float)(b)[1])
#endif

__device__ __forceinline__ float wred(float v){
#pragma unroll
  for (int o = 32; o; o >>= 1) v += __shfl_xor(v, o, 64);
  return v;
}
__device__ __forceinline__ void wred2(float& a, float& b){
#pragma unroll
  for (int o = 32; o; o >>= 1){ a += __shfl_xor(a, o, 64); b += __shfl_xor(b, o, 64); }
}
__device__ __forceinline__ void wred3(float& a, float& b, float& c){
#pragma unroll
  for (int o = 32; o; o >>= 1){
    a += __shfl_xor(a, o, 64); b += __shfl_xor(b, o, 64); c += __shfl_xor(c, o, 64);
  }
}
__device__ __forceinline__ void wred4(float& a, float& b, float& c, float& d){
#pragma unroll
  for (int o = 32; o; o >>= 1){
    a += __shfl_xor(a, o, 64); b += __shfl_xor(b, o, 64);
    c += __shfl_xor(c, o, 64); d += __shfl_xor(d, o, 64);
  }
}
__device__ __forceinline__ float wredmax(float v){
#pragma unroll
  for (int o = 32; o; o >>= 1) v = fmaxf(v, __shfl_xor(v, o, 64));
  return v;
}
__device__ __forceinline__ float snorm(float s){ return sqrtf(fmaxf(s, EPS_)); }
__device__ __forceinline__ float clamp11(float x){
  return fminf(fmaxf(x, -1.f + 1e-7f), 1.f - 1e-7f);
}
__device__ __forceinline__ float bf2f(unsigned short u){
  union { unsigned int i; float f; } v; v.i = ((unsigned int)u) << 16; return v.f;
}
__device__ __forceinline__ unsigned short f2bf(float f){
  union { float f; unsigned int i; } v; v.f = f;
  unsigned int x = v.i;
  x += 0x7fffu + ((x >> 16) & 1u);   // RNE
  return (unsigned short)(x >> 16);
}
__device__ __forceinline__ float bflo(unsigned u){
  union { unsigned i; float f; } v; v.i = u << 16; return v.f;
}
__device__ __forceinline__ float bfhi(unsigned u){
  union { unsigned i; float f; } v; v.i = u & 0xffff0000u; return v.f;
}

template<int N>
__device__ __forceinline__ float sq_part(const float* a){
  float s = 0.f;
#pragma unroll
  for (int i = 0; i < N; i++) s += a[i]*a[i];
  return s;
}
template<int N>
__device__ __forceinline__ float dot_part(const float* a, const float* b){
  float s = 0.f;
#pragma unroll
  for (int i = 0; i < N; i++) s += a[i]*b[i];
  return s;
}
template<int N>
__device__ __forceinline__ void madd_vec(const float* x, float x2, const float* y,
                                         float y2, float xy, float* o){
  const float c1 = 1.f + 2.f*xy + y2;
  const float c2 = 1.f - x2;
  const float inv = 1.f / fmaxf(1.f + 2.f*xy + x2*y2, EPS_);
#pragma unroll
  for (int i = 0; i < N; i++) o[i] = (c1*x[i] + c2*y[i]) * inv;
}
template<int N>
__device__ __forceinline__ void mt_project(float* v, float mxn2, float xn2, float* n2out){
  const float xn  = snorm(xn2);
  const float mxn = snorm(mxn2);
  const float t   = tanhf(mxn/xn * atanhf(clamp11(xn)));
  float sc = t/mxn;
  float n2 = sc*sc*mxn2;
  const float n = snorm(n2);
  if (n > PMAX_){ const float s = PMAX_/n; sc *= s; n2 *= s*s; }
#pragma unroll
  for (int i = 0; i < N; i++) v[i] *= sc;
  *n2out = n2;
}
__device__ __forceinline__ void mt_scale(float mxn2, float xn, float art,
                                         float* sc, float* n2){
  const float mxn = snorm(mxn2);
  const float t   = tanhf(mxn/xn * art);
  float s  = t/mxn;
  float nn = t*t;
  const float n = snorm(nn);
  if (n > PMAX_){ const float f = PMAX_/n; s *= f; nn *= f*f; }
  *sc = s; *n2 = nn;
}
template<int N>
__device__ __forceinline__ void project_vec(float* v, float* n2io){
  float n2 = *n2io;
  const float n = snorm(n2);
  if (n > PMAX_){
    const float s = PMAX_/n;
#pragma unroll
    for (int i = 0; i < N; i++) v[i] *= s;
    n2 *= s*s;
  }
  *n2io = n2;
}

// async 16B global->LDS: linear wave-uniform-base + lane*16
__device__ __forceinline__ void gll16(const void* g, void* l){
  __builtin_amdgcn_global_load_lds(
      (const __attribute__((address_space(1))) void*)g,
      (__attribute__((address_space(3))) void*)l, 16, 0, 0);
}
// stage 64KB with 512 threads (8 waves x 8 x 16B/lane), linear layout
__device__ __forceinline__ void stage64k8(const void* gsrc, float* lbase, int w, int lane){
#pragma unroll
  for (int i = 0; i < 8; i++){
    const char* g = (const char*)gsrc + (size_t)((i*8 + w)*64 + lane)*16;
    char* l = (char*)lbase + (size_t)((i*8 + w)*64)*16;
    gll16(g, l);
  }
}

// ---------------------------------------------------------------------------
// MFMA bf16 GEMM (64x128 tile, unchanged)
// ---------------------------------------------------------------------------
template<int AMODE>
__global__ __launch_bounds__(256) void mfma_mm(const void* __restrict__ Aptr,
    const int* __restrict__ idx, const unsigned short* __restrict__ Bt,
    float* __restrict__ Cm, int M, int N, int K, int Kp)
{
  __shared__ __align__(16) unsigned short As[64][40];
  __shared__ __align__(16) unsigned short Bs[128][40];
  const int tid = threadIdx.x;
  const int n0 = blockIdx.x * 128;
  const int m0 = blockIdx.y * 64;
  const int arow_s = tid >> 2, aq = tid & 3;
  const int brow_s = tid >> 1, bhf = tid & 1;
  const int wv = tid >> 6, lane = tid & 63;
  const int wm = wv >> 1, wn = wv & 1;
  const int lr = lane & 15, lk = lane >> 4;

  long arow;
  if constexpr (AMODE == 1) arow = (long)idx[m0 + arow_s] * K;
  else                      arow = (long)(m0 + arow_s) * K;

  f32x4 acc[2][4];
#pragma unroll
  for (int mf = 0; mf < 2; mf++)
#pragma unroll
    for (int nf = 0; nf < 4; nf++) acc[mf][nf] = (f32x4){0.f,0.f,0.f,0.f};

  for (int k0 = 0; k0 < Kp; k0 += 32){
    const int kbA = k0 + aq*8;
    unsigned short av[8];
    if constexpr (AMODE == 1){
      const float* ar = (const float*)Aptr + arow;
      if (kbA + 8 <= K){
        const float4 f0 = *(const float4*)(ar + kbA);
        const float4 f1 = *(const float4*)(ar + kbA + 4);
        av[0]=f2bf(f0.x); av[1]=f2bf(f0.y); av[2]=f2bf(f0.z); av[3]=f2bf(f0.w);
        av[4]=f2bf(f1.x); av[5]=f2bf(f1.y); av[6]=f2bf(f1.z); av[7]=f2bf(f1.w);
      } else {
#pragma unroll
        for (int v = 0; v < 8; v++){
          const int col = kbA + v;
          av[v] = (col < K) ? f2bf(ar[col]) : (unsigned short)0;
        }
      }
    } else {
      const us8 u0 = *(const us8*)((const unsigned short*)Aptr + arow + kbA);
#pragma unroll
      for (int v = 0; v < 8; v++) av[v] = u0[v];
    }
    unsigned short bvv[16];
    {
      const unsigned short* br = Bt + (long)(n0 + brow_s)*Kp + k0 + bhf*16;
      const us8 u0 = *(const us8*)br;
      const us8 u1 = *(const us8*)(br + 8);
#pragma unroll
      for (int v = 0; v < 8; v++){ bvv[v] = u0[v]; bvv[8+v] = u1[v]; }
    }
    __syncthreads();
    *(us8*)&As[arow_s][aq*8] = *(const us8*)&av[0];
    *(us8*)&Bs[brow_s][bhf*16]   = *(const us8*)&bvv[0];
    *(us8*)&Bs[brow_s][bhf*16+8] = *(const us8*)&bvv[8];
    __syncthreads();
    bf16x8 af[2], bfr[4];
#pragma unroll
    for (int mf = 0; mf < 2; mf++)
      af[mf] = *(const bf16x8*)&As[wm*32 + mf*16 + lr][lk*8];
#pragma unroll
    for (int nf = 0; nf < 4; nf++)
      bfr[nf] = *(const bf16x8*)&Bs[wn*64 + nf*16 + lr][lk*8];
#pragma unroll
    for (int mf = 0; mf < 2; mf++)
#pragma unroll
      for (int nf = 0; nf < 4; nf++)
        acc[mf][nf] = __builtin_amdgcn_mfma_f32_16x16x32_bf16(af[mf], bfr[nf],
                                                              acc[mf][nf], 0, 0, 0);
  }
#pragma unroll
  for (int mf = 0; mf < 2; mf++){
#pragma unroll
    for (int nf = 0; nf < 4; nf++){
#pragma unroll
      for (int r = 0; r < 4; r++){
        const long grow = m0 + wm*32 + mf*16 + lk*4 + r;
        Cm[grow*N + n0 + wn*64 + nf*16 + lr] = acc[mf][nf][r];
      }
    }
  }
}

// ---------------------------------------------------------------------------
// Generic tiled f32 GEMM (small fc GEMMs only)
// ---------------------------------------------------------------------------
template<int AMODE>
__global__ __launch_bounds__(256) void mm_kernel(const void* __restrict__ Aptr,
    const int* __restrict__ idx, const float* __restrict__ Bm,
    float* __restrict__ Cm, int M, int N, int K)
{
  __shared__ __align__(16) float As[8][128];
  __shared__ __align__(16) float Bs[8][132];
  const int tid = threadIdx.x;
  const int n0 = blockIdx.x * 128;
  const int m0 = blockIdx.y * 128;
  const int tr = tid >> 4, tc = tid & 15;
  const int sm = tid & 127, sk = (tid >> 7) * 4;
  const int bk = tid >> 5,  bn = (tid & 31) * 4;
  long arow;
  if constexpr (AMODE == 1) arow = (long)idx[m0 + sm] * K;
  else                      arow = (long)(m0 + sm) * K;
  float acc[8][8];
#pragma unroll
  for (int i = 0; i < 8; i++)
#pragma unroll
    for (int j = 0; j < 8; j++) acc[i][j] = 0.f;

  for (int k0 = 0; k0 < K; k0 += 8){
    float av[4], bv[4];
    {
      const float* A = (const float*)Aptr;
      if (k0 + sk + 3 < K){
        const float4 f = *reinterpret_cast<const float4*>(A + arow + k0 + sk);
        av[0]=f.x; av[1]=f.y; av[2]=f.z; av[3]=f.w;
      } else {
#pragma unroll
        for (int i = 0; i < 4; i++){
          const int kk = k0 + sk + i;
          av[i] = (kk < K) ? A[arow + kk] : 0.f;
        }
      }
    }
    {
      const int kb = k0 + bk;
      if (kb < K){
        const float4 f = *reinterpret_cast<const float4*>(Bm + (long)kb*N + n0 + bn);
        bv[0]=f.x; bv[1]=f.y; bv[2]=f.z; bv[3]=f.w;
      } else { bv[0]=bv[1]=bv[2]=bv[3]=0.f; }
    }
    __syncthreads();
    As[sk+0][sm]=av[0]; As[sk+1][sm]=av[1]; As[sk+2][sm]=av[2]; As[sk+3][sm]=av[3];
    *reinterpret_cast<float4*>(&Bs[bk][bn]) = make_float4(bv[0],bv[1],bv[2],bv[3]);
    __syncthreads();
#pragma unroll
    for (int k = 0; k < 8; k++){
      float a[8], bb[8];
      *(float4*)&a[0]  = *(const float4*)&As[k][tr*8];
      *(float4*)&a[4]  = *(const float4*)&As[k][tr*8+4];
      *(float4*)&bb[0] = *(const float4*)&Bs[k][tc*8];
      *(float4*)&bb[4] = *(const float4*)&Bs[k][tc*8+4];
#pragma unroll
      for (int i = 0; i < 8; i++)
#pragma unroll
        for (int j = 0; j < 8; j++) acc[i][j] += a[i]*bb[j];
    }
  }
#pragma unroll
  for (int i = 0; i < 8; i++){
    const long row = m0 + tr*8 + i;
    *(float4*)(Cm + row*N + n0 + tc*8)     = make_float4(acc[i][0],acc[i][1],acc[i][2],acc[i][3]);
    *(float4*)(Cm + row*N + n0 + tc*8 + 4) = make_float4(acc[i][4],acc[i][5],acc[i][6],acc[i][7]);
  }
}

// ---------------------------------------------------------------------------
// 32x32 LDS-tiled transpose: dst[k*R + j] = src[j*Kc + k]   (f32 -> f32)
// ---------------------------------------------------------------------------
__global__ __launch_bounds__(256) void transpose_k(const float* __restrict__ src,
    float* __restrict__ dst, int R, int Kc)
{
  __shared__ float t[32][33];
  const int bx = blockIdx.x * 32;
  const int by = blockIdx.y * 32;
  const int tx = threadIdx.x & 31, ty = threadIdx.x >> 5;
#pragma unroll
  for (int i = 0; i < 32; i += 8){
    const int j = by + ty + i, k = bx + tx;
    t[ty+i][tx] = (j < R && k < Kc) ? src[(long)j*Kc + k] : 0.f;
  }
  __syncthreads();
#pragma unroll
  for (int i = 0; i < 32; i += 8){
    const int k = bx + ty + i, j = by + tx;
    if (k < Kc && j < R) dst[(long)k*R + j] = t[tx][ty+i];
  }
}

// transpose + bf16 pack: src [K][N] f32 -> dst [N][Kp] bf16 (zero-pad K..Kp)
__global__ __launch_bounds__(256) void packT16(const float* __restrict__ src,
    unsigned short* __restrict__ dst, int K, int N, int Kp)
{
  __shared__ float t[32][33];
  const int bx = blockIdx.x*32;
  const int by = blockIdx.y*32;
  const int tx = threadIdx.x & 31, ty = threadIdx.x >> 5;
#pragma unroll
  for (int i = 0; i < 32; i += 8){
    const int k = bx + ty + i, n = by + tx;
    t[ty+i][tx] = (k < K && n < N) ? src[(long)k*N + n] : 0.f;
  }
  __syncthreads();
#pragma unroll
  for (int i = 0; i < 32; i += 8){
    const int k = bx + tx, n = by + ty + i;
    if (k < Kp && n < N) dst[(long)n*Kp + k] = f2bf(t[tx][ty+i]);
  }
}

// pack Wih (already [768][300] = B^T layout) -> [2][768][320] bf16 zero-padded
__global__ void pack_wih(const float* __restrict__ w0, const float* __restrict__ w1,
                         unsigned short* __restrict__ dst)
{
  const int tid = blockIdx.x*256 + threadIdx.x;
  if (tid < 2*768*320){
    const int d = tid / (768*320);
    const int rem = tid - d*768*320;
    const int n = rem / 320, k = rem - n*320;
    const float* src = d ? w1 : w0;
    dst[tid] = (k < 300) ? f2bf(src[n*300 + k]) : (unsigned short)0;
  }
}

// split+pack WtHH [2][256 k][768 (r|h|z)] f32 -> f16 k-pair layouts
__global__ void pack_whh_f16(const float* __restrict__ WtHH,
                             unsigned* __restrict__ Wrz2,
                             unsigned* __restrict__ Wh2)
{
  const int tid = blockIdx.x*256 + threadIdx.x;   // 0 .. 196607
  if (tid < 2*128*768){
    const int col = tid % 768;
    const int rest = tid / 768;         // dir*128 + kp
    const int kp = rest & 127, dir = rest >> 7;
    const float* s0 = WtHH + ((long)(dir*256 + 2*kp))*768 + col;
    const unsigned u = packh2(s0[0], s0[768]);
    if (col < 256)       Wrz2[(long)(dir*128 + kp)*512 + col] = u;
    else if (col < 512)  Wh2 [(long)(dir*128 + kp)*256 + (col - 256)] = u;
    else                 Wrz2[(long)(dir*128 + kp)*512 + 256 + (col - 512)] = u;
  }
}

// build gather-index arrays
__global__ void build_idx(const int* __restrict__ context, const int* __restrict__ mchars,
                          int* __restrict__ ctxidx, int* __restrict__ chidx)
{
  const int tid = blockIdx.x*256 + threadIdx.x;
  if (tid < 32768){
    const int t = tid >> 8, b = tid & 255;
    ctxidx[tid] = context[b*128 + t];
  } else if (tid < 32768 + 4096){
    const int o = tid - 32768;
    const int t = o >> 8, b = o & 255;
    chidx[o] = mchars[b*16 + t];
  }
}

// out[r] = sum_k lut[idx[r]][k]^2   (one wave per row)
__global__ __launch_bounds__(256) void sqn_gather(const float* __restrict__ lut,
    const int* __restrict__ idx, int K, float* __restrict__ outp)
{
  const int wv = threadIdx.x >> 6, lane = threadIdx.x & 63;
  const int r = blockIdx.x*4 + wv;
  const float* row = lut + (long)idx[r]*K;
  float s = 0.f;
  for (int k = lane; k < K; k += 64) s += row[k]*row[k];
  s = wred(s);
  if (lane == 0) outp[r] = s;
}

// mobius_matvec tail transform per (row, gate); out bf16 + |out_bf16|^2
__global__ __launch_bounds__(256) void xg_transform(const float* __restrict__ mx,
    const float* __restrict__ xsqn, unsigned short* __restrict__ outp,
    float* __restrict__ n2o, int G)
{
  const int wv = threadIdx.x >> 6, lane = threadIdx.x & 63;
  const int wg = blockIdx.x*4 + wv;
  const int row = wg / G, g = wg - row*G;
  const long base = (long)row*(G*256) + g*256;
  float M[4];
#pragma unroll
  for (int i = 0; i < 4; i++) M[i] = mx[base + i*64 + lane];
  const float mxn2 = wred(sq_part<4>(M));
  float pn2; mt_project<4>(M, mxn2, xsqn[row], &pn2);
  float s = 0.f;
#pragma unroll
  for (int i = 0; i < 4; i++){
    const unsigned short u = f2bf(M[i]);
    outp[base + i*64 + lane] = u;
    const float rv = bf2f(u);
    s += rv*rv;
  }
  s = wred(s);
  if (lane == 0) n2o[wg] = s;
}

// ---------------------------------------------------------------------------
// Mobius GRU v9 (round-11 version, 1465us, unchanged)
// ---------------------------------------------------------------------------
#define GRU_LDS_BYTES 151808

__global__ __launch_bounds__(512,1) void gru_kernel(
    const unsigned short* __restrict__ xg,
    const float* __restrict__ xgn2,
    const unsigned* __restrict__ Wrz2,
    const unsigned* __restrict__ Wh2,
    const float* __restrict__ bias_f, const float* __restrict__ bias_b,
    unsigned short* __restrict__ states_f, unsigned short* __restrict__ states_b)
{
  extern __shared__ __align__(16) char smem[];
  float*    wbuf = (float*)smem;
  unsigned* hsp  = (unsigned*)(smem + 131072);
  unsigned* rhp  = (unsigned*)(smem + 132096);
  float*    part = (float*)(smem + 133120);
  float*    zb   = (float*)(smem + 149504);
  float*    scal = (float*)(smem + 151552);

  const int bid = blockIdx.x;
  const int dir = bid >> 7;
  const int brow0 = (bid & 127) * 2;
  const int tid = threadIdx.x;
  const int w = tid >> 6, lane = tid & 63;
  const int j0 = lane << 2;

  const unsigned short* xgd = xg + (long)dir*32768*768;
  const float* xnd = xgn2 + (long)dir*32768*3;
  const unsigned* wrz_d = Wrz2 + (long)dir*128*512;
  const unsigned* wh_d  = Wh2  + (long)dir*128*256;
  const float* bias = dir ? bias_b : bias_f;
  unsigned short* states = dir ? states_b : states_f;

  const int fg  = w & 1;
  const int kq4 = w >> 1;
  const int qk8 = w;
  const int crow  = (w >> 1) & 1;
  const int cgate = w & 1;

  float bg[4], bh4[4] = {0,0,0,0};
  float bg2, bh2 = 0.f;
#pragma unroll
  for (int i = 0; i < 4; i++) bg[i] = bias[(cgate ? 512 : 0) + j0 + i];
  bg2 = wred(sq_part<4>(bg));
  if (w < 2){
#pragma unroll
    for (int i = 0; i < 4; i++) bh4[i] = bias[256 + j0 + i];
    bh2 = wred(sq_part<4>(bh4));
  }

  float h[4] = {0.f,0.f,0.f,0.f};
  float hn2 = 0.f;
  if (w < 2){
    hsp[w*128 + lane*2]     = 0u;
    hsp[w*128 + lane*2 + 1] = 0u;
    if (lane == 0){ scal[w*2 + 0] = 0.f; scal[w*2 + 1] = 0.f; }
  }

  int cb = 0;
  stage64k8(wrz_d, wbuf, w, lane);

  for (int t = 0; t < 128; t++){
    const int tt = dir ? (127 - t) : t;
    float xgv[4] = {0,0,0,0}, y2g = 0.f, xgh4[4] = {0,0,0,0}, y2h = 0.f;
    if (w < 4){
      const long rxg = (long)tt*256 + brow0 + crow;
      const ushort4 u = *(const ushort4*)(xgd + rxg*768 + (cgate ? 512 : 0) + j0);
      xgv[0]=bf2f(u.x); xgv[1]=bf2f(u.y); xgv[2]=bf2f(u.z); xgv[3]=bf2f(u.w);
      y2g = xnd[rxg*3 + (cgate ? 2 : 0)];
      if (w < 2){
        const long rxh = (long)tt*256 + brow0 + w;
        const ushort4 uh = *(const ushort4*)(xgd + rxh*768 + 256 + j0);
        xgh4[0]=bf2f(uh.x); xgh4[1]=bf2f(uh.y); xgh4[2]=bf2f(uh.z); xgh4[3]=bf2f(uh.w);
        y2h = xnd[rxh*3 + 1];
      }
    }

    float s00=0.f,s01=0.f,s02=0.f,s03=0.f, s10=0.f,s11=0.f,s12=0.f,s13=0.f;
#pragma unroll 1
    for (int c = 0; c < 4; c++){
      __syncthreads();
      if (c < 3) stage64k8((const char*)wrz_d + (size_t)(c+1)*65536,
                           wbuf + (cb^1)*16384, w, lane);
      const unsigned* wb = (const unsigned*)(wbuf + cb*16384);
      const int kpg = c*32;
#pragma unroll
      for (int kp8 = 0; kp8 < 8; kp8++){
        const int kpl = kq4*8 + kp8;
        const half2_t h0 = as_h2(hsp[kpg + kpl]);
        const half2_t h1 = as_h2(hsp[128 + kpg + kpl]);
        const uint4 wq = *(const uint4*)&wb[kpl*512 + fg*256 + j0];
        s00 = FDOT2(as_h2(wq.x), h0, s00);
        s01 = FDOT2(as_h2(wq.y), h0, s01);
        s02 = FDOT2(as_h2(wq.z), h0, s02);
        s03 = FDOT2(as_h2(wq.w), h0, s03);
        s10 = FDOT2(as_h2(wq.x), h1, s10);
        s11 = FDOT2(as_h2(wq.y), h1, s11);
        s12 = FDOT2(as_h2(wq.z), h1, s12);
        s13 = FDOT2(as_h2(wq.w), h1, s13);
      }
      cb ^= 1;
    }
    {
      float* p1 = part + kq4*1024 + fg*256 + j0;
      *(float4*)p1         = make_float4(s00,s01,s02,s03);
      *(float4*)(p1 + 512) = make_float4(s10,s11,s12,s13);
    }
    __syncthreads();
    stage64k8(wh_d, wbuf + (cb^1)*16384, w, lane);
    cb ^= 1;

    if (w < 4){
      const float* pa = part + crow*512 + cgate*256 + j0;
      const float4 a0 = *(const float4*)pa;
      const float4 a1 = *(const float4*)(pa + 1024);
      const float4 a2 = *(const float4*)(pa + 2048);
      const float4 a3 = *(const float4*)(pa + 3072);
      float a[4] = { (a0.x+a1.x)+(a2.x+a3.x), (a0.y+a1.y)+(a2.y+a3.y),
                     (a0.z+a1.z)+(a2.z+a3.z), (a0.w+a1.w)+(a2.w+a3.w) };
      const float hn2v = scal[crow*2 + 0];
      const float xn_h = snorm(hn2v), art_h = atanhf(clamp11(xn_h));
      const float p2 = wred(sq_part<4>(a));
      float sc, n2; mt_scale(p2, xn_h, art_h, &sc, &n2);
#pragma unroll
      for (int i = 0; i < 4; i++) a[i] *= sc;
      const float xy = wred(dot_part<4>(a, xgv));
      float m1[4]; madd_vec<4>(a, n2, xgv, y2g, xy, m1);
      float m1n2 = sq_part<4>(m1), xyb = dot_part<4>(m1, bg);
      wred2(m1n2, xyb);
      float m2[4]; madd_vec<4>(m1, m1n2, bg, bg2, xyb, m2);
      const float m2n2 = wred(sq_part<4>(m2));
      const float nn = snorm(m2n2), fgc = atanhf(clamp11(nn))/nn;
      float g4[4];
#pragma unroll
      for (int i = 0; i < 4; i++) g4[i] = 1.f/(1.f + expf(-fgc*m2[i]));
      if (cgate == 0){
        float h4[4];
        {
          const half2_t pa0 = as_h2(hsp[crow*128 + lane*2]);
          const half2_t pa1 = as_h2(hsp[crow*128 + lane*2 + 1]);
          h4[0] = (float)pa0[0]; h4[1] = (float)pa0[1];
          h4[2] = (float)pa1[0]; h4[3] = (float)pa1[1];
        }
        float rh[4]; float wx2 = 0.f;
#pragma unroll
        for (int i = 0; i < 4; i++){ rh[i] = g4[i]*h4[i]; wx2 += rh[i]*rh[i]; }
        wx2 = wred(wx2);
        float rhn2, scrh;
        {
          const float wxn = snorm(wx2);
          const float trh = tanhf(wxn/xn_h * art_h);
          scrh = trh/wxn; rhn2 = trh*trh;
          const float n = snorm(rhn2);
          if (n > PMAX_){ const float f = PMAX_/n; scrh *= f; rhn2 *= f*f; }
        }
#pragma unroll
        for (int i = 0; i < 4; i++) rh[i] *= scrh;
        rhp[crow*128 + lane*2]     = packh2(rh[0], rh[1]);
        rhp[crow*128 + lane*2 + 1] = packh2(rh[2], rh[3]);
        if (lane == 0) scal[crow*2 + 1] = rhn2;
      } else {
        *(float4*)&zb[crow*256 + j0] = make_float4(g4[0],g4[1],g4[2],g4[3]);
      }
    }

    float r00=0.f,r01=0.f,r02=0.f,r03=0.f, r10=0.f,r11=0.f,r12=0.f,r13=0.f;
#pragma unroll 1
    for (int c = 0; c < 2; c++){
      __syncthreads();
      if (c < 1) stage64k8((const char*)wh_d + 65536, wbuf + (cb^1)*16384, w, lane);
      const unsigned* wb = (const unsigned*)(wbuf + cb*16384);
      const int kpg = c*64;
#pragma unroll
      for (int kp8 = 0; kp8 < 8; kp8++){
        const int kpl = qk8*8 + kp8;
        const half2_t h0 = as_h2(rhp[kpg + kpl]);
        const half2_t h1 = as_h2(rhp[128 + kpg + kpl]);
        const uint4 wq = *(const uint4*)&wb[kpl*256 + j0];
        r00 = FDOT2(as_h2(wq.x), h0, r00);
        r01 = FDOT2(as_h2(wq.y), h0, r01);
        r02 = FDOT2(as_h2(wq.z), h0, r02);
        r03 = FDOT2(as_h2(wq.w), h0, r03);
        r10 = FDOT2(as_h2(wq.x), h1, r10);
        r11 = FDOT2(as_h2(wq.y), h1, r11);
        r12 = FDOT2(as_h2(wq.z), h1, r12);
        r13 = FDOT2(as_h2(wq.w), h1, r13);
      }
      cb ^= 1;
    }
    {
      float* p2 = part + qk8*512 + j0;
      *(float4*)p2         = make_float4(r00,r01,r02,r03);
      *(float4*)(p2 + 256) = make_float4(r10,r11,r12,r13);
    }
    __syncthreads();
    if (t < 127){
      stage64k8(wrz_d, wbuf + (cb^1)*16384, w, lane);
      cb ^= 1;
    }

    if (w < 2){
      float ah[4];
      {
        float4 p[8];
#pragma unroll
        for (int q = 0; q < 8; q++)
          p[q] = *(const float4*)(part + q*512 + w*256 + j0);
        ah[0] = ((p[0].x+p[1].x)+(p[2].x+p[3].x)) + ((p[4].x+p[5].x)+(p[6].x+p[7].x));
        ah[1] = ((p[0].y+p[1].y)+(p[2].y+p[3].y)) + ((p[4].y+p[5].y)+(p[6].y+p[7].y));
        ah[2] = ((p[0].z+p[1].z)+(p[2].z+p[3].z)) + ((p[4].z+p[5].z)+(p[6].z+p[7].z));
        ah[3] = ((p[0].w+p[1].w)+(p[2].w+p[3].w)) + ((p[4].w+p[5].w)+(p[6].w+p[7].w));
      }
      const float rhn2v = scal[w*2 + 1];
      const float rxn = snorm(rhn2v), artr = atanhf(clamp11(rxn));
      float mx2 = sq_part<4>(ah), xyraw = dot_part<4>(ah, xgh4);
      wred2(mx2, xyraw);
      float sch, pn2; mt_scale(mx2, rxn, artr, &sch, &pn2);
#pragma unroll
      for (int i = 0; i < 4; i++) ah[i] *= sch;
      const float xy = xyraw * sch;
      float m1[4]; madd_vec<4>(ah, pn2, xgh4, y2h, xy, m1);
      float m1n2 = sq_part<4>(m1), xyb = dot_part<4>(m1, bh4);
      wred2(m1n2, xyb);
      float ht[4]; madd_vec<4>(m1, m1n2, bh4, bh2, xyb, ht);
      float htn2 = sq_part<4>(ht);
      float nh[4];
#pragma unroll
      for (int i = 0; i < 4; i++) nh[i] = -h[i];
      float xyd = dot_part<4>(nh, ht);
      wred2(htn2, xyd);
      float dl[4]; madd_vec<4>(nh, hn2, ht, htn2, xyd, dl);
      float z4[4];
      *(float4*)z4 = *(const float4*)&zb[w*256 + j0];
      float pw[4]; float dln2 = 0.f, wz2 = 0.f, xyhr = 0.f;
#pragma unroll
      for (int i = 0; i < 4; i++){
        dln2 += dl[i]*dl[i];
        pw[i] = z4[i]*dl[i];
        wz2  += pw[i]*pw[i];
        xyhr += h[i]*pw[i];
      }
      wred3(dln2, wz2, xyhr);
      float pwn2, scpw;
      {
        const float dn   = snorm(dln2);
        const float artd = atanhf(clamp11(dn));
        const float wzn  = snorm(wz2);
        const float tpw  = tanhf(wzn/dn * artd);
        scpw = tpw/wzn; pwn2 = tpw*tpw;
        const float n = snorm(pwn2);
        if (n > PMAX_){ const float f = PMAX_/n; scpw *= f; pwn2 *= f*f; }
      }
#pragma unroll
      for (int i = 0; i < 4; i++) pw[i] *= scpw;
      const float xyh = xyhr * scpw;
      float hnew[4]; madd_vec<4>(h, hn2, pw, pwn2, xyh, hnew);
#pragma unroll
      for (int i = 0; i < 4; i++) h[i] = hnew[i];
      hn2 = wred(sq_part<4>(h));
      hsp[w*128 + lane*2]     = packh2(h[0], h[1]);
      hsp[w*128 + lane*2 + 1] = packh2(h[2], h[3]);
      if (lane == 0) scal[w*2 + 0] = hn2;
      unsigned short* srow = states + ((long)(brow0 + w)*128 + tt)*256 + j0;
      ushort4 su; su.x=f2bf(h[0]); su.y=f2bf(h[1]); su.z=f2bf(h[2]); su.w=f2bf(h[3]);
      *(ushort4*)srow = su;
    }
  }
}

// ---------------------------------------------------------------------------
// Char Mobius-RNN (unchanged)
// ---------------------------------------------------------------------------
__global__ __launch_bounds__(256) void char_rnn(
    const unsigned short* __restrict__ xgc,
    const float* __restrict__ Wc,
    const float* __restrict__ cb,
    float* __restrict__ cstates)
{
  const int wv = threadIdx.x >> 6, lane = threadIdx.x & 63;
  const int b = blockIdx.x*4 + wv;
  const int j0 = lane << 2;
  __shared__ __align__(16) float hs[4][256];
  float h[4] = {0.f,0.f,0.f,0.f};
  float hn2 = 0.f;
#pragma unroll
  for (int i = 0; i < 4; i++) hs[wv][j0+i] = 0.f;
  float cbv[4];
#pragma unroll
  for (int i = 0; i < 4; i++) cbv[i] = cb[j0+i];
  const float cb2 = wred(sq_part<4>(cbv));
  for (int t = 0; t < 16; t++){
    __syncthreads();
    const unsigned short* xr = xgc + ((long)t*256 + b)*256;
    float xgv[4];
    { const ushort4 u = *(const ushort4*)(xr + j0); xgv[0]=bf2f(u.x); xgv[1]=bf2f(u.y); xgv[2]=bf2f(u.z); xgv[3]=bf2f(u.w); }
    float a[4]={0.f,0.f,0.f,0.f};
#pragma unroll 2
    for (int k0 = 0; k0 < 256; k0 += 4){
      const float4 hk = *(const float4*)&hs[wv][k0];
#pragma unroll
      for (int kk = 0; kk < 4; kk++){
        const float hv = (&hk.x)[kk];
        const float4 w4 = *(const float4*)(Wc + (long)(k0+kk)*256 + j0);
        a[0] += hv*w4.x; a[1] += hv*w4.y; a[2] += hv*w4.z; a[3] += hv*w4.w;
      }
    }
    const float mxn2 = wred(sq_part<4>(a));
    float pn2; mt_project<4>(a, mxn2, hn2, &pn2);
    const float y2 = wred(sq_part<4>(xgv));
    const float xy = wred(dot_part<4>(a, xgv));
    float m1[4]; madd_vec<4>(a, pn2, xgv, y2, xy, m1);
    const float m1n2 = wred(sq_part<4>(m1));
    const float xyb  = wred(dot_part<4>(m1, cbv));
    float m2[4]; madd_vec<4>(m1, m1n2, cbv, cb2, xyb, m2);
    float m2n2 = wred(sq_part<4>(m2));
    project_vec<4>(m2, &m2n2);
#pragma unroll
    for (int i = 0; i < 4; i++) h[i] = m2[i];
    hn2 = m2n2;
    *(float4*)&hs[wv][j0] = make_float4(h[0],h[1],h[2],h[3]);
    *(float4*)(cstates + ((long)b*16 + t)*256 + j0) = make_float4(h[0],h[1],h[2],h[3]);
  }
}

// ---------------------------------------------------------------------------
// cc concat (unchanged)
// ---------------------------------------------------------------------------
__global__ __launch_bounds__(256) void cc_rowwise(const unsigned short* __restrict__ sf,
    const unsigned short* __restrict__ sb, const float* __restrict__ mxa,
    const float* __restrict__ mxb, const float* __restrict__ ccb,
    unsigned short* __restrict__ ctxo, int rowoff)
{
  const int wv = threadIdx.x >> 6, lane = threadIdx.x & 63;
  const int rloc = blockIdx.x*4 + wv;
  const long r = rowoff + rloc;
  float s = 0.f;
#pragma unroll
  for (int i = 0; i < 4; i++){ const float v = bf2f(sf[r*256 + i*64+lane]); s += v*v; }
  const float sfn2 = wred(s);
  s = 0.f;
#pragma unroll
  for (int i = 0; i < 4; i++){ const float v = bf2f(sb[r*256 + i*64+lane]); s += v*v; }
  const float sbn2 = wred(s);
  float A[8], Bv[8];
#pragma unroll
  for (int i = 0; i < 8; i++){ A[i]  = mxa[(long)rloc*512 + i*64+lane];
                               Bv[i] = mxb[(long)rloc*512 + i*64+lane]; }
  float pan2, pbn2;
  { const float n2 = wred(sq_part<8>(A));  mt_project<8>(A,  n2, sfn2, &pan2); }
  { const float n2 = wred(sq_part<8>(Bv)); mt_project<8>(Bv, n2, sbn2, &pbn2); }
  const float xy = wred(dot_part<8>(A, Bv));
  float M1[8]; madd_vec<8>(A, pan2, Bv, pbn2, xy, M1);
  const float m1n2 = wred(sq_part<8>(M1));
  float Cb[8];
#pragma unroll
  for (int i = 0; i < 8; i++) Cb[i] = ccb[i*64+lane];
  const float cb2 = wred(sq_part<8>(Cb));
  const float xyb = wred(dot_part<8>(M1, Cb));
  float M2[8]; madd_vec<8>(M1, m1n2, Cb, cb2, xyb, M2);
  float m2n2 = wred(sq_part<8>(M2));
  project_vec<8>(M2, &m2n2);
#pragma unroll
  for (int i = 0; i < 8; i++) ctxo[r*512 + i*64+lane] = f2bf(M2[i]);
}

// attn_emb = madd(ctx(bf16), pe) -> BF16 out + sqn of rounded
__global__ __launch_bounds__(256) void attn_add(const unsigned short* __restrict__ ctxv,
    const int* __restrict__ pos, const float* __restrict__ pet,
    unsigned short* __restrict__ oemb, float* __restrict__ osqn)
{
  const int wv = threadIdx.x >> 6, lane = threadIdx.x & 63;
  const long r = blockIdx.x*4 + wv;
  float X[8];
#pragma unroll
  for (int i = 0; i < 8; i++) X[i] = bf2f(ctxv[r*512 + i*64+lane]);
  const float x2 = wred(sq_part<8>(X));
  const int p = pos[r];
  float Y[8];
#pragma unroll
  for (int i = 0; i < 8; i++) Y[i] = pet[(long)p*512 + i*64+lane];
  const float y2 = wred(sq_part<8>(Y));
  const float xy = wred(dot_part<8>(X, Y));
  float O[8]; madd_vec<8>(X, x2, Y, y2, xy, O);
  float s = 0.f;
#pragma unroll
  for (int i = 0; i < 8; i++){
    const unsigned short u = f2bf(O[i]);
    oemb[r*512 + i*64+lane] = u;
    const float rv = bf2f(u);
    s += rv*rv;
  }
  s = wred(s);
  if (lane == 0) osqn[r] = s;
}

// mention variant (bf16 out)
__global__ __launch_bounds__(256) void attn_add_m(const float* __restrict__ mvv,
    const int* __restrict__ mentions, const float* __restrict__ pet,
    unsigned short* __restrict__ oemb, float* __restrict__ osqn)
{
  const int wv = threadIdx.x >> 6, lane = threadIdx.x & 63;
  const long r = blockIdx.x*4 + wv;
  float X[8];
#pragma unroll
  for (int i = 0; i < 8; i++) X[i] = mvv[r*512 + i*64+lane];
  const float x2 = wred(sq_part<8>(X));
  const int men = mentions[r];
  const int p = (men > 0) ? (int)(r & 7) + 1 : 0;
  float Y[8];
#pragma unroll
  for (int i = 0; i < 8; i++) Y[i] = pet[(long)p*512 + i*64+lane];
  const float y2 = wred(sq_part<8>(Y));
  const float xy = wred(dot_part<8>(X, Y));
  float O[8]; madd_vec<8>(X, x2, Y, y2, xy, O);
  float s = 0.f;
#pragma unroll
  for (int i = 0; i < 8; i++){
    const unsigned short u = f2bf(O[i]);
    oemb[r*512 + i*64+lane] = u;
    const float rv = bf2f(u);
    s += rv*rv;
  }
  s = wred(s);
  if (lane == 0) osqn[r] = s;
}

// q/k projection + pdist; fused layout: Q and K are columns of one row,
// mxq/mxk are base pointers, rs = row stride in floats.
__global__ __launch_bounds__(256) void qk_pdist(const float* __restrict__ mxq,
    const float* __restrict__ mxk, const float* __restrict__ sqn,
    const float* __restrict__ bq, const float* __restrict__ bk,
    float* __restrict__ dout, int rs)
{
  const int wv = threadIdx.x >> 6, lane = threadIdx.x & 63;
  const int r = blockIdx.x*4 + wv;
  const float xn2 = sqn[r];
  float Q[8];
#pragma unroll
  for (int i = 0; i < 8; i++) Q[i] = mxq[(long)r*rs + i*64+lane];
  { const float n2 = wred(sq_part<8>(Q)); float pn2; mt_project<8>(Q, n2, xn2, &pn2);
    float Bq[8];
#pragma unroll
    for (int i = 0; i < 8; i++) Bq[i] = bq[i*64+lane];
    const float b2 = wred(sq_part<8>(Bq));
    const float xy = wred(dot_part<8>(Q, Bq));
    float O[8]; madd_vec<8>(Q, pn2, Bq, b2, xy, O);
#pragma unroll
    for (int i = 0; i < 8; i++) Q[i] = O[i];
  }
  float qn2 = wred(sq_part<8>(Q));
  project_vec<8>(Q, &qn2);
  float Kv[8];
#pragma unroll
  for (int i = 0; i < 8; i++) Kv[i] = mxk[(long)r*rs + i*64+lane];
  { const float n2 = wred(sq_part<8>(Kv)); float pn2; mt_project<8>(Kv, n2, xn2, &pn2);
    float Bk[8];
#pragma unroll
    for (int i = 0; i < 8; i++) Bk[i] = bk[i*64+lane];
    const float b2 = wred(sq_part<8>(Bk));
    const float xy = wred(dot_part<8>(Kv, Bk));
    float O[8]; madd_vec<8>(Kv, pn2, Bk, b2, xy, O);
#pragma unroll
    for (int i = 0; i < 8; i++) Kv[i] = O[i];
  }
  float kn2 = wred(sq_part<8>(Kv));
  project_vec<8>(Kv, &kn2);
  float NQ[8];
#pragma unroll
  for (int i = 0; i < 8; i++) NQ[i] = -Q[i];
  const float xy = wred(dot_part<8>(NQ, Kv));
  float Z[8]; madd_vec<8>(NQ, qn2, Kv, kn2, xy, Z);
  const float zn2 = wred(sq_part<8>(Z));
  const float d = 2.f * atanhf(clamp11(snorm(zn2)));
  if (lane == 0) dout[r] = d;
}

__global__ __launch_bounds__(256) void softmax128(const float* __restrict__ d,
    const float* __restrict__ beta, float* __restrict__ w)
{
  const int wv = threadIdx.x >> 6, lane = threadIdx.x & 63;
  const int b = blockIdx.x*4 + wv;
  const float bt = beta[0];
  const float x0 = -bt * d[b*128 + lane];
  const float x1 = -bt * d[b*128 + 64 + lane];
  const float m = wredmax(fmaxf(x0, x1));
  const float e0 = expf(x0 - m), e1 = expf(x1 - m);
  const float s = wred(e0 + e1);
  w[b*128 + lane]      = e0 / s;
  w[b*128 + 64 + lane] = e1 / s;
}

__global__ void softmax8(const float* __restrict__ d, const float* __restrict__ beta,
                         float* __restrict__ w)
{
  const int b = threadIdx.x;   // 256
  const float bt = beta[0];
  float x[8]; float m = -1e30f;
#pragma unroll
  for (int i = 0; i < 8; i++){ x[i] = -bt * d[b*8+i]; m = fmaxf(m, x[i]); }
  float s = 0.f;
#pragma unroll
  for (int i = 0; i < 8; i++){ x[i] = expf(x[i]-m); s += x[i]; }
#pragma unroll
  for (int i = 0; i < 8; i++) w[b*8+i] = x[i] / s;
}

// weighted gyromidpoint via Klein model; one wave per batch row (small Lseq)
template<int NPL, bool BF16V, bool HASW>
__global__ __launch_bounds__(256) void midpoint_kernel(const void* __restrict__ vals,
    const float* __restrict__ wts, float* __restrict__ outp, int Lseq)
{
  const int wv = threadIdx.x >> 6, lane = threadIdx.x & 63;
  const int b = blockIdx.x*4 + wv;
  const int D = NPL*64;
  float num[NPL];
#pragma unroll
  for (int i = 0; i < NPL; i++) num[i] = 0.f;
  float den = 0.f;
  for (int l = 0; l < Lseq; l++){
    const long base = ((long)b*Lseq + l)*D;
    float v[NPL]; float s = 0.f;
#pragma unroll
    for (int i = 0; i < NPL; i++){
      v[i] = BF16V ? bf2f(((const unsigned short*)vals)[base + i*64+lane])
                   : ((const float*)vals)[base + i*64+lane];
      s += v[i]*v[i];
    }
    const float v2 = wred(s);
    const float f = 2.f/(1.f + v2);
    const float kl2 = v2*f*f;
    const float gamma = 1.f/sqrtf(fmaxf(1.f - kl2, EPS_));
    const float wgt = HASW ? wts[b*Lseq + l] : 1.f;
    const float wg = wgt*gamma;
#pragma unroll
    for (int i = 0; i < NPL; i++) num[i] += wg*(f*v[i]);
    den += wg;
  }
  den = fmaxf(den, EPS_);
  float x[NPL]; float s = 0.f;
#pragma unroll
  for (int i = 0; i < NPL; i++){ x[i] = num[i]/den; s += x[i]*x[i]; }
  const float k2 = wred(s);
  const float inv = 1.f/(1.f + sqrtf(fmaxf(1.f - k2, EPS_)));
#pragma unroll
  for (int i = 0; i < NPL; i++) outp[(long)b*D + i*64+lane] = x[i]*inv;
}

// wide gyromidpoint for ctx (unchanged)
__global__ __launch_bounds__(512) void midpoint_wide(
    const unsigned short* __restrict__ vals,
    const float* __restrict__ wts,
    float* __restrict__ outp)
{
  __shared__ float pnum[8][512];
  __shared__ float pden[8];
  __shared__ float red[512];
  __shared__ float kk2[1];
  const int b = blockIdx.x;
  const int tid = threadIdx.x;
  const int w = tid >> 6, lane = tid & 63;
  float num[8] = {0.f,0.f,0.f,0.f,0.f,0.f,0.f,0.f};
  float den = 0.f;
  for (int l = w; l < 128; l += 8){
    const long base = ((long)b*128 + l)*512;
    float v[8]; float s = 0.f;
#pragma unroll
    for (int i = 0; i < 8; i++){
      v[i] = bf2f(vals[base + i*64 + lane]);
      s += v[i]*v[i];
    }
    const float v2 = wred(s);
    const float f = 2.f/(1.f + v2);
    const float kl2 = v2*f*f;
    const float gamma = 1.f/sqrtf(fmaxf(1.f - kl2, EPS_));
    const float wg = wts[b*128 + l]*gamma;
#pragma unroll
    for (int i = 0; i < 8; i++) num[i] += wg*(f*v[i]);
    den += wg;
  }
#pragma unroll
  for (int i = 0; i < 8; i++) pnum[w][i*64 + lane] = num[i];
  if (lane == 0) pden[w] = den;
  __syncthreads();
  float nsum = 0.f, dsum = 0.f;
#pragma unroll
  for (int p = 0; p < 8; p++){ nsum += pnum[p][tid]; dsum += pden[p]; }
  dsum = fmaxf(dsum, EPS_);
  const float x = nsum/dsum;
  red[tid] = x*x;
  __syncthreads();
  if (tid < 64){
    float s2 = 0.f;
#pragma unroll
    for (int i = 0; i < 8; i++) s2 += red[tid + i*64];
    s2 = wred(s2);
    if (tid == 0) kk2[0] = s2;
  }
  __syncthreads();
  const float k2 = kk2[0];
  const float inv = 1.f/(1.f + sqrtf(fmaxf(1.f - k2, EPS_)));
  outp[(long)b*512 + tid] = x*inv;
}

// mention w2s mobius_linear with tanh nonlinearity (unchanged)
__global__ __launch_bounds__(256) void mv_rowwise(const float* __restrict__ mx,
    const float* __restrict__ xsqn, const float* __restrict__ bb, float* __restrict__ outp)
{
  const int wv = threadIdx.x >> 6, lane = threadIdx.x & 63;
  const long r = blockIdx.x*4 + wv;
  float M[8];
#pragma unroll
  for (int i = 0; i < 8; i++) M[i] = mx[r*512 + i*64+lane];
  { const float n2 = wred(sq_part<8>(M)); float pn2; mt_project<8>(M, n2, xsqn[r], &pn2);
    float Bv[8];
#pragma unroll
    for (int i = 0; i < 8; i++) Bv[i] = bb[i*64+lane];
    const float b2 = wred(sq_part<8>(Bv));
    const float xy = wred(dot_part<8>(M, Bv));
    float O[8]; madd_vec<8>(M, pn2, Bv, b2, xy, O);
#pragma unroll
    for (int i = 0; i < 8; i++) M[i] = O[i];
  }
  float on2 = wred(sq_part<8>(M));
  project_vec<8>(M, &on2);
  { const float n = snorm(on2);
    const float fac = atanhf(clamp11(n))/n;
#pragma unroll
    for (int i = 0; i < 8; i++) M[i] = tanhf(fac*M[i]); }
  const float un2 = wred(sq_part<8>(M));
  { const float n = snorm(un2);
    const float fac = tanhf(n)/n;
    float en2 = fac*fac*un2;
#pragma unroll
    for (int i = 0; i < 8; i++) M[i] *= fac;
    project_vec<8>(M, &en2); }
#pragma unroll
  for (int i = 0; i < 8; i++) outp[r*512 + i*64+lane] = M[i];
}

// joint concat (unchanged)
__global__ __launch_bounds__(256) void final_rowwise(const float* __restrict__ jm,
    const float* __restrict__ jc, const float* __restrict__ jch,
    const float* __restrict__ mvec, const float* __restrict__ cvec,
    const float* __restrict__ chvec, const float* __restrict__ fcb,
    float* __restrict__ joint)
{
  const int wv = threadIdx.x >> 6, lane = threadIdx.x & 63;
  const long b = blockIdx.x*4 + wv;
  float s;
  s = 0.f; for (int i = 0; i < 8; i++){ const float v = mvec[b*512 + i*64+lane]; s += v*v; }
  const float mn2 = wred(s);
  s = 0.f; for (int i = 0; i < 8; i++){ const float v = cvec[b*512 + i*64+lane]; s += v*v; }
  const float cn2 = wred(s);
  s = 0.f; for (int i = 0; i < 4; i++){ const float v = chvec[b*256 + i*64+lane]; s += v*v; }
  const float chn2 = wred(s);
  float A[20];
#pragma unroll
  for (int i = 0; i < 20; i++) A[i] = jm[b*1280 + i*64+lane];
  float an2;
  { const float n2 = wred(sq_part<20>(A)); mt_project<20>(A, n2, mn2, &an2); }
  float T[20];
#pragma unroll
  for (int i = 0; i < 20; i++) T[i] = jc[b*1280 + i*64+lane];
  float tn2;
  { const float n2 = wred(sq_part<20>(T)); mt_project<20>(T, n2, cn2, &tn2); }
  { const float xy = wred(dot_part<20>(A, T));
    float O[20]; madd_vec<20>(A, an2, T, tn2, xy, O);
#pragma unroll
    for (int i = 0; i < 20; i++) A[i] = O[i];
    an2 = wred(sq_part<20>(A)); }
#pragma unroll
  for (int i = 0; i < 20; i++) T[i] = jch[b*1280 + i*64+lane];
  { const float n2 = wred(sq_part<20>(T)); mt_project<20>(T, n2, chn2, &tn2); }
  { const float xy = wred(dot_part<20>(A, T));
    float O[20]; madd_vec<20>(A, an2, T, tn2, xy, O);
#pragma unroll
    for (int i = 0; i < 20; i++) A[i] = O[i];
    an2 = wred(sq_part<20>(A)); }
#pragma unroll
  for (int i = 0; i < 20; i++) T[i] = fcb[i*64+lane];
  tn2 = wred(sq_part<20>(T));
  { const float xy = wred(dot_part<20>(A, T));
    float O[20]; madd_vec<20>(A, an2, T, tn2, xy, O);
#pragma unroll
    for (int i = 0; i < 20; i++) A[i] = O[i];
    an2 = wred(sq_part<20>(A)); }
  project_vec<20>(A, &an2);
#pragma unroll
  for (int i = 0; i < 20; i++) joint[b*1280 + i*64+lane] = A[i];
}

// hyperbolic MLR head (unchanged)
__global__ __launch_bounds__(256) void mlr_kernel(const float* __restrict__ joint,
    const float* __restrict__ P, const float* __restrict__ A, float* __restrict__ outp)
{
  const int wv = threadIdx.x >> 6, lane = threadIdx.x & 63;
  const int pair = blockIdx.x*4 + wv;
  const long b = pair >> 7, c = pair & 127;
  float Pv[20], J[20];
#pragma unroll
  for (int i = 0; i < 20; i++){
    Pv[i] = -P[c*1280 + i*64+lane];
    J[i]  = joint[b*1280 + i*64+lane];
  }
  const float p2 = wred(sq_part<20>(Pv));
  const float j2 = wred(sq_part<20>(J));
  const float xy = wred(dot_part<20>(Pv, J));
  float Z[20]; madd_vec<20>(Pv, p2, J, j2, xy, Z);
  float sza = 0.f, sz2 = 0.f, sa2 = 0.f;
#pragma unroll
  for (int i = 0; i < 20; i++){
    const float a = A[c*1280 + i*64+lane];
    sza += Z[i]*a; sz2 += Z[i]*Z[i]; sa2 += a*a;
  }
  float za = sza, z2 = sz2, a2 = sa2;
  wred3(za, z2, a2);
  const float an = sqrtf(fmaxf(a2, EPS_));
  const float v = 2.f*za / (fmaxf(1.f - z2, EPS_)*an);
  if (lane == 0) outp[pair] = 2.f*an*asinhf(v);
}

// ---------------------------------------------------------------------------
extern "C" void kernel_launch(void* const* d_in, const int* in_sizes, int n_in,
                              void* d_out, int out_size, void* d_ws, size_t ws_size,
                              hipStream_t stream)
{
  (void)in_sizes; (void)n_in; (void)out_size;
  const int*   context   = (const int*)  d_in[0];
  const int*   ctx_position=(const int*) d_in[1];
  const int*   mentions  = (const int*)  d_in[2];
  const int*   mchars    = (const int*)  d_in[3];
  const float* word_lut  = (const float*)d_in[4];
  const float* char_lut  = (const float*)d_in[5];
  const float* gf_Wih    = (const float*)d_in[6];
  const float* gf_Whh    = (const float*)d_in[7];
  const float* gf_b      = (const float*)d_in[8];
  const float* gb_Wih    = (const float*)d_in[9];
  const float* gb_Whh    = (const float*)d_in[10];
  const float* gb_b      = (const float*)d_in[11];
  const float* w2s_W     = (const float*)d_in[12];
  const float* w2s_b     = (const float*)d_in[13];
  const float* men_pos   = (const float*)d_in[14];
  const float* men_Wq    = (const float*)d_in[15];
  const float* men_bq    = (const float*)d_in[16];
  const float* men_Wk    = (const float*)d_in[17];
  const float* men_bk    = (const float*)d_in[18];
  const float* men_beta  = (const float*)d_in[19];
  const float* char_W    = (const float*)d_in[20];
  const float* char_U    = (const float*)d_in[21];
  const float* char_b    = (const float*)d_in[22];
  const float* cc_Wa     = (const float*)d_in[23];
  const float* cc_Wb     = (const float*)d_in[24];
  const float* cc_bias   = (const float*)d_in[25];
  const float* ctx_pos_t = (const float*)d_in[26];
  const float* ctx_Wq    = (const float*)d_in[27];
  const float* ctx_bq    = (const float*)d_in[28];
  const float* ctx_Wk    = (const float*)d_in[29];
  const float* ctx_bk    = (const float*)d_in[30];
  const float* ctx_beta  = (const float*)d_in[31];
  const float* fc_Wm     = (const float*)d_in[32];
  const float* fc_Wc     = (const float*)d_in[33];
  const float* fc_Wch    = (const float*)d_in[34];
  const float* fc_bias   = (const float*)d_in[35];
  const float* mlr_p     = (const float*)d_in[36];
  const float* mlr_a     = (const float*)d_in[37];
  float* out = (float*)d_out;

  // ---- workspace bump allocator ----
  char* wsb = (char*)d_ws;
  size_t off = 0;
  auto alloc = [&](size_t bytes) -> void* {
    void* p = wsb + off;
    off += (bytes + 255) & ~(size_t)255;
    return p;
  };
  float* WtHH = (float*)alloc(2UL*256*768*4);
  unsigned* Wrz2 = (unsigned*)alloc(2UL*128*512*4);   // f16 k-pair (r|z)
  unsigned* Wh2  = (unsigned*)alloc(2UL*128*256*4);   // f16 k-pair (h)
  unsigned short* WihP   = (unsigned short*)alloc(2UL*768*320*2);
  unsigned short* ctxWqkP= (unsigned short*)alloc(1024UL*512*2);  // fused Q|K
  unsigned short* ccWaP  = (unsigned short*)alloc(512UL*256*2);
  unsigned short* ccWbP  = (unsigned short*)alloc(512UL*256*2);
  unsigned short* menWqkP= (unsigned short*)alloc(1024UL*512*2);  // fused Q|K
  unsigned short* w2sP   = (unsigned short*)alloc(512UL*320*2);
  unsigned short* charUP = (unsigned short*)alloc(256UL*256*2);
  int*   ctxidx = (int*)alloc(32768UL*4);
  int*   chidx  = (int*)alloc(4096UL*4);
  float* xsqn   = (float*)alloc(32768UL*4);
  float* msqn   = (float*)alloc(2048UL*4);
  float* chsqn  = (float*)alloc(4096UL*4);
  unsigned short* xg = (unsigned short*)alloc(2UL*32768*768*2);
  float* xgn2 = (float*)alloc(2UL*32768*3*4);
  float* chn2d = (float*)alloc(4096UL*4);
  unsigned short* states_f = (unsigned short*)alloc(32768UL*256*2);
  unsigned short* states_b = (unsigned short*)alloc(32768UL*256*2);
  unsigned short* ctxv = (unsigned short*)alloc(32768UL*512*2);
  float* attn_sqn = (float*)alloc(32768UL*4);
  float* dctx = (float*)alloc(32768UL*4);
  float* wctx = (float*)alloc(32768UL*4);
  float* ctx_vec = (float*)alloc(256UL*512*4);
  float* mxbuf = (float*)alloc(2UL*8192*512*4);   // 33.5MB; fused qk uses all
  float* mv = (float*)alloc(2048UL*512*4);
  unsigned short* attn_embm = (unsigned short*)alloc(2048UL*512*2);
  float* amsqn = (float*)alloc(2048UL*4);
  float* dm = (float*)alloc(2048UL*4);
  float* wm = (float*)alloc(2048UL*4);
  float* mention_vec = (float*)alloc(256UL*512*4);
  unsigned short* xgc = (unsigned short*)alloc(4096UL*256*2);
  float* char_states = (float*)alloc(4096UL*256*4);
  float* char_vec = (float*)alloc(256UL*256*4);
  float* joint = (float*)alloc(256UL*1280*4);
  if (off > ws_size) return;
  unsigned short* attn_embc = xg;                  // overlay: xg dead after GRU
  float* mxh0 = mxbuf;
  float* mxh1 = mxbuf + 8192UL*512;

  // ---- weight transposes + packs ----
  transpose_k<<<dim3(8,24), 256,0,stream>>>(gf_Whh, WtHH,            768, 256);
  transpose_k<<<dim3(8,24), 256,0,stream>>>(gb_Whh, WtHH + 256*768,  768, 256);
  pack_whh_f16<<<768,256,0,stream>>>(WtHH, Wrz2, Wh2);
  pack_wih<<<1920,256,0,stream>>>(gf_Wih, gb_Wih, WihP);
  packT16<<<dim3(16,16),256,0,stream>>>(ctx_Wq, ctxWqkP,              512, 512, 512);
  packT16<<<dim3(16,16),256,0,stream>>>(ctx_Wk, ctxWqkP + 512UL*512,  512, 512, 512);
  packT16<<<dim3(8,16), 256,0,stream>>>(cc_Wa,  ccWaP,  256, 512, 256);
  packT16<<<dim3(8,16), 256,0,stream>>>(cc_Wb,  ccWbP,  256, 512, 256);
  packT16<<<dim3(16,16),256,0,stream>>>(men_Wq, menWqkP,             512, 512, 512);
  packT16<<<dim3(16,16),256,0,stream>>>(men_Wk, menWqkP + 512UL*512, 512, 512, 512);
  packT16<<<dim3(10,16),256,0,stream>>>(w2s_W,  w2sP,   300, 512, 320);
  packT16<<<dim3(8,8),  256,0,stream>>>(char_U, charUP, 256, 256, 256);

  // ---- gather indices + input sqn ----
  build_idx<<<144,256,0,stream>>>(context, mchars, ctxidx, chidx);
  sqn_gather<<<8192,256,0,stream>>>(word_lut, ctxidx, 300, xsqn);
  sqn_gather<<<512, 256,0,stream>>>(word_lut, mentions, 300, msqn);
  sqn_gather<<<1024,256,0,stream>>>(char_lut, chidx, 256, chsqn);

  // ---- GRU input precompute: xg[dir] = mobius_matvec(emb, Wih^T), bf16 ----
  for (int d2 = 0; d2 < 2; d2++){
    const unsigned short* wihp = WihP + (size_t)d2*768*320;
    for (int c = 0; c < 4; c++){
      mfma_mm<1><<<dim3(6,128),256,0,stream>>>(word_lut, ctxidx + c*8192, wihp,
                                               mxbuf, 8192, 768, 300, 320);
      xg_transform<<<6144,256,0,stream>>>(mxbuf, xsqn + c*8192,
          xg + ((size_t)d2*32768 + (size_t)c*8192)*768,
          xgn2 + ((size_t)d2*32768 + (size_t)c*8192)*3, 3);
    }
  }

  // ---- bidirectional Mobius GRU (v9 f16-dot2) ----
  (void)hipFuncSetAttribute((const void*)gru_kernel,
      hipFuncAttributeMaxDynamicSharedMemorySize, GRU_LDS_BYTES);
  gru_kernel<<<256,512,GRU_LDS_BYTES,stream>>>(xg, xgn2, Wrz2, Wh2,
                                               gf_b, gb_b, states_f, states_b);

  // ---- mobius concat of directions -> ctx (bf16) ----
  for (int c = 0; c < 4; c++){
    mfma_mm<2><<<dim3(4,128),256,0,stream>>>(states_f + (size_t)c*8192*256, nullptr,
                                             ccWaP, mxh0, 8192, 512, 256, 256);
    mfma_mm<2><<<dim3(4,128),256,0,stream>>>(states_b + (size_t)c*8192*256, nullptr,
                                             ccWbP, mxh1, 8192, 512, 256, 256);
    cc_rowwise<<<2048,256,0,stream>>>(states_f, states_b, mxh0, mxh1, cc_bias,
                                      ctxv, c*8192);
  }

  // ---- context distance attention (fused Q|K GEMM, N=1024) ----
  attn_add<<<8192,256,0,stream>>>(ctxv, ctx_position, ctx_pos_t, attn_embc, attn_sqn);
  for (int c = 0; c < 4; c++){
    mfma_mm<2><<<dim3(8,128),256,0,stream>>>(attn_embc + (size_t)c*8192*512, nullptr,
                                             ctxWqkP, mxh0, 8192, 1024, 512, 512);
    qk_pdist<<<2048,256,0,stream>>>(mxh0, mxh0 + 512, attn_sqn + c*8192,
                                    ctx_bq, ctx_bk, dctx + c*8192, 1024);
  }
  softmax128<<<64,256,0,stream>>>(dctx, ctx_beta, wctx);
  midpoint_wide<<<256,512,0,stream>>>(ctxv, wctx, ctx_vec);

  // ---- mention encoder (fused Q|K GEMM) ----
  mfma_mm<1><<<dim3(4,32),256,0,stream>>>(word_lut, mentions, w2sP, mxh0,
                                          2048, 512, 300, 320);
  mv_rowwise<<<512,256,0,stream>>>(mxh0, msqn, w2s_b, mv);
  attn_add_m<<<512,256,0,stream>>>(mv, mentions, men_pos, attn_embm, amsqn);
  mfma_mm<2><<<dim3(8,32),256,0,stream>>>(attn_embm, nullptr, menWqkP, mxh0,
                                          2048, 1024, 512, 512);
  qk_pdist<<<512,256,0,stream>>>(mxh0, mxh0 + 512, amsqn, men_bq, men_bk, dm, 1024);
  softmax8<<<1,256,0,stream>>>(dm, men_beta, wm);
  midpoint_kernel<8,false,true><<<64,256,0,stream>>>(mv, wm, mention_vec, 8);

  // ---- char encoder ----
  mfma_mm<1><<<dim3(2,64),256,0,stream>>>(char_lut, chidx, charUP, mxh0,
                                          4096, 256, 256, 256);
  xg_transform<<<1024,256,0,stream>>>(mxh0, chsqn, xgc, chn2d, 1);
  char_rnn<<<64,256,0,stream>>>(xgc, char_W, char_b, char_states);
  midpoint_kernel<4,false,false><<<64,256,0,stream>>>(char_states, nullptr, char_vec, 16);

  // ---- full mobius concat + MLR (small, f32 path) ----
  float* jm = mxh0;
  float* jc = mxh0 + 256UL*1280;
  float* jch = mxh0 + 2UL*256*1280;
  mm_kernel<0><<<dim3(10,2),256,0,stream>>>(mention_vec, nullptr, fc_Wm, jm, 256, 1280, 512);
  mm_kernel<0><<<dim3(10,2),256,0,stream>>>(ctx_vec,     nullptr, fc_Wc, jc, 256, 1280, 512);
  mm_kernel<0><<<dim3(10,2),256,0,stream>>>(char_vec,    nullptr, fc_Wch, jch, 256, 1280, 256);
  final_rowwise<<<64,256,0,stream>>>(jm, jc, jch, mention_vec, ctx_vec, char_vec,
                                     fc_bias, joint);
  mlr_kernel<<<8192,256,0,stream>>>(joint, mlr_p, mlr_a, out);
}

// Round 13
// 2448.900 us; speedup vs baseline: 1.2259x; 1.0152x over previous
//
#include <hip/hip_runtime.h>
#include <cstddef>
#include <cstdint>

// ---------------------------------------------------------------------------
// Hyperbolic (Poincare-ball) entity-typing forward pass, MI355X / gfx950.
// Round 13: bf16 GEMM outputs end-to-end (mfma_mm OUT16 epilogue; consumers
// xg_transform / cc_rowwise / qk_pdist / mv_rowwise read bf16) — halves the
// GEMM->rowwise glue traffic. GRU v9 and all else unchanged from round 12.
// ---------------------------------------------------------------------------

#define EPS_  1e-15f
#define PMAX_ 0.99999f    // 1 - 1e-5

typedef __attribute__((ext_vector_type(8))) short bf16x8;
typedef __attribute__((ext_vector_type(4))) float f32x4;
typedef __attribute__((ext_vector_type(8))) unsigned short us8;
typedef _Float16 half2_t __attribute__((ext_vector_type(2)));

__device__ __forceinline__ half2_t as_h2(unsigned u){
  union { unsigned u; half2_t h; } v; v.u = u; return v.h;
}
__device__ __forceinline__ unsigned packh2(float a, float b){
  union { half2_t h; unsigned u; } v;
  v.h[0] = (_Float16)a; v.h[1] = (_Float16)b; return v.u;
}
#if __has_builtin(__builtin_amdgcn_fdot2)
#define FDOT2(a,b,c) __builtin_amdgcn_fdot2((a),(b),(c),false)
#else
#define FDOT2(a,b,c) ((c) + (float)(a)[0]*(float)(b)[0] + (float)(a)[1]*(float)(b)[1])
#endif

__device__ __forceinline__ float wred(float v){
#pragma unroll
  for (int o = 32; o; o >>= 1) v += __shfl_xor(v, o, 64);
  return v;
}
__device__ __forceinline__ void wred2(float& a, float& b){
#pragma unroll
  for (int o = 32; o; o >>= 1){ a += __shfl_xor(a, o, 64); b += __shfl_xor(b, o, 64); }
}
__device__ __forceinline__ void wred3(float& a, float& b, float& c){
#pragma unroll
  for (int o = 32; o; o >>= 1){
    a += __shfl_xor(a, o, 64); b += __shfl_xor(b, o, 64); c += __shfl_xor(c, o, 64);
  }
}
__device__ __forceinline__ void wred4(float& a, float& b, float& c, float& d){
#pragma unroll
  for (int o = 32; o; o >>= 1){
    a += __shfl_xor(a, o, 64); b += __shfl_xor(b, o, 64);
    c += __shfl_xor(c, o, 64); d += __shfl_xor(d, o, 64);
  }
}
__device__ __forceinline__ float wredmax(float v){
#pragma unroll
  for (int o = 32; o; o >>= 1) v = fmaxf(v, __shfl_xor(v, o, 64));
  return v;
}
__device__ __forceinline__ float snorm(float s){ return sqrtf(fmaxf(s, EPS_)); }
__device__ __forceinline__ float clamp11(float x){
  return fminf(fmaxf(x, -1.f + 1e-7f), 1.f - 1e-7f);
}
__device__ __forceinline__ float bf2f(unsigned short u){
  union { unsigned int i; float f; } v; v.i = ((unsigned int)u) << 16; return v.f;
}
__device__ __forceinline__ unsigned short f2bf(float f){
  union { float f; unsigned int i; } v; v.f = f;
  unsigned int x = v.i;
  x += 0x7fffu + ((x >> 16) & 1u);   // RNE
  return (unsigned short)(x >> 16);
}
__device__ __forceinline__ float bflo(unsigned u){
  union { unsigned i; float f; } v; v.i = u << 16; return v.f;
}
__device__ __forceinline__ float bfhi(unsigned u){
  union { unsigned i; float f; } v; v.i = u & 0xffff0000u; return v.f;
}

template<int N>
__device__ __forceinline__ float sq_part(const float* a){
  float s = 0.f;
#pragma unroll
  for (int i = 0; i < N; i++) s += a[i]*a[i];
  return s;
}
template<int N>
__device__ __forceinline__ float dot_part(const float* a, const float* b){
  float s = 0.f;
#pragma unroll
  for (int i = 0; i < N; i++) s += a[i]*b[i];
  return s;
}
template<int N>
__device__ __forceinline__ void madd_vec(const float* x, float x2, const float* y,
                                         float y2, float xy, float* o){
  const float c1 = 1.f + 2.f*xy + y2;
  const float c2 = 1.f - x2;
  const float inv = 1.f / fmaxf(1.f + 2.f*xy + x2*y2, EPS_);
#pragma unroll
  for (int i = 0; i < N; i++) o[i] = (c1*x[i] + c2*y[i]) * inv;
}
template<int N>
__device__ __forceinline__ void mt_project(float* v, float mxn2, float xn2, float* n2out){
  const float xn  = snorm(xn2);
  const float mxn = snorm(mxn2);
  const float t   = tanhf(mxn/xn * atanhf(clamp11(xn)));
  float sc = t/mxn;
  float n2 = sc*sc*mxn2;
  const float n = snorm(n2);
  if (n > PMAX_){ const float s = PMAX_/n; sc *= s; n2 *= s*s; }
#pragma unroll
  for (int i = 0; i < N; i++) v[i] *= sc;
  *n2out = n2;
}
__device__ __forceinline__ void mt_scale(float mxn2, float xn, float art,
                                         float* sc, float* n2){
  const float mxn = snorm(mxn2);
  const float t   = tanhf(mxn/xn * art);
  float s  = t/mxn;
  float nn = t*t;
  const float n = snorm(nn);
  if (n > PMAX_){ const float f = PMAX_/n; s *= f; nn *= f*f; }
  *sc = s; *n2 = nn;
}
template<int N>
__device__ __forceinline__ void project_vec(float* v, float* n2io){
  float n2 = *n2io;
  const float n = snorm(n2);
  if (n > PMAX_){
    const float s = PMAX_/n;
#pragma unroll
    for (int i = 0; i < N; i++) v[i] *= s;
    n2 *= s*s;
  }
  *n2io = n2;
}

// async 16B global->LDS: linear wave-uniform-base + lane*16
__device__ __forceinline__ void gll16(const void* g, void* l){
  __builtin_amdgcn_global_load_lds(
      (const __attribute__((address_space(1))) void*)g,
      (__attribute__((address_space(3))) void*)l, 16, 0, 0);
}
// stage 64KB with 512 threads (8 waves x 8 x 16B/lane), linear layout
__device__ __forceinline__ void stage64k8(const void* gsrc, float* lbase, int w, int lane){
#pragma unroll
  for (int i = 0; i < 8; i++){
    const char* g = (const char*)gsrc + (size_t)((i*8 + w)*64 + lane)*16;
    char* l = (char*)lbase + (size_t)((i*8 + w)*64)*16;
    gll16(g, l);
  }
}

// ---------------------------------------------------------------------------
// MFMA bf16 GEMM (64x128 tile); OUT16=1 -> bf16 C output.
// ---------------------------------------------------------------------------
template<int AMODE, int OUT16>
__global__ __launch_bounds__(256) void mfma_mm(const void* __restrict__ Aptr,
    const int* __restrict__ idx, const unsigned short* __restrict__ Bt,
    void* __restrict__ Cm, int M, int N, int K, int Kp)
{
  __shared__ __align__(16) unsigned short As[64][40];
  __shared__ __align__(16) unsigned short Bs[128][40];
  const int tid = threadIdx.x;
  const int n0 = blockIdx.x * 128;
  const int m0 = blockIdx.y * 64;
  const int arow_s = tid >> 2, aq = tid & 3;
  const int brow_s = tid >> 1, bhf = tid & 1;
  const int wv = tid >> 6, lane = tid & 63;
  const int wm = wv >> 1, wn = wv & 1;
  const int lr = lane & 15, lk = lane >> 4;

  long arow;
  if constexpr (AMODE == 1) arow = (long)idx[m0 + arow_s] * K;
  else                      arow = (long)(m0 + arow_s) * K;

  f32x4 acc[2][4];
#pragma unroll
  for (int mf = 0; mf < 2; mf++)
#pragma unroll
    for (int nf = 0; nf < 4; nf++) acc[mf][nf] = (f32x4){0.f,0.f,0.f,0.f};

  for (int k0 = 0; k0 < Kp; k0 += 32){
    const int kbA = k0 + aq*8;
    unsigned short av[8];
    if constexpr (AMODE == 1){
      const float* ar = (const float*)Aptr + arow;
      if (kbA + 8 <= K){
        const float4 f0 = *(const float4*)(ar + kbA);
        const float4 f1 = *(const float4*)(ar + kbA + 4);
        av[0]=f2bf(f0.x); av[1]=f2bf(f0.y); av[2]=f2bf(f0.z); av[3]=f2bf(f0.w);
        av[4]=f2bf(f1.x); av[5]=f2bf(f1.y); av[6]=f2bf(f1.z); av[7]=f2bf(f1.w);
      } else {
#pragma unroll
        for (int v = 0; v < 8; v++){
          const int col = kbA + v;
          av[v] = (col < K) ? f2bf(ar[col]) : (unsigned short)0;
        }
      }
    } else {
      const us8 u0 = *(const us8*)((const unsigned short*)Aptr + arow + kbA);
#pragma unroll
      for (int v = 0; v < 8; v++) av[v] = u0[v];
    }
    unsigned short bvv[16];
    {
      const unsigned short* br = Bt + (long)(n0 + brow_s)*Kp + k0 + bhf*16;
      const us8 u0 = *(const us8*)br;
      const us8 u1 = *(const us8*)(br + 8);
#pragma unroll
      for (int v = 0; v < 8; v++){ bvv[v] = u0[v]; bvv[8+v] = u1[v]; }
    }
    __syncthreads();
    *(us8*)&As[arow_s][aq*8] = *(const us8*)&av[0];
    *(us8*)&Bs[brow_s][bhf*16]   = *(const us8*)&bvv[0];
    *(us8*)&Bs[brow_s][bhf*16+8] = *(const us8*)&bvv[8];
    __syncthreads();
    bf16x8 af[2], bfr[4];
#pragma unroll
    for (int mf = 0; mf < 2; mf++)
      af[mf] = *(const bf16x8*)&As[wm*32 + mf*16 + lr][lk*8];
#pragma unroll
    for (int nf = 0; nf < 4; nf++)
      bfr[nf] = *(const bf16x8*)&Bs[wn*64 + nf*16 + lr][lk*8];
#pragma unroll
    for (int mf = 0; mf < 2; mf++)
#pragma unroll
      for (int nf = 0; nf < 4; nf++)
        acc[mf][nf] = __builtin_amdgcn_mfma_f32_16x16x32_bf16(af[mf], bfr[nf],
                                                              acc[mf][nf], 0, 0, 0);
  }
#pragma unroll
  for (int mf = 0; mf < 2; mf++){
#pragma unroll
    for (int nf = 0; nf < 4; nf++){
#pragma unroll
      for (int r = 0; r < 4; r++){
        const long grow = m0 + wm*32 + mf*16 + lk*4 + r;
        const long gcol = n0 + wn*64 + nf*16 + lr;
        if constexpr (OUT16)
          ((unsigned short*)Cm)[grow*N + gcol] = f2bf(acc[mf][nf][r]);
        else
          ((float*)Cm)[grow*N + gcol] = acc[mf][nf][r];
      }
    }
  }
}

// ---------------------------------------------------------------------------
// Generic tiled f32 GEMM (small fc GEMMs only)
// ---------------------------------------------------------------------------
template<int AMODE>
__global__ __launch_bounds__(256) void mm_kernel(const void* __restrict__ Aptr,
    const int* __restrict__ idx, const float* __restrict__ Bm,
    float* __restrict__ Cm, int M, int N, int K)
{
  __shared__ __align__(16) float As[8][128];
  __shared__ __align__(16) float Bs[8][132];
  const int tid = threadIdx.x;
  const int n0 = blockIdx.x * 128;
  const int m0 = blockIdx.y * 128;
  const int tr = tid >> 4, tc = tid & 15;
  const int sm = tid & 127, sk = (tid >> 7) * 4;
  const int bk = tid >> 5,  bn = (tid & 31) * 4;
  long arow;
  if constexpr (AMODE == 1) arow = (long)idx[m0 + sm] * K;
  else                      arow = (long)(m0 + sm) * K;
  float acc[8][8];
#pragma unroll
  for (int i = 0; i < 8; i++)
#pragma unroll
    for (int j = 0; j < 8; j++) acc[i][j] = 0.f;

  for (int k0 = 0; k0 < K; k0 += 8){
    float av[4], bv[4];
    {
      const float* A = (const float*)Aptr;
      if (k0 + sk + 3 < K){
        const float4 f = *reinterpret_cast<const float4*>(A + arow + k0 + sk);
        av[0]=f.x; av[1]=f.y; av[2]=f.z; av[3]=f.w;
      } else {
#pragma unroll
        for (int i = 0; i < 4; i++){
          const int kk = k0 + sk + i;
          av[i] = (kk < K) ? A[arow + kk] : 0.f;
        }
      }
    }
    {
      const int kb = k0 + bk;
      if (kb < K){
        const float4 f = *reinterpret_cast<const float4*>(Bm + (long)kb*N + n0 + bn);
        bv[0]=f.x; bv[1]=f.y; bv[2]=f.z; bv[3]=f.w;
      } else { bv[0]=bv[1]=bv[2]=bv[3]=0.f; }
    }
    __syncthreads();
    As[sk+0][sm]=av[0]; As[sk+1][sm]=av[1]; As[sk+2][sm]=av[2]; As[sk+3][sm]=av[3];
    *reinterpret_cast<float4*>(&Bs[bk][bn]) = make_float4(bv[0],bv[1],bv[2],bv[3]);
    __syncthreads();
#pragma unroll
    for (int k = 0; k < 8; k++){
      float a[8], bb[8];
      *(float4*)&a[0]  = *(const float4*)&As[k][tr*8];
      *(float4*)&a[4]  = *(const float4*)&As[k][tr*8+4];
      *(float4*)&bb[0] = *(const float4*)&Bs[k][tc*8];
      *(float4*)&bb[4] = *(const float4*)&Bs[k][tc*8+4];
#pragma unroll
      for (int i = 0; i < 8; i++)
#pragma unroll
        for (int j = 0; j < 8; j++) acc[i][j] += a[i]*bb[j];
    }
  }
#pragma unroll
  for (int i = 0; i < 8; i++){
    const long row = m0 + tr*8 + i;
    *(float4*)(Cm + row*N + n0 + tc*8)     = make_float4(acc[i][0],acc[i][1],acc[i][2],acc[i][3]);
    *(float4*)(Cm + row*N + n0 + tc*8 + 4) = make_float4(acc[i][4],acc[i][5],acc[i][6],acc[i][7]);
  }
}

// ---------------------------------------------------------------------------
// 32x32 LDS-tiled transpose: dst[k*R + j] = src[j*Kc + k]   (f32 -> f32)
// ---------------------------------------------------------------------------
__global__ __launch_bounds__(256) void transpose_k(const float* __restrict__ src,
    float* __restrict__ dst, int R, int Kc)
{
  __shared__ float t[32][33];
  const int bx = blockIdx.x * 32;
  const int by = blockIdx.y * 32;
  const int tx = threadIdx.x & 31, ty = threadIdx.x >> 5;
#pragma unroll
  for (int i = 0; i < 32; i += 8){
    const int j = by + ty + i, k = bx + tx;
    t[ty+i][tx] = (j < R && k < Kc) ? src[(long)j*Kc + k] : 0.f;
  }
  __syncthreads();
#pragma unroll
  for (int i = 0; i < 32; i += 8){
    const int k = bx + ty + i, j = by + tx;
    if (k < Kc && j < R) dst[(long)k*R + j] = t[tx][ty+i];
  }
}

// transpose + bf16 pack: src [K][N] f32 -> dst [N][Kp] bf16 (zero-pad K..Kp)
__global__ __launch_bounds__(256) void packT16(const float* __restrict__ src,
    unsigned short* __restrict__ dst, int K, int N, int Kp)
{
  __shared__ float t[32][33];
  const int bx = blockIdx.x*32;
  const int by = blockIdx.y*32;
  const int tx = threadIdx.x & 31, ty = threadIdx.x >> 5;
#pragma unroll
  for (int i = 0; i < 32; i += 8){
    const int k = bx + ty + i, n = by + tx;
    t[ty+i][tx] = (k < K && n < N) ? src[(long)k*N + n] : 0.f;
  }
  __syncthreads();
#pragma unroll
  for (int i = 0; i < 32; i += 8){
    const int k = bx + tx, n = by + ty + i;
    if (k < Kp && n < N) dst[(long)n*Kp + k] = f2bf(t[tx][ty+i]);
  }
}

// pack Wih (already [768][300] = B^T layout) -> [2][768][320] bf16 zero-padded
__global__ void pack_wih(const float* __restrict__ w0, const float* __restrict__ w1,
                         unsigned short* __restrict__ dst)
{
  const int tid = blockIdx.x*256 + threadIdx.x;
  if (tid < 2*768*320){
    const int d = tid / (768*320);
    const int rem = tid - d*768*320;
    const int n = rem / 320, k = rem - n*320;
    const float* src = d ? w1 : w0;
    dst[tid] = (k < 300) ? f2bf(src[n*300 + k]) : (unsigned short)0;
  }
}

// split+pack WtHH [2][256 k][768 (r|h|z)] f32 -> f16 k-pair layouts
__global__ void pack_whh_f16(const float* __restrict__ WtHH,
                             unsigned* __restrict__ Wrz2,
                             unsigned* __restrict__ Wh2)
{
  const int tid = blockIdx.x*256 + threadIdx.x;   // 0 .. 196607
  if (tid < 2*128*768){
    const int col = tid % 768;
    const int rest = tid / 768;         // dir*128 + kp
    const int kp = rest & 127, dir = rest >> 7;
    const float* s0 = WtHH + ((long)(dir*256 + 2*kp))*768 + col;
    const unsigned u = packh2(s0[0], s0[768]);
    if (col < 256)       Wrz2[(long)(dir*128 + kp)*512 + col] = u;
    else if (col < 512)  Wh2 [(long)(dir*128 + kp)*256 + (col - 256)] = u;
    else                 Wrz2[(long)(dir*128 + kp)*512 + 256 + (col - 512)] = u;
  }
}

// build gather-index arrays
__global__ void build_idx(const int* __restrict__ context, const int* __restrict__ mchars,
                          int* __restrict__ ctxidx, int* __restrict__ chidx)
{
  const int tid = blockIdx.x*256 + threadIdx.x;
  if (tid < 32768){
    const int t = tid >> 8, b = tid & 255;
    ctxidx[tid] = context[b*128 + t];
  } else if (tid < 32768 + 4096){
    const int o = tid - 32768;
    const int t = o >> 8, b = o & 255;
    chidx[o] = mchars[b*16 + t];
  }
}

// out[r] = sum_k lut[idx[r]][k]^2   (one wave per row)
__global__ __launch_bounds__(256) void sqn_gather(const float* __restrict__ lut,
    const int* __restrict__ idx, int K, float* __restrict__ outp)
{
  const int wv = threadIdx.x >> 6, lane = threadIdx.x & 63;
  const int r = blockIdx.x*4 + wv;
  const float* row = lut + (long)idx[r]*K;
  float s = 0.f;
  for (int k = lane; k < K; k += 64) s += row[k]*row[k];
  s = wred(s);
  if (lane == 0) outp[r] = s;
}

// mobius_matvec tail transform per (row, gate); mx is bf16 now.
__global__ __launch_bounds__(256) void xg_transform(const unsigned short* __restrict__ mx,
    const float* __restrict__ xsqn, unsigned short* __restrict__ outp,
    float* __restrict__ n2o, int G)
{
  const int wv = threadIdx.x >> 6, lane = threadIdx.x & 63;
  const int wg = blockIdx.x*4 + wv;
  const int row = wg / G, g = wg - row*G;
  const long base = (long)row*(G*256) + g*256;
  float M[4];
#pragma unroll
  for (int i = 0; i < 4; i++) M[i] = bf2f(mx[base + i*64 + lane]);
  const float mxn2 = wred(sq_part<4>(M));
  float pn2; mt_project<4>(M, mxn2, xsqn[row], &pn2);
  float s = 0.f;
#pragma unroll
  for (int i = 0; i < 4; i++){
    const unsigned short u = f2bf(M[i]);
    outp[base + i*64 + lane] = u;
    const float rv = bf2f(u);
    s += rv*rv;
  }
  s = wred(s);
  if (lane == 0) n2o[wg] = s;
}

// ---------------------------------------------------------------------------
// Mobius GRU v9 (round-11/12 version, 1453us, unchanged)
// ---------------------------------------------------------------------------
#define GRU_LDS_BYTES 151808

__global__ __launch_bounds__(512,1) void gru_kernel(
    const unsigned short* __restrict__ xg,
    const float* __restrict__ xgn2,
    const unsigned* __restrict__ Wrz2,
    const unsigned* __restrict__ Wh2,
    const float* __restrict__ bias_f, const float* __restrict__ bias_b,
    unsigned short* __restrict__ states_f, unsigned short* __restrict__ states_b)
{
  extern __shared__ __align__(16) char smem[];
  float*    wbuf = (float*)smem;
  unsigned* hsp  = (unsigned*)(smem + 131072);
  unsigned* rhp  = (unsigned*)(smem + 132096);
  float*    part = (float*)(smem + 133120);
  float*    zb   = (float*)(smem + 149504);
  float*    scal = (float*)(smem + 151552);

  const int bid = blockIdx.x;
  const int dir = bid >> 7;
  const int brow0 = (bid & 127) * 2;
  const int tid = threadIdx.x;
  const int w = tid >> 6, lane = tid & 63;
  const int j0 = lane << 2;

  const unsigned short* xgd = xg + (long)dir*32768*768;
  const float* xnd = xgn2 + (long)dir*32768*3;
  const unsigned* wrz_d = Wrz2 + (long)dir*128*512;
  const unsigned* wh_d  = Wh2  + (long)dir*128*256;
  const float* bias = dir ? bias_b : bias_f;
  unsigned short* states = dir ? states_b : states_f;

  const int fg  = w & 1;
  const int kq4 = w >> 1;
  const int qk8 = w;
  const int crow  = (w >> 1) & 1;
  const int cgate = w & 1;

  float bg[4], bh4[4] = {0,0,0,0};
  float bg2, bh2 = 0.f;
#pragma unroll
  for (int i = 0; i < 4; i++) bg[i] = bias[(cgate ? 512 : 0) + j0 + i];
  bg2 = wred(sq_part<4>(bg));
  if (w < 2){
#pragma unroll
    for (int i = 0; i < 4; i++) bh4[i] = bias[256 + j0 + i];
    bh2 = wred(sq_part<4>(bh4));
  }

  float h[4] = {0.f,0.f,0.f,0.f};
  float hn2 = 0.f;
  if (w < 2){
    hsp[w*128 + lane*2]     = 0u;
    hsp[w*128 + lane*2 + 1] = 0u;
    if (lane == 0){ scal[w*2 + 0] = 0.f; scal[w*2 + 1] = 0.f; }
  }

  int cb = 0;
  stage64k8(wrz_d, wbuf, w, lane);

  for (int t = 0; t < 128; t++){
    const int tt = dir ? (127 - t) : t;
    float xgv[4] = {0,0,0,0}, y2g = 0.f, xgh4[4] = {0,0,0,0}, y2h = 0.f;
    if (w < 4){
      const long rxg = (long)tt*256 + brow0 + crow;
      const ushort4 u = *(const ushort4*)(xgd + rxg*768 + (cgate ? 512 : 0) + j0);
      xgv[0]=bf2f(u.x); xgv[1]=bf2f(u.y); xgv[2]=bf2f(u.z); xgv[3]=bf2f(u.w);
      y2g = xnd[rxg*3 + (cgate ? 2 : 0)];
      if (w < 2){
        const long rxh = (long)tt*256 + brow0 + w;
        const ushort4 uh = *(const ushort4*)(xgd + rxh*768 + 256 + j0);
        xgh4[0]=bf2f(uh.x); xgh4[1]=bf2f(uh.y); xgh4[2]=bf2f(uh.z); xgh4[3]=bf2f(uh.w);
        y2h = xnd[rxh*3 + 1];
      }
    }

    float s00=0.f,s01=0.f,s02=0.f,s03=0.f, s10=0.f,s11=0.f,s12=0.f,s13=0.f;
#pragma unroll 1
    for (int c = 0; c < 4; c++){
      __syncthreads();
      if (c < 3) stage64k8((const char*)wrz_d + (size_t)(c+1)*65536,
                           wbuf + (cb^1)*16384, w, lane);
      const unsigned* wb = (const unsigned*)(wbuf + cb*16384);
      const int kpg = c*32;
#pragma unroll
      for (int kp8 = 0; kp8 < 8; kp8++){
        const int kpl = kq4*8 + kp8;
        const half2_t h0 = as_h2(hsp[kpg + kpl]);
        const half2_t h1 = as_h2(hsp[128 + kpg + kpl]);
        const uint4 wq = *(const uint4*)&wb[kpl*512 + fg*256 + j0];
        s00 = FDOT2(as_h2(wq.x), h0, s00);
        s01 = FDOT2(as_h2(wq.y), h0, s01);
        s02 = FDOT2(as_h2(wq.z), h0, s02);
        s03 = FDOT2(as_h2(wq.w), h0, s03);
        s10 = FDOT2(as_h2(wq.x), h1, s10);
        s11 = FDOT2(as_h2(wq.y), h1, s11);
        s12 = FDOT2(as_h2(wq.z), h1, s12);
        s13 = FDOT2(as_h2(wq.w), h1, s13);
      }
      cb ^= 1;
    }
    {
      float* p1 = part + kq4*1024 + fg*256 + j0;
      *(float4*)p1         = make_float4(s00,s01,s02,s03);
      *(float4*)(p1 + 512) = make_float4(s10,s11,s12,s13);
    }
    __syncthreads();
    stage64k8(wh_d, wbuf + (cb^1)*16384, w, lane);
    cb ^= 1;

    if (w < 4){
      const float* pa = part + crow*512 + cgate*256 + j0;
      const float4 a0 = *(const float4*)pa;
      const float4 a1 = *(const float4*)(pa + 1024);
      const float4 a2 = *(const float4*)(pa + 2048);
      const float4 a3 = *(const float4*)(pa + 3072);
      float a[4] = { (a0.x+a1.x)+(a2.x+a3.x), (a0.y+a1.y)+(a2.y+a3.y),
                     (a0.z+a1.z)+(a2.z+a3.z), (a0.w+a1.w)+(a2.w+a3.w) };
      const float hn2v = scal[crow*2 + 0];
      const float xn_h = snorm(hn2v), art_h = atanhf(clamp11(xn_h));
      const float p2 = wred(sq_part<4>(a));
      float sc, n2; mt_scale(p2, xn_h, art_h, &sc, &n2);
#pragma unroll
      for (int i = 0; i < 4; i++) a[i] *= sc;
      const float xy = wred(dot_part<4>(a, xgv));
      float m1[4]; madd_vec<4>(a, n2, xgv, y2g, xy, m1);
      float m1n2 = sq_part<4>(m1), xyb = dot_part<4>(m1, bg);
      wred2(m1n2, xyb);
      float m2[4]; madd_vec<4>(m1, m1n2, bg, bg2, xyb, m2);
      const float m2n2 = wred(sq_part<4>(m2));
      const float nn = snorm(m2n2), fgc = atanhf(clamp11(nn))/nn;
      float g4[4];
#pragma unroll
      for (int i = 0; i < 4; i++) g4[i] = 1.f/(1.f + expf(-fgc*m2[i]));
      if (cgate == 0){
        float h4[4];
        {
          const half2_t pa0 = as_h2(hsp[crow*128 + lane*2]);
          const half2_t pa1 = as_h2(hsp[crow*128 + lane*2 + 1]);
          h4[0] = (float)pa0[0]; h4[1] = (float)pa0[1];
          h4[2] = (float)pa1[0]; h4[3] = (float)pa1[1];
        }
        float rh[4]; float wx2 = 0.f;
#pragma unroll
        for (int i = 0; i < 4; i++){ rh[i] = g4[i]*h4[i]; wx2 += rh[i]*rh[i]; }
        wx2 = wred(wx2);
        float rhn2, scrh;
        {
          const float wxn = snorm(wx2);
          const float trh = tanhf(wxn/xn_h * art_h);
          scrh = trh/wxn; rhn2 = trh*trh;
          const float n = snorm(rhn2);
          if (n > PMAX_){ const float f = PMAX_/n; scrh *= f; rhn2 *= f*f; }
        }
#pragma unroll
        for (int i = 0; i < 4; i++) rh[i] *= scrh;
        rhp[crow*128 + lane*2]     = packh2(rh[0], rh[1]);
        rhp[crow*128 + lane*2 + 1] = packh2(rh[2], rh[3]);
        if (lane == 0) scal[crow*2 + 1] = rhn2;
      } else {
        *(float4*)&zb[crow*256 + j0] = make_float4(g4[0],g4[1],g4[2],g4[3]);
      }
    }

    float r00=0.f,r01=0.f,r02=0.f,r03=0.f, r10=0.f,r11=0.f,r12=0.f,r13=0.f;
#pragma unroll 1
    for (int c = 0; c < 2; c++){
      __syncthreads();
      if (c < 1) stage64k8((const char*)wh_d + 65536, wbuf + (cb^1)*16384, w, lane);
      const unsigned* wb = (const unsigned*)(wbuf + cb*16384);
      const int kpg = c*64;
#pragma unroll
      for (int kp8 = 0; kp8 < 8; kp8++){
        const int kpl = qk8*8 + kp8;
        const half2_t h0 = as_h2(rhp[kpg + kpl]);
        const half2_t h1 = as_h2(rhp[128 + kpg + kpl]);
        const uint4 wq = *(const uint4*)&wb[kpl*256 + j0];
        r00 = FDOT2(as_h2(wq.x), h0, r00);
        r01 = FDOT2(as_h2(wq.y), h0, r01);
        r02 = FDOT2(as_h2(wq.z), h0, r02);
        r03 = FDOT2(as_h2(wq.w), h0, r03);
        r10 = FDOT2(as_h2(wq.x), h1, r10);
        r11 = FDOT2(as_h2(wq.y), h1, r11);
        r12 = FDOT2(as_h2(wq.z), h1, r12);
        r13 = FDOT2(as_h2(wq.w), h1, r13);
      }
      cb ^= 1;
    }
    {
      float* p2 = part + qk8*512 + j0;
      *(float4*)p2         = make_float4(r00,r01,r02,r03);
      *(float4*)(p2 + 256) = make_float4(r10,r11,r12,r13);
    }
    __syncthreads();
    if (t < 127){
      stage64k8(wrz_d, wbuf + (cb^1)*16384, w, lane);
      cb ^= 1;
    }

    if (w < 2){
      float ah[4];
      {
        float4 p[8];
#pragma unroll
        for (int q = 0; q < 8; q++)
          p[q] = *(const float4*)(part + q*512 + w*256 + j0);
        ah[0] = ((p[0].x+p[1].x)+(p[2].x+p[3].x)) + ((p[4].x+p[5].x)+(p[6].x+p[7].x));
        ah[1] = ((p[0].y+p[1].y)+(p[2].y+p[3].y)) + ((p[4].y+p[5].y)+(p[6].y+p[7].y));
        ah[2] = ((p[0].z+p[1].z)+(p[2].z+p[3].z)) + ((p[4].z+p[5].z)+(p[6].z+p[7].z));
        ah[3] = ((p[0].w+p[1].w)+(p[2].w+p[3].w)) + ((p[4].w+p[5].w)+(p[6].w+p[7].w));
      }
      const float rhn2v = scal[w*2 + 1];
      const float rxn = snorm(rhn2v), artr = atanhf(clamp11(rxn));
      float mx2 = sq_part<4>(ah), xyraw = dot_part<4>(ah, xgh4);
      wred2(mx2, xyraw);
      float sch, pn2; mt_scale(mx2, rxn, artr, &sch, &pn2);
#pragma unroll
      for (int i = 0; i < 4; i++) ah[i] *= sch;
      const float xy = xyraw * sch;
      float m1[4]; madd_vec<4>(ah, pn2, xgh4, y2h, xy, m1);
      float m1n2 = sq_part<4>(m1), xyb = dot_part<4>(m1, bh4);
      wred2(m1n2, xyb);
      float ht[4]; madd_vec<4>(m1, m1n2, bh4, bh2, xyb, ht);
      float htn2 = sq_part<4>(ht);
      float nh[4];
#pragma unroll
      for (int i = 0; i < 4; i++) nh[i] = -h[i];
      float xyd = dot_part<4>(nh, ht);
      wred2(htn2, xyd);
      float dl[4]; madd_vec<4>(nh, hn2, ht, htn2, xyd, dl);
      float z4[4];
      *(float4*)z4 = *(const float4*)&zb[w*256 + j0];
      float pw[4]; float dln2 = 0.f, wz2 = 0.f, xyhr = 0.f;
#pragma unroll
      for (int i = 0; i < 4; i++){
        dln2 += dl[i]*dl[i];
        pw[i] = z4[i]*dl[i];
        wz2  += pw[i]*pw[i];
        xyhr += h[i]*pw[i];
      }
      wred3(dln2, wz2, xyhr);
      float pwn2, scpw;
      {
        const float dn   = snorm(dln2);
        const float artd = atanhf(clamp11(dn));
        const float wzn  = snorm(wz2);
        const float tpw  = tanhf(wzn/dn * artd);
        scpw = tpw/wzn; pwn2 = tpw*tpw;
        const float n = snorm(pwn2);
        if (n > PMAX_){ const float f = PMAX_/n; scpw *= f; pwn2 *= f*f; }
      }
#pragma unroll
      for (int i = 0; i < 4; i++) pw[i] *= scpw;
      const float xyh = xyhr * scpw;
      float hnew[4]; madd_vec<4>(h, hn2, pw, pwn2, xyh, hnew);
#pragma unroll
      for (int i = 0; i < 4; i++) h[i] = hnew[i];
      hn2 = wred(sq_part<4>(h));
      hsp[w*128 + lane*2]     = packh2(h[0], h[1]);
      hsp[w*128 + lane*2 + 1] = packh2(h[2], h[3]);
      if (lane == 0) scal[w*2 + 0] = hn2;
      unsigned short* srow = states + ((long)(brow0 + w)*128 + tt)*256 + j0;
      ushort4 su; su.x=f2bf(h[0]); su.y=f2bf(h[1]); su.z=f2bf(h[2]); su.w=f2bf(h[3]);
      *(ushort4*)srow = su;
    }
  }
}

// ---------------------------------------------------------------------------
// Char Mobius-RNN (unchanged)
// ---------------------------------------------------------------------------
__global__ __launch_bounds__(256) void char_rnn(
    const unsigned short* __restrict__ xgc,
    const float* __restrict__ Wc,
    const float* __restrict__ cb,
    float* __restrict__ cstates)
{
  const int wv = threadIdx.x >> 6, lane = threadIdx.x & 63;
  const int b = blockIdx.x*4 + wv;
  const int j0 = lane << 2;
  __shared__ __align__(16) float hs[4][256];
  float h[4] = {0.f,0.f,0.f,0.f};
  float hn2 = 0.f;
#pragma unroll
  for (int i = 0; i < 4; i++) hs[wv][j0+i] = 0.f;
  float cbv[4];
#pragma unroll
  for (int i = 0; i < 4; i++) cbv[i] = cb[j0+i];
  const float cb2 = wred(sq_part<4>(cbv));
  for (int t = 0; t < 16; t++){
    __syncthreads();
    const unsigned short* xr = xgc + ((long)t*256 + b)*256;
    float xgv[4];
    { const ushort4 u = *(const ushort4*)(xr + j0); xgv[0]=bf2f(u.x); xgv[1]=bf2f(u.y); xgv[2]=bf2f(u.z); xgv[3]=bf2f(u.w); }
    float a[4]={0.f,0.f,0.f,0.f};
#pragma unroll 2
    for (int k0 = 0; k0 < 256; k0 += 4){
      const float4 hk = *(const float4*)&hs[wv][k0];
#pragma unroll
      for (int kk = 0; kk < 4; kk++){
        const float hv = (&hk.x)[kk];
        const float4 w4 = *(const float4*)(Wc + (long)(k0+kk)*256 + j0);
        a[0] += hv*w4.x; a[1] += hv*w4.y; a[2] += hv*w4.z; a[3] += hv*w4.w;
      }
    }
    const float mxn2 = wred(sq_part<4>(a));
    float pn2; mt_project<4>(a, mxn2, hn2, &pn2);
    const float y2 = wred(sq_part<4>(xgv));
    const float xy = wred(dot_part<4>(a, xgv));
    float m1[4]; madd_vec<4>(a, pn2, xgv, y2, xy, m1);
    const float m1n2 = wred(sq_part<4>(m1));
    const float xyb  = wred(dot_part<4>(m1, cbv));
    float m2[4]; madd_vec<4>(m1, m1n2, cbv, cb2, xyb, m2);
    float m2n2 = wred(sq_part<4>(m2));
    project_vec<4>(m2, &m2n2);
#pragma unroll
    for (int i = 0; i < 4; i++) h[i] = m2[i];
    hn2 = m2n2;
    *(float4*)&hs[wv][j0] = make_float4(h[0],h[1],h[2],h[3]);
    *(float4*)(cstates + ((long)b*16 + t)*256 + j0) = make_float4(h[0],h[1],h[2],h[3]);
  }
}

// ---------------------------------------------------------------------------
// cc concat; mxa/mxb are bf16 GEMM outputs now.
// ---------------------------------------------------------------------------
__global__ __launch_bounds__(256) void cc_rowwise(const unsigned short* __restrict__ sf,
    const unsigned short* __restrict__ sb, const unsigned short* __restrict__ mxa,
    const unsigned short* __restrict__ mxb, const float* __restrict__ ccb,
    unsigned short* __restrict__ ctxo, int rowoff)
{
  const int wv = threadIdx.x >> 6, lane = threadIdx.x & 63;
  const int rloc = blockIdx.x*4 + wv;
  const long r = rowoff + rloc;
  float s = 0.f;
#pragma unroll
  for (int i = 0; i < 4; i++){ const float v = bf2f(sf[r*256 + i*64+lane]); s += v*v; }
  const float sfn2 = wred(s);
  s = 0.f;
#pragma unroll
  for (int i = 0; i < 4; i++){ const float v = bf2f(sb[r*256 + i*64+lane]); s += v*v; }
  const float sbn2 = wred(s);
  float A[8], Bv[8];
#pragma unroll
  for (int i = 0; i < 8; i++){ A[i]  = bf2f(mxa[(long)rloc*512 + i*64+lane]);
                               Bv[i] = bf2f(mxb[(long)rloc*512 + i*64+lane]); }
  float pan2, pbn2;
  { const float n2 = wred(sq_part<8>(A));  mt_project<8>(A,  n2, sfn2, &pan2); }
  { const float n2 = wred(sq_part<8>(Bv)); mt_project<8>(Bv, n2, sbn2, &pbn2); }
  const float xy = wred(dot_part<8>(A, Bv));
  float M1[8]; madd_vec<8>(A, pan2, Bv, pbn2, xy, M1);
  const float m1n2 = wred(sq_part<8>(M1));
  float Cb[8];
#pragma unroll
  for (int i = 0; i < 8; i++) Cb[i] = ccb[i*64+lane];
  const float cb2 = wred(sq_part<8>(Cb));
  const float xyb = wred(dot_part<8>(M1, Cb));
  float M2[8]; madd_vec<8>(M1, m1n2, Cb, cb2, xyb, M2);
  float m2n2 = wred(sq_part<8>(M2));
  project_vec<8>(M2, &m2n2);
#pragma unroll
  for (int i = 0; i < 8; i++) ctxo[r*512 + i*64+lane] = f2bf(M2[i]);
}

// attn_emb = madd(ctx(bf16), pe) -> BF16 out + sqn of rounded
__global__ __launch_bounds__(256) void attn_add(const unsigned short* __restrict__ ctxv,
    const int* __restrict__ pos, const float* __restrict__ pet,
    unsigned short* __restrict__ oemb, float* __restrict__ osqn)
{
  const int wv = threadIdx.x >> 6, lane = threadIdx.x & 63;
  const long r = blockIdx.x*4 + wv;
  float X[8];
#pragma unroll
  for (int i = 0; i < 8; i++) X[i] = bf2f(ctxv[r*512 + i*64+lane]);
  const float x2 = wred(sq_part<8>(X));
  const int p = pos[r];
  float Y[8];
#pragma unroll
  for (int i = 0; i < 8; i++) Y[i] = pet[(long)p*512 + i*64+lane];
  const float y2 = wred(sq_part<8>(Y));
  const float xy = wred(dot_part<8>(X, Y));
  float O[8]; madd_vec<8>(X, x2, Y, y2, xy, O);
  float s = 0.f;
#pragma unroll
  for (int i = 0; i < 8; i++){
    const unsigned short u = f2bf(O[i]);
    oemb[r*512 + i*64+lane] = u;
    const float rv = bf2f(u);
    s += rv*rv;
  }
  s = wred(s);
  if (lane == 0) osqn[r] = s;
}

// mention variant (bf16 out)
__global__ __launch_bounds__(256) void attn_add_m(const float* __restrict__ mvv,
    const int* __restrict__ mentions, const float* __restrict__ pet,
    unsigned short* __restrict__ oemb, float* __restrict__ osqn)
{
  const int wv = threadIdx.x >> 6, lane = threadIdx.x & 63;
  const long r = blockIdx.x*4 + wv;
  float X[8];
#pragma unroll
  for (int i = 0; i < 8; i++) X[i] = mvv[r*512 + i*64+lane];
  const float x2 = wred(sq_part<8>(X));
  const int men = mentions[r];
  const int p = (men > 0) ? (int)(r & 7) + 1 : 0;
  float Y[8];
#pragma unroll
  for (int i = 0; i < 8; i++) Y[i] = pet[(long)p*512 + i*64+lane];
  const float y2 = wred(sq_part<8>(Y));
  const float xy = wred(dot_part<8>(X, Y));
  float O[8]; madd_vec<8>(X, x2, Y, y2, xy, O);
  float s = 0.f;
#pragma unroll
  for (int i = 0; i < 8; i++){
    const unsigned short u = f2bf(O[i]);
    oemb[r*512 + i*64+lane] = u;
    const float rv = bf2f(u);
    s += rv*rv;
  }
  s = wred(s);
  if (lane == 0) osqn[r] = s;
}

// q/k projection + pdist; mxq/mxk are bf16, rs = row stride in elements.
__global__ __launch_bounds__(256) void qk_pdist(const unsigned short* __restrict__ mxq,
    const unsigned short* __restrict__ mxk, const float* __restrict__ sqn,
    const float* __restrict__ bq, const float* __restrict__ bk,
    float* __restrict__ dout, int rs)
{
  const int wv = threadIdx.x >> 6, lane = threadIdx.x & 63;
  const int r = blockIdx.x*4 + wv;
  const float xn2 = sqn[r];
  float Q[8];
#pragma unroll
  for (int i = 0; i < 8; i++) Q[i] = bf2f(mxq[(long)r*rs + i*64+lane]);
  { const float n2 = wred(sq_part<8>(Q)); float pn2; mt_project<8>(Q, n2, xn2, &pn2);
    float Bq[8];
#pragma unroll
    for (int i = 0; i < 8; i++) Bq[i] = bq[i*64+lane];
    const float b2 = wred(sq_part<8>(Bq));
    const float xy = wred(dot_part<8>(Q, Bq));
    float O[8]; madd_vec<8>(Q, pn2, Bq, b2, xy, O);
#pragma unroll
    for (int i = 0; i < 8; i++) Q[i] = O[i];
  }
  float qn2 = wred(sq_part<8>(Q));
  project_vec<8>(Q, &qn2);
  float Kv[8];
#pragma unroll
  for (int i = 0; i < 8; i++) Kv[i] = bf2f(mxk[(long)r*rs + i*64+lane]);
  { const float n2 = wred(sq_part<8>(Kv)); float pn2; mt_project<8>(Kv, n2, xn2, &pn2);
    float Bk[8];
#pragma unroll
    for (int i = 0; i < 8; i++) Bk[i] = bk[i*64+lane];
    const float b2 = wred(sq_part<8>(Bk));
    const float xy = wred(dot_part<8>(Kv, Bk));
    float O[8]; madd_vec<8>(Kv, pn2, Bk, b2, xy, O);
#pragma unroll
    for (int i = 0; i < 8; i++) Kv[i] = O[i];
  }
  float kn2 = wred(sq_part<8>(Kv));
  project_vec<8>(Kv, &kn2);
  float NQ[8];
#pragma unroll
  for (int i = 0; i < 8; i++) NQ[i] = -Q[i];
  const float xy = wred(dot_part<8>(NQ, Kv));
  float Z[8]; madd_vec<8>(NQ, qn2, Kv, kn2, xy, Z);
  const float zn2 = wred(sq_part<8>(Z));
  const float d = 2.f * atanhf(clamp11(snorm(zn2)));
  if (lane == 0) dout[r] = d;
}

__global__ __launch_bounds__(256) void softmax128(const float* __restrict__ d,
    const float* __restrict__ beta, float* __restrict__ w)
{
  const int wv = threadIdx.x >> 6, lane = threadIdx.x & 63;
  const int b = blockIdx.x*4 + wv;
  const float bt = beta[0];
  const float x0 = -bt * d[b*128 + lane];
  const float x1 = -bt * d[b*128 + 64 + lane];
  const float m = wredmax(fmaxf(x0, x1));
  const float e0 = expf(x0 - m), e1 = expf(x1 - m);
  const float s = wred(e0 + e1);
  w[b*128 + lane]      = e0 / s;
  w[b*128 + 64 + lane] = e1 / s;
}

__global__ void softmax8(const float* __restrict__ d, const float* __restrict__ beta,
                         float* __restrict__ w)
{
  const int b = threadIdx.x;   // 256
  const float bt = beta[0];
  float x[8]; float m = -1e30f;
#pragma unroll
  for (int i = 0; i < 8; i++){ x[i] = -bt * d[b*8+i]; m = fmaxf(m, x[i]); }
  float s = 0.f;
#pragma unroll
  for (int i = 0; i < 8; i++){ x[i] = expf(x[i]-m); s += x[i]; }
#pragma unroll
  for (int i = 0; i < 8; i++) w[b*8+i] = x[i] / s;
}

// weighted gyromidpoint via Klein model; one wave per batch row (small Lseq)
template<int NPL, bool BF16V, bool HASW>
__global__ __launch_bounds__(256) void midpoint_kernel(const void* __restrict__ vals,
    const float* __restrict__ wts, float* __restrict__ outp, int Lseq)
{
  const int wv = threadIdx.x >> 6, lane = threadIdx.x & 63;
  const int b = blockIdx.x*4 + wv;
  const int D = NPL*64;
  float num[NPL];
#pragma unroll
  for (int i = 0; i < NPL; i++) num[i] = 0.f;
  float den = 0.f;
  for (int l = 0; l < Lseq; l++){
    const long base = ((long)b*Lseq + l)*D;
    float v[NPL]; float s = 0.f;
#pragma unroll
    for (int i = 0; i < NPL; i++){
      v[i] = BF16V ? bf2f(((const unsigned short*)vals)[base + i*64+lane])
                   : ((const float*)vals)[base + i*64+lane];
      s += v[i]*v[i];
    }
    const float v2 = wred(s);
    const float f = 2.f/(1.f + v2);
    const float kl2 = v2*f*f;
    const float gamma = 1.f/sqrtf(fmaxf(1.f - kl2, EPS_));
    const float wgt = HASW ? wts[b*Lseq + l] : 1.f;
    const float wg = wgt*gamma;
#pragma unroll
    for (int i = 0; i < NPL; i++) num[i] += wg*(f*v[i]);
    den += wg;
  }
  den = fmaxf(den, EPS_);
  float x[NPL]; float s = 0.f;
#pragma unroll
  for (int i = 0; i < NPL; i++){ x[i] = num[i]/den; s += x[i]*x[i]; }
  const float k2 = wred(s);
  const float inv = 1.f/(1.f + sqrtf(fmaxf(1.f - k2, EPS_)));
#pragma unroll
  for (int i = 0; i < NPL; i++) outp[(long)b*D + i*64+lane] = x[i]*inv;
}

// wide gyromidpoint for ctx (unchanged)
__global__ __launch_bounds__(512) void midpoint_wide(
    const unsigned short* __restrict__ vals,
    const float* __restrict__ wts,
    float* __restrict__ outp)
{
  __shared__ float pnum[8][512];
  __shared__ float pden[8];
  __shared__ float red[512];
  __shared__ float kk2[1];
  const int b = blockIdx.x;
  const int tid = threadIdx.x;
  const int w = tid >> 6, lane = tid & 63;
  float num[8] = {0.f,0.f,0.f,0.f,0.f,0.f,0.f,0.f};
  float den = 0.f;
  for (int l = w; l < 128; l += 8){
    const long base = ((long)b*128 + l)*512;
    float v[8]; float s = 0.f;
#pragma unroll
    for (int i = 0; i < 8; i++){
      v[i] = bf2f(vals[base + i*64 + lane]);
      s += v[i]*v[i];
    }
    const float v2 = wred(s);
    const float f = 2.f/(1.f + v2);
    const float kl2 = v2*f*f;
    const float gamma = 1.f/sqrtf(fmaxf(1.f - kl2, EPS_));
    const float wg = wts[b*128 + l]*gamma;
#pragma unroll
    for (int i = 0; i < 8; i++) num[i] += wg*(f*v[i]);
    den += wg;
  }
#pragma unroll
  for (int i = 0; i < 8; i++) pnum[w][i*64 + lane] = num[i];
  if (lane == 0) pden[w] = den;
  __syncthreads();
  float nsum = 0.f, dsum = 0.f;
#pragma unroll
  for (int p = 0; p < 8; p++){ nsum += pnum[p][tid]; dsum += pden[p]; }
  dsum = fmaxf(dsum, EPS_);
  const float x = nsum/dsum;
  red[tid] = x*x;
  __syncthreads();
  if (tid < 64){
    float s2 = 0.f;
#pragma unroll
    for (int i = 0; i < 8; i++) s2 += red[tid + i*64];
    s2 = wred(s2);
    if (tid == 0) kk2[0] = s2;
  }
  __syncthreads();
  const float k2 = kk2[0];
  const float inv = 1.f/(1.f + sqrtf(fmaxf(1.f - k2, EPS_)));
  outp[(long)b*512 + tid] = x*inv;
}

// mention w2s mobius_linear with tanh nonlinearity; mx is bf16 now.
__global__ __launch_bounds__(256) void mv_rowwise(const unsigned short* __restrict__ mx,
    const float* __restrict__ xsqn, const float* __restrict__ bb, float* __restrict__ outp)
{
  const int wv = threadIdx.x >> 6, lane = threadIdx.x & 63;
  const long r = blockIdx.x*4 + wv;
  float M[8];
#pragma unroll
  for (int i = 0; i < 8; i++) M[i] = bf2f(mx[r*512 + i*64+lane]);
  { const float n2 = wred(sq_part<8>(M)); float pn2; mt_project<8>(M, n2, xsqn[r], &pn2);
    float Bv[8];
#pragma unroll
    for (int i = 0; i < 8; i++) Bv[i] = bb[i*64+lane];
    const float b2 = wred(sq_part<8>(Bv));
    const float xy = wred(dot_part<8>(M, Bv));
    float O[8]; madd_vec<8>(M, pn2, Bv, b2, xy, O);
#pragma unroll
    for (int i = 0; i < 8; i++) M[i] = O[i];
  }
  float on2 = wred(sq_part<8>(M));
  project_vec<8>(M, &on2);
  { const float n = snorm(on2);
    const float fac = atanhf(clamp11(n))/n;
#pragma unroll
    for (int i = 0; i < 8; i++) M[i] = tanhf(fac*M[i]); }
  const float un2 = wred(sq_part<8>(M));
  { const float n = snorm(un2);
    const float fac = tanhf(n)/n;
    float en2 = fac*fac*un2;
#pragma unroll
    for (int i = 0; i < 8; i++) M[i] *= fac;
    project_vec<8>(M, &en2); }
#pragma unroll
  for (int i = 0; i < 8; i++) outp[r*512 + i*64+lane] = M[i];
}

// joint concat (unchanged)
__global__ __launch_bounds__(256) void final_rowwise(const float* __restrict__ jm,
    const float* __restrict__ jc, const float* __restrict__ jch,
    const float* __restrict__ mvec, const float* __restrict__ cvec,
    const float* __restrict__ chvec, const float* __restrict__ fcb,
    float* __restrict__ joint)
{
  const int wv = threadIdx.x >> 6, lane = threadIdx.x & 63;
  const long b = blockIdx.x*4 + wv;
  float s;
  s = 0.f; for (int i = 0; i < 8; i++){ const float v = mvec[b*512 + i*64+lane]; s += v*v; }
  const float mn2 = wred(s);
  s = 0.f; for (int i = 0; i < 8; i++){ const float v = cvec[b*512 + i*64+lane]; s += v*v; }
  const float cn2 = wred(s);
  s = 0.f; for (int i = 0; i < 4; i++){ const float v = chvec[b*256 + i*64+lane]; s += v*v; }
  const float chn2 = wred(s);
  float A[20];
#pragma unroll
  for (int i = 0; i < 20; i++) A[i] = jm[b*1280 + i*64+lane];
  float an2;
  { const float n2 = wred(sq_part<20>(A)); mt_project<20>(A, n2, mn2, &an2); }
  float T[20];
#pragma unroll
  for (int i = 0; i < 20; i++) T[i] = jc[b*1280 + i*64+lane];
  float tn2;
  { const float n2 = wred(sq_part<20>(T)); mt_project<20>(T, n2, cn2, &tn2); }
  { const float xy = wred(dot_part<20>(A, T));
    float O[20]; madd_vec<20>(A, an2, T, tn2, xy, O);
#pragma unroll
    for (int i = 0; i < 20; i++) A[i] = O[i];
    an2 = wred(sq_part<20>(A)); }
#pragma unroll
  for (int i = 0; i < 20; i++) T[i] = jch[b*1280 + i*64+lane];
  { const float n2 = wred(sq_part<20>(T)); mt_project<20>(T, n2, chn2, &tn2); }
  { const float xy = wred(dot_part<20>(A, T));
    float O[20]; madd_vec<20>(A, an2, T, tn2, xy, O);
#pragma unroll
    for (int i = 0; i < 20; i++) A[i] = O[i];
    an2 = wred(sq_part<20>(A)); }
#pragma unroll
  for (int i = 0; i < 20; i++) T[i] = fcb[i*64+lane];
  tn2 = wred(sq_part<20>(T));
  { const float xy = wred(dot_part<20>(A, T));
    float O[20]; madd_vec<20>(A, an2, T, tn2, xy, O);
#pragma unroll
    for (int i = 0; i < 20; i++) A[i] = O[i];
    an2 = wred(sq_part<20>(A)); }
  project_vec<20>(A, &an2);
#pragma unroll
  for (int i = 0; i < 20; i++) joint[b*1280 + i*64+lane] = A[i];
}

// hyperbolic MLR head (unchanged)
__global__ __launch_bounds__(256) void mlr_kernel(const float* __restrict__ joint,
    const float* __restrict__ P, const float* __restrict__ A, float* __restrict__ outp)
{
  const int wv = threadIdx.x >> 6, lane = threadIdx.x & 63;
  const int pair = blockIdx.x*4 + wv;
  const long b = pair >> 7, c = pair & 127;
  float Pv[20], J[20];
#pragma unroll
  for (int i = 0; i < 20; i++){
    Pv[i] = -P[c*1280 + i*64+lane];
    J[i]  = joint[b*1280 + i*64+lane];
  }
  const float p2 = wred(sq_part<20>(Pv));
  const float j2 = wred(sq_part<20>(J));
  const float xy = wred(dot_part<20>(Pv, J));
  float Z[20]; madd_vec<20>(Pv, p2, J, j2, xy, Z);
  float sza = 0.f, sz2 = 0.f, sa2 = 0.f;
#pragma unroll
  for (int i = 0; i < 20; i++){
    const float a = A[c*1280 + i*64+lane];
    sza += Z[i]*a; sz2 += Z[i]*Z[i]; sa2 += a*a;
  }
  float za = sza, z2 = sz2, a2 = sa2;
  wred3(za, z2, a2);
  const float an = sqrtf(fmaxf(a2, EPS_));
  const float v = 2.f*za / (fmaxf(1.f - z2, EPS_)*an);
  if (lane == 0) outp[pair] = 2.f*an*asinhf(v);
}

// ---------------------------------------------------------------------------
extern "C" void kernel_launch(void* const* d_in, const int* in_sizes, int n_in,
                              void* d_out, int out_size, void* d_ws, size_t ws_size,
                              hipStream_t stream)
{
  (void)in_sizes; (void)n_in; (void)out_size;
  const int*   context   = (const int*)  d_in[0];
  const int*   ctx_position=(const int*) d_in[1];
  const int*   mentions  = (const int*)  d_in[2];
  const int*   mchars    = (const int*)  d_in[3];
  const float* word_lut  = (const float*)d_in[4];
  const float* char_lut  = (const float*)d_in[5];
  const float* gf_Wih    = (const float*)d_in[6];
  const float* gf_Whh    = (const float*)d_in[7];
  const float* gf_b      = (const float*)d_in[8];
  const float* gb_Wih    = (const float*)d_in[9];
  const float* gb_Whh    = (const float*)d_in[10];
  const float* gb_b      = (const float*)d_in[11];
  const float* w2s_W     = (const float*)d_in[12];
  const float* w2s_b     = (const float*)d_in[13];
  const float* men_pos   = (const float*)d_in[14];
  const float* men_Wq    = (const float*)d_in[15];
  const float* men_bq    = (const float*)d_in[16];
  const float* men_Wk    = (const float*)d_in[17];
  const float* men_bk    = (const float*)d_in[18];
  const float* men_beta  = (const float*)d_in[19];
  const float* char_W    = (const float*)d_in[20];
  const float* char_U    = (const float*)d_in[21];
  const float* char_b    = (const float*)d_in[22];
  const float* cc_Wa     = (const float*)d_in[23];
  const float* cc_Wb     = (const float*)d_in[24];
  const float* cc_bias   = (const float*)d_in[25];
  const float* ctx_pos_t = (const float*)d_in[26];
  const float* ctx_Wq    = (const float*)d_in[27];
  const float* ctx_bq    = (const float*)d_in[28];
  const float* ctx_Wk    = (const float*)d_in[29];
  const float* ctx_bk    = (const float*)d_in[30];
  const float* ctx_beta  = (const float*)d_in[31];
  const float* fc_Wm     = (const float*)d_in[32];
  const float* fc_Wc     = (const float*)d_in[33];
  const float* fc_Wch    = (const float*)d_in[34];
  const float* fc_bias   = (const float*)d_in[35];
  const float* mlr_p     = (const float*)d_in[36];
  const float* mlr_a     = (const float*)d_in[37];
  float* out = (float*)d_out;

  // ---- workspace bump allocator ----
  char* wsb = (char*)d_ws;
  size_t off = 0;
  auto alloc = [&](size_t bytes) -> void* {
    void* p = wsb + off;
    off += (bytes + 255) & ~(size_t)255;
    return p;
  };
  float* WtHH = (float*)alloc(2UL*256*768*4);
  unsigned* Wrz2 = (unsigned*)alloc(2UL*128*512*4);   // f16 k-pair (r|z)
  unsigned* Wh2  = (unsigned*)alloc(2UL*128*256*4);   // f16 k-pair (h)
  unsigned short* WihP   = (unsigned short*)alloc(2UL*768*320*2);
  unsigned short* ctxWqkP= (unsigned short*)alloc(1024UL*512*2);  // fused Q|K
  unsigned short* ccWaP  = (unsigned short*)alloc(512UL*256*2);
  unsigned short* ccWbP  = (unsigned short*)alloc(512UL*256*2);
  unsigned short* menWqkP= (unsigned short*)alloc(1024UL*512*2);  // fused Q|K
  unsigned short* w2sP   = (unsigned short*)alloc(512UL*320*2);
  unsigned short* charUP = (unsigned short*)alloc(256UL*256*2);
  int*   ctxidx = (int*)alloc(32768UL*4);
  int*   chidx  = (int*)alloc(4096UL*4);
  float* xsqn   = (float*)alloc(32768UL*4);
  float* msqn   = (float*)alloc(2048UL*4);
  float* chsqn  = (float*)alloc(4096UL*4);
  unsigned short* xg = (unsigned short*)alloc(2UL*32768*768*2);
  float* xgn2 = (float*)alloc(2UL*32768*3*4);
  float* chn2d = (float*)alloc(4096UL*4);
  unsigned short* states_f = (unsigned short*)alloc(32768UL*256*2);
  unsigned short* states_b = (unsigned short*)alloc(32768UL*256*2);
  unsigned short* ctxv = (unsigned short*)alloc(32768UL*512*2);
  float* attn_sqn = (float*)alloc(32768UL*4);
  float* dctx = (float*)alloc(32768UL*4);
  float* wctx = (float*)alloc(32768UL*4);
  float* ctx_vec = (float*)alloc(256UL*512*4);
  float* mxbuf = (float*)alloc(2UL*8192*512*4);   // 33.5MB scratch region
  float* mv = (float*)alloc(2048UL*512*4);
  unsigned short* attn_embm = (unsigned short*)alloc(2048UL*512*2);
  float* amsqn = (float*)alloc(2048UL*4);
  float* dm = (float*)alloc(2048UL*4);
  float* wm = (float*)alloc(2048UL*4);
  float* mention_vec = (float*)alloc(256UL*512*4);
  unsigned short* xgc = (unsigned short*)alloc(4096UL*256*2);
  float* char_states = (float*)alloc(4096UL*256*4);
  float* char_vec = (float*)alloc(256UL*256*4);
  float* joint = (float*)alloc(256UL*1280*4);
  if (off > ws_size) return;
  unsigned short* attn_embc = xg;                  // overlay: xg dead after GRU
  unsigned short* mx16  = (unsigned short*)mxbuf;  // bf16 GEMM-output views
  unsigned short* mx16b = mx16 + 8192UL*512;
  float* mxh0 = mxbuf;                             // f32 view (fc path)

  // ---- weight transposes + packs ----
  transpose_k<<<dim3(8,24), 256,0,stream>>>(gf_Whh, WtHH,            768, 256);
  transpose_k<<<dim3(8,24), 256,0,stream>>>(gb_Whh, WtHH + 256*768,  768, 256);
  pack_whh_f16<<<768,256,0,stream>>>(WtHH, Wrz2, Wh2);
  pack_wih<<<1920,256,0,stream>>>(gf_Wih, gb_Wih, WihP);
  packT16<<<dim3(16,16),256,0,stream>>>(ctx_Wq, ctxWqkP,              512, 512, 512);
  packT16<<<dim3(16,16),256,0,stream>>>(ctx_Wk, ctxWqkP + 512UL*512,  512, 512, 512);
  packT16<<<dim3(8,16), 256,0,stream>>>(cc_Wa,  ccWaP,  256, 512, 256);
  packT16<<<dim3(8,16), 256,0,stream>>>(cc_Wb,  ccWbP,  256, 512, 256);
  packT16<<<dim3(16,16),256,0,stream>>>(men_Wq, menWqkP,             512, 512, 512);
  packT16<<<dim3(16,16),256,0,stream>>>(men_Wk, menWqkP + 512UL*512, 512, 512, 512);
  packT16<<<dim3(10,16),256,0,stream>>>(w2s_W,  w2sP,   300, 512, 320);
  packT16<<<dim3(8,8),  256,0,stream>>>(char_U, charUP, 256, 256, 256);

  // ---- gather indices + input sqn ----
  build_idx<<<144,256,0,stream>>>(context, mchars, ctxidx, chidx);
  sqn_gather<<<8192,256,0,stream>>>(word_lut, ctxidx, 300, xsqn);
  sqn_gather<<<512, 256,0,stream>>>(word_lut, mentions, 300, msqn);
  sqn_gather<<<1024,256,0,stream>>>(char_lut, chidx, 256, chsqn);

  // ---- GRU input precompute: xg[dir] = mobius_matvec(emb, Wih^T), bf16 ----
  for (int d2 = 0; d2 < 2; d2++){
    const unsigned short* wihp = WihP + (size_t)d2*768*320;
    for (int c = 0; c < 4; c++){
      mfma_mm<1,1><<<dim3(6,128),256,0,stream>>>(word_lut, ctxidx + c*8192, wihp,
                                                 mx16, 8192, 768, 300, 320);
      xg_transform<<<6144,256,0,stream>>>(mx16, xsqn + c*8192,
          xg + ((size_t)d2*32768 + (size_t)c*8192)*768,
          xgn2 + ((size_t)d2*32768 + (size_t)c*8192)*3, 3);
    }
  }

  // ---- bidirectional Mobius GRU (v9 f16-dot2) ----
  (void)hipFuncSetAttribute((const void*)gru_kernel,
      hipFuncAttributeMaxDynamicSharedMemorySize, GRU_LDS_BYTES);
  gru_kernel<<<256,512,GRU_LDS_BYTES,stream>>>(xg, xgn2, Wrz2, Wh2,
                                               gf_b, gb_b, states_f, states_b);

  // ---- mobius concat of directions -> ctx (bf16) ----
  for (int c = 0; c < 4; c++){
    mfma_mm<2,1><<<dim3(4,128),256,0,stream>>>(states_f + (size_t)c*8192*256, nullptr,
                                               ccWaP, mx16, 8192, 512, 256, 256);
    mfma_mm<2,1><<<dim3(4,128),256,0,stream>>>(states_b + (size_t)c*8192*256, nullptr,
                                               ccWbP, mx16b, 8192, 512, 256, 256);
    cc_rowwise<<<2048,256,0,stream>>>(states_f, states_b, mx16, mx16b, cc_bias,
                                      ctxv, c*8192);
  }

  // ---- context distance attention (fused Q|K GEMM, N=1024, bf16 out) ----
  attn_add<<<8192,256,0,stream>>>(ctxv, ctx_position, ctx_pos_t, attn_embc, attn_sqn);
  for (int c = 0; c < 4; c++){
    mfma_mm<2,1><<<dim3(8,128),256,0,stream>>>(attn_embc + (size_t)c*8192*512, nullptr,
                                               ctxWqkP, mx16, 8192, 1024, 512, 512);
    qk_pdist<<<2048,256,0,stream>>>(mx16, mx16 + 512, attn_sqn + c*8192,
                                    ctx_bq, ctx_bk, dctx + c*8192, 1024);
  }
  softmax128<<<64,256,0,stream>>>(dctx, ctx_beta, wctx);
  midpoint_wide<<<256,512,0,stream>>>(ctxv, wctx, ctx_vec);

  // ---- mention encoder (fused Q|K GEMM, bf16 out) ----
  mfma_mm<1,1><<<dim3(4,32),256,0,stream>>>(word_lut, mentions, w2sP, mx16,
                                            2048, 512, 300, 320);
  mv_rowwise<<<512,256,0,stream>>>(mx16, msqn, w2s_b, mv);
  attn_add_m<<<512,256,0,stream>>>(mv, mentions, men_pos, attn_embm, amsqn);
  mfma_mm<2,1><<<dim3(8,32),256,0,stream>>>(attn_embm, nullptr, menWqkP, mx16,
                                            2048, 1024, 512, 512);
  qk_pdist<<<512,256,0,stream>>>(mx16, mx16 + 512, amsqn, men_bq, men_bk, dm, 1024);
  softmax8<<<1,256,0,stream>>>(dm, men_beta, wm);
  midpoint_kernel<8,false,true><<<64,256,0,stream>>>(mv, wm, mention_vec, 8);

  // ---- char encoder (bf16 GEMM out) ----
  mfma_mm<1,1><<<dim3(2,64),256,0,stream>>>(char_lut, chidx, charUP, mx16,
                                            4096, 256, 256, 256);
  xg_transform<<<1024,256,0,stream>>>(mx16, chsqn, xgc, chn2d, 1);
  char_rnn<<<64,256,0,stream>>>(xgc, char_W, char_b, char_states);
  midpoint_kernel<4,false,false><<<64,256,0,stream>>>(char_states, nullptr, char_vec, 16);

  // ---- full mobius concat + MLR (small, f32 path) ----
  float* jm = mxh0;
  float* jc = mxh0 + 256UL*1280;
  float* jch = mxh0 + 2UL*256*1280;
  mm_kernel<0><<<dim3(10,2),256,0,stream>>>(mention_vec, nullptr, fc_Wm, jm, 256, 1280, 512);
  mm_kernel<0><<<dim3(10,2),256,0,stream>>>(ctx_vec,     nullptr, fc_Wc, jc, 256, 1280, 512);
  mm_kernel<0><<<dim3(10,2),256,0,stream>>>(char_vec,    nullptr, fc_Wch, jch, 256, 1280, 256);
  final_rowwise<<<64,256,0,stream>>>(jm, jc, jch, mention_vec, ctx_vec, char_vec,
                                     fc_bias, joint);
  mlr_kernel<<<8192,256,0,stream>>>(joint, mlr_p, mlr_a, out);
}

// Round 14
// 2353.744 us; speedup vs baseline: 1.2755x; 1.0404x over previous
//
#include <hip/hip_runtime.h>
#include <cstddef>
#include <cstdint>

// ---------------------------------------------------------------------------
// Hyperbolic (Poincare-ball) entity-typing forward pass, MI355X / gfx950.
// Round 14: de-chunked pipeline — xg GEMM writes into xg buffer + in-place
// transform (16->4 dispatches); cc full-M via xg overlay (12->3); attn Q|K in
// 2 half-M chunks (8->4). Math byte-identical to round 13 (2449us, passing).
// ---------------------------------------------------------------------------

#define EPS_  1e-15f
#define PMAX_ 0.99999f    // 1 - 1e-5

typedef __attribute__((ext_vector_type(8))) short bf16x8;
typedef __attribute__((ext_vector_type(4))) float f32x4;
typedef __attribute__((ext_vector_type(8))) unsigned short us8;
typedef _Float16 half2_t __attribute__((ext_vector_type(2)));

__device__ __forceinline__ half2_t as_h2(unsigned u){
  union { unsigned u; half2_t h; } v; v.u = u; return v.h;
}
__device__ __forceinline__ unsigned packh2(float a, float b){
  union { half2_t h; unsigned u; } v;
  v.h[0] = (_Float16)a; v.h[1] = (_Float16)b; return v.u;
}
#if __has_builtin(__builtin_amdgcn_fdot2)
#define FDOT2(a,b,c) __builtin_amdgcn_fdot2((a),(b),(c),false)
#else
#define FDOT2(a,b,c) ((c) + (float)(a)[0]*(float)(b)[0] + (float)(a)[1]*(float)(b)[1])
#endif

__device__ __forceinline__ float wred(float v){
#pragma unroll
  for (int o = 32; o; o >>= 1) v += __shfl_xor(v, o, 64);
  return v;
}
__device__ __forceinline__ void wred2(float& a, float& b){
#pragma unroll
  for (int o = 32; o; o >>= 1){ a += __shfl_xor(a, o, 64); b += __shfl_xor(b, o, 64); }
}
__device__ __forceinline__ void wred3(float& a, float& b, float& c){
#pragma unroll
  for (int o = 32; o; o >>= 1){
    a += __shfl_xor(a, o, 64); b += __shfl_xor(b, o, 64); c += __shfl_xor(c, o, 64);
  }
}
__device__ __forceinline__ void wred4(float& a, float& b, float& c, float& d){
#pragma unroll
  for (int o = 32; o; o >>= 1){
    a += __shfl_xor(a, o, 64); b += __shfl_xor(b, o, 64);
    c += __shfl_xor(c, o, 64); d += __shfl_xor(d, o, 64);
  }
}
__device__ __forceinline__ float wredmax(float v){
#pragma unroll
  for (int o = 32; o; o >>= 1) v = fmaxf(v, __shfl_xor(v, o, 64));
  return v;
}
__device__ __forceinline__ float snorm(float s){ return sqrtf(fmaxf(s, EPS_)); }
__device__ __forceinline__ float clamp11(float x){
  return fminf(fmaxf(x, -1.f + 1e-7f), 1.f - 1e-7f);
}
__device__ __forceinline__ float bf2f(unsigned short u){
  union { unsigned int i; float f; } v; v.i = ((unsigned int)u) << 16; return v.f;
}
__device__ __forceinline__ unsigned short f2bf(float f){
  union { float f; unsigned int i; } v; v.f = f;
  unsigned int x = v.i;
  x += 0x7fffu + ((x >> 16) & 1u);   // RNE
  return (unsigned short)(x >> 16);
}
__device__ __forceinline__ float bflo(unsigned u){
  union { unsigned i; float f; } v; v.i = u << 16; return v.f;
}
__device__ __forceinline__ float bfhi(unsigned u){
  union { unsigned i; float f; } v; v.i = u & 0xffff0000u; return v.f;
}

template<int N>
__device__ __forceinline__ float sq_part(const float* a){
  float s = 0.f;
#pragma unroll
  for (int i = 0; i < N; i++) s += a[i]*a[i];
  return s;
}
template<int N>
__device__ __forceinline__ float dot_part(const float* a, const float* b){
  float s = 0.f;
#pragma unroll
  for (int i = 0; i < N; i++) s += a[i]*b[i];
  return s;
}
template<int N>
__device__ __forceinline__ void madd_vec(const float* x, float x2, const float* y,
                                         float y2, float xy, float* o){
  const float c1 = 1.f + 2.f*xy + y2;
  const float c2 = 1.f - x2;
  const float inv = 1.f / fmaxf(1.f + 2.f*xy + x2*y2, EPS_);
#pragma unroll
  for (int i = 0; i < N; i++) o[i] = (c1*x[i] + c2*y[i]) * inv;
}
template<int N>
__device__ __forceinline__ void mt_project(float* v, float mxn2, float xn2, float* n2out){
  const float xn  = snorm(xn2);
  const float mxn = snorm(mxn2);
  const float t   = tanhf(mxn/xn * atanhf(clamp11(xn)));
  float sc = t/mxn;
  float n2 = sc*sc*mxn2;
  const float n = snorm(n2);
  if (n > PMAX_){ const float s = PMAX_/n; sc *= s; n2 *= s*s; }
#pragma unroll
  for (int i = 0; i < N; i++) v[i] *= sc;
  *n2out = n2;
}
__device__ __forceinline__ void mt_scale(float mxn2, float xn, float art,
                                         float* sc, float* n2){
  const float mxn = snorm(mxn2);
  const float t   = tanhf(mxn/xn * art);
  float s  = t/mxn;
  float nn = t*t;
  const float n = snorm(nn);
  if (n > PMAX_){ const float f = PMAX_/n; s *= f; nn *= f*f; }
  *sc = s; *n2 = nn;
}
template<int N>
__device__ __forceinline__ void project_vec(float* v, float* n2io){
  float n2 = *n2io;
  const float n = snorm(n2);
  if (n > PMAX_){
    const float s = PMAX_/n;
#pragma unroll
    for (int i = 0; i < N; i++) v[i] *= s;
    n2 *= s*s;
  }
  *n2io = n2;
}

// async 16B global->LDS: linear wave-uniform-base + lane*16
__device__ __forceinline__ void gll16(const void* g, void* l){
  __builtin_amdgcn_global_load_lds(
      (const __attribute__((address_space(1))) void*)g,
      (__attribute__((address_space(3))) void*)l, 16, 0, 0);
}
// stage 64KB with 512 threads (8 waves x 8 x 16B/lane), linear layout
__device__ __forceinline__ void stage64k8(const void* gsrc, float* lbase, int w, int lane){
#pragma unroll
  for (int i = 0; i < 8; i++){
    const char* g = (const char*)gsrc + (size_t)((i*8 + w)*64 + lane)*16;
    char* l = (char*)lbase + (size_t)((i*8 + w)*64)*16;
    gll16(g, l);
  }
}

// ---------------------------------------------------------------------------
// MFMA bf16 GEMM (64x128 tile); OUT16=1 -> bf16 C output.
// ---------------------------------------------------------------------------
template<int AMODE, int OUT16>
__global__ __launch_bounds__(256) void mfma_mm(const void* __restrict__ Aptr,
    const int* __restrict__ idx, const unsigned short* __restrict__ Bt,
    void* __restrict__ Cm, int M, int N, int K, int Kp)
{
  __shared__ __align__(16) unsigned short As[64][40];
  __shared__ __align__(16) unsigned short Bs[128][40];
  const int tid = threadIdx.x;
  const int n0 = blockIdx.x * 128;
  const int m0 = blockIdx.y * 64;
  const int arow_s = tid >> 2, aq = tid & 3;
  const int brow_s = tid >> 1, bhf = tid & 1;
  const int wv = tid >> 6, lane = tid & 63;
  const int wm = wv >> 1, wn = wv & 1;
  const int lr = lane & 15, lk = lane >> 4;

  long arow;
  if constexpr (AMODE == 1) arow = (long)idx[m0 + arow_s] * K;
  else                      arow = (long)(m0 + arow_s) * K;

  f32x4 acc[2][4];
#pragma unroll
  for (int mf = 0; mf < 2; mf++)
#pragma unroll
    for (int nf = 0; nf < 4; nf++) acc[mf][nf] = (f32x4){0.f,0.f,0.f,0.f};

  for (int k0 = 0; k0 < Kp; k0 += 32){
    const int kbA = k0 + aq*8;
    unsigned short av[8];
    if constexpr (AMODE == 1){
      const float* ar = (const float*)Aptr + arow;
      if (kbA + 8 <= K){
        const float4 f0 = *(const float4*)(ar + kbA);
        const float4 f1 = *(const float4*)(ar + kbA + 4);
        av[0]=f2bf(f0.x); av[1]=f2bf(f0.y); av[2]=f2bf(f0.z); av[3]=f2bf(f0.w);
        av[4]=f2bf(f1.x); av[5]=f2bf(f1.y); av[6]=f2bf(f1.z); av[7]=f2bf(f1.w);
      } else {
#pragma unroll
        for (int v = 0; v < 8; v++){
          const int col = kbA + v;
          av[v] = (col < K) ? f2bf(ar[col]) : (unsigned short)0;
        }
      }
    } else {
      const us8 u0 = *(const us8*)((const unsigned short*)Aptr + arow + kbA);
#pragma unroll
      for (int v = 0; v < 8; v++) av[v] = u0[v];
    }
    unsigned short bvv[16];
    {
      const unsigned short* br = Bt + (long)(n0 + brow_s)*Kp + k0 + bhf*16;
      const us8 u0 = *(const us8*)br;
      const us8 u1 = *(const us8*)(br + 8);
#pragma unroll
      for (int v = 0; v < 8; v++){ bvv[v] = u0[v]; bvv[8+v] = u1[v]; }
    }
    __syncthreads();
    *(us8*)&As[arow_s][aq*8] = *(const us8*)&av[0];
    *(us8*)&Bs[brow_s][bhf*16]   = *(const us8*)&bvv[0];
    *(us8*)&Bs[brow_s][bhf*16+8] = *(const us8*)&bvv[8];
    __syncthreads();
    bf16x8 af[2], bfr[4];
#pragma unroll
    for (int mf = 0; mf < 2; mf++)
      af[mf] = *(const bf16x8*)&As[wm*32 + mf*16 + lr][lk*8];
#pragma unroll
    for (int nf = 0; nf < 4; nf++)
      bfr[nf] = *(const bf16x8*)&Bs[wn*64 + nf*16 + lr][lk*8];
#pragma unroll
    for (int mf = 0; mf < 2; mf++)
#pragma unroll
      for (int nf = 0; nf < 4; nf++)
        acc[mf][nf] = __builtin_amdgcn_mfma_f32_16x16x32_bf16(af[mf], bfr[nf],
                                                              acc[mf][nf], 0, 0, 0);
  }
#pragma unroll
  for (int mf = 0; mf < 2; mf++){
#pragma unroll
    for (int nf = 0; nf < 4; nf++){
#pragma unroll
      for (int r = 0; r < 4; r++){
        const long grow = m0 + wm*32 + mf*16 + lk*4 + r;
        const long gcol = n0 + wn*64 + nf*16 + lr;
        if constexpr (OUT16)
          ((unsigned short*)Cm)[grow*N + gcol] = f2bf(acc[mf][nf][r]);
        else
          ((float*)Cm)[grow*N + gcol] = acc[mf][nf][r];
      }
    }
  }
}

// ---------------------------------------------------------------------------
// Generic tiled f32 GEMM (small fc GEMMs only)
// ---------------------------------------------------------------------------
template<int AMODE>
__global__ __launch_bounds__(256) void mm_kernel(const void* __restrict__ Aptr,
    const int* __restrict__ idx, const float* __restrict__ Bm,
    float* __restrict__ Cm, int M, int N, int K)
{
  __shared__ __align__(16) float As[8][128];
  __shared__ __align__(16) float Bs[8][132];
  const int tid = threadIdx.x;
  const int n0 = blockIdx.x * 128;
  const int m0 = blockIdx.y * 128;
  const int tr = tid >> 4, tc = tid & 15;
  const int sm = tid & 127, sk = (tid >> 7) * 4;
  const int bk = tid >> 5,  bn = (tid & 31) * 4;
  long arow;
  if constexpr (AMODE == 1) arow = (long)idx[m0 + sm] * K;
  else                      arow = (long)(m0 + sm) * K;
  float acc[8][8];
#pragma unroll
  for (int i = 0; i < 8; i++)
#pragma unroll
    for (int j = 0; j < 8; j++) acc[i][j] = 0.f;

  for (int k0 = 0; k0 < K; k0 += 8){
    float av[4], bv[4];
    {
      const float* A = (const float*)Aptr;
      if (k0 + sk + 3 < K){
        const float4 f = *reinterpret_cast<const float4*>(A + arow + k0 + sk);
        av[0]=f.x; av[1]=f.y; av[2]=f.z; av[3]=f.w;
      } else {
#pragma unroll
        for (int i = 0; i < 4; i++){
          const int kk = k0 + sk + i;
          av[i] = (kk < K) ? A[arow + kk] : 0.f;
        }
      }
    }
    {
      const int kb = k0 + bk;
      if (kb < K){
        const float4 f = *reinterpret_cast<const float4*>(Bm + (long)kb*N + n0 + bn);
        bv[0]=f.x; bv[1]=f.y; bv[2]=f.z; bv[3]=f.w;
      } else { bv[0]=bv[1]=bv[2]=bv[3]=0.f; }
    }
    __syncthreads();
    As[sk+0][sm]=av[0]; As[sk+1][sm]=av[1]; As[sk+2][sm]=av[2]; As[sk+3][sm]=av[3];
    *reinterpret_cast<float4*>(&Bs[bk][bn]) = make_float4(bv[0],bv[1],bv[2],bv[3]);
    __syncthreads();
#pragma unroll
    for (int k = 0; k < 8; k++){
      float a[8], bb[8];
      *(float4*)&a[0]  = *(const float4*)&As[k][tr*8];
      *(float4*)&a[4]  = *(const float4*)&As[k][tr*8+4];
      *(float4*)&bb[0] = *(const float4*)&Bs[k][tc*8];
      *(float4*)&bb[4] = *(const float4*)&Bs[k][tc*8+4];
#pragma unroll
      for (int i = 0; i < 8; i++)
#pragma unroll
        for (int j = 0; j < 8; j++) acc[i][j] += a[i]*bb[j];
    }
  }
#pragma unroll
  for (int i = 0; i < 8; i++){
    const long row = m0 + tr*8 + i;
    *(float4*)(Cm + row*N + n0 + tc*8)     = make_float4(acc[i][0],acc[i][1],acc[i][2],acc[i][3]);
    *(float4*)(Cm + row*N + n0 + tc*8 + 4) = make_float4(acc[i][4],acc[i][5],acc[i][6],acc[i][7]);
  }
}

// ---------------------------------------------------------------------------
// 32x32 LDS-tiled transpose: dst[k*R + j] = src[j*Kc + k]   (f32 -> f32)
// ---------------------------------------------------------------------------
__global__ __launch_bounds__(256) void transpose_k(const float* __restrict__ src,
    float* __restrict__ dst, int R, int Kc)
{
  __shared__ float t[32][33];
  const int bx = blockIdx.x * 32;
  const int by = blockIdx.y * 32;
  const int tx = threadIdx.x & 31, ty = threadIdx.x >> 5;
#pragma unroll
  for (int i = 0; i < 32; i += 8){
    const int j = by + ty + i, k = bx + tx;
    t[ty+i][tx] = (j < R && k < Kc) ? src[(long)j*Kc + k] : 0.f;
  }
  __syncthreads();
#pragma unroll
  for (int i = 0; i < 32; i += 8){
    const int k = bx + ty + i, j = by + tx;
    if (k < Kc && j < R) dst[(long)k*R + j] = t[tx][ty+i];
  }
}

// transpose + bf16 pack: src [K][N] f32 -> dst [N][Kp] bf16 (zero-pad K..Kp)
__global__ __launch_bounds__(256) void packT16(const float* __restrict__ src,
    unsigned short* __restrict__ dst, int K, int N, int Kp)
{
  __shared__ float t[32][33];
  const int bx = blockIdx.x*32;
  const int by = blockIdx.y*32;
  const int tx = threadIdx.x & 31, ty = threadIdx.x >> 5;
#pragma unroll
  for (int i = 0; i < 32; i += 8){
    const int k = bx + ty + i, n = by + tx;
    t[ty+i][tx] = (k < K && n < N) ? src[(long)k*N + n] : 0.f;
  }
  __syncthreads();
#pragma unroll
  for (int i = 0; i < 32; i += 8){
    const int k = bx + tx, n = by + ty + i;
    if (k < Kp && n < N) dst[(long)n*Kp + k] = f2bf(t[tx][ty+i]);
  }
}

// pack Wih (already [768][300] = B^T layout) -> [2][768][320] bf16 zero-padded
__global__ void pack_wih(const float* __restrict__ w0, const float* __restrict__ w1,
                         unsigned short* __restrict__ dst)
{
  const int tid = blockIdx.x*256 + threadIdx.x;
  if (tid < 2*768*320){
    const int d = tid / (768*320);
    const int rem = tid - d*768*320;
    const int n = rem / 320, k = rem - n*320;
    const float* src = d ? w1 : w0;
    dst[tid] = (k < 300) ? f2bf(src[n*300 + k]) : (unsigned short)0;
  }
}

// split+pack WtHH [2][256 k][768 (r|h|z)] f32 -> f16 k-pair layouts
__global__ void pack_whh_f16(const float* __restrict__ WtHH,
                             unsigned* __restrict__ Wrz2,
                             unsigned* __restrict__ Wh2)
{
  const int tid = blockIdx.x*256 + threadIdx.x;   // 0 .. 196607
  if (tid < 2*128*768){
    const int col = tid % 768;
    const int rest = tid / 768;         // dir*128 + kp
    const int kp = rest & 127, dir = rest >> 7;
    const float* s0 = WtHH + ((long)(dir*256 + 2*kp))*768 + col;
    const unsigned u = packh2(s0[0], s0[768]);
    if (col < 256)       Wrz2[(long)(dir*128 + kp)*512 + col] = u;
    else if (col < 512)  Wh2 [(long)(dir*128 + kp)*256 + (col - 256)] = u;
    else                 Wrz2[(long)(dir*128 + kp)*512 + 256 + (col - 512)] = u;
  }
}

// build gather-index arrays
__global__ void build_idx(const int* __restrict__ context, const int* __restrict__ mchars,
                          int* __restrict__ ctxidx, int* __restrict__ chidx)
{
  const int tid = blockIdx.x*256 + threadIdx.x;
  if (tid < 32768){
    const int t = tid >> 8, b = tid & 255;
    ctxidx[tid] = context[b*128 + t];
  } else if (tid < 32768 + 4096){
    const int o = tid - 32768;
    const int t = o >> 8, b = o & 255;
    chidx[o] = mchars[b*16 + t];
  }
}

// out[r] = sum_k lut[idx[r]][k]^2   (one wave per row)
__global__ __launch_bounds__(256) void sqn_gather(const float* __restrict__ lut,
    const int* __restrict__ idx, int K, float* __restrict__ outp)
{
  const int wv = threadIdx.x >> 6, lane = threadIdx.x & 63;
  const int r = blockIdx.x*4 + wv;
  const float* row = lut + (long)idx[r]*K;
  float s = 0.f;
  for (int k = lane; k < K; k += 64) s += row[k]*row[k];
  s = wred(s);
  if (lane == 0) outp[r] = s;
}

// mobius_matvec tail transform per (row, gate); mx bf16; in-place capable.
__global__ __launch_bounds__(256) void xg_transform(const unsigned short* __restrict__ mx,
    const float* __restrict__ xsqn, unsigned short* __restrict__ outp,
    float* __restrict__ n2o, int G)
{
  const int wv = threadIdx.x >> 6, lane = threadIdx.x & 63;
  const int wg = blockIdx.x*4 + wv;
  const int row = wg / G, g = wg - row*G;
  const long base = (long)row*(G*256) + g*256;
  float M[4];
#pragma unroll
  for (int i = 0; i < 4; i++) M[i] = bf2f(mx[base + i*64 + lane]);
  const float mxn2 = wred(sq_part<4>(M));
  float pn2; mt_project<4>(M, mxn2, xsqn[row], &pn2);
  float s = 0.f;
#pragma unroll
  for (int i = 0; i < 4; i++){
    const unsigned short u = f2bf(M[i]);
    outp[base + i*64 + lane] = u;
    const float rv = bf2f(u);
    s += rv*rv;
  }
  s = wred(s);
  if (lane == 0) n2o[wg] = s;
}

// ---------------------------------------------------------------------------
// Mobius GRU v9 (unchanged, 1453us)
// ---------------------------------------------------------------------------
#define GRU_LDS_BYTES 151808

__global__ __launch_bounds__(512,1) void gru_kernel(
    const unsigned short* __restrict__ xg,
    const float* __restrict__ xgn2,
    const unsigned* __restrict__ Wrz2,
    const unsigned* __restrict__ Wh2,
    const float* __restrict__ bias_f, const float* __restrict__ bias_b,
    unsigned short* __restrict__ states_f, unsigned short* __restrict__ states_b)
{
  extern __shared__ __align__(16) char smem[];
  float*    wbuf = (float*)smem;
  unsigned* hsp  = (unsigned*)(smem + 131072);
  unsigned* rhp  = (unsigned*)(smem + 132096);
  float*    part = (float*)(smem + 133120);
  float*    zb   = (float*)(smem + 149504);
  float*    scal = (float*)(smem + 151552);

  const int bid = blockIdx.x;
  const int dir = bid >> 7;
  const int brow0 = (bid & 127) * 2;
  const int tid = threadIdx.x;
  const int w = tid >> 6, lane = tid & 63;
  const int j0 = lane << 2;

  const unsigned short* xgd = xg + (long)dir*32768*768;
  const float* xnd = xgn2 + (long)dir*32768*3;
  const unsigned* wrz_d = Wrz2 + (long)dir*128*512;
  const unsigned* wh_d  = Wh2  + (long)dir*128*256;
  const float* bias = dir ? bias_b : bias_f;
  unsigned short* states = dir ? states_b : states_f;

  const int fg  = w & 1;
  const int kq4 = w >> 1;
  const int qk8 = w;
  const int crow  = (w >> 1) & 1;
  const int cgate = w & 1;

  float bg[4], bh4[4] = {0,0,0,0};
  float bg2, bh2 = 0.f;
#pragma unroll
  for (int i = 0; i < 4; i++) bg[i] = bias[(cgate ? 512 : 0) + j0 + i];
  bg2 = wred(sq_part<4>(bg));
  if (w < 2){
#pragma unroll
    for (int i = 0; i < 4; i++) bh4[i] = bias[256 + j0 + i];
    bh2 = wred(sq_part<4>(bh4));
  }

  float h[4] = {0.f,0.f,0.f,0.f};
  float hn2 = 0.f;
  if (w < 2){
    hsp[w*128 + lane*2]     = 0u;
    hsp[w*128 + lane*2 + 1] = 0u;
    if (lane == 0){ scal[w*2 + 0] = 0.f; scal[w*2 + 1] = 0.f; }
  }

  int cb = 0;
  stage64k8(wrz_d, wbuf, w, lane);

  for (int t = 0; t < 128; t++){
    const int tt = dir ? (127 - t) : t;
    float xgv[4] = {0,0,0,0}, y2g = 0.f, xgh4[4] = {0,0,0,0}, y2h = 0.f;
    if (w < 4){
      const long rxg = (long)tt*256 + brow0 + crow;
      const ushort4 u = *(const ushort4*)(xgd + rxg*768 + (cgate ? 512 : 0) + j0);
      xgv[0]=bf2f(u.x); xgv[1]=bf2f(u.y); xgv[2]=bf2f(u.z); xgv[3]=bf2f(u.w);
      y2g = xnd[rxg*3 + (cgate ? 2 : 0)];
      if (w < 2){
        const long rxh = (long)tt*256 + brow0 + w;
        const ushort4 uh = *(const ushort4*)(xgd + rxh*768 + 256 + j0);
        xgh4[0]=bf2f(uh.x); xgh4[1]=bf2f(uh.y); xgh4[2]=bf2f(uh.z); xgh4[3]=bf2f(uh.w);
        y2h = xnd[rxh*3 + 1];
      }
    }

    float s00=0.f,s01=0.f,s02=0.f,s03=0.f, s10=0.f,s11=0.f,s12=0.f,s13=0.f;
#pragma unroll 1
    for (int c = 0; c < 4; c++){
      __syncthreads();
      if (c < 3) stage64k8((const char*)wrz_d + (size_t)(c+1)*65536,
                           wbuf + (cb^1)*16384, w, lane);
      const unsigned* wb = (const unsigned*)(wbuf + cb*16384);
      const int kpg = c*32;
#pragma unroll
      for (int kp8 = 0; kp8 < 8; kp8++){
        const int kpl = kq4*8 + kp8;
        const half2_t h0 = as_h2(hsp[kpg + kpl]);
        const half2_t h1 = as_h2(hsp[128 + kpg + kpl]);
        const uint4 wq = *(const uint4*)&wb[kpl*512 + fg*256 + j0];
        s00 = FDOT2(as_h2(wq.x), h0, s00);
        s01 = FDOT2(as_h2(wq.y), h0, s01);
        s02 = FDOT2(as_h2(wq.z), h0, s02);
        s03 = FDOT2(as_h2(wq.w), h0, s03);
        s10 = FDOT2(as_h2(wq.x), h1, s10);
        s11 = FDOT2(as_h2(wq.y), h1, s11);
        s12 = FDOT2(as_h2(wq.z), h1, s12);
        s13 = FDOT2(as_h2(wq.w), h1, s13);
      }
      cb ^= 1;
    }
    {
      float* p1 = part + kq4*1024 + fg*256 + j0;
      *(float4*)p1         = make_float4(s00,s01,s02,s03);
      *(float4*)(p1 + 512) = make_float4(s10,s11,s12,s13);
    }
    __syncthreads();
    stage64k8(wh_d, wbuf + (cb^1)*16384, w, lane);
    cb ^= 1;

    if (w < 4){
      const float* pa = part + crow*512 + cgate*256 + j0;
      const float4 a0 = *(const float4*)pa;
      const float4 a1 = *(const float4*)(pa + 1024);
      const float4 a2 = *(const float4*)(pa + 2048);
      const float4 a3 = *(const float4*)(pa + 3072);
      float a[4] = { (a0.x+a1.x)+(a2.x+a3.x), (a0.y+a1.y)+(a2.y+a3.y),
                     (a0.z+a1.z)+(a2.z+a3.z), (a0.w+a1.w)+(a2.w+a3.w) };
      const float hn2v = scal[crow*2 + 0];
      const float xn_h = snorm(hn2v), art_h = atanhf(clamp11(xn_h));
      const float p2 = wred(sq_part<4>(a));
      float sc, n2; mt_scale(p2, xn_h, art_h, &sc, &n2);
#pragma unroll
      for (int i = 0; i < 4; i++) a[i] *= sc;
      const float xy = wred(dot_part<4>(a, xgv));
      float m1[4]; madd_vec<4>(a, n2, xgv, y2g, xy, m1);
      float m1n2 = sq_part<4>(m1), xyb = dot_part<4>(m1, bg);
      wred2(m1n2, xyb);
      float m2[4]; madd_vec<4>(m1, m1n2, bg, bg2, xyb, m2);
      const float m2n2 = wred(sq_part<4>(m2));
      const float nn = snorm(m2n2), fgc = atanhf(clamp11(nn))/nn;
      float g4[4];
#pragma unroll
      for (int i = 0; i < 4; i++) g4[i] = 1.f/(1.f + expf(-fgc*m2[i]));
      if (cgate == 0){
        float h4[4];
        {
          const half2_t pa0 = as_h2(hsp[crow*128 + lane*2]);
          const half2_t pa1 = as_h2(hsp[crow*128 + lane*2 + 1]);
          h4[0] = (float)pa0[0]; h4[1] = (float)pa0[1];
          h4[2] = (float)pa1[0]; h4[3] = (float)pa1[1];
        }
        float rh[4]; float wx2 = 0.f;
#pragma unroll
        for (int i = 0; i < 4; i++){ rh[i] = g4[i]*h4[i]; wx2 += rh[i]*rh[i]; }
        wx2 = wred(wx2);
        float rhn2, scrh;
        {
          const float wxn = snorm(wx2);
          const float trh = tanhf(wxn/xn_h * art_h);
          scrh = trh/wxn; rhn2 = trh*trh;
          const float n = snorm(rhn2);
          if (n > PMAX_){ const float f = PMAX_/n; scrh *= f; rhn2 *= f*f; }
        }
#pragma unroll
        for (int i = 0; i < 4; i++) rh[i] *= scrh;
        rhp[crow*128 + lane*2]     = packh2(rh[0], rh[1]);
        rhp[crow*128 + lane*2 + 1] = packh2(rh[2], rh[3]);
        if (lane == 0) scal[crow*2 + 1] = rhn2;
      } else {
        *(float4*)&zb[crow*256 + j0] = make_float4(g4[0],g4[1],g4[2],g4[3]);
      }
    }

    float r00=0.f,r01=0.f,r02=0.f,r03=0.f, r10=0.f,r11=0.f,r12=0.f,r13=0.f;
#pragma unroll 1
    for (int c = 0; c < 2; c++){
      __syncthreads();
      if (c < 1) stage64k8((const char*)wh_d + 65536, wbuf + (cb^1)*16384, w, lane);
      const unsigned* wb = (const unsigned*)(wbuf + cb*16384);
      const int kpg = c*64;
#pragma unroll
      for (int kp8 = 0; kp8 < 8; kp8++){
        const int kpl = qk8*8 + kp8;
        const half2_t h0 = as_h2(rhp[kpg + kpl]);
        const half2_t h1 = as_h2(rhp[128 + kpg + kpl]);
        const uint4 wq = *(const uint4*)&wb[kpl*256 + j0];
        r00 = FDOT2(as_h2(wq.x), h0, r00);
        r01 = FDOT2(as_h2(wq.y), h0, r01);
        r02 = FDOT2(as_h2(wq.z), h0, r02);
        r03 = FDOT2(as_h2(wq.w), h0, r03);
        r10 = FDOT2(as_h2(wq.x), h1, r10);
        r11 = FDOT2(as_h2(wq.y), h1, r11);
        r12 = FDOT2(as_h2(wq.z), h1, r12);
        r13 = FDOT2(as_h2(wq.w), h1, r13);
      }
      cb ^= 1;
    }
    {
      float* p2 = part + qk8*512 + j0;
      *(float4*)p2         = make_float4(r00,r01,r02,r03);
      *(float4*)(p2 + 256) = make_float4(r10,r11,r12,r13);
    }
    __syncthreads();
    if (t < 127){
      stage64k8(wrz_d, wbuf + (cb^1)*16384, w, lane);
      cb ^= 1;
    }

    if (w < 2){
      float ah[4];
      {
        float4 p[8];
#pragma unroll
        for (int q = 0; q < 8; q++)
          p[q] = *(const float4*)(part + q*512 + w*256 + j0);
        ah[0] = ((p[0].x+p[1].x)+(p[2].x+p[3].x)) + ((p[4].x+p[5].x)+(p[6].x+p[7].x));
        ah[1] = ((p[0].y+p[1].y)+(p[2].y+p[3].y)) + ((p[4].y+p[5].y)+(p[6].y+p[7].y));
        ah[2] = ((p[0].z+p[1].z)+(p[2].z+p[3].z)) + ((p[4].z+p[5].z)+(p[6].z+p[7].z));
        ah[3] = ((p[0].w+p[1].w)+(p[2].w+p[3].w)) + ((p[4].w+p[5].w)+(p[6].w+p[7].w));
      }
      const float rhn2v = scal[w*2 + 1];
      const float rxn = snorm(rhn2v), artr = atanhf(clamp11(rxn));
      float mx2 = sq_part<4>(ah), xyraw = dot_part<4>(ah, xgh4);
      wred2(mx2, xyraw);
      float sch, pn2; mt_scale(mx2, rxn, artr, &sch, &pn2);
#pragma unroll
      for (int i = 0; i < 4; i++) ah[i] *= sch;
      const float xy = xyraw * sch;
      float m1[4]; madd_vec<4>(ah, pn2, xgh4, y2h, xy, m1);
      float m1n2 = sq_part<4>(m1), xyb = dot_part<4>(m1, bh4);
      wred2(m1n2, xyb);
      float ht[4]; madd_vec<4>(m1, m1n2, bh4, bh2, xyb, ht);
      float htn2 = sq_part<4>(ht);
      float nh[4];
#pragma unroll
      for (int i = 0; i < 4; i++) nh[i] = -h[i];
      float xyd = dot_part<4>(nh, ht);
      wred2(htn2, xyd);
      float dl[4]; madd_vec<4>(nh, hn2, ht, htn2, xyd, dl);
      float z4[4];
      *(float4*)z4 = *(const float4*)&zb[w*256 + j0];
      float pw[4]; float dln2 = 0.f, wz2 = 0.f, xyhr = 0.f;
#pragma unroll
      for (int i = 0; i < 4; i++){
        dln2 += dl[i]*dl[i];
        pw[i] = z4[i]*dl[i];
        wz2  += pw[i]*pw[i];
        xyhr += h[i]*pw[i];
      }
      wred3(dln2, wz2, xyhr);
      float pwn2, scpw;
      {
        const float dn   = snorm(dln2);
        const float artd = atanhf(clamp11(dn));
        const float wzn  = snorm(wz2);
        const float tpw  = tanhf(wzn/dn * artd);
        scpw = tpw/wzn; pwn2 = tpw*tpw;
        const float n = snorm(pwn2);
        if (n > PMAX_){ const float f = PMAX_/n; scpw *= f; pwn2 *= f*f; }
      }
#pragma unroll
      for (int i = 0; i < 4; i++) pw[i] *= scpw;
      const float xyh = xyhr * scpw;
      float hnew[4]; madd_vec<4>(h, hn2, pw, pwn2, xyh, hnew);
#pragma unroll
      for (int i = 0; i < 4; i++) h[i] = hnew[i];
      hn2 = wred(sq_part<4>(h));
      hsp[w*128 + lane*2]     = packh2(h[0], h[1]);
      hsp[w*128 + lane*2 + 1] = packh2(h[2], h[3]);
      if (lane == 0) scal[w*2 + 0] = hn2;
      unsigned short* srow = states + ((long)(brow0 + w)*128 + tt)*256 + j0;
      ushort4 su; su.x=f2bf(h[0]); su.y=f2bf(h[1]); su.z=f2bf(h[2]); su.w=f2bf(h[3]);
      *(ushort4*)srow = su;
    }
  }
}

// ---------------------------------------------------------------------------
// Char Mobius-RNN (unchanged)
// ---------------------------------------------------------------------------
__global__ __launch_bounds__(256) void char_rnn(
    const unsigned short* __restrict__ xgc,
    const float* __restrict__ Wc,
    const float* __restrict__ cb,
    float* __restrict__ cstates)
{
  const int wv = threadIdx.x >> 6, lane = threadIdx.x & 63;
  const int b = blockIdx.x*4 + wv;
  const int j0 = lane << 2;
  __shared__ __align__(16) float hs[4][256];
  float h[4] = {0.f,0.f,0.f,0.f};
  float hn2 = 0.f;
#pragma unroll
  for (int i = 0; i < 4; i++) hs[wv][j0+i] = 0.f;
  float cbv[4];
#pragma unroll
  for (int i = 0; i < 4; i++) cbv[i] = cb[j0+i];
  const float cb2 = wred(sq_part<4>(cbv));
  for (int t = 0; t < 16; t++){
    __syncthreads();
    const unsigned short* xr = xgc + ((long)t*256 + b)*256;
    float xgv[4];
    { const ushort4 u = *(const ushort4*)(xr + j0); xgv[0]=bf2f(u.x); xgv[1]=bf2f(u.y); xgv[2]=bf2f(u.z); xgv[3]=bf2f(u.w); }
    float a[4]={0.f,0.f,0.f,0.f};
#pragma unroll 2
    for (int k0 = 0; k0 < 256; k0 += 4){
      const float4 hk = *(const float4*)&hs[wv][k0];
#pragma unroll
      for (int kk = 0; kk < 4; kk++){
        const float hv = (&hk.x)[kk];
        const float4 w4 = *(const float4*)(Wc + (long)(k0+kk)*256 + j0);
        a[0] += hv*w4.x; a[1] += hv*w4.y; a[2] += hv*w4.z; a[3] += hv*w4.w;
      }
    }
    const float mxn2 = wred(sq_part<4>(a));
    float pn2; mt_project<4>(a, mxn2, hn2, &pn2);
    const float y2 = wred(sq_part<4>(xgv));
    const float xy = wred(dot_part<4>(a, xgv));
    float m1[4]; madd_vec<4>(a, pn2, xgv, y2, xy, m1);
    const float m1n2 = wred(sq_part<4>(m1));
    const float xyb  = wred(dot_part<4>(m1, cbv));
    float m2[4]; madd_vec<4>(m1, m1n2, cbv, cb2, xyb, m2);
    float m2n2 = wred(sq_part<4>(m2));
    project_vec<4>(m2, &m2n2);
#pragma unroll
    for (int i = 0; i < 4; i++) h[i] = m2[i];
    hn2 = m2n2;
    *(float4*)&hs[wv][j0] = make_float4(h[0],h[1],h[2],h[3]);
    *(float4*)(cstates + ((long)b*16 + t)*256 + j0) = make_float4(h[0],h[1],h[2],h[3]);
  }
}

// ---------------------------------------------------------------------------
// cc concat; mxa/mxb bf16, full-M (rowoff kept for compat, pass 0)
// ---------------------------------------------------------------------------
__global__ __launch_bounds__(256) void cc_rowwise(const unsigned short* __restrict__ sf,
    const unsigned short* __restrict__ sb, const unsigned short* __restrict__ mxa,
    const unsigned short* __restrict__ mxb, const float* __restrict__ ccb,
    unsigned short* __restrict__ ctxo, int rowoff)
{
  const int wv = threadIdx.x >> 6, lane = threadIdx.x & 63;
  const int rloc = blockIdx.x*4 + wv;
  const long r = rowoff + rloc;
  float s = 0.f;
#pragma unroll
  for (int i = 0; i < 4; i++){ const float v = bf2f(sf[r*256 + i*64+lane]); s += v*v; }
  const float sfn2 = wred(s);
  s = 0.f;
#pragma unroll
  for (int i = 0; i < 4; i++){ const float v = bf2f(sb[r*256 + i*64+lane]); s += v*v; }
  const float sbn2 = wred(s);
  float A[8], Bv[8];
#pragma unroll
  for (int i = 0; i < 8; i++){ A[i]  = bf2f(mxa[(long)rloc*512 + i*64+lane]);
                               Bv[i] = bf2f(mxb[(long)rloc*512 + i*64+lane]); }
  float pan2, pbn2;
  { const float n2 = wred(sq_part<8>(A));  mt_project<8>(A,  n2, sfn2, &pan2); }
  { const float n2 = wred(sq_part<8>(Bv)); mt_project<8>(Bv, n2, sbn2, &pbn2); }
  const float xy = wred(dot_part<8>(A, Bv));
  float M1[8]; madd_vec<8>(A, pan2, Bv, pbn2, xy, M1);
  const float m1n2 = wred(sq_part<8>(M1));
  float Cb[8];
#pragma unroll
  for (int i = 0; i < 8; i++) Cb[i] = ccb[i*64+lane];
  const float cb2 = wred(sq_part<8>(Cb));
  const float xyb = wred(dot_part<8>(M1, Cb));
  float M2[8]; madd_vec<8>(M1, m1n2, Cb, cb2, xyb, M2);
  float m2n2 = wred(sq_part<8>(M2));
  project_vec<8>(M2, &m2n2);
#pragma unroll
  for (int i = 0; i < 8; i++) ctxo[r*512 + i*64+lane] = f2bf(M2[i]);
}

// attn_emb = madd(ctx(bf16), pe) -> BF16 out + sqn of rounded
__global__ __launch_bounds__(256) void attn_add(const unsigned short* __restrict__ ctxv,
    const int* __restrict__ pos, const float* __restrict__ pet,
    unsigned short* __restrict__ oemb, float* __restrict__ osqn)
{
  const int wv = threadIdx.x >> 6, lane = threadIdx.x & 63;
  const long r = blockIdx.x*4 + wv;
  float X[8];
#pragma unroll
  for (int i = 0; i < 8; i++) X[i] = bf2f(ctxv[r*512 + i*64+lane]);
  const float x2 = wred(sq_part<8>(X));
  const int p = pos[r];
  float Y[8];
#pragma unroll
  for (int i = 0; i < 8; i++) Y[i] = pet[(long)p*512 + i*64+lane];
  const float y2 = wred(sq_part<8>(Y));
  const float xy = wred(dot_part<8>(X, Y));
  float O[8]; madd_vec<8>(X, x2, Y, y2, xy, O);
  float s = 0.f;
#pragma unroll
  for (int i = 0; i < 8; i++){
    const unsigned short u = f2bf(O[i]);
    oemb[r*512 + i*64+lane] = u;
    const float rv = bf2f(u);
    s += rv*rv;
  }
  s = wred(s);
  if (lane == 0) osqn[r] = s;
}

// mention variant (bf16 out)
__global__ __launch_bounds__(256) void attn_add_m(const float* __restrict__ mvv,
    const int* __restrict__ mentions, const float* __restrict__ pet,
    unsigned short* __restrict__ oemb, float* __restrict__ osqn)
{
  const int wv = threadIdx.x >> 6, lane = threadIdx.x & 63;
  const long r = blockIdx.x*4 + wv;
  float X[8];
#pragma unroll
  for (int i = 0; i < 8; i++) X[i] = mvv[r*512 + i*64+lane];
  const float x2 = wred(sq_part<8>(X));
  const int men = mentions[r];
  const int p = (men > 0) ? (int)(r & 7) + 1 : 0;
  float Y[8];
#pragma unroll
  for (int i = 0; i < 8; i++) Y[i] = pet[(long)p*512 + i*64+lane];
  const float y2 = wred(sq_part<8>(Y));
  const float xy = wred(dot_part<8>(X, Y));
  float O[8]; madd_vec<8>(X, x2, Y, y2, xy, O);
  float s = 0.f;
#pragma unroll
  for (int i = 0; i < 8; i++){
    const unsigned short u = f2bf(O[i]);
    oemb[r*512 + i*64+lane] = u;
    const float rv = bf2f(u);
    s += rv*rv;
  }
  s = wred(s);
  if (lane == 0) osqn[r] = s;
}

// q/k projection + pdist; mxq/mxk bf16, rs = row stride in elements.
__global__ __launch_bounds__(256) void qk_pdist(const unsigned short* __restrict__ mxq,
    const unsigned short* __restrict__ mxk, const float* __restrict__ sqn,
    const float* __restrict__ bq, const float* __restrict__ bk,
    float* __restrict__ dout, int rs)
{
  const int wv = threadIdx.x >> 6, lane = threadIdx.x & 63;
  const int r = blockIdx.x*4 + wv;
  const float xn2 = sqn[r];
  float Q[8];
#pragma unroll
  for (int i = 0; i < 8; i++) Q[i] = bf2f(mxq[(long)r*rs + i*64+lane]);
  { const float n2 = wred(sq_part<8>(Q)); float pn2; mt_project<8>(Q, n2, xn2, &pn2);
    float Bq[8];
#pragma unroll
    for (int i = 0; i < 8; i++) Bq[i] = bq[i*64+lane];
    const float b2 = wred(sq_part<8>(Bq));
    const float xy = wred(dot_part<8>(Q, Bq));
    float O[8]; madd_vec<8>(Q, pn2, Bq, b2, xy, O);
#pragma unroll
    for (int i = 0; i < 8; i++) Q[i] = O[i];
  }
  float qn2 = wred(sq_part<8>(Q));
  project_vec<8>(Q, &qn2);
  float Kv[8];
#pragma unroll
  for (int i = 0; i < 8; i++) Kv[i] = bf2f(mxk[(long)r*rs + i*64+lane]);
  { const float n2 = wred(sq_part<8>(Kv)); float pn2; mt_project<8>(Kv, n2, xn2, &pn2);
    float Bk[8];
#pragma unroll
    for (int i = 0; i < 8; i++) Bk[i] = bk[i*64+lane];
    const float b2 = wred(sq_part<8>(Bk));
    const float xy = wred(dot_part<8>(Kv, Bk));
    float O[8]; madd_vec<8>(Kv, pn2, Bk, b2, xy, O);
#pragma unroll
    for (int i = 0; i < 8; i++) Kv[i] = O[i];
  }
  float kn2 = wred(sq_part<8>(Kv));
  project_vec<8>(Kv, &kn2);
  float NQ[8];
#pragma unroll
  for (int i = 0; i < 8; i++) NQ[i] = -Q[i];
  const float xy = wred(dot_part<8>(NQ, Kv));
  float Z[8]; madd_vec<8>(NQ, qn2, Kv, kn2, xy, Z);
  const float zn2 = wred(sq_part<8>(Z));
  const float d = 2.f * atanhf(clamp11(snorm(zn2)));
  if (lane == 0) dout[r] = d;
}

__global__ __launch_bounds__(256) void softmax128(const float* __restrict__ d,
    const float* __restrict__ beta, float* __restrict__ w)
{
  const int wv = threadIdx.x >> 6, lane = threadIdx.x & 63;
  const int b = blockIdx.x*4 + wv;
  const float bt = beta[0];
  const float x0 = -bt * d[b*128 + lane];
  const float x1 = -bt * d[b*128 + 64 + lane];
  const float m = wredmax(fmaxf(x0, x1));
  const float e0 = expf(x0 - m), e1 = expf(x1 - m);
  const float s = wred(e0 + e1);
  w[b*128 + lane]      = e0 / s;
  w[b*128 + 64 + lane] = e1 / s;
}

__global__ void softmax8(const float* __restrict__ d, const float* __restrict__ beta,
                         float* __restrict__ w)
{
  const int b = threadIdx.x;   // 256
  const float bt = beta[0];
  float x[8]; float m = -1e30f;
#pragma unroll
  for (int i = 0; i < 8; i++){ x[i] = -bt * d[b*8+i]; m = fmaxf(m, x[i]); }
  float s = 0.f;
#pragma unroll
  for (int i = 0; i < 8; i++){ x[i] = expf(x[i]-m); s += x[i]; }
#pragma unroll
  for (int i = 0; i < 8; i++) w[b*8+i] = x[i] / s;
}

// weighted gyromidpoint via Klein model; one wave per batch row (small Lseq)
template<int NPL, bool BF16V, bool HASW>
__global__ __launch_bounds__(256) void midpoint_kernel(const void* __restrict__ vals,
    const float* __restrict__ wts, float* __restrict__ outp, int Lseq)
{
  const int wv = threadIdx.x >> 6, lane = threadIdx.x & 63;
  const int b = blockIdx.x*4 + wv;
  const int D = NPL*64;
  float num[NPL];
#pragma unroll
  for (int i = 0; i < NPL; i++) num[i] = 0.f;
  float den = 0.f;
  for (int l = 0; l < Lseq; l++){
    const long base = ((long)b*Lseq + l)*D;
    float v[NPL]; float s = 0.f;
#pragma unroll
    for (int i = 0; i < NPL; i++){
      v[i] = BF16V ? bf2f(((const unsigned short*)vals)[base + i*64+lane])
                   : ((const float*)vals)[base + i*64+lane];
      s += v[i]*v[i];
    }
    const float v2 = wred(s);
    const float f = 2.f/(1.f + v2);
    const float kl2 = v2*f*f;
    const float gamma = 1.f/sqrtf(fmaxf(1.f - kl2, EPS_));
    const float wgt = HASW ? wts[b*Lseq + l] : 1.f;
    const float wg = wgt*gamma;
#pragma unroll
    for (int i = 0; i < NPL; i++) num[i] += wg*(f*v[i]);
    den += wg;
  }
  den = fmaxf(den, EPS_);
  float x[NPL]; float s = 0.f;
#pragma unroll
  for (int i = 0; i < NPL; i++){ x[i] = num[i]/den; s += x[i]*x[i]; }
  const float k2 = wred(s);
  const float inv = 1.f/(1.f + sqrtf(fmaxf(1.f - k2, EPS_)));
#pragma unroll
  for (int i = 0; i < NPL; i++) outp[(long)b*D + i*64+lane] = x[i]*inv;
}

// wide gyromidpoint for ctx (unchanged)
__global__ __launch_bounds__(512) void midpoint_wide(
    const unsigned short* __restrict__ vals,
    const float* __restrict__ wts,
    float* __restrict__ outp)
{
  __shared__ float pnum[8][512];
  __shared__ float pden[8];
  __shared__ float red[512];
  __shared__ float kk2[1];
  const int b = blockIdx.x;
  const int tid = threadIdx.x;
  const int w = tid >> 6, lane = tid & 63;
  float num[8] = {0.f,0.f,0.f,0.f,0.f,0.f,0.f,0.f};
  float den = 0.f;
  for (int l = w; l < 128; l += 8){
    const long base = ((long)b*128 + l)*512;
    float v[8]; float s = 0.f;
#pragma unroll
    for (int i = 0; i < 8; i++){
      v[i] = bf2f(vals[base + i*64 + lane]);
      s += v[i]*v[i];
    }
    const float v2 = wred(s);
    const float f = 2.f/(1.f + v2);
    const float kl2 = v2*f*f;
    const float gamma = 1.f/sqrtf(fmaxf(1.f - kl2, EPS_));
    const float wg = wts[b*128 + l]*gamma;
#pragma unroll
    for (int i = 0; i < 8; i++) num[i] += wg*(f*v[i]);
    den += wg;
  }
#pragma unroll
  for (int i = 0; i < 8; i++) pnum[w][i*64 + lane] = num[i];
  if (lane == 0) pden[w] = den;
  __syncthreads();
  float nsum = 0.f, dsum = 0.f;
#pragma unroll
  for (int p = 0; p < 8; p++){ nsum += pnum[p][tid]; dsum += pden[p]; }
  dsum = fmaxf(dsum, EPS_);
  const float x = nsum/dsum;
  red[tid] = x*x;
  __syncthreads();
  if (tid < 64){
    float s2 = 0.f;
#pragma unroll
    for (int i = 0; i < 8; i++) s2 += red[tid + i*64];
    s2 = wred(s2);
    if (tid == 0) kk2[0] = s2;
  }
  __syncthreads();
  const float k2 = kk2[0];
  const float inv = 1.f/(1.f + sqrtf(fmaxf(1.f - k2, EPS_)));
  outp[(long)b*512 + tid] = x*inv;
}

// mention w2s mobius_linear with tanh nonlinearity; mx bf16.
__global__ __launch_bounds__(256) void mv_rowwise(const unsigned short* __restrict__ mx,
    const float* __restrict__ xsqn, const float* __restrict__ bb, float* __restrict__ outp)
{
  const int wv = threadIdx.x >> 6, lane = threadIdx.x & 63;
  const long r = blockIdx.x*4 + wv;
  float M[8];
#pragma unroll
  for (int i = 0; i < 8; i++) M[i] = bf2f(mx[r*512 + i*64+lane]);
  { const float n2 = wred(sq_part<8>(M)); float pn2; mt_project<8>(M, n2, xsqn[r], &pn2);
    float Bv[8];
#pragma unroll
    for (int i = 0; i < 8; i++) Bv[i] = bb[i*64+lane];
    const float b2 = wred(sq_part<8>(Bv));
    const float xy = wred(dot_part<8>(M, Bv));
    float O[8]; madd_vec<8>(M, pn2, Bv, b2, xy, O);
#pragma unroll
    for (int i = 0; i < 8; i++) M[i] = O[i];
  }
  float on2 = wred(sq_part<8>(M));
  project_vec<8>(M, &on2);
  { const float n = snorm(on2);
    const float fac = atanhf(clamp11(n))/n;
#pragma unroll
    for (int i = 0; i < 8; i++) M[i] = tanhf(fac*M[i]); }
  const float un2 = wred(sq_part<8>(M));
  { const float n = snorm(un2);
    const float fac = tanhf(n)/n;
    float en2 = fac*fac*un2;
#pragma unroll
    for (int i = 0; i < 8; i++) M[i] *= fac;
    project_vec<8>(M, &en2); }
#pragma unroll
  for (int i = 0; i < 8; i++) outp[r*512 + i*64+lane] = M[i];
}

// joint concat (unchanged)
__global__ __launch_bounds__(256) void final_rowwise(const float* __restrict__ jm,
    const float* __restrict__ jc, const float* __restrict__ jch,
    const float* __restrict__ mvec, const float* __restrict__ cvec,
    const float* __restrict__ chvec, const float* __restrict__ fcb,
    float* __restrict__ joint)
{
  const int wv = threadIdx.x >> 6, lane = threadIdx.x & 63;
  const long b = blockIdx.x*4 + wv;
  float s;
  s = 0.f; for (int i = 0; i < 8; i++){ const float v = mvec[b*512 + i*64+lane]; s += v*v; }
  const float mn2 = wred(s);
  s = 0.f; for (int i = 0; i < 8; i++){ const float v = cvec[b*512 + i*64+lane]; s += v*v; }
  const float cn2 = wred(s);
  s = 0.f; for (int i = 0; i < 4; i++){ const float v = chvec[b*256 + i*64+lane]; s += v*v; }
  const float chn2 = wred(s);
  float A[20];
#pragma unroll
  for (int i = 0; i < 20; i++) A[i] = jm[b*1280 + i*64+lane];
  float an2;
  { const float n2 = wred(sq_part<20>(A)); mt_project<20>(A, n2, mn2, &an2); }
  float T[20];
#pragma unroll
  for (int i = 0; i < 20; i++) T[i] = jc[b*1280 + i*64+lane];
  float tn2;
  { const float n2 = wred(sq_part<20>(T)); mt_project<20>(T, n2, cn2, &tn2); }
  { const float xy = wred(dot_part<20>(A, T));
    float O[20]; madd_vec<20>(A, an2, T, tn2, xy, O);
#pragma unroll
    for (int i = 0; i < 20; i++) A[i] = O[i];
    an2 = wred(sq_part<20>(A)); }
#pragma unroll
  for (int i = 0; i < 20; i++) T[i] = jch[b*1280 + i*64+lane];
  { const float n2 = wred(sq_part<20>(T)); mt_project<20>(T, n2, chn2, &tn2); }
  { const float xy = wred(dot_part<20>(A, T));
    float O[20]; madd_vec<20>(A, an2, T, tn2, xy, O);
#pragma unroll
    for (int i = 0; i < 20; i++) A[i] = O[i];
    an2 = wred(sq_part<20>(A)); }
#pragma unroll
  for (int i = 0; i < 20; i++) T[i] = fcb[i*64+lane];
  tn2 = wred(sq_part<20>(T));
  { const float xy = wred(dot_part<20>(A, T));
    float O[20]; madd_vec<20>(A, an2, T, tn2, xy, O);
#pragma unroll
    for (int i = 0; i < 20; i++) A[i] = O[i];
    an2 = wred(sq_part<20>(A)); }
  project_vec<20>(A, &an2);
#pragma unroll
  for (int i = 0; i < 20; i++) joint[b*1280 + i*64+lane] = A[i];
}

// hyperbolic MLR head (unchanged)
__global__ __launch_bounds__(256) void mlr_kernel(const float* __restrict__ joint,
    const float* __restrict__ P, const float* __restrict__ A, float* __restrict__ outp)
{
  const int wv = threadIdx.x >> 6, lane = threadIdx.x & 63;
  const int pair = blockIdx.x*4 + wv;
  const long b = pair >> 7, c = pair & 127;
  float Pv[20], J[20];
#pragma unroll
  for (int i = 0; i < 20; i++){
    Pv[i] = -P[c*1280 + i*64+lane];
    J[i]  = joint[b*1280 + i*64+lane];
  }
  const float p2 = wred(sq_part<20>(Pv));
  const float j2 = wred(sq_part<20>(J));
  const float xy = wred(dot_part<20>(Pv, J));
  float Z[20]; madd_vec<20>(Pv, p2, J, j2, xy, Z);
  float sza = 0.f, sz2 = 0.f, sa2 = 0.f;
#pragma unroll
  for (int i = 0; i < 20; i++){
    const float a = A[c*1280 + i*64+lane];
    sza += Z[i]*a; sz2 += Z[i]*Z[i]; sa2 += a*a;
  }
  float za = sza, z2 = sz2, a2 = sa2;
  wred3(za, z2, a2);
  const float an = sqrtf(fmaxf(a2, EPS_));
  const float v = 2.f*za / (fmaxf(1.f - z2, EPS_)*an);
  if (lane == 0) outp[pair] = 2.f*an*asinhf(v);
}

// ---------------------------------------------------------------------------
extern "C" void kernel_launch(void* const* d_in, const int* in_sizes, int n_in,
                              void* d_out, int out_size, void* d_ws, size_t ws_size,
                              hipStream_t stream)
{
  (void)in_sizes; (void)n_in; (void)out_size;
  const int*   context   = (const int*)  d_in[0];
  const int*   ctx_position=(const int*) d_in[1];
  const int*   mentions  = (const int*)  d_in[2];
  const int*   mchars    = (const int*)  d_in[3];
  const float* word_lut  = (const float*)d_in[4];
  const float* char_lut  = (const float*)d_in[5];
  const float* gf_Wih    = (const float*)d_in[6];
  const float* gf_Whh    = (const float*)d_in[7];
  const float* gf_b      = (const float*)d_in[8];
  const float* gb_Wih    = (const float*)d_in[9];
  const float* gb_Whh    = (const float*)d_in[10];
  const float* gb_b      = (const float*)d_in[11];
  const float* w2s_W     = (const float*)d_in[12];
  const float* w2s_b     = (const float*)d_in[13];
  const float* men_pos   = (const float*)d_in[14];
  const float* men_Wq    = (const float*)d_in[15];
  const float* men_bq    = (const float*)d_in[16];
  const float* men_Wk    = (const float*)d_in[17];
  const float* men_bk    = (const float*)d_in[18];
  const float* men_beta  = (const float*)d_in[19];
  const float* char_W    = (const float*)d_in[20];
  const float* char_U    = (const float*)d_in[21];
  const float* char_b    = (const float*)d_in[22];
  const float* cc_Wa     = (const float*)d_in[23];
  const float* cc_Wb     = (const float*)d_in[24];
  const float* cc_bias   = (const float*)d_in[25];
  const float* ctx_pos_t = (const float*)d_in[26];
  const float* ctx_Wq    = (const float*)d_in[27];
  const float* ctx_bq    = (const float*)d_in[28];
  const float* ctx_Wk    = (const float*)d_in[29];
  const float* ctx_bk    = (const float*)d_in[30];
  const float* ctx_beta  = (const float*)d_in[31];
  const float* fc_Wm     = (const float*)d_in[32];
  const float* fc_Wc     = (const float*)d_in[33];
  const float* fc_Wch    = (const float*)d_in[34];
  const float* fc_bias   = (const float*)d_in[35];
  const float* mlr_p     = (const float*)d_in[36];
  const float* mlr_a     = (const float*)d_in[37];
  float* out = (float*)d_out;

  // ---- workspace bump allocator ----
  char* wsb = (char*)d_ws;
  size_t off = 0;
  auto alloc = [&](size_t bytes) -> void* {
    void* p = wsb + off;
    off += (bytes + 255) & ~(size_t)255;
    return p;
  };
  float* WtHH = (float*)alloc(2UL*256*768*4);
  unsigned* Wrz2 = (unsigned*)alloc(2UL*128*512*4);
  unsigned* Wh2  = (unsigned*)alloc(2UL*128*256*4);
  unsigned short* WihP   = (unsigned short*)alloc(2UL*768*320*2);
  unsigned short* ctxWqkP= (unsigned short*)alloc(1024UL*512*2);
  unsigned short* ccWaP  = (unsigned short*)alloc(512UL*256*2);
  unsigned short* ccWbP  = (unsigned short*)alloc(512UL*256*2);
  unsigned short* menWqkP= (unsigned short*)alloc(1024UL*512*2);
  unsigned short* w2sP   = (unsigned short*)alloc(512UL*320*2);
  unsigned short* charUP = (unsigned short*)alloc(256UL*256*2);
  int*   ctxidx = (int*)alloc(32768UL*4);
  int*   chidx  = (int*)alloc(4096UL*4);
  float* xsqn   = (float*)alloc(32768UL*4);
  float* msqn   = (float*)alloc(2048UL*4);
  float* chsqn  = (float*)alloc(4096UL*4);
  unsigned short* xg = (unsigned short*)alloc(2UL*32768*768*2);
  float* xgn2 = (float*)alloc(2UL*32768*3*4);
  float* chn2d = (float*)alloc(4096UL*4);
  unsigned short* states_f = (unsigned short*)alloc(32768UL*256*2);
  unsigned short* states_b = (unsigned short*)alloc(32768UL*256*2);
  unsigned short* ctxv = (unsigned short*)alloc(32768UL*512*2);
  float* attn_sqn = (float*)alloc(32768UL*4);
  float* dctx = (float*)alloc(32768UL*4);
  float* wctx = (float*)alloc(32768UL*4);
  float* ctx_vec = (float*)alloc(256UL*512*4);
  float* mxbuf = (float*)alloc(2UL*8192*512*4);   // 33.5MB scratch
  float* mv = (float*)alloc(2048UL*512*4);
  unsigned short* attn_embm = (unsigned short*)alloc(2048UL*512*2);
  float* amsqn = (float*)alloc(2048UL*4);
  float* dm = (float*)alloc(2048UL*4);
  float* wm = (float*)alloc(2048UL*4);
  float* mention_vec = (float*)alloc(256UL*512*4);
  unsigned short* xgc = (unsigned short*)alloc(4096UL*256*2);
  float* char_states = (float*)alloc(4096UL*256*4);
  float* char_vec = (float*)alloc(256UL*256*4);
  float* joint = (float*)alloc(256UL*1280*4);
  if (off > ws_size) return;
  // overlays on xg (dead after GRU): ccA | ccB | attn_embc = exactly xg size
  unsigned short* ccA = xg;                        // 16,777,216 u16
  unsigned short* ccB = xg + 16777216UL;
  unsigned short* attn_embc = xg + 33554432UL;     // 16,777,216 u16
  unsigned short* mx16 = (unsigned short*)mxbuf;   // 16.8M u16 capacity
  float* mxh0 = mxbuf;                             // f32 view (fc path)

  // ---- weight transposes + packs ----
  transpose_k<<<dim3(8,24), 256,0,stream>>>(gf_Whh, WtHH,            768, 256);
  transpose_k<<<dim3(8,24), 256,0,stream>>>(gb_Whh, WtHH + 256*768,  768, 256);
  pack_whh_f16<<<768,256,0,stream>>>(WtHH, Wrz2, Wh2);
  pack_wih<<<1920,256,0,stream>>>(gf_Wih, gb_Wih, WihP);
  packT16<<<dim3(16,16),256,0,stream>>>(ctx_Wq, ctxWqkP,              512, 512, 512);
  packT16<<<dim3(16,16),256,0,stream>>>(ctx_Wk, ctxWqkP + 512UL*512,  512, 512, 512);
  packT16<<<dim3(8,16), 256,0,stream>>>(cc_Wa,  ccWaP,  256, 512, 256);
  packT16<<<dim3(8,16), 256,0,stream>>>(cc_Wb,  ccWbP,  256, 512, 256);
  packT16<<<dim3(16,16),256,0,stream>>>(men_Wq, menWqkP,             512, 512, 512);
  packT16<<<dim3(16,16),256,0,stream>>>(men_Wk, menWqkP + 512UL*512, 512, 512, 512);
  packT16<<<dim3(10,16),256,0,stream>>>(w2s_W,  w2sP,   300, 512, 320);
  packT16<<<dim3(8,8),  256,0,stream>>>(char_U, charUP, 256, 256, 256);

  // ---- gather indices + input sqn ----
  build_idx<<<144,256,0,stream>>>(context, mchars, ctxidx, chidx);
  sqn_gather<<<8192,256,0,stream>>>(word_lut, ctxidx, 300, xsqn);
  sqn_gather<<<512, 256,0,stream>>>(word_lut, mentions, 300, msqn);
  sqn_gather<<<1024,256,0,stream>>>(char_lut, chidx, 256, chsqn);

  // ---- GRU input precompute: full-M GEMM into xg, in-place transform ----
  for (int d2 = 0; d2 < 2; d2++){
    unsigned short* xgd = xg + (size_t)d2*32768*768;
    mfma_mm<1,1><<<dim3(6,512),256,0,stream>>>(word_lut, ctxidx,
        WihP + (size_t)d2*768*320, xgd, 32768, 768, 300, 320);
    xg_transform<<<24576,256,0,stream>>>(xgd, xsqn, xgd,
        xgn2 + (size_t)d2*32768*3, 3);
  }

  // ---- bidirectional Mobius GRU (v9 f16-dot2) ----
  (void)hipFuncSetAttribute((const void*)gru_kernel,
      hipFuncAttributeMaxDynamicSharedMemorySize, GRU_LDS_BYTES);
  gru_kernel<<<256,512,GRU_LDS_BYTES,stream>>>(xg, xgn2, Wrz2, Wh2,
                                               gf_b, gb_b, states_f, states_b);

  // ---- mobius concat of directions -> ctx (full-M, xg overlay) ----
  mfma_mm<2,1><<<dim3(4,512),256,0,stream>>>(states_f, nullptr, ccWaP, ccA,
                                             32768, 512, 256, 256);
  mfma_mm<2,1><<<dim3(4,512),256,0,stream>>>(states_b, nullptr, ccWbP, ccB,
                                             32768, 512, 256, 256);
  cc_rowwise<<<8192,256,0,stream>>>(states_f, states_b, ccA, ccB, cc_bias, ctxv, 0);

  // ---- context distance attention (fused Q|K, 2 half-M chunks) ----
  attn_add<<<8192,256,0,stream>>>(ctxv, ctx_position, ctx_pos_t, attn_embc, attn_sqn);
  for (int c = 0; c < 2; c++){
    mfma_mm<2,1><<<dim3(8,256),256,0,stream>>>(attn_embc + (size_t)c*16384*512, nullptr,
                                               ctxWqkP, mx16, 16384, 1024, 512, 512);
    qk_pdist<<<4096,256,0,stream>>>(mx16, mx16 + 512, attn_sqn + c*16384,
                                    ctx_bq, ctx_bk, dctx + c*16384, 1024);
  }
  softmax128<<<64,256,0,stream>>>(dctx, ctx_beta, wctx);
  midpoint_wide<<<256,512,0,stream>>>(ctxv, wctx, ctx_vec);

  // ---- mention encoder (fused Q|K GEMM, bf16 out) ----
  mfma_mm<1,1><<<dim3(4,32),256,0,stream>>>(word_lut, mentions, w2sP, mx16,
                                            2048, 512, 300, 320);
  mv_rowwise<<<512,256,0,stream>>>(mx16, msqn, w2s_b, mv);
  attn_add_m<<<512,256,0,stream>>>(mv, mentions, men_pos, attn_embm, amsqn);
  mfma_mm<2,1><<<dim3(8,32),256,0,stream>>>(attn_embm, nullptr, menWqkP, mx16,
                                            2048, 1024, 512, 512);
  qk_pdist<<<512,256,0,stream>>>(mx16, mx16 + 512, amsqn, men_bq, men_bk, dm, 1024);
  softmax8<<<1,256,0,stream>>>(dm, men_beta, wm);
  midpoint_kernel<8,false,true><<<64,256,0,stream>>>(mv, wm, mention_vec, 8);

  // ---- char encoder (bf16 GEMM out) ----
  mfma_mm<1,1><<<dim3(2,64),256,0,stream>>>(char_lut, chidx, charUP, mx16,
                                            4096, 256, 256, 256);
  xg_transform<<<1024,256,0,stream>>>(mx16, chsqn, xgc, chn2d, 1);
  char_rnn<<<64,256,0,stream>>>(xgc, char_W, char_b, char_states);
  midpoint_kernel<4,false,false><<<64,256,0,stream>>>(char_states, nullptr, char_vec, 16);

  // ---- full mobius concat + MLR (small, f32 path) ----
  float* jm = mxh0;
  float* jc = mxh0 + 256UL*1280;
  float* jch = mxh0 + 2UL*256*1280;
  mm_kernel<0><<<dim3(10,2),256,0,stream>>>(mention_vec, nullptr, fc_Wm, jm, 256, 1280, 512);
  mm_kernel<0><<<dim3(10,2),256,0,stream>>>(ctx_vec,     nullptr, fc_Wc, jc, 256, 1280, 512);
  mm_kernel<0><<<dim3(10,2),256,0,stream>>>(char_vec,    nullptr, fc_Wch, jch, 256, 1280, 256);
  final_rowwise<<<64,256,0,stream>>>(jm, jc, jch, mention_vec, ctx_vec, char_vec,
                                     fc_bias, joint);
  mlr_kernel<<<8192,256,0,stream>>>(joint, mlr_p, mlr_a, out);
}